// Round 1
// baseline (16998.123 us; speedup 1.0000x reference)
//
#include <hip/hip_runtime.h>
#include <hip/hip_bf16.h>

#define DI 1536
#define DS 16
#define DC 4
#define DTR 48
#define NB 2
#define SL 1024
#define DM 768
#define NLAYER 12
#define VOCAB 50257
#define ROWS (NB*SL)   // 2048

// ---------------------------------------------------------------------------
// Embedding: x[b,s,:] = emb[ids[b,s]] * sqrt(768)
// ---------------------------------------------------------------------------
__global__ __launch_bounds__(256) void embed_k(const int* __restrict__ ids,
                                               const float* __restrict__ emb,
                                               float* __restrict__ x) {
    int i = blockIdx.x * 256 + threadIdx.x;      // over ROWS*DM
    if (i >= ROWS * DM) return;
    int row = i / DM;
    int c = i - row * DM;
    x[i] = emb[(size_t)ids[row] * DM + c] * 27.712812921102035f;
}

// ---------------------------------------------------------------------------
// Main fp32 GEMM: C(M,N) = A(M,K) @ W(N,K)^T   (+ optional bias/softplus)
// 128x128 tile, BK=16, 256 threads, 8x8 per thread.
// M must be a multiple of 128 (always 2048 here); K multiple of 16; N guarded.
// EPI: 0 = plain store, 1 = softplus(acc + bias[n])
// ---------------------------------------------------------------------------
template<int EPI>
__global__ __launch_bounds__(256) void gemm_tn(
    const float* __restrict__ A, int lda,
    const float* __restrict__ W, int ldw,
    float* __restrict__ C, int ldc,
    int M, int N, int K,
    const float* __restrict__ bias)
{
    __shared__ __align__(16) float As[16][132];
    __shared__ __align__(16) float Ws[16][132];
    int tid = threadIdx.x;
    int tx = tid & 15, ty = tid >> 4;
    int row0 = blockIdx.y * 128;
    int col0 = blockIdx.x * 128;
    float acc[8][8] = {};

    for (int k0 = 0; k0 < K; k0 += 16) {
        #pragma unroll
        for (int l = 0; l < 2; ++l) {
            int f4 = tid * 2 + l;          // 0..511
            int r = f4 >> 2;               // 0..127
            int kc = (f4 & 3) * 4;         // 0,4,8,12
            const float4 av = *reinterpret_cast<const float4*>(
                &A[(size_t)(row0 + r) * lda + k0 + kc]);
            As[kc + 0][r] = av.x; As[kc + 1][r] = av.y;
            As[kc + 2][r] = av.z; As[kc + 3][r] = av.w;
        }
        #pragma unroll
        for (int l = 0; l < 2; ++l) {
            int f4 = tid * 2 + l;
            int n = f4 >> 2;
            int kc = (f4 & 3) * 4;
            float4 wv = make_float4(0.f, 0.f, 0.f, 0.f);
            if (col0 + n < N)
                wv = *reinterpret_cast<const float4*>(
                    &W[(size_t)(col0 + n) * ldw + k0 + kc]);
            Ws[kc + 0][n] = wv.x; Ws[kc + 1][n] = wv.y;
            Ws[kc + 2][n] = wv.z; Ws[kc + 3][n] = wv.w;
        }
        __syncthreads();
        #pragma unroll
        for (int kk = 0; kk < 16; ++kk) {
            float a[8], w[8];
            const float4* ap = reinterpret_cast<const float4*>(&As[kk][ty * 8]);
            const float4* wp = reinterpret_cast<const float4*>(&Ws[kk][tx * 8]);
            float4 a0 = ap[0], a1 = ap[1];
            float4 w0 = wp[0], w1 = wp[1];
            a[0]=a0.x; a[1]=a0.y; a[2]=a0.z; a[3]=a0.w;
            a[4]=a1.x; a[5]=a1.y; a[6]=a1.z; a[7]=a1.w;
            w[0]=w0.x; w[1]=w0.y; w[2]=w0.z; w[3]=w0.w;
            w[4]=w1.x; w[5]=w1.y; w[6]=w1.z; w[7]=w1.w;
            #pragma unroll
            for (int i = 0; i < 8; ++i)
                #pragma unroll
                for (int j = 0; j < 8; ++j)
                    acc[i][j] += a[i] * w[j];
        }
        __syncthreads();
    }

    #pragma unroll
    for (int i = 0; i < 8; ++i) {
        int r = row0 + ty * 8 + i;
        #pragma unroll
        for (int j = 0; j < 8; ++j) {
            int c = col0 + tx * 8 + j;
            if (c < N) {
                float v = acc[i][j];
                if (EPI == 1) {
                    v += bias[c];
                    v = (v > 20.f) ? v : log1pf(__expf(v));
                }
                C[(size_t)r * ldc + c] = v;
            }
        }
    }
}

// ---------------------------------------------------------------------------
// Skinny split-K GEMM for x_proj (N=80). Block: 64 rows x 80 cols, K chunked.
// Accumulates with atomicAdd into a zeroed C.
// ---------------------------------------------------------------------------
__global__ __launch_bounds__(256) void gemm_skinny(
    const float* __restrict__ A, int lda,
    const float* __restrict__ W, int ldw,
    float* __restrict__ C, int ldc,
    int N, int K, int kchunks)
{
    __shared__ __align__(16) float As[16][68];
    __shared__ __align__(16) float Ws[16][84];
    int row0 = blockIdx.x * 64;
    int klen = K / kchunks;
    int kbeg = blockIdx.y * klen;
    int tid = threadIdx.x;
    int tx = tid & 15, ty = tid >> 4;   // tx: 5 cols each, ty: 4 rows each
    float acc[4][5] = {};

    for (int k0 = kbeg; k0 < kbeg + klen; k0 += 16) {
        {
            int f4 = tid;                  // 64 rows x 16k = 256 float4
            int r = f4 >> 2; int kc = (f4 & 3) * 4;
            const float4 av = *reinterpret_cast<const float4*>(
                &A[(size_t)(row0 + r) * lda + k0 + kc]);
            As[kc + 0][r] = av.x; As[kc + 1][r] = av.y;
            As[kc + 2][r] = av.z; As[kc + 3][r] = av.w;
        }
        #pragma unroll
        for (int l = 0; l < 2; ++l) {
            int f4 = tid + l * 256;        // 80 rows x 16k = 320 float4
            if (f4 < 320) {
                int n = f4 >> 2; int kc = (f4 & 3) * 4;
                float4 wv = make_float4(0.f, 0.f, 0.f, 0.f);
                if (n < N)
                    wv = *reinterpret_cast<const float4*>(
                        &W[(size_t)n * ldw + k0 + kc]);
                Ws[kc + 0][n] = wv.x; Ws[kc + 1][n] = wv.y;
                Ws[kc + 2][n] = wv.z; Ws[kc + 3][n] = wv.w;
            }
        }
        __syncthreads();
        #pragma unroll
        for (int kk = 0; kk < 16; ++kk) {
            float a[4], w[5];
            const float4* ap = reinterpret_cast<const float4*>(&As[kk][ty * 4]);
            float4 a0 = ap[0];
            a[0]=a0.x; a[1]=a0.y; a[2]=a0.z; a[3]=a0.w;
            #pragma unroll
            for (int j = 0; j < 5; ++j) w[j] = Ws[kk][tx * 5 + j];
            #pragma unroll
            for (int i = 0; i < 4; ++i)
                #pragma unroll
                for (int j = 0; j < 5; ++j)
                    acc[i][j] += a[i] * w[j];
        }
        __syncthreads();
    }
    #pragma unroll
    for (int i = 0; i < 4; ++i) {
        int r = row0 + ty * 4 + i;
        #pragma unroll
        for (int j = 0; j < 5; ++j) {
            int c = tx * 5 + j;
            if (c < N)
                atomicAdd(&C[(size_t)r * ldc + c], acc[i][j]);
        }
    }
}

// ---------------------------------------------------------------------------
// Depthwise causal conv(4) + bias + silu
// ---------------------------------------------------------------------------
__global__ __launch_bounds__(256) void conv_silu_k(
    const float* __restrict__ xz, const float* __restrict__ cw,
    const float* __restrict__ cb, float* __restrict__ xin)
{
    int i = blockIdx.x * 256 + threadIdx.x;   // over ROWS*DI
    if (i >= ROWS * DI) return;
    int row = i / DI;
    int c = i - row * DI;
    int t = row & (SL - 1);
    int b = row >> 10;
    float acc = cb[c];
    const float* base = xz + (size_t)(b * SL) * (2 * DI) + c;
    #pragma unroll
    for (int k = 0; k < DC; ++k) {
        int tt = t + k - (DC - 1);
        if (tt >= 0) acc += base[(size_t)tt * (2 * DI)] * cw[c * DC + k];
    }
    xin[i] = acc / (1.f + __expf(-acc));
}

// ---------------------------------------------------------------------------
// Selective scan. Block: 256 threads = 16 d-channels x 16 states; grid B*(DI/16).
// Fused epilogue: y = (scan_y + xin*Dp) * silu(z)
// ---------------------------------------------------------------------------
__global__ __launch_bounds__(256) void scan_k(
    const float* __restrict__ dt,   // (ROWS, DI)
    const float* __restrict__ dbl,  // (ROWS, 80): [48:64]=B, [64:80]=C
    const float* __restrict__ xin,  // (ROWS, DI)
    const float* __restrict__ xz,   // (ROWS, 2*DI), z = cols [DI:2*DI)
    const float* __restrict__ Alog, // (DI, DS)
    const float* __restrict__ Dp,   // (DI)
    float* __restrict__ y)          // (ROWS, DI)
{
    int b = blockIdx.x / (DI / 16);
    int dblk = blockIdx.x % (DI / 16);
    int s = threadIdx.x & 15;
    int d = dblk * 16 + (threadIdx.x >> 4);
    float A = -__expf(Alog[d * DS + s]);
    float Dv = Dp[d];
    float h = 0.f;
    const int rowbase = b * SL;
    #pragma unroll 2
    for (int t = 0; t < SL; ++t) {
        int r = rowbase + t;
        float dtv = dt[(size_t)r * DI + d];
        float xv  = xin[(size_t)r * DI + d];
        float Bv  = dbl[(size_t)r * 80 + 48 + s];
        float Cv  = dbl[(size_t)r * 80 + 64 + s];
        float e = __expf(dtv * A);
        h = h * e + dtv * xv * Bv;
        float p = h * Cv;
        p += __shfl_xor(p, 1, 64);
        p += __shfl_xor(p, 2, 64);
        p += __shfl_xor(p, 4, 64);
        p += __shfl_xor(p, 8, 64);
        if (s == 0) {
            float z = xz[(size_t)r * (2 * DI) + DI + d];
            float yv = (p + xv * Dv) * (z / (1.f + __expf(-z)));
            y[(size_t)r * DI + d] = yv;
        }
    }
}

// ---------------------------------------------------------------------------
// LayerNorm over rows of 768
// ---------------------------------------------------------------------------
__global__ __launch_bounds__(256) void ln_k(
    const float* __restrict__ x, const float* __restrict__ w,
    const float* __restrict__ b, float* __restrict__ o)
{
    int row = blockIdx.x;
    int tid = threadIdx.x;
    const float* xr = x + (size_t)row * DM;
    float v0 = xr[tid], v1 = xr[tid + 256], v2 = xr[tid + 512];
    float s = v0 + v1 + v2;
    #pragma unroll
    for (int off = 1; off < 64; off <<= 1) s += __shfl_xor(s, off, 64);
    __shared__ float red[4];
    __shared__ float red2[4];
    int wid = tid >> 6, lane = tid & 63;
    if (lane == 0) red[wid] = s;
    __syncthreads();
    float mu = (red[0] + red[1] + red[2] + red[3]) * (1.f / 768.f);
    float d0 = v0 - mu, d1 = v1 - mu, d2 = v2 - mu;
    float q = d0 * d0 + d1 * d1 + d2 * d2;
    #pragma unroll
    for (int off = 1; off < 64; off <<= 1) q += __shfl_xor(q, off, 64);
    if (lane == 0) red2[wid] = q;
    __syncthreads();
    float var = (red2[0] + red2[1] + red2[2] + red2[3]) * (1.f / 768.f);
    float rs = rsqrtf(var + 1e-5f);
    o[(size_t)row * DM + tid]       = d0 * rs * w[tid]       + b[tid];
    o[(size_t)row * DM + tid + 256] = d1 * rs * w[tid + 256] + b[tid + 256];
    o[(size_t)row * DM + tid + 512] = d2 * rs * w[tid + 512] + b[tid + 512];
}

// ---------------------------------------------------------------------------
extern "C" void kernel_launch(void* const* d_in, const int* in_sizes, int n_in,
                              void* d_out, int out_size, void* d_ws, size_t ws_size,
                              hipStream_t stream) {
    const int*   ids        = (const int*)d_in[0];
    const float* emb        = (const float*)d_in[1];
    const float* in_proj_w  = (const float*)d_in[2];
    const float* conv_w     = (const float*)d_in[3];
    const float* conv_b     = (const float*)d_in[4];
    const float* x_proj_w   = (const float*)d_in[5];
    const float* dt_proj_w  = (const float*)d_in[6];
    const float* dt_proj_b  = (const float*)d_in[7];
    const float* A_log      = (const float*)d_in[8];
    const float* D_param    = (const float*)d_in[9];
    const float* out_proj_w = (const float*)d_in[10];
    const float* norm_w     = (const float*)d_in[11];
    const float* norm_b     = (const float*)d_in[12];
    float* out = (float*)d_out;

    float* ws  = (float*)d_ws;
    float* x   = ws;                                // 2048*768
    float* xz  = x   + (size_t)ROWS * DM;           // 2048*3072
    float* xin = xz  + (size_t)ROWS * 2 * DI;       // 2048*1536
    float* dbl = xin + (size_t)ROWS * DI;           // 2048*80
    float* dt  = dbl + (size_t)ROWS * 80;           // 2048*1536
    float* y   = dt  + (size_t)ROWS * DI;           // 2048*1536
    float* xln = xz;                                // reuse xz after layers

    embed_k<<<6144, 256, 0, stream>>>(ids, emb, x);

    for (int i = 0; i < NLAYER; ++i) {
        const float* inw = in_proj_w  + (size_t)i * 2 * DI * DM;
        const float* cw  = conv_w     + (size_t)i * DI * DC;
        const float* cb  = conv_b     + (size_t)i * DI;
        const float* xpw = x_proj_w   + (size_t)i * (DTR + 2 * DS) * DI;
        const float* dtw = dt_proj_w  + (size_t)i * DI * DTR;
        const float* dtb = dt_proj_b  + (size_t)i * DI;
        const float* Al  = A_log      + (size_t)i * DI * DS;
        const float* Dpar= D_param    + (size_t)i * DI;
        const float* ow  = out_proj_w + (size_t)i * DM * DI;

        // in_proj: xz = x @ inw^T   (2048 x 3072, K=768)
        gemm_tn<0><<<dim3(24, 16), 256, 0, stream>>>(
            x, DM, inw, DM, xz, 2 * DI, ROWS, 2 * DI, DM, nullptr);
        // conv + silu
        conv_silu_k<<<(ROWS * DI) / 256, 256, 0, stream>>>(xz, cw, cb, xin);
        // x_proj: dbl = xin @ xpw^T  (2048 x 80, K=1536), split-K + atomics
        hipMemsetAsync(dbl, 0, (size_t)ROWS * 80 * sizeof(float), stream);
        gemm_skinny<<<dim3(32, 8), 256, 0, stream>>>(
            xin, DI, xpw, DI, dbl, 80, 80, DI, 8);
        // dt_proj + softplus: dt = softplus(dbl[:, :48] @ dtw^T + dtb)
        gemm_tn<1><<<dim3(12, 16), 256, 0, stream>>>(
            dbl, 80, dtw, DTR, dt, DI, ROWS, DI, DTR, dtb);
        // selective scan + gating epilogue
        scan_k<<<NB * (DI / 16), 256, 0, stream>>>(
            dt, dbl, xin, xz, Al, Dpar, y);
        // out_proj: x = y @ ow^T   (2048 x 768, K=1536)
        gemm_tn<0><<<dim3(6, 16), 256, 0, stream>>>(
            y, DI, ow, DI, x, DM, ROWS, DM, DI, nullptr);
    }

    ln_k<<<ROWS, 256, 0, stream>>>(x, norm_w, norm_b, xln);
    // logits: out = xln @ emb^T   (2048 x 50257, K=768)
    gemm_tn<0><<<dim3(393, 16), 256, 0, stream>>>(
        xln, DM, emb, DM, out, VOCAB, ROWS, VOCAB, DM, nullptr);
}

// Round 2
// 9678.939 us; speedup vs baseline: 1.7562x; 1.7562x over previous
//
#include <hip/hip_runtime.h>
#include <hip/hip_bf16.h>

#define DI 1536
#define DS 16
#define DC 4
#define DTR 48
#define NB 2
#define SL 1024
#define DM 768
#define NLAYER 12
#define VOCAB 50257
#define ROWS (NB*SL)   // 2048
#define CCH 8          // scan chunks
#define CLEN (SL/CCH)  // 128

// ---------------------------------------------------------------------------
// Embedding: x[b,s,:] = emb[ids[b,s]] * sqrt(768)
// ---------------------------------------------------------------------------
__global__ __launch_bounds__(256) void embed_k(const int* __restrict__ ids,
                                               const float* __restrict__ emb,
                                               float* __restrict__ x) {
    int i = blockIdx.x * 256 + threadIdx.x;      // over ROWS*DM
    if (i >= ROWS * DM) return;
    int row = i / DM;
    int c = i - row * DM;
    x[i] = emb[(size_t)ids[row] * DM + c] * 27.712812921102035f;
}

// ---------------------------------------------------------------------------
// Main fp32 GEMM: C(M,N) = A(M,K) @ W(N,K)^T   (+ optional bias/softplus)
// 128x128 tile, BK=16, 256 threads, 8x8 per thread.
// ---------------------------------------------------------------------------
template<int EPI>
__global__ __launch_bounds__(256) void gemm_tn(
    const float* __restrict__ A, int lda,
    const float* __restrict__ W, int ldw,
    float* __restrict__ C, int ldc,
    int M, int N, int K,
    const float* __restrict__ bias)
{
    __shared__ __align__(16) float As[16][132];
    __shared__ __align__(16) float Ws[16][132];
    int tid = threadIdx.x;
    int tx = tid & 15, ty = tid >> 4;
    int row0 = blockIdx.y * 128;
    int col0 = blockIdx.x * 128;
    float acc[8][8] = {};

    for (int k0 = 0; k0 < K; k0 += 16) {
        #pragma unroll
        for (int l = 0; l < 2; ++l) {
            int f4 = tid * 2 + l;          // 0..511
            int r = f4 >> 2;               // 0..127
            int kc = (f4 & 3) * 4;         // 0,4,8,12
            const float4 av = *reinterpret_cast<const float4*>(
                &A[(size_t)(row0 + r) * lda + k0 + kc]);
            As[kc + 0][r] = av.x; As[kc + 1][r] = av.y;
            As[kc + 2][r] = av.z; As[kc + 3][r] = av.w;
        }
        #pragma unroll
        for (int l = 0; l < 2; ++l) {
            int f4 = tid * 2 + l;
            int n = f4 >> 2;
            int kc = (f4 & 3) * 4;
            float4 wv = make_float4(0.f, 0.f, 0.f, 0.f);
            if (col0 + n < N)
                wv = *reinterpret_cast<const float4*>(
                    &W[(size_t)(col0 + n) * ldw + k0 + kc]);
            Ws[kc + 0][n] = wv.x; Ws[kc + 1][n] = wv.y;
            Ws[kc + 2][n] = wv.z; Ws[kc + 3][n] = wv.w;
        }
        __syncthreads();
        #pragma unroll
        for (int kk = 0; kk < 16; ++kk) {
            float a[8], w[8];
            const float4* ap = reinterpret_cast<const float4*>(&As[kk][ty * 8]);
            const float4* wp = reinterpret_cast<const float4*>(&Ws[kk][tx * 8]);
            float4 a0 = ap[0], a1 = ap[1];
            float4 w0 = wp[0], w1 = wp[1];
            a[0]=a0.x; a[1]=a0.y; a[2]=a0.z; a[3]=a0.w;
            a[4]=a1.x; a[5]=a1.y; a[6]=a1.z; a[7]=a1.w;
            w[0]=w0.x; w[1]=w0.y; w[2]=w0.z; w[3]=w0.w;
            w[4]=w1.x; w[5]=w1.y; w[6]=w1.z; w[7]=w1.w;
            #pragma unroll
            for (int i = 0; i < 8; ++i)
                #pragma unroll
                for (int j = 0; j < 8; ++j)
                    acc[i][j] += a[i] * w[j];
        }
        __syncthreads();
    }

    #pragma unroll
    for (int i = 0; i < 8; ++i) {
        int r = row0 + ty * 8 + i;
        #pragma unroll
        for (int j = 0; j < 8; ++j) {
            int c = col0 + tx * 8 + j;
            if (c < N) {
                float v = acc[i][j];
                if (EPI == 1) {
                    v += bias[c];
                    v = (v > 20.f) ? v : log1pf(__expf(v));
                }
                C[(size_t)r * ldc + c] = v;
            }
        }
    }
}

// ---------------------------------------------------------------------------
// Skinny split-K GEMM for x_proj (N=80).
// ---------------------------------------------------------------------------
__global__ __launch_bounds__(256) void gemm_skinny(
    const float* __restrict__ A, int lda,
    const float* __restrict__ W, int ldw,
    float* __restrict__ C, int ldc,
    int N, int K, int kchunks)
{
    __shared__ __align__(16) float As[16][68];
    __shared__ __align__(16) float Ws[16][84];
    int row0 = blockIdx.x * 64;
    int klen = K / kchunks;
    int kbeg = blockIdx.y * klen;
    int tid = threadIdx.x;
    int tx = tid & 15, ty = tid >> 4;
    float acc[4][5] = {};

    for (int k0 = kbeg; k0 < kbeg + klen; k0 += 16) {
        {
            int f4 = tid;
            int r = f4 >> 2; int kc = (f4 & 3) * 4;
            const float4 av = *reinterpret_cast<const float4*>(
                &A[(size_t)(row0 + r) * lda + k0 + kc]);
            As[kc + 0][r] = av.x; As[kc + 1][r] = av.y;
            As[kc + 2][r] = av.z; As[kc + 3][r] = av.w;
        }
        #pragma unroll
        for (int l = 0; l < 2; ++l) {
            int f4 = tid + l * 256;
            if (f4 < 320) {
                int n = f4 >> 2; int kc = (f4 & 3) * 4;
                float4 wv = make_float4(0.f, 0.f, 0.f, 0.f);
                if (n < N)
                    wv = *reinterpret_cast<const float4*>(
                        &W[(size_t)n * ldw + k0 + kc]);
                Ws[kc + 0][n] = wv.x; Ws[kc + 1][n] = wv.y;
                Ws[kc + 2][n] = wv.z; Ws[kc + 3][n] = wv.w;
            }
        }
        __syncthreads();
        #pragma unroll
        for (int kk = 0; kk < 16; ++kk) {
            float a[4], w[5];
            const float4* ap = reinterpret_cast<const float4*>(&As[kk][ty * 4]);
            float4 a0 = ap[0];
            a[0]=a0.x; a[1]=a0.y; a[2]=a0.z; a[3]=a0.w;
            #pragma unroll
            for (int j = 0; j < 5; ++j) w[j] = Ws[kk][tx * 5 + j];
            #pragma unroll
            for (int i = 0; i < 4; ++i)
                #pragma unroll
                for (int j = 0; j < 5; ++j)
                    acc[i][j] += a[i] * w[j];
        }
        __syncthreads();
    }
    #pragma unroll
    for (int i = 0; i < 4; ++i) {
        int r = row0 + ty * 4 + i;
        #pragma unroll
        for (int j = 0; j < 5; ++j) {
            int c = tx * 5 + j;
            if (c < N)
                atomicAdd(&C[(size_t)r * ldc + c], acc[i][j]);
        }
    }
}

// ---------------------------------------------------------------------------
// Depthwise causal conv(4) + bias + silu
// ---------------------------------------------------------------------------
__global__ __launch_bounds__(256) void conv_silu_k(
    const float* __restrict__ xz, const float* __restrict__ cw,
    const float* __restrict__ cb, float* __restrict__ xin)
{
    int i = blockIdx.x * 256 + threadIdx.x;   // over ROWS*DI
    if (i >= ROWS * DI) return;
    int row = i / DI;
    int c = i - row * DI;
    int t = row & (SL - 1);
    int b = row >> 10;
    float acc = cb[c];
    const float* base = xz + (size_t)(b * SL) * (2 * DI) + c;
    #pragma unroll
    for (int k = 0; k < DC; ++k) {
        int tt = t + k - (DC - 1);
        if (tt >= 0) acc += base[(size_t)tt * (2 * DI)] * cw[c * DC + k];
    }
    xin[i] = acc / (1.f + __expf(-acc));
}

// ---------------------------------------------------------------------------
// Chunked selective scan.
// Phase 1: per-chunk local scan from h=0; writes h_end and decay product.
// Block: 256 = 16 d x 16 s. Grid: NB*(DI/16)*CCH.
// ---------------------------------------------------------------------------
__global__ __launch_bounds__(256) void scan_phase1(
    const float* __restrict__ dt,   // (ROWS, DI)
    const float* __restrict__ dbl,  // (ROWS, 80)
    const float* __restrict__ xin,  // (ROWS, DI)
    const float* __restrict__ Alog, // (DI, DS)
    float* __restrict__ hend,       // (NB*CCH, DI, DS)
    float* __restrict__ eprod)      // (NB*CCH, DI, DS)
{
    int blk = blockIdx.x;
    int c = blk % CCH;
    int tmp = blk / CCH;
    int dblk = tmp % (DI / 16);
    int b = tmp / (DI / 16);
    int s = threadIdx.x & 15;
    int d = dblk * 16 + (threadIdx.x >> 4);
    float A = -__expf(Alog[d * DS + s]);
    float h = 0.f, P = 1.f;
    const int rowbase = b * SL + c * CLEN;
    #pragma unroll 4
    for (int t = 0; t < CLEN; ++t) {
        int r = rowbase + t;
        float dtv = dt[(size_t)r * DI + d];
        float xv  = xin[(size_t)r * DI + d];
        float Bv  = dbl[(size_t)r * 80 + 48 + s];
        float e = __expf(dtv * A);
        h = h * e + dtv * xv * Bv;
        P *= e;
    }
    size_t idx = ((size_t)(b * CCH + c) * DI + d) * DS + s;
    hend[idx]  = h;
    eprod[idx] = P;
}

// ---------------------------------------------------------------------------
// Phase 2: sequential combine across chunks (tiny): hinit[c] = H(c-1)
// ---------------------------------------------------------------------------
__global__ __launch_bounds__(256) void scan_combine(
    const float* __restrict__ hend, const float* __restrict__ eprod,
    float* __restrict__ hinit)
{
    int i = blockIdx.x * 256 + threadIdx.x;     // over NB*DI*DS
    if (i >= NB * DI * DS) return;
    int b = i / (DI * DS);
    int ds_ = i - b * (DI * DS);
    float H = 0.f;
    #pragma unroll
    for (int c = 0; c < CCH; ++c) {
        size_t idx = (size_t)(b * CCH + c) * (DI * DS) + ds_;
        hinit[idx] = H;
        H = H * eprod[idx] + hend[idx];
    }
}

// ---------------------------------------------------------------------------
// Phase 3: re-scan each chunk from correct hinit, produce gated y.
// ---------------------------------------------------------------------------
__global__ __launch_bounds__(256) void scan_phase3(
    const float* __restrict__ dt,
    const float* __restrict__ dbl,
    const float* __restrict__ xin,
    const float* __restrict__ xz,   // z = cols [DI:2*DI)
    const float* __restrict__ Alog,
    const float* __restrict__ Dp,
    const float* __restrict__ hinit,
    float* __restrict__ y)
{
    int blk = blockIdx.x;
    int c = blk % CCH;
    int tmp = blk / CCH;
    int dblk = tmp % (DI / 16);
    int b = tmp / (DI / 16);
    int s = threadIdx.x & 15;
    int d = dblk * 16 + (threadIdx.x >> 4);
    float A = -__expf(Alog[d * DS + s]);
    float Dv = Dp[d];
    float h = hinit[((size_t)(b * CCH + c) * DI + d) * DS + s];
    const int rowbase = b * SL + c * CLEN;
    #pragma unroll 2
    for (int t = 0; t < CLEN; ++t) {
        int r = rowbase + t;
        float dtv = dt[(size_t)r * DI + d];
        float xv  = xin[(size_t)r * DI + d];
        float Bv  = dbl[(size_t)r * 80 + 48 + s];
        float Cv  = dbl[(size_t)r * 80 + 64 + s];
        float e = __expf(dtv * A);
        h = h * e + dtv * xv * Bv;
        float p = h * Cv;
        p += __shfl_xor(p, 1, 64);
        p += __shfl_xor(p, 2, 64);
        p += __shfl_xor(p, 4, 64);
        p += __shfl_xor(p, 8, 64);
        if (s == 0) {
            float z = xz[(size_t)r * (2 * DI) + DI + d];
            float yv = (p + xv * Dv) * (z / (1.f + __expf(-z)));
            y[(size_t)r * DI + d] = yv;
        }
    }
}

// ---------------------------------------------------------------------------
// LayerNorm over rows of 768
// ---------------------------------------------------------------------------
__global__ __launch_bounds__(256) void ln_k(
    const float* __restrict__ x, const float* __restrict__ w,
    const float* __restrict__ b, float* __restrict__ o)
{
    int row = blockIdx.x;
    int tid = threadIdx.x;
    const float* xr = x + (size_t)row * DM;
    float v0 = xr[tid], v1 = xr[tid + 256], v2 = xr[tid + 512];
    float s = v0 + v1 + v2;
    #pragma unroll
    for (int off = 1; off < 64; off <<= 1) s += __shfl_xor(s, off, 64);
    __shared__ float red[4];
    __shared__ float red2[4];
    int wid = tid >> 6, lane = tid & 63;
    if (lane == 0) red[wid] = s;
    __syncthreads();
    float mu = (red[0] + red[1] + red[2] + red[3]) * (1.f / 768.f);
    float d0 = v0 - mu, d1 = v1 - mu, d2 = v2 - mu;
    float q = d0 * d0 + d1 * d1 + d2 * d2;
    #pragma unroll
    for (int off = 1; off < 64; off <<= 1) q += __shfl_xor(q, off, 64);
    if (lane == 0) red2[wid] = q;
    __syncthreads();
    float var = (red2[0] + red2[1] + red2[2] + red2[3]) * (1.f / 768.f);
    float rs = rsqrtf(var + 1e-5f);
    o[(size_t)row * DM + tid]       = d0 * rs * w[tid]       + b[tid];
    o[(size_t)row * DM + tid + 256] = d1 * rs * w[tid + 256] + b[tid + 256];
    o[(size_t)row * DM + tid + 512] = d2 * rs * w[tid + 512] + b[tid + 512];
}

// ---------------------------------------------------------------------------
extern "C" void kernel_launch(void* const* d_in, const int* in_sizes, int n_in,
                              void* d_out, int out_size, void* d_ws, size_t ws_size,
                              hipStream_t stream) {
    const int*   ids        = (const int*)d_in[0];
    const float* emb        = (const float*)d_in[1];
    const float* in_proj_w  = (const float*)d_in[2];
    const float* conv_w     = (const float*)d_in[3];
    const float* conv_b     = (const float*)d_in[4];
    const float* x_proj_w   = (const float*)d_in[5];
    const float* dt_proj_w  = (const float*)d_in[6];
    const float* dt_proj_b  = (const float*)d_in[7];
    const float* A_log      = (const float*)d_in[8];
    const float* D_param    = (const float*)d_in[9];
    const float* out_proj_w = (const float*)d_in[10];
    const float* norm_w     = (const float*)d_in[11];
    const float* norm_b     = (const float*)d_in[12];
    float* out = (float*)d_out;

    float* ws    = (float*)d_ws;
    float* x     = ws;                               // 2048*768
    float* xz    = x    + (size_t)ROWS * DM;         // 2048*3072
    float* xin   = xz   + (size_t)ROWS * 2 * DI;     // 2048*1536
    float* dbl   = xin  + (size_t)ROWS * DI;         // 2048*80
    float* dt    = dbl  + (size_t)ROWS * 80;         // 2048*1536
    float* y     = dt   + (size_t)ROWS * DI;         // 2048*1536
    float* hend  = y    + (size_t)ROWS * DI;         // NB*CCH*DI*DS
    float* eprod = hend + (size_t)NB * CCH * DI * DS;
    float* hinit = eprod+ (size_t)NB * CCH * DI * DS;
    float* xln   = xz;                               // reuse xz after layers

    embed_k<<<6144, 256, 0, stream>>>(ids, emb, x);

    const int scan_grid = NB * (DI / 16) * CCH;      // 1536 blocks

    for (int i = 0; i < NLAYER; ++i) {
        const float* inw = in_proj_w  + (size_t)i * 2 * DI * DM;
        const float* cw  = conv_w     + (size_t)i * DI * DC;
        const float* cb  = conv_b     + (size_t)i * DI;
        const float* xpw = x_proj_w   + (size_t)i * (DTR + 2 * DS) * DI;
        const float* dtw = dt_proj_w  + (size_t)i * DI * DTR;
        const float* dtb = dt_proj_b  + (size_t)i * DI;
        const float* Al  = A_log      + (size_t)i * DI * DS;
        const float* Dpar= D_param    + (size_t)i * DI;
        const float* ow  = out_proj_w + (size_t)i * DM * DI;

        gemm_tn<0><<<dim3(24, 16), 256, 0, stream>>>(
            x, DM, inw, DM, xz, 2 * DI, ROWS, 2 * DI, DM, nullptr);
        conv_silu_k<<<(ROWS * DI) / 256, 256, 0, stream>>>(xz, cw, cb, xin);
        hipMemsetAsync(dbl, 0, (size_t)ROWS * 80 * sizeof(float), stream);
        gemm_skinny<<<dim3(32, 8), 256, 0, stream>>>(
            xin, DI, xpw, DI, dbl, 80, 80, DI, 8);
        gemm_tn<1><<<dim3(12, 16), 256, 0, stream>>>(
            dbl, 80, dtw, DTR, dt, DI, ROWS, DI, DTR, dtb);

        // chunked scan
        scan_phase1<<<scan_grid, 256, 0, stream>>>(dt, dbl, xin, Al, hend, eprod);
        scan_combine<<<(NB * DI * DS + 255) / 256, 256, 0, stream>>>(hend, eprod, hinit);
        scan_phase3<<<scan_grid, 256, 0, stream>>>(dt, dbl, xin, xz, Al, Dpar, hinit, y);

        gemm_tn<0><<<dim3(6, 16), 256, 0, stream>>>(
            y, DI, ow, DI, x, DM, ROWS, DM, DI, nullptr);
    }

    ln_k<<<ROWS, 256, 0, stream>>>(x, norm_w, norm_b, xln);
    gemm_tn<0><<<dim3(393, 16), 256, 0, stream>>>(
        xln, DM, emb, DM, out, VOCAB, ROWS, VOCAB, DM, nullptr);
}

// Round 3
// 5542.117 us; speedup vs baseline: 3.0671x; 1.7464x over previous
//
#include <hip/hip_runtime.h>
#include <hip/hip_bf16.h>

#define DI 1536
#define DS 16
#define DC 4
#define DTR 48
#define NB 2
#define SL 1024
#define DM 768
#define NLAYER 12
#define VOCAB 50257
#define ROWS (NB*SL)   // 2048
#define CCH 8          // scan chunks
#define CLEN (SL/CCH)  // 128

typedef __attribute__((ext_vector_type(8))) short bf16x8;
typedef __attribute__((ext_vector_type(4))) float f32x4;

__device__ inline short f2bf(float f) {
    unsigned u = __builtin_bit_cast(unsigned, f);
    unsigned r = (u + 0x7fffu + ((u >> 16) & 1u)) >> 16;
    return (short)r;
}

// ---------------------------------------------------------------------------
// Embedding: x[b,s,:] = emb[ids[b,s]] * sqrt(768)
// ---------------------------------------------------------------------------
__global__ __launch_bounds__(256) void embed_k(const int* __restrict__ ids,
                                               const float* __restrict__ emb,
                                               float* __restrict__ x) {
    int i = blockIdx.x * 256 + threadIdx.x;      // over ROWS*DM
    if (i >= ROWS * DM) return;
    int row = i / DM;
    int c = i - row * DM;
    x[i] = emb[(size_t)ids[row] * DM + c] * 27.712812921102035f;
}

// ---------------------------------------------------------------------------
// bf16-MFMA GEMM: C(M,N) fp32 = A(M,K) @ W(N,K)^T, A/W fp32 in memory,
// converted to bf16 during LDS staging. 128x128 tile, BK=32, 4 waves,
// each wave 4x4 frags of v_mfma_f32_16x16x32_bf16.
// LDS tiles [128][32] bf16 with 16B-chunk XOR swizzle perm = c ^ ((row>>1)&3)
// -> conflict-free ds_read_b128 fragment reads.
// M multiple of 128 via grid; K multiple of 32; N guarded (staging + store).
// ---------------------------------------------------------------------------
__global__ __launch_bounds__(256) void gemm_bf16mfma(
    const float* __restrict__ A, int lda,
    const float* __restrict__ W, int ldw,
    float* __restrict__ C, int ldc,
    int N, int K)
{
    __shared__ __align__(16) short As[128 * 32];
    __shared__ __align__(16) short Ws[128 * 32];
    const int tid  = threadIdx.x;
    const int lane = tid & 63;
    const int wid  = tid >> 6;
    const int wr   = wid >> 1, wc = wid & 1;
    const int row0 = blockIdx.y * 128;
    const int col0 = blockIdx.x * 128;

    // staging assignments: chunk id = tid + i*256; chunk = (row, kc) of 8 elems
    int srow[2], soff[2];
    const float* gA[2];
    const float* gW[2];
    bool okW[2];
    #pragma unroll
    for (int i = 0; i < 2; ++i) {
        int cid = tid + i * 256;        // 0..511
        int r   = cid >> 2;             // 0..127
        int c   = cid & 3;              // 16B chunk within row
        srow[i] = r;
        int perm = c ^ ((r >> 1) & 3);
        soff[i] = r * 32 + perm * 8;
        gA[i] = A + (size_t)(row0 + r) * lda + c * 8;
        gW[i] = W + (size_t)(col0 + r) * ldw + c * 8;
        okW[i] = (col0 + r) < N;
    }

    // fragment read offsets (shorts)
    int arow = wr * 64 + (lane & 15);
    int abase = arow * 32 + (((lane >> 4) ^ ((arow >> 1) & 3)) * 8);
    int brow = wc * 64 + (lane & 15);
    int bbase = brow * 32 + (((lane >> 4) ^ ((brow >> 1) & 3)) * 8);

    f32x4 acc[4][4] = {};

    for (int k0 = 0; k0 < K; k0 += 32) {
        #pragma unroll
        for (int i = 0; i < 2; ++i) {
            const float4* pa = reinterpret_cast<const float4*>(gA[i]);
            float4 a0 = pa[0], a1 = pa[1];
            bf16x8 av;
            av[0]=f2bf(a0.x); av[1]=f2bf(a0.y); av[2]=f2bf(a0.z); av[3]=f2bf(a0.w);
            av[4]=f2bf(a1.x); av[5]=f2bf(a1.y); av[6]=f2bf(a1.z); av[7]=f2bf(a1.w);
            *reinterpret_cast<bf16x8*>(&As[soff[i]]) = av;

            float4 w0 = make_float4(0.f,0.f,0.f,0.f), w1 = w0;
            if (okW[i]) {
                const float4* pw = reinterpret_cast<const float4*>(gW[i]);
                w0 = pw[0]; w1 = pw[1];
            }
            bf16x8 wv;
            wv[0]=f2bf(w0.x); wv[1]=f2bf(w0.y); wv[2]=f2bf(w0.z); wv[3]=f2bf(w0.w);
            wv[4]=f2bf(w1.x); wv[5]=f2bf(w1.y); wv[6]=f2bf(w1.z); wv[7]=f2bf(w1.w);
            *reinterpret_cast<bf16x8*>(&Ws[soff[i]]) = wv;
            gA[i] += 32; gW[i] += 32;
        }
        __syncthreads();

        bf16x8 a[4], b[4];
        #pragma unroll
        for (int mf = 0; mf < 4; ++mf)
            a[mf] = *reinterpret_cast<const bf16x8*>(&As[abase + mf * 512]);
        #pragma unroll
        for (int nf = 0; nf < 4; ++nf)
            b[nf] = *reinterpret_cast<const bf16x8*>(&Ws[bbase + nf * 512]);
        #pragma unroll
        for (int mf = 0; mf < 4; ++mf)
            #pragma unroll
            for (int nf = 0; nf < 4; ++nf)
                acc[mf][nf] = __builtin_amdgcn_mfma_f32_16x16x32_bf16(
                    a[mf], b[nf], acc[mf][nf], 0, 0, 0);
        __syncthreads();
    }

    // epilogue: C/D layout col = lane&15, row = (lane>>4)*4 + reg
    #pragma unroll
    for (int mf = 0; mf < 4; ++mf) {
        #pragma unroll
        for (int nf = 0; nf < 4; ++nf) {
            int r  = row0 + wr * 64 + mf * 16 + (lane >> 4) * 4;
            int cc = col0 + wc * 64 + nf * 16 + (lane & 15);
            if (cc < N) {
                f32x4 d = acc[mf][nf];
                #pragma unroll
                for (int j = 0; j < 4; ++j)
                    C[(size_t)(r + j) * ldc + cc] = d[j];
            }
        }
    }
}

// ---------------------------------------------------------------------------
// fp32 GEMM (kept for dt_proj, K=48): C = A @ W^T (+bias/softplus)
// ---------------------------------------------------------------------------
template<int EPI>
__global__ __launch_bounds__(256) void gemm_tn(
    const float* __restrict__ A, int lda,
    const float* __restrict__ W, int ldw,
    float* __restrict__ C, int ldc,
    int M, int N, int K,
    const float* __restrict__ bias)
{
    __shared__ __align__(16) float As[16][132];
    __shared__ __align__(16) float Ws[16][132];
    int tid = threadIdx.x;
    int tx = tid & 15, ty = tid >> 4;
    int row0 = blockIdx.y * 128;
    int col0 = blockIdx.x * 128;
    float acc[8][8] = {};

    for (int k0 = 0; k0 < K; k0 += 16) {
        #pragma unroll
        for (int l = 0; l < 2; ++l) {
            int f4 = tid * 2 + l;
            int r = f4 >> 2;
            int kc = (f4 & 3) * 4;
            const float4 av = *reinterpret_cast<const float4*>(
                &A[(size_t)(row0 + r) * lda + k0 + kc]);
            As[kc + 0][r] = av.x; As[kc + 1][r] = av.y;
            As[kc + 2][r] = av.z; As[kc + 3][r] = av.w;
        }
        #pragma unroll
        for (int l = 0; l < 2; ++l) {
            int f4 = tid * 2 + l;
            int n = f4 >> 2;
            int kc = (f4 & 3) * 4;
            float4 wv = make_float4(0.f, 0.f, 0.f, 0.f);
            if (col0 + n < N)
                wv = *reinterpret_cast<const float4*>(
                    &W[(size_t)(col0 + n) * ldw + k0 + kc]);
            Ws[kc + 0][n] = wv.x; Ws[kc + 1][n] = wv.y;
            Ws[kc + 2][n] = wv.z; Ws[kc + 3][n] = wv.w;
        }
        __syncthreads();
        #pragma unroll
        for (int kk = 0; kk < 16; ++kk) {
            float a[8], w[8];
            const float4* ap = reinterpret_cast<const float4*>(&As[kk][ty * 8]);
            const float4* wp = reinterpret_cast<const float4*>(&Ws[kk][tx * 8]);
            float4 a0 = ap[0], a1 = ap[1];
            float4 w0 = wp[0], w1 = wp[1];
            a[0]=a0.x; a[1]=a0.y; a[2]=a0.z; a[3]=a0.w;
            a[4]=a1.x; a[5]=a1.y; a[6]=a1.z; a[7]=a1.w;
            w[0]=w0.x; w[1]=w0.y; w[2]=w0.z; w[3]=w0.w;
            w[4]=w1.x; w[5]=w1.y; w[6]=w1.z; w[7]=w1.w;
            #pragma unroll
            for (int i = 0; i < 8; ++i)
                #pragma unroll
                for (int j = 0; j < 8; ++j)
                    acc[i][j] += a[i] * w[j];
        }
        __syncthreads();
    }

    #pragma unroll
    for (int i = 0; i < 8; ++i) {
        int r = row0 + ty * 8 + i;
        #pragma unroll
        for (int j = 0; j < 8; ++j) {
            int c = col0 + tx * 8 + j;
            if (c < N) {
                float v = acc[i][j];
                if (EPI == 1) {
                    v += bias[c];
                    v = (v > 20.f) ? v : log1pf(__expf(v));
                }
                C[(size_t)r * ldc + c] = v;
            }
        }
    }
}

// ---------------------------------------------------------------------------
// Skinny split-K GEMM for x_proj (N=80).
// ---------------------------------------------------------------------------
__global__ __launch_bounds__(256) void gemm_skinny(
    const float* __restrict__ A, int lda,
    const float* __restrict__ W, int ldw,
    float* __restrict__ C, int ldc,
    int N, int K, int kchunks)
{
    __shared__ __align__(16) float As[16][68];
    __shared__ __align__(16) float Ws[16][84];
    int row0 = blockIdx.x * 64;
    int klen = K / kchunks;
    int kbeg = blockIdx.y * klen;
    int tid = threadIdx.x;
    int tx = tid & 15, ty = tid >> 4;
    float acc[4][5] = {};

    for (int k0 = kbeg; k0 < kbeg + klen; k0 += 16) {
        {
            int f4 = tid;
            int r = f4 >> 2; int kc = (f4 & 3) * 4;
            const float4 av = *reinterpret_cast<const float4*>(
                &A[(size_t)(row0 + r) * lda + k0 + kc]);
            As[kc + 0][r] = av.x; As[kc + 1][r] = av.y;
            As[kc + 2][r] = av.z; As[kc + 3][r] = av.w;
        }
        #pragma unroll
        for (int l = 0; l < 2; ++l) {
            int f4 = tid + l * 256;
            if (f4 < 320) {
                int n = f4 >> 2; int kc = (f4 & 3) * 4;
                float4 wv = make_float4(0.f, 0.f, 0.f, 0.f);
                if (n < N)
                    wv = *reinterpret_cast<const float4*>(
                        &W[(size_t)n * ldw + k0 + kc]);
                Ws[kc + 0][n] = wv.x; Ws[kc + 1][n] = wv.y;
                Ws[kc + 2][n] = wv.z; Ws[kc + 3][n] = wv.w;
            }
        }
        __syncthreads();
        #pragma unroll
        for (int kk = 0; kk < 16; ++kk) {
            float a[4], w[5];
            const float4* ap = reinterpret_cast<const float4*>(&As[kk][ty * 4]);
            float4 a0 = ap[0];
            a[0]=a0.x; a[1]=a0.y; a[2]=a0.z; a[3]=a0.w;
            #pragma unroll
            for (int j = 0; j < 5; ++j) w[j] = Ws[kk][tx * 5 + j];
            #pragma unroll
            for (int i = 0; i < 4; ++i)
                #pragma unroll
                for (int j = 0; j < 5; ++j)
                    acc[i][j] += a[i] * w[j];
        }
        __syncthreads();
    }
    #pragma unroll
    for (int i = 0; i < 4; ++i) {
        int r = row0 + ty * 4 + i;
        #pragma unroll
        for (int j = 0; j < 5; ++j) {
            int c = tx * 5 + j;
            if (c < N)
                atomicAdd(&C[(size_t)r * ldc + c], acc[i][j]);
        }
    }
}

// ---------------------------------------------------------------------------
// Depthwise causal conv(4) + bias + silu
// ---------------------------------------------------------------------------
__global__ __launch_bounds__(256) void conv_silu_k(
    const float* __restrict__ xz, const float* __restrict__ cw,
    const float* __restrict__ cb, float* __restrict__ xin)
{
    int i = blockIdx.x * 256 + threadIdx.x;   // over ROWS*DI
    if (i >= ROWS * DI) return;
    int row = i / DI;
    int c = i - row * DI;
    int t = row & (SL - 1);
    int b = row >> 10;
    float acc = cb[c];
    const float* base = xz + (size_t)(b * SL) * (2 * DI) + c;
    #pragma unroll
    for (int k = 0; k < DC; ++k) {
        int tt = t + k - (DC - 1);
        if (tt >= 0) acc += base[(size_t)tt * (2 * DI)] * cw[c * DC + k];
    }
    xin[i] = acc / (1.f + __expf(-acc));
}

// ---------------------------------------------------------------------------
// Chunked selective scan, 3 phases.
// ---------------------------------------------------------------------------
__global__ __launch_bounds__(256) void scan_phase1(
    const float* __restrict__ dt,
    const float* __restrict__ dbl,
    const float* __restrict__ xin,
    const float* __restrict__ Alog,
    float* __restrict__ hend,
    float* __restrict__ eprod)
{
    int blk = blockIdx.x;
    int c = blk % CCH;
    int tmp = blk / CCH;
    int dblk = tmp % (DI / 16);
    int b = tmp / (DI / 16);
    int s = threadIdx.x & 15;
    int d = dblk * 16 + (threadIdx.x >> 4);
    float A = -__expf(Alog[d * DS + s]);
    float h = 0.f, P = 1.f;
    const int rowbase = b * SL + c * CLEN;
    #pragma unroll 4
    for (int t = 0; t < CLEN; ++t) {
        int r = rowbase + t;
        float dtv = dt[(size_t)r * DI + d];
        float xv  = xin[(size_t)r * DI + d];
        float Bv  = dbl[(size_t)r * 80 + 48 + s];
        float e = __expf(dtv * A);
        h = h * e + dtv * xv * Bv;
        P *= e;
    }
    size_t idx = ((size_t)(b * CCH + c) * DI + d) * DS + s;
    hend[idx]  = h;
    eprod[idx] = P;
}

__global__ __launch_bounds__(256) void scan_combine(
    const float* __restrict__ hend, const float* __restrict__ eprod,
    float* __restrict__ hinit)
{
    int i = blockIdx.x * 256 + threadIdx.x;     // over NB*DI*DS
    if (i >= NB * DI * DS) return;
    int b = i / (DI * DS);
    int ds_ = i - b * (DI * DS);
    float H = 0.f;
    #pragma unroll
    for (int c = 0; c < CCH; ++c) {
        size_t idx = (size_t)(b * CCH + c) * (DI * DS) + ds_;
        hinit[idx] = H;
        H = H * eprod[idx] + hend[idx];
    }
}

__global__ __launch_bounds__(256) void scan_phase3(
    const float* __restrict__ dt,
    const float* __restrict__ dbl,
    const float* __restrict__ xin,
    const float* __restrict__ xz,
    const float* __restrict__ Alog,
    const float* __restrict__ Dp,
    const float* __restrict__ hinit,
    float* __restrict__ y)
{
    int blk = blockIdx.x;
    int c = blk % CCH;
    int tmp = blk / CCH;
    int dblk = tmp % (DI / 16);
    int b = tmp / (DI / 16);
    int s = threadIdx.x & 15;
    int d = dblk * 16 + (threadIdx.x >> 4);
    float A = -__expf(Alog[d * DS + s]);
    float Dv = Dp[d];
    float h = hinit[((size_t)(b * CCH + c) * DI + d) * DS + s];
    const int rowbase = b * SL + c * CLEN;
    #pragma unroll 2
    for (int t = 0; t < CLEN; ++t) {
        int r = rowbase + t;
        float dtv = dt[(size_t)r * DI + d];
        float xv  = xin[(size_t)r * DI + d];
        float Bv  = dbl[(size_t)r * 80 + 48 + s];
        float Cv  = dbl[(size_t)r * 80 + 64 + s];
        float e = __expf(dtv * A);
        h = h * e + dtv * xv * Bv;
        float p = h * Cv;
        p += __shfl_xor(p, 1, 64);
        p += __shfl_xor(p, 2, 64);
        p += __shfl_xor(p, 4, 64);
        p += __shfl_xor(p, 8, 64);
        if (s == 0) {
            float z = xz[(size_t)r * (2 * DI) + DI + d];
            float yv = (p + xv * Dv) * (z / (1.f + __expf(-z)));
            y[(size_t)r * DI + d] = yv;
        }
    }
}

// ---------------------------------------------------------------------------
// LayerNorm over rows of 768
// ---------------------------------------------------------------------------
__global__ __launch_bounds__(256) void ln_k(
    const float* __restrict__ x, const float* __restrict__ w,
    const float* __restrict__ b, float* __restrict__ o)
{
    int row = blockIdx.x;
    int tid = threadIdx.x;
    const float* xr = x + (size_t)row * DM;
    float v0 = xr[tid], v1 = xr[tid + 256], v2 = xr[tid + 512];
    float s = v0 + v1 + v2;
    #pragma unroll
    for (int off = 1; off < 64; off <<= 1) s += __shfl_xor(s, off, 64);
    __shared__ float red[4];
    __shared__ float red2[4];
    int wid = tid >> 6, lane = tid & 63;
    if (lane == 0) red[wid] = s;
    __syncthreads();
    float mu = (red[0] + red[1] + red[2] + red[3]) * (1.f / 768.f);
    float d0 = v0 - mu, d1 = v1 - mu, d2 = v2 - mu;
    float q = d0 * d0 + d1 * d1 + d2 * d2;
    #pragma unroll
    for (int off = 1; off < 64; off <<= 1) q += __shfl_xor(q, off, 64);
    if (lane == 0) red2[wid] = q;
    __syncthreads();
    float var = (red2[0] + red2[1] + red2[2] + red2[3]) * (1.f / 768.f);
    float rs = rsqrtf(var + 1e-5f);
    o[(size_t)row * DM + tid]       = d0 * rs * w[tid]       + b[tid];
    o[(size_t)row * DM + tid + 256] = d1 * rs * w[tid + 256] + b[tid + 256];
    o[(size_t)row * DM + tid + 512] = d2 * rs * w[tid + 512] + b[tid + 512];
}

// ---------------------------------------------------------------------------
extern "C" void kernel_launch(void* const* d_in, const int* in_sizes, int n_in,
                              void* d_out, int out_size, void* d_ws, size_t ws_size,
                              hipStream_t stream) {
    const int*   ids        = (const int*)d_in[0];
    const float* emb        = (const float*)d_in[1];
    const float* in_proj_w  = (const float*)d_in[2];
    const float* conv_w     = (const float*)d_in[3];
    const float* conv_b     = (const float*)d_in[4];
    const float* x_proj_w   = (const float*)d_in[5];
    const float* dt_proj_w  = (const float*)d_in[6];
    const float* dt_proj_b  = (const float*)d_in[7];
    const float* A_log      = (const float*)d_in[8];
    const float* D_param    = (const float*)d_in[9];
    const float* out_proj_w = (const float*)d_in[10];
    const float* norm_w     = (const float*)d_in[11];
    const float* norm_b     = (const float*)d_in[12];
    float* out = (float*)d_out;

    float* ws    = (float*)d_ws;
    float* x     = ws;                               // 2048*768
    float* xz    = x    + (size_t)ROWS * DM;         // 2048*3072
    float* xin   = xz   + (size_t)ROWS * 2 * DI;     // 2048*1536
    float* dbl   = xin  + (size_t)ROWS * DI;         // 2048*80
    float* dt    = dbl  + (size_t)ROWS * 80;         // 2048*1536
    float* y     = dt   + (size_t)ROWS * DI;         // 2048*1536
    float* hend  = y    + (size_t)ROWS * DI;         // NB*CCH*DI*DS
    float* eprod = hend + (size_t)NB * CCH * DI * DS;
    float* hinit = eprod+ (size_t)NB * CCH * DI * DS;
    float* xln   = xz;                               // reuse xz after layers

    embed_k<<<6144, 256, 0, stream>>>(ids, emb, x);

    const int scan_grid = NB * (DI / 16) * CCH;      // 1536 blocks

    for (int i = 0; i < NLAYER; ++i) {
        const float* inw = in_proj_w  + (size_t)i * 2 * DI * DM;
        const float* cw  = conv_w     + (size_t)i * DI * DC;
        const float* cb  = conv_b     + (size_t)i * DI;
        const float* xpw = x_proj_w   + (size_t)i * (DTR + 2 * DS) * DI;
        const float* dtw = dt_proj_w  + (size_t)i * DI * DTR;
        const float* dtb = dt_proj_b  + (size_t)i * DI;
        const float* Al  = A_log      + (size_t)i * DI * DS;
        const float* Dpar= D_param    + (size_t)i * DI;
        const float* ow  = out_proj_w + (size_t)i * DM * DI;

        // in_proj: xz = x @ inw^T (bf16 MFMA)
        gemm_bf16mfma<<<dim3(24, 16), 256, 0, stream>>>(
            x, DM, inw, DM, xz, 2 * DI, 2 * DI, DM);
        conv_silu_k<<<(ROWS * DI) / 256, 256, 0, stream>>>(xz, cw, cb, xin);
        hipMemsetAsync(dbl, 0, (size_t)ROWS * 80 * sizeof(float), stream);
        gemm_skinny<<<dim3(32, 8), 256, 0, stream>>>(
            xin, DI, xpw, DI, dbl, 80, 80, DI, 8);
        gemm_tn<1><<<dim3(12, 16), 256, 0, stream>>>(
            dbl, 80, dtw, DTR, dt, DI, ROWS, DI, DTR, dtb);

        scan_phase1<<<scan_grid, 256, 0, stream>>>(dt, dbl, xin, Al, hend, eprod);
        scan_combine<<<(NB * DI * DS + 255) / 256, 256, 0, stream>>>(hend, eprod, hinit);
        scan_phase3<<<scan_grid, 256, 0, stream>>>(dt, dbl, xin, xz, Al, Dpar, hinit, y);

        // out_proj: x = y @ ow^T (bf16 MFMA)
        gemm_bf16mfma<<<dim3(6, 16), 256, 0, stream>>>(
            y, DI, ow, DI, x, DM, DM, DI);
    }

    ln_k<<<ROWS, 256, 0, stream>>>(x, norm_w, norm_b, xln);
    // logits: out = xln @ emb^T (bf16 MFMA)
    gemm_bf16mfma<<<dim3(393, 16), 256, 0, stream>>>(
        xln, DM, emb, DM, out, VOCAB, VOCAB, DM);
}

// Round 4
// 4651.714 us; speedup vs baseline: 3.6542x; 1.1914x over previous
//
#include <hip/hip_runtime.h>
#include <hip/hip_bf16.h>

#define DI 1536
#define DS 16
#define DC 4
#define DTR 48
#define NB 2
#define SL 1024
#define DM 768
#define NLAYER 12
#define VOCAB 50257
#define ROWS (NB*SL)   // 2048
#define CCH 32         // scan chunks
#define CLEN (SL/CCH)  // 32

typedef __attribute__((ext_vector_type(8))) short bf16x8;
typedef __attribute__((ext_vector_type(4))) short short4v;
typedef __attribute__((ext_vector_type(4))) float f32x4;

__device__ inline short f2bf(float f) {
    unsigned u = __builtin_bit_cast(unsigned, f);
    unsigned r = (u + 0x7fffu + ((u >> 16) & 1u)) >> 16;
    return (short)r;
}

// ---------------------------------------------------------------------------
// fp32 -> bf16 elementwise convert (n multiple of 4)
// ---------------------------------------------------------------------------
__global__ __launch_bounds__(256) void cvt_bf16_k(const float* __restrict__ src,
                                                  unsigned short* __restrict__ dst,
                                                  int n4) {
    int i = blockIdx.x * 256 + threadIdx.x;
    if (i >= n4) return;
    float4 v = *reinterpret_cast<const float4*>(src + (size_t)i * 4);
    short4v o;
    o[0] = f2bf(v.x); o[1] = f2bf(v.y); o[2] = f2bf(v.z); o[3] = f2bf(v.w);
    *reinterpret_cast<short4v*>(dst + (size_t)i * 4) = o;
}

// ---------------------------------------------------------------------------
// Embedding: xbf[b,s,:] = bf16(emb[ids[b,s]] * sqrt(768))
// ---------------------------------------------------------------------------
__global__ __launch_bounds__(256) void embed_k(const int* __restrict__ ids,
                                               const float* __restrict__ emb,
                                               unsigned short* __restrict__ xbf) {
    int i = blockIdx.x * 256 + threadIdx.x;      // over ROWS*DM
    if (i >= ROWS * DM) return;
    int row = i / DM;
    int c = i - row * DM;
    xbf[i] = (unsigned short)f2bf(emb[(size_t)ids[row] * DM + c] * 27.712812921102035f);
}

// ---------------------------------------------------------------------------
// bf16-MFMA GEMM: C(M,N) = A(M,K)bf16 @ W(N,K)^T, W bf16 (WBF=1) or fp32.
// 128x128 tile, BK=32, 4 waves x (4x4) mfma_f32_16x16x32_bf16.
// Grid: 1D nwg = (N/128 col tiles)*(GY row tiles); col-major over rows
// (consecutive wg share a col tile) + bijective XCD-chunk swizzle.
// OUT: 0 = fp32 store; 1 = fp32 + bf16 dual store; 2 unused.
// ---------------------------------------------------------------------------
template<bool WBF, int OUT>
__global__ __launch_bounds__(256) void gemm_bf16(
    const unsigned short* __restrict__ A, int lda,
    const void* __restrict__ Wv, int ldw,
    float* __restrict__ C, unsigned short* __restrict__ Cbf, int ldc,
    int GY, int N, int K)
{
    __shared__ __align__(16) short As[128 * 32];
    __shared__ __align__(16) short Ws[128 * 32];
    const int tid  = threadIdx.x;
    const int lane = tid & 63;
    const int wid  = tid >> 6;
    const int wr   = wid >> 1, wc = wid & 1;

    // bijective XCD-chunked swizzle (m204), then col-major decode
    const int nwg = gridDim.x;
    const int q = nwg >> 3, rm = nwg & 7;
    const int xcd = blockIdx.x & 7, idx = blockIdx.x >> 3;
    const int wg = (xcd < rm ? xcd * (q + 1) : rm * (q + 1) + (xcd - rm) * q) + idx;
    const int row0 = (wg % GY) * 128;
    const int col0 = (wg / GY) * 128;

    // staging: chunk id = tid + i*256 -> (row r, 8-elem chunk c), XOR swizzle
    int soff[2];
    const unsigned short* gAb[2];
    const unsigned short* gWb[2];
    const float* gWf[2];
    bool okW[2];
    #pragma unroll
    for (int i = 0; i < 2; ++i) {
        int cid = tid + i * 256;        // 0..511
        int r   = cid >> 2;             // 0..127
        int c   = cid & 3;              // 16B chunk within row
        int perm = c ^ ((r >> 1) & 3);
        soff[i] = r * 32 + perm * 8;
        gAb[i] = A + (size_t)(row0 + r) * lda + c * 8;
        if (WBF) gWb[i] = (const unsigned short*)Wv + (size_t)(col0 + r) * ldw + c * 8;
        else     gWf[i] = (const float*)Wv + (size_t)(col0 + r) * ldw + c * 8;
        okW[i] = (col0 + r) < N;
    }

    // fragment read offsets (in shorts)
    int arow = wr * 64 + (lane & 15);
    int abase = arow * 32 + (((lane >> 4) ^ ((arow >> 1) & 3)) * 8);
    int brow = wc * 64 + (lane & 15);
    int bbase = brow * 32 + (((lane >> 4) ^ ((brow >> 1) & 3)) * 8);

    f32x4 acc[4][4] = {};

    for (int k0 = 0; k0 < K; k0 += 32) {
        #pragma unroll
        for (int i = 0; i < 2; ++i) {
            bf16x8 av = *reinterpret_cast<const bf16x8*>(gAb[i]);
            *reinterpret_cast<bf16x8*>(&As[soff[i]]) = av;
            gAb[i] += 32;

            bf16x8 wv = {};
            if (WBF) {
                if (okW[i]) wv = *reinterpret_cast<const bf16x8*>(gWb[i]);
                gWb[i] += 32;
            } else {
                if (okW[i]) {
                    const float4* pw = reinterpret_cast<const float4*>(gWf[i]);
                    float4 w0 = pw[0], w1 = pw[1];
                    wv[0]=f2bf(w0.x); wv[1]=f2bf(w0.y); wv[2]=f2bf(w0.z); wv[3]=f2bf(w0.w);
                    wv[4]=f2bf(w1.x); wv[5]=f2bf(w1.y); wv[6]=f2bf(w1.z); wv[7]=f2bf(w1.w);
                }
                gWf[i] += 32;
            }
            *reinterpret_cast<bf16x8*>(&Ws[soff[i]]) = wv;
        }
        __syncthreads();

        bf16x8 a[4], b[4];
        #pragma unroll
        for (int mf = 0; mf < 4; ++mf)
            a[mf] = *reinterpret_cast<const bf16x8*>(&As[abase + mf * 512]);
        #pragma unroll
        for (int nf = 0; nf < 4; ++nf)
            b[nf] = *reinterpret_cast<const bf16x8*>(&Ws[bbase + nf * 512]);
        #pragma unroll
        for (int mf = 0; mf < 4; ++mf)
            #pragma unroll
            for (int nf = 0; nf < 4; ++nf)
                acc[mf][nf] = __builtin_amdgcn_mfma_f32_16x16x32_bf16(
                    a[mf], b[nf], acc[mf][nf], 0, 0, 0);
        __syncthreads();
    }

    // epilogue: C/D layout col = lane&15, row = (lane>>4)*4 + reg
    #pragma unroll
    for (int mf = 0; mf < 4; ++mf) {
        #pragma unroll
        for (int nf = 0; nf < 4; ++nf) {
            int r  = row0 + wr * 64 + mf * 16 + (lane >> 4) * 4;
            int cc = col0 + wc * 64 + nf * 16 + (lane & 15);
            if (cc < N) {
                f32x4 d = acc[mf][nf];
                #pragma unroll
                for (int j = 0; j < 4; ++j) {
                    C[(size_t)(r + j) * ldc + cc] = d[j];
                    if (OUT == 1)
                        Cbf[(size_t)(r + j) * ldc + cc] = (unsigned short)f2bf(d[j]);
                }
            }
        }
    }
}

// ---------------------------------------------------------------------------
// fp32 GEMM (dt_proj, K=48): C = A @ W^T (+bias/softplus)
// ---------------------------------------------------------------------------
template<int EPI>
__global__ __launch_bounds__(256) void gemm_tn(
    const float* __restrict__ A, int lda,
    const float* __restrict__ W, int ldw,
    float* __restrict__ C, int ldc,
    int M, int N, int K,
    const float* __restrict__ bias)
{
    __shared__ __align__(16) float As[16][132];
    __shared__ __align__(16) float Ws[16][132];
    int tid = threadIdx.x;
    int tx = tid & 15, ty = tid >> 4;
    int row0 = blockIdx.y * 128;
    int col0 = blockIdx.x * 128;
    float acc[8][8] = {};

    for (int k0 = 0; k0 < K; k0 += 16) {
        #pragma unroll
        for (int l = 0; l < 2; ++l) {
            int f4 = tid * 2 + l;
            int r = f4 >> 2;
            int kc = (f4 & 3) * 4;
            const float4 av = *reinterpret_cast<const float4*>(
                &A[(size_t)(row0 + r) * lda + k0 + kc]);
            As[kc + 0][r] = av.x; As[kc + 1][r] = av.y;
            As[kc + 2][r] = av.z; As[kc + 3][r] = av.w;
        }
        #pragma unroll
        for (int l = 0; l < 2; ++l) {
            int f4 = tid * 2 + l;
            int n = f4 >> 2;
            int kc = (f4 & 3) * 4;
            float4 wv = make_float4(0.f, 0.f, 0.f, 0.f);
            if (col0 + n < N)
                wv = *reinterpret_cast<const float4*>(
                    &W[(size_t)(col0 + n) * ldw + k0 + kc]);
            Ws[kc + 0][n] = wv.x; Ws[kc + 1][n] = wv.y;
            Ws[kc + 2][n] = wv.z; Ws[kc + 3][n] = wv.w;
        }
        __syncthreads();
        #pragma unroll
        for (int kk = 0; kk < 16; ++kk) {
            float a[8], w[8];
            const float4* ap = reinterpret_cast<const float4*>(&As[kk][ty * 8]);
            const float4* wp = reinterpret_cast<const float4*>(&Ws[kk][tx * 8]);
            float4 a0 = ap[0], a1 = ap[1];
            float4 w0 = wp[0], w1 = wp[1];
            a[0]=a0.x; a[1]=a0.y; a[2]=a0.z; a[3]=a0.w;
            a[4]=a1.x; a[5]=a1.y; a[6]=a1.z; a[7]=a1.w;
            w[0]=w0.x; w[1]=w0.y; w[2]=w0.z; w[3]=w0.w;
            w[4]=w1.x; w[5]=w1.y; w[6]=w1.z; w[7]=w1.w;
            #pragma unroll
            for (int i = 0; i < 8; ++i)
                #pragma unroll
                for (int j = 0; j < 8; ++j)
                    acc[i][j] += a[i] * w[j];
        }
        __syncthreads();
    }

    #pragma unroll
    for (int i = 0; i < 8; ++i) {
        int r = row0 + ty * 8 + i;
        #pragma unroll
        for (int j = 0; j < 8; ++j) {
            int c = col0 + tx * 8 + j;
            if (c < N) {
                float v = acc[i][j];
                if (EPI == 1) {
                    v += bias[c];
                    v = (v > 20.f) ? v : log1pf(__expf(v));
                }
                C[(size_t)r * ldc + c] = v;
            }
        }
    }
}

// ---------------------------------------------------------------------------
// Skinny split-K GEMM for x_proj (N=80).
// ---------------------------------------------------------------------------
__global__ __launch_bounds__(256) void gemm_skinny(
    const float* __restrict__ A, int lda,
    const float* __restrict__ W, int ldw,
    float* __restrict__ C, int ldc,
    int N, int K, int kchunks)
{
    __shared__ __align__(16) float As[16][68];
    __shared__ __align__(16) float Ws[16][84];
    int row0 = blockIdx.x * 64;
    int klen = K / kchunks;
    int kbeg = blockIdx.y * klen;
    int tid = threadIdx.x;
    int tx = tid & 15, ty = tid >> 4;
    float acc[4][5] = {};

    for (int k0 = kbeg; k0 < kbeg + klen; k0 += 16) {
        {
            int f4 = tid;
            int r = f4 >> 2; int kc = (f4 & 3) * 4;
            const float4 av = *reinterpret_cast<const float4*>(
                &A[(size_t)(row0 + r) * lda + k0 + kc]);
            As[kc + 0][r] = av.x; As[kc + 1][r] = av.y;
            As[kc + 2][r] = av.z; As[kc + 3][r] = av.w;
        }
        #pragma unroll
        for (int l = 0; l < 2; ++l) {
            int f4 = tid + l * 256;
            if (f4 < 320) {
                int n = f4 >> 2; int kc = (f4 & 3) * 4;
                float4 wv = make_float4(0.f, 0.f, 0.f, 0.f);
                if (n < N)
                    wv = *reinterpret_cast<const float4*>(
                        &W[(size_t)n * ldw + k0 + kc]);
                Ws[kc + 0][n] = wv.x; Ws[kc + 1][n] = wv.y;
                Ws[kc + 2][n] = wv.z; Ws[kc + 3][n] = wv.w;
            }
        }
        __syncthreads();
        #pragma unroll
        for (int kk = 0; kk < 16; ++kk) {
            float a[4], w[5];
            const float4* ap = reinterpret_cast<const float4*>(&As[kk][ty * 4]);
            float4 a0 = ap[0];
            a[0]=a0.x; a[1]=a0.y; a[2]=a0.z; a[3]=a0.w;
            #pragma unroll
            for (int j = 0; j < 5; ++j) w[j] = Ws[kk][tx * 5 + j];
            #pragma unroll
            for (int i = 0; i < 4; ++i)
                #pragma unroll
                for (int j = 0; j < 5; ++j)
                    acc[i][j] += a[i] * w[j];
        }
        __syncthreads();
    }
    #pragma unroll
    for (int i = 0; i < 4; ++i) {
        int r = row0 + ty * 4 + i;
        #pragma unroll
        for (int j = 0; j < 5; ++j) {
            int c = tx * 5 + j;
            if (c < N)
                atomicAdd(&C[(size_t)r * ldc + c], acc[i][j]);
        }
    }
}

// ---------------------------------------------------------------------------
// Depthwise causal conv(4) + bias + silu
// ---------------------------------------------------------------------------
__global__ __launch_bounds__(256) void conv_silu_k(
    const float* __restrict__ xz, const float* __restrict__ cw,
    const float* __restrict__ cb, float* __restrict__ xin)
{
    int i = blockIdx.x * 256 + threadIdx.x;   // over ROWS*DI
    if (i >= ROWS * DI) return;
    int row = i / DI;
    int c = i - row * DI;
    int t = row & (SL - 1);
    int b = row >> 10;
    float acc = cb[c];
    const float* base = xz + (size_t)(b * SL) * (2 * DI) + c;
    #pragma unroll
    for (int k = 0; k < DC; ++k) {
        int tt = t + k - (DC - 1);
        if (tt >= 0) acc += base[(size_t)tt * (2 * DI)] * cw[c * DC + k];
    }
    xin[i] = acc / (1.f + __expf(-acc));
}

// ---------------------------------------------------------------------------
// Chunked selective scan, 3 phases. CCH=32 chunks of CLEN=32.
// ---------------------------------------------------------------------------
__global__ __launch_bounds__(256) void scan_phase1(
    const float* __restrict__ dt,
    const float* __restrict__ dbl,
    const float* __restrict__ xin,
    const float* __restrict__ Alog,
    float* __restrict__ hend,
    float* __restrict__ eprod)
{
    int blk = blockIdx.x;
    int c = blk % CCH;
    int tmp = blk / CCH;
    int dblk = tmp % (DI / 16);
    int b = tmp / (DI / 16);
    int s = threadIdx.x & 15;
    int d = dblk * 16 + (threadIdx.x >> 4);
    float A = -__expf(Alog[d * DS + s]);
    float h = 0.f, P = 1.f;
    const int rowbase = b * SL + c * CLEN;
    #pragma unroll 4
    for (int t = 0; t < CLEN; ++t) {
        int r = rowbase + t;
        float dtv = dt[(size_t)r * DI + d];
        float xv  = xin[(size_t)r * DI + d];
        float Bv  = dbl[(size_t)r * 80 + 48 + s];
        float e = __expf(dtv * A);
        h = h * e + dtv * xv * Bv;
        P *= e;
    }
    size_t idx = ((size_t)(b * CCH + c) * DI + d) * DS + s;
    hend[idx]  = h;
    eprod[idx] = P;
}

__global__ __launch_bounds__(256) void scan_combine(
    const float* __restrict__ hend, const float* __restrict__ eprod,
    float* __restrict__ hinit)
{
    int i = blockIdx.x * 256 + threadIdx.x;     // over NB*DI*DS
    if (i >= NB * DI * DS) return;
    int b = i / (DI * DS);
    int ds_ = i - b * (DI * DS);
    float H = 0.f;
    #pragma unroll 8
    for (int c = 0; c < CCH; ++c) {
        size_t idx = (size_t)(b * CCH + c) * (DI * DS) + ds_;
        hinit[idx] = H;
        H = H * eprod[idx] + hend[idx];
    }
}

__global__ __launch_bounds__(256) void scan_phase3(
    const float* __restrict__ dt,
    const float* __restrict__ dbl,
    const float* __restrict__ xin,
    const float* __restrict__ xz,
    const float* __restrict__ Alog,
    const float* __restrict__ Dp,
    const float* __restrict__ hinit,
    unsigned short* __restrict__ ybf)
{
    int blk = blockIdx.x;
    int c = blk % CCH;
    int tmp = blk / CCH;
    int dblk = tmp % (DI / 16);
    int b = tmp / (DI / 16);
    int s = threadIdx.x & 15;
    int d = dblk * 16 + (threadIdx.x >> 4);
    float A = -__expf(Alog[d * DS + s]);
    float Dv = Dp[d];
    float h = hinit[((size_t)(b * CCH + c) * DI + d) * DS + s];
    const int rowbase = b * SL + c * CLEN;
    #pragma unroll 2
    for (int t = 0; t < CLEN; ++t) {
        int r = rowbase + t;
        float dtv = dt[(size_t)r * DI + d];
        float xv  = xin[(size_t)r * DI + d];
        float Bv  = dbl[(size_t)r * 80 + 48 + s];
        float Cv  = dbl[(size_t)r * 80 + 64 + s];
        float e = __expf(dtv * A);
        h = h * e + dtv * xv * Bv;
        float p = h * Cv;
        p += __shfl_xor(p, 1, 64);
        p += __shfl_xor(p, 2, 64);
        p += __shfl_xor(p, 4, 64);
        p += __shfl_xor(p, 8, 64);
        if (s == 0) {
            float z = xz[(size_t)r * (2 * DI) + DI + d];
            float yv = (p + xv * Dv) * (z / (1.f + __expf(-z)));
            ybf[(size_t)r * DI + d] = (unsigned short)f2bf(yv);
        }
    }
}

// ---------------------------------------------------------------------------
// LayerNorm over rows of 768, bf16 output
// ---------------------------------------------------------------------------
__global__ __launch_bounds__(256) void ln_k(
    const float* __restrict__ x, const float* __restrict__ w,
    const float* __restrict__ b, unsigned short* __restrict__ o)
{
    int row = blockIdx.x;
    int tid = threadIdx.x;
    const float* xr = x + (size_t)row * DM;
    float v0 = xr[tid], v1 = xr[tid + 256], v2 = xr[tid + 512];
    float s = v0 + v1 + v2;
    #pragma unroll
    for (int off = 1; off < 64; off <<= 1) s += __shfl_xor(s, off, 64);
    __shared__ float red[4];
    __shared__ float red2[4];
    int wid = tid >> 6, lane = tid & 63;
    if (lane == 0) red[wid] = s;
    __syncthreads();
    float mu = (red[0] + red[1] + red[2] + red[3]) * (1.f / 768.f);
    float d0 = v0 - mu, d1 = v1 - mu, d2 = v2 - mu;
    float q = d0 * d0 + d1 * d1 + d2 * d2;
    #pragma unroll
    for (int off = 1; off < 64; off <<= 1) q += __shfl_xor(q, off, 64);
    if (lane == 0) red2[wid] = q;
    __syncthreads();
    float var = (red2[0] + red2[1] + red2[2] + red2[3]) * (1.f / 768.f);
    float rs = rsqrtf(var + 1e-5f);
    o[(size_t)row * DM + tid]       = (unsigned short)f2bf(d0 * rs * w[tid]       + b[tid]);
    o[(size_t)row * DM + tid + 256] = (unsigned short)f2bf(d1 * rs * w[tid + 256] + b[tid + 256]);
    o[(size_t)row * DM + tid + 512] = (unsigned short)f2bf(d2 * rs * w[tid + 512] + b[tid + 512]);
}

// ---------------------------------------------------------------------------
extern "C" void kernel_launch(void* const* d_in, const int* in_sizes, int n_in,
                              void* d_out, int out_size, void* d_ws, size_t ws_size,
                              hipStream_t stream) {
    const int*   ids        = (const int*)d_in[0];
    const float* emb        = (const float*)d_in[1];
    const float* in_proj_w  = (const float*)d_in[2];
    const float* conv_w     = (const float*)d_in[3];
    const float* conv_b     = (const float*)d_in[4];
    const float* x_proj_w   = (const float*)d_in[5];
    const float* dt_proj_w  = (const float*)d_in[6];
    const float* dt_proj_b  = (const float*)d_in[7];
    const float* A_log      = (const float*)d_in[8];
    const float* D_param    = (const float*)d_in[9];
    const float* out_proj_w = (const float*)d_in[10];
    const float* norm_w     = (const float*)d_in[11];
    const float* norm_b     = (const float*)d_in[12];
    float* out = (float*)d_out;

    // ---- workspace layout (floats first, then bf16/ushort) ----
    char* base = (char*)d_ws;
    size_t off = 0;
    auto alloc_f = [&](size_t n) { float* p = (float*)(base + off); off += n * 4; return p; };
    auto alloc_u = [&](size_t n) { unsigned short* p = (unsigned short*)(base + off); off += n * 2; return p; };

    float* x     = alloc_f((size_t)ROWS * DM);
    float* xz    = alloc_f((size_t)ROWS * 2 * DI);
    float* xin   = alloc_f((size_t)ROWS * DI);
    float* dbl   = alloc_f((size_t)ROWS * 80);
    float* dt    = alloc_f((size_t)ROWS * DI);
    float* hend  = alloc_f((size_t)NB * CCH * DI * DS);
    float* eprod = alloc_f((size_t)NB * CCH * DI * DS);
    float* hinit = alloc_f((size_t)NB * CCH * DI * DS);
    unsigned short* xbf   = alloc_u((size_t)ROWS * DM);
    unsigned short* ybf   = alloc_u((size_t)ROWS * DI);
    unsigned short* xlnbf = alloc_u((size_t)ROWS * DM);
    unsigned short* inw_bf = alloc_u((size_t)NLAYER * 2 * DI * DM);
    unsigned short* ow_bf  = alloc_u((size_t)NLAYER * DM * DI);
    size_t off_noemb = off;
    unsigned short* emb_bf = alloc_u((size_t)VOCAB * DM);
    const bool emb_fits = (off <= ws_size);
    const bool layers_fit = (off_noemb <= ws_size);

    // ---- weight preconversion (once per call) ----
    if (layers_fit) {
        int n4a = NLAYER * 2 * DI * DM / 4;
        cvt_bf16_k<<<(n4a + 255) / 256, 256, 0, stream>>>(in_proj_w, inw_bf, n4a);
        int n4b = NLAYER * DM * DI / 4;
        cvt_bf16_k<<<(n4b + 255) / 256, 256, 0, stream>>>(out_proj_w, ow_bf, n4b);
    }
    if (emb_fits) {
        int n4e = VOCAB * DM / 4;
        cvt_bf16_k<<<(n4e + 255) / 256, 256, 0, stream>>>(emb, emb_bf, n4e);
    }

    embed_k<<<(ROWS * DM + 255) / 256, 256, 0, stream>>>(ids, emb, xbf);

    const int scan_grid = NB * (DI / 16) * CCH;      // 6144 blocks

    for (int i = 0; i < NLAYER; ++i) {
        const float* cw  = conv_w     + (size_t)i * DI * DC;
        const float* cb  = conv_b     + (size_t)i * DI;
        const float* xpw = x_proj_w   + (size_t)i * (DTR + 2 * DS) * DI;
        const float* dtw = dt_proj_w  + (size_t)i * DI * DTR;
        const float* dtb = dt_proj_b  + (size_t)i * DI;
        const float* Al  = A_log      + (size_t)i * DI * DS;
        const float* Dpar= D_param    + (size_t)i * DI;

        // in_proj: xz = xbf @ inw^T  (grid 24 cols x 16 rows = 384)
        if (layers_fit) {
            const unsigned short* inw = inw_bf + (size_t)i * 2 * DI * DM;
            gemm_bf16<true, 0><<<24 * 16, 256, 0, stream>>>(
                xbf, DM, inw, DM, xz, nullptr, 2 * DI, 16, 2 * DI, DM);
        } else {
            const float* inw = in_proj_w + (size_t)i * 2 * DI * DM;
            gemm_bf16<false, 0><<<24 * 16, 256, 0, stream>>>(
                xbf, DM, inw, DM, xz, nullptr, 2 * DI, 16, 2 * DI, DM);
        }
        conv_silu_k<<<(ROWS * DI) / 256, 256, 0, stream>>>(xz, cw, cb, xin);
        hipMemsetAsync(dbl, 0, (size_t)ROWS * 80 * sizeof(float), stream);
        gemm_skinny<<<dim3(32, 8), 256, 0, stream>>>(
            xin, DI, xpw, DI, dbl, 80, 80, DI, 8);
        gemm_tn<1><<<dim3(12, 16), 256, 0, stream>>>(
            dbl, 80, dtw, DTR, dt, DI, ROWS, DI, DTR, dtb);

        scan_phase1<<<scan_grid, 256, 0, stream>>>(dt, dbl, xin, Al, hend, eprod);
        scan_combine<<<(NB * DI * DS + 255) / 256, 256, 0, stream>>>(hend, eprod, hinit);
        scan_phase3<<<scan_grid, 256, 0, stream>>>(dt, dbl, xin, xz, Al, Dpar, hinit, ybf);

        // out_proj: x(fp32) + xbf(bf16) = ybf @ ow^T  (grid 6x16 = 96)
        if (layers_fit) {
            const unsigned short* ow = ow_bf + (size_t)i * DM * DI;
            gemm_bf16<true, 1><<<6 * 16, 256, 0, stream>>>(
                ybf, DI, ow, DI, x, xbf, DM, 16, DM, DI);
        } else {
            const float* ow = out_proj_w + (size_t)i * DM * DI;
            gemm_bf16<false, 1><<<6 * 16, 256, 0, stream>>>(
                ybf, DI, ow, DI, x, xbf, DM, 16, DM, DI);
        }
    }

    ln_k<<<ROWS, 256, 0, stream>>>(x, norm_w, norm_b, xlnbf);
    // logits: out = xlnbf @ emb^T  (grid 393 cols x 16 rows = 6288)
    if (emb_fits) {
        gemm_bf16<true, 0><<<393 * 16, 256, 0, stream>>>(
            xlnbf, DM, emb_bf, DM, out, nullptr, VOCAB, 16, VOCAB, DM);
    } else {
        gemm_bf16<false, 0><<<393 * 16, 256, 0, stream>>>(
            xlnbf, DM, emb, DM, out, nullptr, VOCAB, 16, VOCAB, DM);
    }
}

// Round 5
// 4444.205 us; speedup vs baseline: 3.8248x; 1.0467x over previous
//
#include <hip/hip_runtime.h>
#include <hip/hip_bf16.h>

#define DI 1536
#define DS 16
#define DC 4
#define DTR 48
#define NB 2
#define SL 1024
#define DM 768
#define NLAYER 12
#define VOCAB 50257
#define ROWS (NB*SL)   // 2048
#define CCH 32         // scan chunks
#define CLEN (SL/CCH)  // 32

typedef __attribute__((ext_vector_type(8))) short bf16x8;
typedef __attribute__((ext_vector_type(4))) short short4v;
typedef __attribute__((ext_vector_type(4))) float f32x4;

__device__ inline short f2bf(float f) {
    unsigned u = __builtin_bit_cast(unsigned, f);
    unsigned r = (u + 0x7fffu + ((u >> 16) & 1u)) >> 16;
    return (short)r;
}

__device__ __forceinline__ void gl_lds16(const void* g, void* l) {
    __builtin_amdgcn_global_load_lds(
        (const __attribute__((address_space(1))) unsigned int*)g,
        (__attribute__((address_space(3))) unsigned int*)l, 16, 0, 0);
}

// ---------------------------------------------------------------------------
// fp32 -> bf16 elementwise convert (n multiple of 4)
// ---------------------------------------------------------------------------
__global__ __launch_bounds__(256) void cvt_bf16_k(const float* __restrict__ src,
                                                  unsigned short* __restrict__ dst,
                                                  int n4) {
    int i = blockIdx.x * 256 + threadIdx.x;
    if (i >= n4) return;
    float4 v = *reinterpret_cast<const float4*>(src + (size_t)i * 4);
    short4v o;
    o[0] = f2bf(v.x); o[1] = f2bf(v.y); o[2] = f2bf(v.z); o[3] = f2bf(v.w);
    *reinterpret_cast<short4v*>(dst + (size_t)i * 4) = o;
}

// ---------------------------------------------------------------------------
// Embedding: xbf[b,s,:] = bf16(emb[ids[b,s]] * sqrt(768))
// ---------------------------------------------------------------------------
__global__ __launch_bounds__(256) void embed_k(const int* __restrict__ ids,
                                               const float* __restrict__ emb,
                                               unsigned short* __restrict__ xbf) {
    int i = blockIdx.x * 256 + threadIdx.x;      // over ROWS*DM
    if (i >= ROWS * DM) return;
    int row = i / DM;
    int c = i - row * DM;
    xbf[i] = (unsigned short)f2bf(emb[(size_t)ids[row] * DM + c] * 27.712812921102035f);
}

// ---------------------------------------------------------------------------
// bf16-MFMA GEMM: C(M,N) = A(M,K)bf16 @ W(N,K)^T.
// MT x 128 tile (MT=128 or 64), BK=32, 4 waves, mfma_f32_16x16x32_bf16.
// WBF: W already bf16 -> stage via global_load_lds (16B, linear LDS dest,
//      pre-swizzled global source; involution c^((r>>1)&3) both sides).
// else: W fp32 -> register staging + on-the-fly convert.
// Grid: 1D, col-major over row tiles + bijective XCD-chunk swizzle.
// OUT: 0 = fp32 store; 1 = fp32 + bf16 dual store.
// ---------------------------------------------------------------------------
template<int MT, bool WBF, int OUT>
__global__ __launch_bounds__(256) void gemm_bf16(
    const unsigned short* __restrict__ A, int lda,
    const void* __restrict__ Wv, int ldw,
    float* __restrict__ C, unsigned short* __restrict__ Cbf, int ldc,
    int GY, int N, int K)
{
    constexpr int ALD = MT / 64;          // A-staging passes (16B chunks/thread)
    constexpr int MFR = MT / 32;          // M fragments per wave
    __shared__ __align__(16) short As[MT * 32];
    __shared__ __align__(16) short Ws[128 * 32];
    const int tid  = threadIdx.x;
    const int lane = tid & 63;
    const int wid  = tid >> 6;
    const int wr   = wid >> 1, wc = wid & 1;

    // bijective XCD-chunked swizzle, then col-major decode
    const int nwg = gridDim.x;
    const int q = nwg >> 3, rm = nwg & 7;
    const int xcd = blockIdx.x & 7, idx = blockIdx.x >> 3;
    const int wg = (xcd < rm ? xcd * (q + 1) : rm * (q + 1) + (xcd - rm) * q) + idx;
    const int row0 = (wg % GY) * MT;
    const int col0 = (wg / GY) * 128;

    // ---- staging setup ----
    const unsigned short* gA[ALD];
    short* ldsA[ALD];
    int soffA[ALD];
    #pragma unroll
    for (int i = 0; i < ALD; ++i) {
        int cid = i * 256 + tid;
        int r = cid >> 2, c = cid & 3;
        if (WBF) {
            int cp = c ^ ((r >> 1) & 3);               // pre-swizzled source
            gA[i]   = A + (size_t)(row0 + r) * lda + cp * 8;
            ldsA[i] = &As[(i * 256 + wid * 64) * 8];   // wave-uniform base
        } else {
            int perm = c ^ ((r >> 1) & 3);
            soffA[i] = r * 32 + perm * 8;
            gA[i]    = A + (size_t)(row0 + r) * lda + c * 8;
        }
    }
    const unsigned short* gWb[2];
    const float* gWf[2];
    short* ldsW[2];
    int soffW[2];
    bool okW[2];
    #pragma unroll
    for (int i = 0; i < 2; ++i) {
        int cid = i * 256 + tid;
        int r = cid >> 2, c = cid & 3;
        if (WBF) {
            int cp = c ^ ((r >> 1) & 3);
            int rg = col0 + r; if (rg > N - 1) rg = N - 1;   // clamp (dup data, discarded)
            gWb[i]  = (const unsigned short*)Wv + (size_t)rg * ldw + cp * 8;
            ldsW[i] = &Ws[(i * 256 + wid * 64) * 8];
        } else {
            int perm = c ^ ((r >> 1) & 3);
            soffW[i] = r * 32 + perm * 8;
            gWf[i]   = (const float*)Wv + (size_t)(col0 + r) * ldw + c * 8;
            okW[i]   = (col0 + r) < N;
        }
    }

    // fragment read offsets (shorts); XOR term invariant under row+16
    const int arow = wr * (MT / 2) + (lane & 15);
    const int abase = arow * 32 + (((lane >> 4) ^ ((arow >> 1) & 3)) * 8);
    const int brow = wc * 64 + (lane & 15);
    const int bbase = brow * 32 + (((lane >> 4) ^ ((brow >> 1) & 3)) * 8);

    f32x4 acc[MFR][4] = {};

    for (int k0 = 0; k0 < K; k0 += 32) {
        if (WBF) {
            #pragma unroll
            for (int i = 0; i < ALD; ++i) { gl_lds16(gA[i], ldsA[i]); gA[i] += 32; }
            #pragma unroll
            for (int i = 0; i < 2; ++i)   { gl_lds16(gWb[i], ldsW[i]); gWb[i] += 32; }
        } else {
            #pragma unroll
            for (int i = 0; i < ALD; ++i) {
                bf16x8 av = *reinterpret_cast<const bf16x8*>(gA[i]);
                *reinterpret_cast<bf16x8*>(&As[soffA[i]]) = av;
                gA[i] += 32;
            }
            #pragma unroll
            for (int i = 0; i < 2; ++i) {
                bf16x8 wv = {};
                if (okW[i]) {
                    const float4* pw = reinterpret_cast<const float4*>(gWf[i]);
                    float4 w0 = pw[0], w1 = pw[1];
                    wv[0]=f2bf(w0.x); wv[1]=f2bf(w0.y); wv[2]=f2bf(w0.z); wv[3]=f2bf(w0.w);
                    wv[4]=f2bf(w1.x); wv[5]=f2bf(w1.y); wv[6]=f2bf(w1.z); wv[7]=f2bf(w1.w);
                }
                gWf[i] += 32;
                *reinterpret_cast<bf16x8*>(&Ws[soffW[i]]) = wv;
            }
        }
        __syncthreads();

        bf16x8 a[MFR], b[4];
        #pragma unroll
        for (int mf = 0; mf < MFR; ++mf)
            a[mf] = *reinterpret_cast<const bf16x8*>(&As[abase + mf * 512]);
        #pragma unroll
        for (int nf = 0; nf < 4; ++nf)
            b[nf] = *reinterpret_cast<const bf16x8*>(&Ws[bbase + nf * 512]);
        #pragma unroll
        for (int mf = 0; mf < MFR; ++mf)
            #pragma unroll
            for (int nf = 0; nf < 4; ++nf)
                acc[mf][nf] = __builtin_amdgcn_mfma_f32_16x16x32_bf16(
                    a[mf], b[nf], acc[mf][nf], 0, 0, 0);
        __syncthreads();
    }

    // epilogue: C/D layout col = lane&15, row = (lane>>4)*4 + reg
    #pragma unroll
    for (int mf = 0; mf < MFR; ++mf) {
        #pragma unroll
        for (int nf = 0; nf < 4; ++nf) {
            int r  = row0 + wr * (MT / 2) + mf * 16 + (lane >> 4) * 4;
            int cc = col0 + wc * 64 + nf * 16 + (lane & 15);
            if (cc < N) {
                f32x4 d = acc[mf][nf];
                #pragma unroll
                for (int j = 0; j < 4; ++j) {
                    C[(size_t)(r + j) * ldc + cc] = d[j];
                    if (OUT == 1)
                        Cbf[(size_t)(r + j) * ldc + cc] = (unsigned short)f2bf(d[j]);
                }
            }
        }
    }
}

// ---------------------------------------------------------------------------
// fp32 GEMM (dt_proj, K=48): C = A @ W^T (+bias/softplus)
// ---------------------------------------------------------------------------
template<int EPI>
__global__ __launch_bounds__(256) void gemm_tn(
    const float* __restrict__ A, int lda,
    const float* __restrict__ W, int ldw,
    float* __restrict__ C, int ldc,
    int M, int N, int K,
    const float* __restrict__ bias)
{
    __shared__ __align__(16) float As[16][132];
    __shared__ __align__(16) float Ws[16][132];
    int tid = threadIdx.x;
    int tx = tid & 15, ty = tid >> 4;
    int row0 = blockIdx.y * 128;
    int col0 = blockIdx.x * 128;
    float acc[8][8] = {};

    for (int k0 = 0; k0 < K; k0 += 16) {
        #pragma unroll
        for (int l = 0; l < 2; ++l) {
            int f4 = tid * 2 + l;
            int r = f4 >> 2;
            int kc = (f4 & 3) * 4;
            const float4 av = *reinterpret_cast<const float4*>(
                &A[(size_t)(row0 + r) * lda + k0 + kc]);
            As[kc + 0][r] = av.x; As[kc + 1][r] = av.y;
            As[kc + 2][r] = av.z; As[kc + 3][r] = av.w;
        }
        #pragma unroll
        for (int l = 0; l < 2; ++l) {
            int f4 = tid * 2 + l;
            int n = f4 >> 2;
            int kc = (f4 & 3) * 4;
            float4 wv = make_float4(0.f, 0.f, 0.f, 0.f);
            if (col0 + n < N)
                wv = *reinterpret_cast<const float4*>(
                    &W[(size_t)(col0 + n) * ldw + k0 + kc]);
            Ws[kc + 0][n] = wv.x; Ws[kc + 1][n] = wv.y;
            Ws[kc + 2][n] = wv.z; Ws[kc + 3][n] = wv.w;
        }
        __syncthreads();
        #pragma unroll
        for (int kk = 0; kk < 16; ++kk) {
            float a[8], w[8];
            const float4* ap = reinterpret_cast<const float4*>(&As[kk][ty * 8]);
            const float4* wp = reinterpret_cast<const float4*>(&Ws[kk][tx * 8]);
            float4 a0 = ap[0], a1 = ap[1];
            float4 w0 = wp[0], w1 = wp[1];
            a[0]=a0.x; a[1]=a0.y; a[2]=a0.z; a[3]=a0.w;
            a[4]=a1.x; a[5]=a1.y; a[6]=a1.z; a[7]=a1.w;
            w[0]=w0.x; w[1]=w0.y; w[2]=w0.z; w[3]=w0.w;
            w[4]=w1.x; w[5]=w1.y; w[6]=w1.z; w[7]=w1.w;
            #pragma unroll
            for (int i = 0; i < 8; ++i)
                #pragma unroll
                for (int j = 0; j < 8; ++j)
                    acc[i][j] += a[i] * w[j];
        }
        __syncthreads();
    }

    #pragma unroll
    for (int i = 0; i < 8; ++i) {
        int r = row0 + ty * 8 + i;
        #pragma unroll
        for (int j = 0; j < 8; ++j) {
            int c = col0 + tx * 8 + j;
            if (c < N) {
                float v = acc[i][j];
                if (EPI == 1) {
                    v += bias[c];
                    v = (v > 20.f) ? v : log1pf(__expf(v));
                }
                C[(size_t)r * ldc + c] = v;
            }
        }
    }
}

// ---------------------------------------------------------------------------
// Skinny split-K GEMM for x_proj (N=80).
// ---------------------------------------------------------------------------
__global__ __launch_bounds__(256) void gemm_skinny(
    const float* __restrict__ A, int lda,
    const float* __restrict__ W, int ldw,
    float* __restrict__ C, int ldc,
    int N, int K, int kchunks)
{
    __shared__ __align__(16) float As[16][68];
    __shared__ __align__(16) float Ws[16][84];
    int row0 = blockIdx.x * 64;
    int klen = K / kchunks;
    int kbeg = blockIdx.y * klen;
    int tid = threadIdx.x;
    int tx = tid & 15, ty = tid >> 4;
    float acc[4][5] = {};

    for (int k0 = kbeg; k0 < kbeg + klen; k0 += 16) {
        {
            int f4 = tid;
            int r = f4 >> 2; int kc = (f4 & 3) * 4;
            const float4 av = *reinterpret_cast<const float4*>(
                &A[(size_t)(row0 + r) * lda + k0 + kc]);
            As[kc + 0][r] = av.x; As[kc + 1][r] = av.y;
            As[kc + 2][r] = av.z; As[kc + 3][r] = av.w;
        }
        #pragma unroll
        for (int l = 0; l < 2; ++l) {
            int f4 = tid + l * 256;
            if (f4 < 320) {
                int n = f4 >> 2; int kc = (f4 & 3) * 4;
                float4 wv = make_float4(0.f, 0.f, 0.f, 0.f);
                if (n < N)
                    wv = *reinterpret_cast<const float4*>(
                        &W[(size_t)n * ldw + k0 + kc]);
                Ws[kc + 0][n] = wv.x; Ws[kc + 1][n] = wv.y;
                Ws[kc + 2][n] = wv.z; Ws[kc + 3][n] = wv.w;
            }
        }
        __syncthreads();
        #pragma unroll
        for (int kk = 0; kk < 16; ++kk) {
            float a[4], w[5];
            const float4* ap = reinterpret_cast<const float4*>(&As[kk][ty * 4]);
            float4 a0 = ap[0];
            a[0]=a0.x; a[1]=a0.y; a[2]=a0.z; a[3]=a0.w;
            #pragma unroll
            for (int j = 0; j < 5; ++j) w[j] = Ws[kk][tx * 5 + j];
            #pragma unroll
            for (int i = 0; i < 4; ++i)
                #pragma unroll
                for (int j = 0; j < 5; ++j)
                    acc[i][j] += a[i] * w[j];
        }
        __syncthreads();
    }
    #pragma unroll
    for (int i = 0; i < 4; ++i) {
        int r = row0 + ty * 4 + i;
        #pragma unroll
        for (int j = 0; j < 5; ++j) {
            int c = tx * 5 + j;
            if (c < N)
                atomicAdd(&C[(size_t)r * ldc + c], acc[i][j]);
        }
    }
}

// ---------------------------------------------------------------------------
// Depthwise causal conv(4) + bias + silu
// ---------------------------------------------------------------------------
__global__ __launch_bounds__(256) void conv_silu_k(
    const float* __restrict__ xz, const float* __restrict__ cw,
    const float* __restrict__ cb, float* __restrict__ xin)
{
    int i = blockIdx.x * 256 + threadIdx.x;   // over ROWS*DI
    if (i >= ROWS * DI) return;
    int row = i / DI;
    int c = i - row * DI;
    int t = row & (SL - 1);
    int b = row >> 10;
    float acc = cb[c];
    const float* base = xz + (size_t)(b * SL) * (2 * DI) + c;
    #pragma unroll
    for (int k = 0; k < DC; ++k) {
        int tt = t + k - (DC - 1);
        if (tt >= 0) acc += base[(size_t)tt * (2 * DI)] * cw[c * DC + k];
    }
    xin[i] = acc / (1.f + __expf(-acc));
}

// ---------------------------------------------------------------------------
// Chunked selective scan, 2 kernels. CCH=32 chunks of CLEN=32.
// phase1: per-chunk local scan from h=0 -> hend, eprod.
// phase3: per-chunk prefix-combine (reads hend/eprod of earlier chunks,
//         L2-resident) then re-scan producing gated y (bf16).
// ---------------------------------------------------------------------------
__global__ __launch_bounds__(256) void scan_phase1(
    const float* __restrict__ dt,
    const float* __restrict__ dbl,
    const float* __restrict__ xin,
    const float* __restrict__ Alog,
    float* __restrict__ hend,
    float* __restrict__ eprod)
{
    int blk = blockIdx.x;
    int c = blk % CCH;
    int tmp = blk / CCH;
    int dblk = tmp % (DI / 16);
    int b = tmp / (DI / 16);
    int s = threadIdx.x & 15;
    int d = dblk * 16 + (threadIdx.x >> 4);
    float A = -__expf(Alog[d * DS + s]);
    float h = 0.f, P = 1.f;
    const int rowbase = b * SL + c * CLEN;
    #pragma unroll 4
    for (int t = 0; t < CLEN; ++t) {
        int r = rowbase + t;
        float dtv = dt[(size_t)r * DI + d];
        float xv  = xin[(size_t)r * DI + d];
        float Bv  = dbl[(size_t)r * 80 + 48 + s];
        float e = __expf(dtv * A);
        h = h * e + dtv * xv * Bv;
        P *= e;
    }
    size_t idx = ((size_t)(b * CCH + c) * DI + d) * DS + s;
    hend[idx]  = h;
    eprod[idx] = P;
}

__global__ __launch_bounds__(256) void scan_phase3(
    const float* __restrict__ dt,
    const float* __restrict__ dbl,
    const float* __restrict__ xin,
    const float* __restrict__ xz,
    const float* __restrict__ Alog,
    const float* __restrict__ Dp,
    const float* __restrict__ hend,
    const float* __restrict__ eprod,
    unsigned short* __restrict__ ybf)
{
    int blk = blockIdx.x;
    int c = blk % CCH;
    int tmp = blk / CCH;
    int dblk = tmp % (DI / 16);
    int b = tmp / (DI / 16);
    int s = threadIdx.x & 15;
    int d = dblk * 16 + (threadIdx.x >> 4);
    float A = -__expf(Alog[d * DS + s]);
    float Dv = Dp[d];

    // prefix combine over earlier chunks (L2-hit loads)
    float h = 0.f;
    const size_t pbase = ((size_t)b * CCH * DI + d) * DS + s;
    for (int j = 0; j < c; ++j) {
        size_t idx = pbase + (size_t)j * (DI * DS);
        h = h * eprod[idx] + hend[idx];
    }

    const int rowbase = b * SL + c * CLEN;
    #pragma unroll 2
    for (int t = 0; t < CLEN; ++t) {
        int r = rowbase + t;
        float dtv = dt[(size_t)r * DI + d];
        float xv  = xin[(size_t)r * DI + d];
        float Bv  = dbl[(size_t)r * 80 + 48 + s];
        float Cv  = dbl[(size_t)r * 80 + 64 + s];
        float e = __expf(dtv * A);
        h = h * e + dtv * xv * Bv;
        float p = h * Cv;
        p += __shfl_xor(p, 1, 64);
        p += __shfl_xor(p, 2, 64);
        p += __shfl_xor(p, 4, 64);
        p += __shfl_xor(p, 8, 64);
        if (s == 0) {
            float z = xz[(size_t)r * (2 * DI) + DI + d];
            float yv = (p + xv * Dv) * (z / (1.f + __expf(-z)));
            ybf[(size_t)r * DI + d] = (unsigned short)f2bf(yv);
        }
    }
}

// ---------------------------------------------------------------------------
// LayerNorm over rows of 768, bf16 output
// ---------------------------------------------------------------------------
__global__ __launch_bounds__(256) void ln_k(
    const float* __restrict__ x, const float* __restrict__ w,
    const float* __restrict__ b, unsigned short* __restrict__ o)
{
    int row = blockIdx.x;
    int tid = threadIdx.x;
    const float* xr = x + (size_t)row * DM;
    float v0 = xr[tid], v1 = xr[tid + 256], v2 = xr[tid + 512];
    float s = v0 + v1 + v2;
    #pragma unroll
    for (int off = 1; off < 64; off <<= 1) s += __shfl_xor(s, off, 64);
    __shared__ float red[4];
    __shared__ float red2[4];
    int wid = tid >> 6, lane = tid & 63;
    if (lane == 0) red[wid] = s;
    __syncthreads();
    float mu = (red[0] + red[1] + red[2] + red[3]) * (1.f / 768.f);
    float d0 = v0 - mu, d1 = v1 - mu, d2 = v2 - mu;
    float q = d0 * d0 + d1 * d1 + d2 * d2;
    #pragma unroll
    for (int off = 1; off < 64; off <<= 1) q += __shfl_xor(q, off, 64);
    if (lane == 0) red2[wid] = q;
    __syncthreads();
    float var = (red2[0] + red2[1] + red2[2] + red2[3]) * (1.f / 768.f);
    float rs = rsqrtf(var + 1e-5f);
    o[(size_t)row * DM + tid]       = (unsigned short)f2bf(d0 * rs * w[tid]       + b[tid]);
    o[(size_t)row * DM + tid + 256] = (unsigned short)f2bf(d1 * rs * w[tid + 256] + b[tid + 256]);
    o[(size_t)row * DM + tid + 512] = (unsigned short)f2bf(d2 * rs * w[tid + 512] + b[tid + 512]);
}

// ---------------------------------------------------------------------------
extern "C" void kernel_launch(void* const* d_in, const int* in_sizes, int n_in,
                              void* d_out, int out_size, void* d_ws, size_t ws_size,
                              hipStream_t stream) {
    const int*   ids        = (const int*)d_in[0];
    const float* emb        = (const float*)d_in[1];
    const float* in_proj_w  = (const float*)d_in[2];
    const float* conv_w     = (const float*)d_in[3];
    const float* conv_b     = (const float*)d_in[4];
    const float* x_proj_w   = (const float*)d_in[5];
    const float* dt_proj_w  = (const float*)d_in[6];
    const float* dt_proj_b  = (const float*)d_in[7];
    const float* A_log      = (const float*)d_in[8];
    const float* D_param    = (const float*)d_in[9];
    const float* out_proj_w = (const float*)d_in[10];
    const float* norm_w     = (const float*)d_in[11];
    const float* norm_b     = (const float*)d_in[12];
    float* out = (float*)d_out;

    // ---- workspace layout ----
    char* base = (char*)d_ws;
    size_t off = 0;
    auto alloc_f = [&](size_t n) { float* p = (float*)(base + off); off += n * 4; return p; };
    auto alloc_u = [&](size_t n) { unsigned short* p = (unsigned short*)(base + off); off += n * 2; return p; };

    float* x     = alloc_f((size_t)ROWS * DM);
    float* xz    = alloc_f((size_t)ROWS * 2 * DI);
    float* xin   = alloc_f((size_t)ROWS * DI);
    float* dbl   = alloc_f((size_t)ROWS * 80);
    float* dt    = alloc_f((size_t)ROWS * DI);
    float* hend  = alloc_f((size_t)NB * CCH * DI * DS);
    float* eprod = alloc_f((size_t)NB * CCH * DI * DS);
    unsigned short* xbf   = alloc_u((size_t)ROWS * DM);
    unsigned short* ybf   = alloc_u((size_t)ROWS * DI);
    unsigned short* xlnbf = alloc_u((size_t)ROWS * DM);
    unsigned short* inw_bf = alloc_u((size_t)NLAYER * 2 * DI * DM);
    unsigned short* ow_bf  = alloc_u((size_t)NLAYER * DM * DI);
    size_t off_noemb = off;
    unsigned short* emb_bf = alloc_u((size_t)VOCAB * DM);
    const bool emb_fits = (off <= ws_size);
    const bool layers_fit = (off_noemb <= ws_size);

    // ---- weight preconversion (once per call) ----
    if (layers_fit) {
        int n4a = NLAYER * 2 * DI * DM / 4;
        cvt_bf16_k<<<(n4a + 255) / 256, 256, 0, stream>>>(in_proj_w, inw_bf, n4a);
        int n4b = NLAYER * DM * DI / 4;
        cvt_bf16_k<<<(n4b + 255) / 256, 256, 0, stream>>>(out_proj_w, ow_bf, n4b);
    }
    if (emb_fits) {
        int n4e = VOCAB * DM / 4;
        cvt_bf16_k<<<(n4e + 255) / 256, 256, 0, stream>>>(emb, emb_bf, n4e);
    }

    embed_k<<<(ROWS * DM + 255) / 256, 256, 0, stream>>>(ids, emb, xbf);

    const int scan_grid = NB * (DI / 16) * CCH;      // 6144 blocks

    for (int i = 0; i < NLAYER; ++i) {
        const float* cw  = conv_w     + (size_t)i * DI * DC;
        const float* cb  = conv_b     + (size_t)i * DI;
        const float* xpw = x_proj_w   + (size_t)i * (DTR + 2 * DS) * DI;
        const float* dtw = dt_proj_w  + (size_t)i * DI * DTR;
        const float* dtb = dt_proj_b  + (size_t)i * DI;
        const float* Al  = A_log      + (size_t)i * DI * DS;
        const float* Dpar= D_param    + (size_t)i * DI;

        // in_proj: xz = xbf @ inw^T  (128-tile, GY=16, 24 col tiles)
        if (layers_fit) {
            const unsigned short* inw = inw_bf + (size_t)i * 2 * DI * DM;
            gemm_bf16<128, true, 0><<<24 * 16, 256, 0, stream>>>(
                xbf, DM, inw, DM, xz, nullptr, 2 * DI, 16, 2 * DI, DM);
        } else {
            const float* inw = in_proj_w + (size_t)i * 2 * DI * DM;
            gemm_bf16<128, false, 0><<<24 * 16, 256, 0, stream>>>(
                xbf, DM, inw, DM, xz, nullptr, 2 * DI, 16, 2 * DI, DM);
        }
        conv_silu_k<<<(ROWS * DI) / 256, 256, 0, stream>>>(xz, cw, cb, xin);
        hipMemsetAsync(dbl, 0, (size_t)ROWS * 80 * sizeof(float), stream);
        gemm_skinny<<<dim3(32, 8), 256, 0, stream>>>(
            xin, DI, xpw, DI, dbl, 80, 80, DI, 8);
        gemm_tn<1><<<dim3(12, 16), 256, 0, stream>>>(
            dbl, 80, dtw, DTR, dt, DI, ROWS, DI, DTR, dtb);

        scan_phase1<<<scan_grid, 256, 0, stream>>>(dt, dbl, xin, Al, hend, eprod);
        scan_phase3<<<scan_grid, 256, 0, stream>>>(dt, dbl, xin, xz, Al, Dpar,
                                                   hend, eprod, ybf);

        // out_proj: x(fp32) + xbf(bf16) = ybf @ ow^T  (64-tile, GY=32, 6 col tiles)
        if (layers_fit) {
            const unsigned short* ow = ow_bf + (size_t)i * DM * DI;
            gemm_bf16<64, true, 1><<<6 * 32, 256, 0, stream>>>(
                ybf, DI, ow, DI, x, xbf, DM, 32, DM, DI);
        } else {
            const float* ow = out_proj_w + (size_t)i * DM * DI;
            gemm_bf16<64, false, 1><<<6 * 32, 256, 0, stream>>>(
                ybf, DI, ow, DI, x, xbf, DM, 32, DM, DI);
        }
    }

    ln_k<<<ROWS, 256, 0, stream>>>(x, norm_w, norm_b, xlnbf);
    // logits: out = xlnbf @ emb^T  (393 col tiles x GY=16)
    if (emb_fits) {
        gemm_bf16<128, true, 0><<<393 * 16, 256, 0, stream>>>(
            xlnbf, DM, emb_bf, DM, out, nullptr, VOCAB, 16, VOCAB, DM);
    } else {
        gemm_bf16<128, false, 0><<<393 * 16, 256, 0, stream>>>(
            xlnbf, DM, emb, DM, out, nullptr, VOCAB, 16, VOCAB, DM);
    }
}

// Round 6
// 4191.558 us; speedup vs baseline: 4.0553x; 1.0603x over previous
//
#include <hip/hip_runtime.h>
#include <hip/hip_bf16.h>

#define DI 1536
#define DS 16
#define DC 4
#define DTR 48
#define NB 2
#define SL 1024
#define DM 768
#define NLAYER 12
#define VOCAB 50257
#define ROWS (NB*SL)   // 2048
#define CCH 32         // scan chunks
#define CLEN (SL/CCH)  // 32
#define NBIG (DI+32)   // 1568: fused dt(1536) + B/C(32) outputs

typedef __attribute__((ext_vector_type(8))) short bf16x8;
typedef __attribute__((ext_vector_type(4))) short short4v;
typedef __attribute__((ext_vector_type(4))) float f32x4;

__device__ inline short f2bf(float f) {
    unsigned u = __builtin_bit_cast(unsigned, f);
    unsigned r = (u + 0x7fffu + ((u >> 16) & 1u)) >> 16;
    return (short)r;
}

__device__ __forceinline__ void gl_lds16(const void* g, void* l) {
    __builtin_amdgcn_global_load_lds(
        (const __attribute__((address_space(1))) unsigned int*)g,
        (__attribute__((address_space(3))) unsigned int*)l, 16, 0, 0);
}

// ---------------------------------------------------------------------------
// fp32 -> bf16 elementwise convert (n multiple of 4)
// ---------------------------------------------------------------------------
__global__ __launch_bounds__(256) void cvt_bf16_k(const float* __restrict__ src,
                                                  unsigned short* __restrict__ dst,
                                                  int n4) {
    int i = blockIdx.x * 256 + threadIdx.x;
    if (i >= n4) return;
    float4 v = *reinterpret_cast<const float4*>(src + (size_t)i * 4);
    short4v o;
    o[0] = f2bf(v.x); o[1] = f2bf(v.y); o[2] = f2bf(v.z); o[3] = f2bf(v.w);
    *reinterpret_cast<short4v*>(dst + (size_t)i * 4) = o;
}

// ---------------------------------------------------------------------------
// Wc precompute: wbig[l] rows 0..1535 = dtw @ xpw[:48]  (bf16),
//                rows 1536..1567 = xpw[48:80] (bf16).
// Grid dim3(12, 13, NLAYER), 256 threads.
// ---------------------------------------------------------------------------
__global__ __launch_bounds__(256) void wc_k(
    const float* __restrict__ dtw_all,   // (NL, DI, DTR)
    const float* __restrict__ xpw_all,   // (NL, 80, DI)
    unsigned short* __restrict__ wbig)   // (NL, NBIG, DI)
{
    int l = blockIdx.z;
    const float* dtw = dtw_all + (size_t)l * DI * DTR;
    const float* xpw = xpw_all + (size_t)l * 80 * DI;
    unsigned short* wb = wbig + (size_t)l * NBIG * DI;
    int tid = threadIdx.x;
    if (blockIdx.y == 12) {
        if (blockIdx.x == 0) {
            for (int idx = tid; idx < 32 * DI; idx += 256) {
                int rr = idx / DI, k = idx - rr * DI;
                wb[(size_t)(DI + rr) * DI + k] =
                    (unsigned short)f2bf(xpw[(size_t)(48 + rr) * DI + k]);
            }
        }
        return;
    }
    __shared__ float sd[128 * 48];
    __shared__ float sx[48 * 128];
    int d0 = blockIdx.y * 128, k0 = blockIdx.x * 128;
    for (int idx = tid; idx < 128 * 48; idx += 256) {
        int r = idx / 48, j = idx - r * 48;
        sd[idx] = dtw[(size_t)(d0 + r) * DTR + j];
    }
    for (int idx = tid; idx < 48 * 128; idx += 256) {
        int j = idx / 128, k = idx - j * 128;
        sx[idx] = xpw[(size_t)j * DI + k0 + k];
    }
    __syncthreads();
    int tx = tid & 15, ty = tid >> 4;
    float acc[8][8] = {};
    for (int j = 0; j < 48; ++j) {
        float a[8], w[8];
        #pragma unroll
        for (int i = 0; i < 8; ++i) a[i] = sd[(ty * 8 + i) * 48 + j];
        #pragma unroll
        for (int i = 0; i < 8; ++i) w[i] = sx[j * 128 + tx * 8 + i];
        #pragma unroll
        for (int i = 0; i < 8; ++i)
            #pragma unroll
            for (int jj = 0; jj < 8; ++jj)
                acc[i][jj] += a[i] * w[jj];
    }
    for (int i = 0; i < 8; ++i)
        for (int jj = 0; jj < 8; ++jj)
            wb[(size_t)(d0 + ty * 8 + i) * DI + k0 + tx * 8 + jj] =
                (unsigned short)f2bf(acc[i][jj]);
}

// ---------------------------------------------------------------------------
// Embedding: xbf[b,s,:] = bf16(emb[ids[b,s]] * sqrt(768))
// ---------------------------------------------------------------------------
__global__ __launch_bounds__(256) void embed_k(const int* __restrict__ ids,
                                               const float* __restrict__ emb,
                                               unsigned short* __restrict__ xbf) {
    int i = blockIdx.x * 256 + threadIdx.x;      // over ROWS*DM
    if (i >= ROWS * DM) return;
    int row = i / DM;
    int c = i - row * DM;
    xbf[i] = (unsigned short)f2bf(emb[(size_t)ids[row] * DM + c] * 27.712812921102035f);
}

// ---------------------------------------------------------------------------
// bf16-MFMA GEMM: C(M,N) = A(M,K)bf16 @ W(N,K)^T.
// MT x 128 tile, BK=32, 4 waves, mfma_f32_16x16x32_bf16.
// WBF: W bf16 -> global_load_lds staging (pre-swizzled source, linear dest).
// OUT: 0 = fp32 store (NT optional); 1 = fp32 + bf16 dual store;
//      3 = fused dt/BC epilogue: cc<DI -> softplus(v+bias[cc]) into C (ld DI),
//          cc>=DI -> aux[r*32 + cc-DI] (B/C columns).
// ---------------------------------------------------------------------------
template<int MT, bool WBF, int OUT, bool NT>
__global__ __launch_bounds__(256) void gemm_bf16(
    const unsigned short* __restrict__ A, int lda,
    const void* __restrict__ Wv, int ldw,
    float* __restrict__ C, unsigned short* __restrict__ Cbf, int ldc,
    int GY, int N, int K,
    const float* __restrict__ bias, float* __restrict__ aux)
{
    constexpr int ALD = MT / 64;
    constexpr int MFR = MT / 32;
    __shared__ __align__(16) short As[MT * 32];
    __shared__ __align__(16) short Ws[128 * 32];
    const int tid  = threadIdx.x;
    const int lane = tid & 63;
    const int wid  = tid >> 6;
    const int wr   = wid >> 1, wc = wid & 1;

    const int nwg = gridDim.x;
    const int q = nwg >> 3, rm = nwg & 7;
    const int xcd = blockIdx.x & 7, idx = blockIdx.x >> 3;
    const int wg = (xcd < rm ? xcd * (q + 1) : rm * (q + 1) + (xcd - rm) * q) + idx;
    const int row0 = (wg % GY) * MT;
    const int col0 = (wg / GY) * 128;

    const unsigned short* gA[ALD];
    short* ldsA[ALD];
    int soffA[ALD];
    #pragma unroll
    for (int i = 0; i < ALD; ++i) {
        int cid = i * 256 + tid;
        int r = cid >> 2, c = cid & 3;
        if (WBF) {
            int cp = c ^ ((r >> 1) & 3);
            gA[i]   = A + (size_t)(row0 + r) * lda + cp * 8;
            ldsA[i] = &As[(i * 256 + wid * 64) * 8];
        } else {
            int perm = c ^ ((r >> 1) & 3);
            soffA[i] = r * 32 + perm * 8;
            gA[i]    = A + (size_t)(row0 + r) * lda + c * 8;
        }
    }
    const unsigned short* gWb[2];
    const float* gWf[2];
    short* ldsW[2];
    int soffW[2];
    bool okW[2];
    #pragma unroll
    for (int i = 0; i < 2; ++i) {
        int cid = i * 256 + tid;
        int r = cid >> 2, c = cid & 3;
        if (WBF) {
            int cp = c ^ ((r >> 1) & 3);
            int rg = col0 + r; if (rg > N - 1) rg = N - 1;
            gWb[i]  = (const unsigned short*)Wv + (size_t)rg * ldw + cp * 8;
            ldsW[i] = &Ws[(i * 256 + wid * 64) * 8];
        } else {
            int perm = c ^ ((r >> 1) & 3);
            soffW[i] = r * 32 + perm * 8;
            gWf[i]   = (const float*)Wv + (size_t)(col0 + r) * ldw + c * 8;
            okW[i]   = (col0 + r) < N;
        }
    }

    const int arow = wr * (MT / 2) + (lane & 15);
    const int abase = arow * 32 + (((lane >> 4) ^ ((arow >> 1) & 3)) * 8);
    const int brow = wc * 64 + (lane & 15);
    const int bbase = brow * 32 + (((lane >> 4) ^ ((brow >> 1) & 3)) * 8);

    f32x4 acc[MFR][4] = {};

    for (int k0 = 0; k0 < K; k0 += 32) {
        if (WBF) {
            #pragma unroll
            for (int i = 0; i < ALD; ++i) { gl_lds16(gA[i], ldsA[i]); gA[i] += 32; }
            #pragma unroll
            for (int i = 0; i < 2; ++i)   { gl_lds16(gWb[i], ldsW[i]); gWb[i] += 32; }
        } else {
            #pragma unroll
            for (int i = 0; i < ALD; ++i) {
                bf16x8 av = *reinterpret_cast<const bf16x8*>(gA[i]);
                *reinterpret_cast<bf16x8*>(&As[soffA[i]]) = av;
                gA[i] += 32;
            }
            #pragma unroll
            for (int i = 0; i < 2; ++i) {
                bf16x8 wv = {};
                if (okW[i]) {
                    const float4* pw = reinterpret_cast<const float4*>(gWf[i]);
                    float4 w0 = pw[0], w1 = pw[1];
                    wv[0]=f2bf(w0.x); wv[1]=f2bf(w0.y); wv[2]=f2bf(w0.z); wv[3]=f2bf(w0.w);
                    wv[4]=f2bf(w1.x); wv[5]=f2bf(w1.y); wv[6]=f2bf(w1.z); wv[7]=f2bf(w1.w);
                }
                gWf[i] += 32;
                *reinterpret_cast<bf16x8*>(&Ws[soffW[i]]) = wv;
            }
        }
        __syncthreads();

        bf16x8 a[MFR], b[4];
        #pragma unroll
        for (int mf = 0; mf < MFR; ++mf)
            a[mf] = *reinterpret_cast<const bf16x8*>(&As[abase + mf * 512]);
        #pragma unroll
        for (int nf = 0; nf < 4; ++nf)
            b[nf] = *reinterpret_cast<const bf16x8*>(&Ws[bbase + nf * 512]);
        #pragma unroll
        for (int mf = 0; mf < MFR; ++mf)
            #pragma unroll
            for (int nf = 0; nf < 4; ++nf)
                acc[mf][nf] = __builtin_amdgcn_mfma_f32_16x16x32_bf16(
                    a[mf], b[nf], acc[mf][nf], 0, 0, 0);
        __syncthreads();
    }

    #pragma unroll
    for (int mf = 0; mf < MFR; ++mf) {
        #pragma unroll
        for (int nf = 0; nf < 4; ++nf) {
            int r  = row0 + wr * (MT / 2) + mf * 16 + (lane >> 4) * 4;
            int cc = col0 + wc * 64 + nf * 16 + (lane & 15);
            if (cc < N) {
                f32x4 d = acc[mf][nf];
                if (OUT == 3) {
                    if (cc < DI) {
                        float bv = bias[cc];
                        #pragma unroll
                        for (int j = 0; j < 4; ++j) {
                            float v = d[j] + bv;
                            v = (v > 20.f) ? v : log1pf(__expf(v));
                            C[(size_t)(r + j) * ldc + cc] = v;
                        }
                    } else {
                        #pragma unroll
                        for (int j = 0; j < 4; ++j)
                            aux[(size_t)(r + j) * 32 + (cc - DI)] = d[j];
                    }
                } else {
                    #pragma unroll
                    for (int j = 0; j < 4; ++j) {
                        if (NT)
                            __builtin_nontemporal_store(d[j], &C[(size_t)(r + j) * ldc + cc]);
                        else
                            C[(size_t)(r + j) * ldc + cc] = d[j];
                        if (OUT == 1)
                            Cbf[(size_t)(r + j) * ldc + cc] = (unsigned short)f2bf(d[j]);
                    }
                }
            }
        }
    }
}

// ---------------------------------------------------------------------------
// fp32 GEMM (legacy fallback, dt_proj): C = A @ W^T (+bias/softplus)
// ---------------------------------------------------------------------------
template<int EPI>
__global__ __launch_bounds__(256) void gemm_tn(
    const float* __restrict__ A, int lda,
    const float* __restrict__ W, int ldw,
    float* __restrict__ C, int ldc,
    int M, int N, int K,
    const float* __restrict__ bias)
{
    __shared__ __align__(16) float As[16][132];
    __shared__ __align__(16) float Ws[16][132];
    int tid = threadIdx.x;
    int tx = tid & 15, ty = tid >> 4;
    int row0 = blockIdx.y * 128;
    int col0 = blockIdx.x * 128;
    float acc[8][8] = {};

    for (int k0 = 0; k0 < K; k0 += 16) {
        #pragma unroll
        for (int l = 0; l < 2; ++l) {
            int f4 = tid * 2 + l;
            int r = f4 >> 2;
            int kc = (f4 & 3) * 4;
            const float4 av = *reinterpret_cast<const float4*>(
                &A[(size_t)(row0 + r) * lda + k0 + kc]);
            As[kc + 0][r] = av.x; As[kc + 1][r] = av.y;
            As[kc + 2][r] = av.z; As[kc + 3][r] = av.w;
        }
        #pragma unroll
        for (int l = 0; l < 2; ++l) {
            int f4 = tid * 2 + l;
            int n = f4 >> 2;
            int kc = (f4 & 3) * 4;
            float4 wv = make_float4(0.f, 0.f, 0.f, 0.f);
            if (col0 + n < N)
                wv = *reinterpret_cast<const float4*>(
                    &W[(size_t)(col0 + n) * ldw + k0 + kc]);
            Ws[kc + 0][n] = wv.x; Ws[kc + 1][n] = wv.y;
            Ws[kc + 2][n] = wv.z; Ws[kc + 3][n] = wv.w;
        }
        __syncthreads();
        #pragma unroll
        for (int kk = 0; kk < 16; ++kk) {
            float a[8], w[8];
            const float4* ap = reinterpret_cast<const float4*>(&As[kk][ty * 8]);
            const float4* wp = reinterpret_cast<const float4*>(&Ws[kk][tx * 8]);
            float4 a0 = ap[0], a1 = ap[1];
            float4 w0 = wp[0], w1 = wp[1];
            a[0]=a0.x; a[1]=a0.y; a[2]=a0.z; a[3]=a0.w;
            a[4]=a1.x; a[5]=a1.y; a[6]=a1.z; a[7]=a1.w;
            w[0]=w0.x; w[1]=w0.y; w[2]=w0.z; w[3]=w0.w;
            w[4]=w1.x; w[5]=w1.y; w[6]=w1.z; w[7]=w1.w;
            #pragma unroll
            for (int i = 0; i < 8; ++i)
                #pragma unroll
                for (int j = 0; j < 8; ++j)
                    acc[i][j] += a[i] * w[j];
        }
        __syncthreads();
    }

    #pragma unroll
    for (int i = 0; i < 8; ++i) {
        int r = row0 + ty * 8 + i;
        #pragma unroll
        for (int j = 0; j < 8; ++j) {
            int c = col0 + tx * 8 + j;
            if (c < N) {
                float v = acc[i][j];
                if (EPI == 1) {
                    v += bias[c];
                    v = (v > 20.f) ? v : log1pf(__expf(v));
                }
                C[(size_t)r * ldc + c] = v;
            }
        }
    }
}

// ---------------------------------------------------------------------------
// Skinny split-K GEMM (legacy fallback, x_proj N=80).
// ---------------------------------------------------------------------------
__global__ __launch_bounds__(256) void gemm_skinny(
    const float* __restrict__ A, int lda,
    const float* __restrict__ W, int ldw,
    float* __restrict__ C, int ldc,
    int N, int K, int kchunks)
{
    __shared__ __align__(16) float As[16][68];
    __shared__ __align__(16) float Ws[16][84];
    int row0 = blockIdx.x * 64;
    int klen = K / kchunks;
    int kbeg = blockIdx.y * klen;
    int tid = threadIdx.x;
    int tx = tid & 15, ty = tid >> 4;
    float acc[4][5] = {};

    for (int k0 = kbeg; k0 < kbeg + klen; k0 += 16) {
        {
            int f4 = tid;
            int r = f4 >> 2; int kc = (f4 & 3) * 4;
            const float4 av = *reinterpret_cast<const float4*>(
                &A[(size_t)(row0 + r) * lda + k0 + kc]);
            As[kc + 0][r] = av.x; As[kc + 1][r] = av.y;
            As[kc + 2][r] = av.z; As[kc + 3][r] = av.w;
        }
        #pragma unroll
        for (int l = 0; l < 2; ++l) {
            int f4 = tid + l * 256;
            if (f4 < 320) {
                int n = f4 >> 2; int kc = (f4 & 3) * 4;
                float4 wv = make_float4(0.f, 0.f, 0.f, 0.f);
                if (n < N)
                    wv = *reinterpret_cast<const float4*>(
                        &W[(size_t)n * ldw + k0 + kc]);
                Ws[kc + 0][n] = wv.x; Ws[kc + 1][n] = wv.y;
                Ws[kc + 2][n] = wv.z; Ws[kc + 3][n] = wv.w;
            }
        }
        __syncthreads();
        #pragma unroll
        for (int kk = 0; kk < 16; ++kk) {
            float a[4], w[5];
            const float4* ap = reinterpret_cast<const float4*>(&As[kk][ty * 4]);
            float4 a0 = ap[0];
            a[0]=a0.x; a[1]=a0.y; a[2]=a0.z; a[3]=a0.w;
            #pragma unroll
            for (int j = 0; j < 5; ++j) w[j] = Ws[kk][tx * 5 + j];
            #pragma unroll
            for (int i = 0; i < 4; ++i)
                #pragma unroll
                for (int j = 0; j < 5; ++j)
                    acc[i][j] += a[i] * w[j];
        }
        __syncthreads();
    }
    #pragma unroll
    for (int i = 0; i < 4; ++i) {
        int r = row0 + ty * 4 + i;
        #pragma unroll
        for (int j = 0; j < 5; ++j) {
            int c = tx * 5 + j;
            if (c < N)
                atomicAdd(&C[(size_t)r * ldc + c], acc[i][j]);
        }
    }
}

// ---------------------------------------------------------------------------
// Depthwise causal conv(4) + bias + silu; dual write fp32 + bf16
// ---------------------------------------------------------------------------
__global__ __launch_bounds__(256) void conv_silu_k(
    const float* __restrict__ xz, const float* __restrict__ cw,
    const float* __restrict__ cb, float* __restrict__ xinf,
    unsigned short* __restrict__ xinb)
{
    int i = blockIdx.x * 256 + threadIdx.x;   // over ROWS*DI
    if (i >= ROWS * DI) return;
    int row = i / DI;
    int c = i - row * DI;
    int t = row & (SL - 1);
    int b = row >> 10;
    float acc = cb[c];
    const float* base = xz + (size_t)(b * SL) * (2 * DI) + c;
    #pragma unroll
    for (int k = 0; k < DC; ++k) {
        int tt = t + k - (DC - 1);
        if (tt >= 0) acc += base[(size_t)tt * (2 * DI)] * cw[c * DC + k];
    }
    float v = acc / (1.f + __expf(-acc));
    xinf[i] = v;
    xinb[i] = (unsigned short)f2bf(v);
}

// ---------------------------------------------------------------------------
// Chunked selective scan, 2 kernels. CCH=32 chunks of CLEN=32.
// bc buffer: B = bc[r*bstride + boff + s], C = bc[r*bstride + boff + 16 + s].
// ---------------------------------------------------------------------------
__global__ __launch_bounds__(256) void scan_phase1(
    const float* __restrict__ dt,
    const float* __restrict__ bc, int bstride, int boff,
    const float* __restrict__ xin,
    const float* __restrict__ Alog,
    float* __restrict__ hend,
    float* __restrict__ eprod)
{
    int blk = blockIdx.x;
    int c = blk % CCH;
    int tmp = blk / CCH;
    int dblk = tmp % (DI / 16);
    int b = tmp / (DI / 16);
    int s = threadIdx.x & 15;
    int d = dblk * 16 + (threadIdx.x >> 4);
    float A = -__expf(Alog[d * DS + s]);
    float h = 0.f, P = 1.f;
    const int rowbase = b * SL + c * CLEN;
    #pragma unroll 4
    for (int t = 0; t < CLEN; ++t) {
        int r = rowbase + t;
        float dtv = dt[(size_t)r * DI + d];
        float xv  = xin[(size_t)r * DI + d];
        float Bv  = bc[(size_t)r * bstride + boff + s];
        float e = __expf(dtv * A);
        h = h * e + dtv * xv * Bv;
        P *= e;
    }
    size_t idx = ((size_t)(b * CCH + c) * DI + d) * DS + s;
    hend[idx]  = h;
    eprod[idx] = P;
}

__global__ __launch_bounds__(256) void scan_phase3(
    const float* __restrict__ dt,
    const float* __restrict__ bc, int bstride, int boff,
    const float* __restrict__ xin,
    const float* __restrict__ xz,
    const float* __restrict__ Alog,
    const float* __restrict__ Dp,
    const float* __restrict__ hend,
    const float* __restrict__ eprod,
    unsigned short* __restrict__ ybf)
{
    int blk = blockIdx.x;
    int c = blk % CCH;
    int tmp = blk / CCH;
    int dblk = tmp % (DI / 16);
    int b = tmp / (DI / 16);
    int s = threadIdx.x & 15;
    int d = dblk * 16 + (threadIdx.x >> 4);
    float A = -__expf(Alog[d * DS + s]);
    float Dv = Dp[d];

    float h = 0.f;
    const size_t pbase = ((size_t)b * CCH * DI + d) * DS + s;
    for (int j = 0; j < c; ++j) {
        size_t idx = pbase + (size_t)j * (DI * DS);
        h = h * eprod[idx] + hend[idx];
    }

    const int rowbase = b * SL + c * CLEN;
    #pragma unroll 2
    for (int t = 0; t < CLEN; ++t) {
        int r = rowbase + t;
        float dtv = dt[(size_t)r * DI + d];
        float xv  = xin[(size_t)r * DI + d];
        float Bv  = bc[(size_t)r * bstride + boff + s];
        float Cv  = bc[(size_t)r * bstride + boff + 16 + s];
        float e = __expf(dtv * A);
        h = h * e + dtv * xv * Bv;
        float p = h * Cv;
        p += __shfl_xor(p, 1, 64);
        p += __shfl_xor(p, 2, 64);
        p += __shfl_xor(p, 4, 64);
        p += __shfl_xor(p, 8, 64);
        if (s == 0) {
            float z = xz[(size_t)r * (2 * DI) + DI + d];
            float yv = (p + xv * Dv) * (z / (1.f + __expf(-z)));
            ybf[(size_t)r * DI + d] = (unsigned short)f2bf(yv);
        }
    }
}

// ---------------------------------------------------------------------------
// LayerNorm over rows of 768, bf16 output
// ---------------------------------------------------------------------------
__global__ __launch_bounds__(256) void ln_k(
    const float* __restrict__ x, const float* __restrict__ w,
    const float* __restrict__ b, unsigned short* __restrict__ o)
{
    int row = blockIdx.x;
    int tid = threadIdx.x;
    const float* xr = x + (size_t)row * DM;
    float v0 = xr[tid], v1 = xr[tid + 256], v2 = xr[tid + 512];
    float s = v0 + v1 + v2;
    #pragma unroll
    for (int off = 1; off < 64; off <<= 1) s += __shfl_xor(s, off, 64);
    __shared__ float red[4];
    __shared__ float red2[4];
    int wid = tid >> 6, lane = tid & 63;
    if (lane == 0) red[wid] = s;
    __syncthreads();
    float mu = (red[0] + red[1] + red[2] + red[3]) * (1.f / 768.f);
    float d0 = v0 - mu, d1 = v1 - mu, d2 = v2 - mu;
    float q = d0 * d0 + d1 * d1 + d2 * d2;
    #pragma unroll
    for (int off = 1; off < 64; off <<= 1) q += __shfl_xor(q, off, 64);
    if (lane == 0) red2[wid] = q;
    __syncthreads();
    float var = (red2[0] + red2[1] + red2[2] + red2[3]) * (1.f / 768.f);
    float rs = rsqrtf(var + 1e-5f);
    o[(size_t)row * DM + tid]       = (unsigned short)f2bf(d0 * rs * w[tid]       + b[tid]);
    o[(size_t)row * DM + tid + 256] = (unsigned short)f2bf(d1 * rs * w[tid + 256] + b[tid + 256]);
    o[(size_t)row * DM + tid + 512] = (unsigned short)f2bf(d2 * rs * w[tid + 512] + b[tid + 512]);
}

// ---------------------------------------------------------------------------
extern "C" void kernel_launch(void* const* d_in, const int* in_sizes, int n_in,
                              void* d_out, int out_size, void* d_ws, size_t ws_size,
                              hipStream_t stream) {
    const int*   ids        = (const int*)d_in[0];
    const float* emb        = (const float*)d_in[1];
    const float* in_proj_w  = (const float*)d_in[2];
    const float* conv_w     = (const float*)d_in[3];
    const float* conv_b     = (const float*)d_in[4];
    const float* x_proj_w   = (const float*)d_in[5];
    const float* dt_proj_w  = (const float*)d_in[6];
    const float* dt_proj_b  = (const float*)d_in[7];
    const float* A_log      = (const float*)d_in[8];
    const float* D_param    = (const float*)d_in[9];
    const float* out_proj_w = (const float*)d_in[10];
    const float* norm_w     = (const float*)d_in[11];
    const float* norm_b     = (const float*)d_in[12];
    float* out = (float*)d_out;

    // ---- workspace layout ----
    char* base = (char*)d_ws;
    size_t off = 0;
    auto alloc_f = [&](size_t n) { float* p = (float*)(base + off); off += n * 4; return p; };
    auto alloc_u = [&](size_t n) { unsigned short* p = (unsigned short*)(base + off); off += n * 2; return p; };

    float* x     = alloc_f((size_t)ROWS * DM);
    float* xz    = alloc_f((size_t)ROWS * 2 * DI);
    float* xinf  = alloc_f((size_t)ROWS * DI);
    float* dbl   = alloc_f((size_t)ROWS * 80);    // legacy fallback
    float* bc    = alloc_f((size_t)ROWS * 32);
    float* dt    = alloc_f((size_t)ROWS * DI);
    float* hend  = alloc_f((size_t)NB * CCH * DI * DS);
    float* eprod = alloc_f((size_t)NB * CCH * DI * DS);
    unsigned short* xbf   = alloc_u((size_t)ROWS * DM);
    unsigned short* ybf   = alloc_u((size_t)ROWS * DI);
    unsigned short* xinb  = alloc_u((size_t)ROWS * DI);
    unsigned short* xlnbf = alloc_u((size_t)ROWS * DM);
    unsigned short* inw_bf = alloc_u((size_t)NLAYER * 2 * DI * DM);
    unsigned short* ow_bf  = alloc_u((size_t)NLAYER * DM * DI);
    size_t off_layers = off;
    unsigned short* wbig  = alloc_u((size_t)NLAYER * NBIG * DI);
    size_t off_wbig = off;
    unsigned short* emb_bf = alloc_u((size_t)VOCAB * DM);
    const bool layers_fit = (off_layers <= ws_size);
    const bool wbig_fits  = (off_wbig <= ws_size);
    const bool emb_fits   = (off <= ws_size);

    // ---- weight preconversion (once per call) ----
    if (layers_fit) {
        int n4a = NLAYER * 2 * DI * DM / 4;
        cvt_bf16_k<<<(n4a + 255) / 256, 256, 0, stream>>>(in_proj_w, inw_bf, n4a);
        int n4b = NLAYER * DM * DI / 4;
        cvt_bf16_k<<<(n4b + 255) / 256, 256, 0, stream>>>(out_proj_w, ow_bf, n4b);
    }
    if (wbig_fits)
        wc_k<<<dim3(12, 13, NLAYER), 256, 0, stream>>>(dt_proj_w, x_proj_w, wbig);
    if (emb_fits) {
        int n4e = VOCAB * DM / 4;
        cvt_bf16_k<<<(n4e + 255) / 256, 256, 0, stream>>>(emb, emb_bf, n4e);
    }

    embed_k<<<(ROWS * DM + 255) / 256, 256, 0, stream>>>(ids, emb, xbf);

    const int scan_grid = NB * (DI / 16) * CCH;      // 6144 blocks

    for (int i = 0; i < NLAYER; ++i) {
        const float* cw  = conv_w     + (size_t)i * DI * DC;
        const float* cb  = conv_b     + (size_t)i * DI;
        const float* xpw = x_proj_w   + (size_t)i * (DTR + 2 * DS) * DI;
        const float* dtw = dt_proj_w  + (size_t)i * DI * DTR;
        const float* dtb = dt_proj_b  + (size_t)i * DI;
        const float* Al  = A_log      + (size_t)i * DI * DS;
        const float* Dpar= D_param    + (size_t)i * DI;

        // in_proj: xz = xbf @ inw^T
        if (layers_fit) {
            const unsigned short* inw = inw_bf + (size_t)i * 2 * DI * DM;
            gemm_bf16<128, true, 0, false><<<24 * 16, 256, 0, stream>>>(
                xbf, DM, inw, DM, xz, nullptr, 2 * DI, 16, 2 * DI, DM, nullptr, nullptr);
        } else {
            const float* inw = in_proj_w + (size_t)i * 2 * DI * DM;
            gemm_bf16<128, false, 0, false><<<24 * 16, 256, 0, stream>>>(
                xbf, DM, inw, DM, xz, nullptr, 2 * DI, 16, 2 * DI, DM, nullptr, nullptr);
        }
        conv_silu_k<<<(ROWS * DI) / 256, 256, 0, stream>>>(xz, cw, cb, xinf, xinb);

        if (wbig_fits) {
            // fused dt + B/C: [dt | bc] = xinb @ wbig[i]^T  (N=1568, K=1536)
            const unsigned short* wb = wbig + (size_t)i * NBIG * DI;
            gemm_bf16<128, true, 3, false><<<13 * 16, 256, 0, stream>>>(
                xinb, DI, wb, DI, dt, nullptr, DI, 16, NBIG, DI, dtb, bc);
            scan_phase1<<<scan_grid, 256, 0, stream>>>(dt, bc, 32, 0, xinf, Al, hend, eprod);
            scan_phase3<<<scan_grid, 256, 0, stream>>>(dt, bc, 32, 0, xinf, xz, Al, Dpar,
                                                       hend, eprod, ybf);
        } else {
            hipMemsetAsync(dbl, 0, (size_t)ROWS * 80 * sizeof(float), stream);
            gemm_skinny<<<dim3(32, 8), 256, 0, stream>>>(
                xinf, DI, xpw, DI, dbl, 80, 80, DI, 8);
            gemm_tn<1><<<dim3(12, 16), 256, 0, stream>>>(
                dbl, 80, dtw, DTR, dt, DI, ROWS, DI, DTR, dtb);
            scan_phase1<<<scan_grid, 256, 0, stream>>>(dt, dbl, 80, 48, xinf, Al, hend, eprod);
            scan_phase3<<<scan_grid, 256, 0, stream>>>(dt, dbl, 80, 48, xinf, xz, Al, Dpar,
                                                       hend, eprod, ybf);
        }

        // out_proj: x(fp32) + xbf(bf16) = ybf @ ow^T
        if (layers_fit) {
            const unsigned short* ow = ow_bf + (size_t)i * DM * DI;
            gemm_bf16<64, true, 1, false><<<6 * 32, 256, 0, stream>>>(
                ybf, DI, ow, DI, x, xbf, DM, 32, DM, DI, nullptr, nullptr);
        } else {
            const float* ow = out_proj_w + (size_t)i * DM * DI;
            gemm_bf16<64, false, 1, false><<<6 * 32, 256, 0, stream>>>(
                ybf, DI, ow, DI, x, xbf, DM, 32, DM, DI, nullptr, nullptr);
        }
    }

    ln_k<<<ROWS, 256, 0, stream>>>(x, norm_w, norm_b, xlnbf);
    // logits: out = xlnbf @ emb^T  (NT stores keep 412MB of C out of L2)
    if (emb_fits) {
        gemm_bf16<128, true, 0, true><<<393 * 16, 256, 0, stream>>>(
            xlnbf, DM, emb_bf, DM, out, nullptr, VOCAB, 16, VOCAB, DM, nullptr, nullptr);
    } else {
        gemm_bf16<128, false, 0, true><<<393 * 16, 256, 0, stream>>>(
            xlnbf, DM, emb, DM, out, nullptr, VOCAB, 16, VOCAB, DM, nullptr, nullptr);
    }
}

// Round 7
// 3993.377 us; speedup vs baseline: 4.2566x; 1.0496x over previous
//
#include <hip/hip_runtime.h>
#include <hip/hip_bf16.h>

#define DI 1536
#define DS 16
#define DC 4
#define DTR 48
#define NB 2
#define SL 1024
#define DM 768
#define NLAYER 12
#define VOCAB 50257
#define ROWS (NB*SL)   // 2048
#define CCH 32         // scan chunks
#define CLEN (SL/CCH)  // 32
#define NBIG (DI+32)   // 1568: fused dt(1536) + B/C(32) outputs

typedef __attribute__((ext_vector_type(8))) short bf16x8;
typedef __attribute__((ext_vector_type(4))) short short4v;
typedef __attribute__((ext_vector_type(4))) float f32x4;

__device__ inline short f2bf(float f) {
    unsigned u = __builtin_bit_cast(unsigned, f);
    unsigned r = (u + 0x7fffu + ((u >> 16) & 1u)) >> 16;
    return (short)r;
}

__device__ __forceinline__ void gl_lds16(const void* g, void* l) {
    __builtin_amdgcn_global_load_lds(
        (const __attribute__((address_space(1))) unsigned int*)g,
        (__attribute__((address_space(3))) unsigned int*)l, 16, 0, 0);
}

// ---------------------------------------------------------------------------
// fp32 -> bf16 elementwise convert (n multiple of 4)
// ---------------------------------------------------------------------------
__global__ __launch_bounds__(256) void cvt_bf16_k(const float* __restrict__ src,
                                                  unsigned short* __restrict__ dst,
                                                  int n4) {
    int i = blockIdx.x * 256 + threadIdx.x;
    if (i >= n4) return;
    float4 v = *reinterpret_cast<const float4*>(src + (size_t)i * 4);
    short4v o;
    o[0] = f2bf(v.x); o[1] = f2bf(v.y); o[2] = f2bf(v.z); o[3] = f2bf(v.w);
    *reinterpret_cast<short4v*>(dst + (size_t)i * 4) = o;
}

// ---------------------------------------------------------------------------
// Wc precompute: wbig[l] rows 0..1535 = dtw @ xpw[:48]  (bf16),
//                rows 1536..1567 = xpw[48:80] (bf16).
// ---------------------------------------------------------------------------
__global__ __launch_bounds__(256) void wc_k(
    const float* __restrict__ dtw_all,   // (NL, DI, DTR)
    const float* __restrict__ xpw_all,   // (NL, 80, DI)
    unsigned short* __restrict__ wbig)   // (NL, NBIG, DI)
{
    int l = blockIdx.z;
    const float* dtw = dtw_all + (size_t)l * DI * DTR;
    const float* xpw = xpw_all + (size_t)l * 80 * DI;
    unsigned short* wb = wbig + (size_t)l * NBIG * DI;
    int tid = threadIdx.x;
    if (blockIdx.y == 12) {
        if (blockIdx.x == 0) {
            for (int idx = tid; idx < 32 * DI; idx += 256) {
                int rr = idx / DI, k = idx - rr * DI;
                wb[(size_t)(DI + rr) * DI + k] =
                    (unsigned short)f2bf(xpw[(size_t)(48 + rr) * DI + k]);
            }
        }
        return;
    }
    __shared__ float sd[128 * 48];
    __shared__ float sx[48 * 128];
    int d0 = blockIdx.y * 128, k0 = blockIdx.x * 128;
    for (int idx = tid; idx < 128 * 48; idx += 256) {
        int r = idx / 48, j = idx - r * 48;
        sd[idx] = dtw[(size_t)(d0 + r) * DTR + j];
    }
    for (int idx = tid; idx < 48 * 128; idx += 256) {
        int j = idx / 128, k = idx - j * 128;
        sx[idx] = xpw[(size_t)j * DI + k0 + k];
    }
    __syncthreads();
    int tx = tid & 15, ty = tid >> 4;
    float acc[8][8] = {};
    for (int j = 0; j < 48; ++j) {
        float a[8], w[8];
        #pragma unroll
        for (int i = 0; i < 8; ++i) a[i] = sd[(ty * 8 + i) * 48 + j];
        #pragma unroll
        for (int i = 0; i < 8; ++i) w[i] = sx[j * 128 + tx * 8 + i];
        #pragma unroll
        for (int i = 0; i < 8; ++i)
            #pragma unroll
            for (int jj = 0; jj < 8; ++jj)
                acc[i][jj] += a[i] * w[jj];
    }
    for (int i = 0; i < 8; ++i)
        for (int jj = 0; jj < 8; ++jj)
            wb[(size_t)(d0 + ty * 8 + i) * DI + k0 + tx * 8 + jj] =
                (unsigned short)f2bf(acc[i][jj]);
}

// ---------------------------------------------------------------------------
// Embedding: xbf[b,s,:] = bf16(emb[ids[b,s]] * sqrt(768))
// ---------------------------------------------------------------------------
__global__ __launch_bounds__(256) void embed_k(const int* __restrict__ ids,
                                               const float* __restrict__ emb,
                                               unsigned short* __restrict__ xbf) {
    int i = blockIdx.x * 256 + threadIdx.x;      // over ROWS*DM
    if (i >= ROWS * DM) return;
    int row = i / DM;
    int c = i - row * DM;
    xbf[i] = (unsigned short)f2bf(emb[(size_t)ids[row] * DM + c] * 27.712812921102035f);
}

// ---------------------------------------------------------------------------
// bf16-MFMA GEMM: C(M,N) = A(M,K)bf16 @ W(N,K)^T.   BK=64 (K%64==0).
// MT x 128 tile, 4 waves, mfma_f32_16x16x32_bf16, 2 k-subs per barrier pair.
// LDS layout [rows][64] bf16 with chunk-XOR swizzle phys = c ^ (r&7)
// (involution; applied to gl_lds SOURCE and ds_read side -> conflict-free).
// WBF: W bf16 -> global_load_lds; else W fp32 reg-staged + converted.
// OUT: 0 = fp32 store (NT -> LDS-transposed full-line NT epilogue);
//      1 = fp32 + bf16 dual store; 3 = fused dt softplus / BC split.
// ---------------------------------------------------------------------------
template<int MT, bool WBF, int OUT, bool NT>
__global__ __launch_bounds__(256) void gemm_bf16(
    const unsigned short* __restrict__ A, int lda,
    const void* __restrict__ Wv, int ldw,
    float* __restrict__ C, unsigned short* __restrict__ Cbf, int ldc,
    int GY, int N, int K,
    const float* __restrict__ bias, float* __restrict__ aux)
{
    constexpr int MFR = MT / 32;          // M fragments per wave
    constexpr int AC  = MT / 32;          // A staging chunks per thread
    __shared__ __align__(16) char smem[MT * 64 * 2 + 128 * 64 * 2];
    short* As = (short*)smem;
    short* Ws = (short*)(smem + MT * 64 * 2);

    const int tid  = threadIdx.x;
    const int lane = tid & 63;
    const int wid  = tid >> 6;
    const int wr   = wid >> 1, wc = wid & 1;

    // bijective XCD-chunked swizzle, then col-major decode
    const int nwg = gridDim.x;
    const int q = nwg >> 3, rm = nwg & 7;
    const int xcd = blockIdx.x & 7, bidx = blockIdx.x >> 3;
    const int wg = (xcd < rm ? xcd * (q + 1) : rm * (q + 1) + (xcd - rm) * q) + bidx;
    const int row0 = (wg % GY) * MT;
    const int col0 = (wg / GY) * 128;

    // ---- staging setup ----
    const unsigned short* gA[AC];
    const unsigned short* gWb[4];
    const float* gWf[4];
    int soffA[AC], soffW[4];
    #pragma unroll
    for (int i = 0; i < AC; ++i) {
        int cid = i * 256 + tid;
        int r = cid >> 3, c = cid & 7;
        if (WBF) {
            gA[i] = A + (size_t)(row0 + r) * lda + ((c ^ (r & 7)) * 8);
        } else {
            gA[i]    = A + (size_t)(row0 + r) * lda + c * 8;
            soffA[i] = r * 64 + ((c ^ (r & 7)) * 8);
        }
    }
    #pragma unroll
    for (int i = 0; i < 4; ++i) {
        int cid = i * 256 + tid;
        int r = cid >> 3, c = cid & 7;
        int rg = col0 + r; if (rg > N - 1) rg = N - 1;   // clamp: dup data, store-guarded
        if (WBF) {
            gWb[i] = (const unsigned short*)Wv + (size_t)rg * ldw + ((c ^ (r & 7)) * 8);
        } else {
            gWf[i]   = (const float*)Wv + (size_t)rg * ldw + c * 8;
            soffW[i] = r * 64 + ((c ^ (r & 7)) * 8);
        }
    }

    const int arow = wr * (MT / 2) + (lane & 15);
    const int brow = wc * 64 + (lane & 15);
    const int lx = lane & 7;       // = row&7 for both frag rows
    const int hi = lane >> 4;      // 0..3

    f32x4 acc[MFR][4] = {};

    for (int k0 = 0; k0 < K; k0 += 64) {
        if (WBF) {
            #pragma unroll
            for (int i = 0; i < AC; ++i) {
                gl_lds16(gA[i], &As[(size_t)(i * 256 + wid * 64) * 8]);
                gA[i] += 64;
            }
            #pragma unroll
            for (int i = 0; i < 4; ++i) {
                gl_lds16(gWb[i], &Ws[(size_t)(i * 256 + wid * 64) * 8]);
                gWb[i] += 64;
            }
        } else {
            #pragma unroll
            for (int i = 0; i < AC; ++i) {
                bf16x8 av = *reinterpret_cast<const bf16x8*>(gA[i]);
                *reinterpret_cast<bf16x8*>(&As[soffA[i]]) = av;
                gA[i] += 64;
            }
            #pragma unroll
            for (int i = 0; i < 4; ++i) {
                const float4* pw = reinterpret_cast<const float4*>(gWf[i]);
                float4 w0 = pw[0], w1 = pw[1];
                bf16x8 wv;
                wv[0]=f2bf(w0.x); wv[1]=f2bf(w0.y); wv[2]=f2bf(w0.z); wv[3]=f2bf(w0.w);
                wv[4]=f2bf(w1.x); wv[5]=f2bf(w1.y); wv[6]=f2bf(w1.z); wv[7]=f2bf(w1.w);
                *reinterpret_cast<bf16x8*>(&Ws[soffW[i]]) = wv;
                gWf[i] += 64;
            }
        }
        __syncthreads();

        #pragma unroll
        for (int ks = 0; ks < 2; ++ks) {
            const int kc = hi + 4 * ks;
            bf16x8 a[MFR], b[4];
            #pragma unroll
            for (int mf = 0; mf < MFR; ++mf)
                a[mf] = *reinterpret_cast<const bf16x8*>(
                    &As[(arow + mf * 16) * 64 + ((kc ^ lx) * 8)]);
            #pragma unroll
            for (int nf = 0; nf < 4; ++nf)
                b[nf] = *reinterpret_cast<const bf16x8*>(
                    &Ws[(brow + nf * 16) * 64 + ((kc ^ lx) * 8)]);
            #pragma unroll
            for (int mf = 0; mf < MFR; ++mf)
                #pragma unroll
                for (int nf = 0; nf < 4; ++nf)
                    acc[mf][nf] = __builtin_amdgcn_mfma_f32_16x16x32_bf16(
                        a[mf], b[nf], acc[mf][nf], 0, 0, 0);
        }
        __syncthreads();
    }

    if (OUT == 0 && NT) {
        // LDS-transposed epilogue: full-line NT dword stores.
        float* Cs = (float*)smem;    // [32][132] fp32, reuses As/Ws space
        #pragma unroll
        for (int mf = 0; mf < MFR; ++mf) {
            __syncthreads();
            #pragma unroll
            for (int nf = 0; nf < 4; ++nf) {
                #pragma unroll
                for (int j = 0; j < 4; ++j)
                    Cs[(wr * 16 + hi * 4 + j) * 132 + wc * 64 + nf * 16 + (lane & 15)]
                        = acc[mf][nf][j];
            }
            __syncthreads();
            // 4 waves x 8 rows; per row two 64-lane contiguous dword stores
            #pragma unroll
            for (int rr = 0; rr < 8; ++rr) {
                int lrow = wid * 8 + rr;      // 0..31
                int grow = row0 + (lrow < 16 ? mf * 16 + lrow
                                             : 64 + mf * 16 + (lrow - 16));
                #pragma unroll
                for (int hf = 0; hf < 2; ++hf) {
                    int cc = col0 + hf * 64 + lane;
                    if (cc < N)
                        __builtin_nontemporal_store(
                            Cs[lrow * 132 + hf * 64 + lane],
                            &C[(size_t)grow * ldc + cc]);
                }
            }
        }
    } else {
        #pragma unroll
        for (int mf = 0; mf < MFR; ++mf) {
            #pragma unroll
            for (int nf = 0; nf < 4; ++nf) {
                int r  = row0 + wr * (MT / 2) + mf * 16 + hi * 4;
                int cc = col0 + wc * 64 + nf * 16 + (lane & 15);
                if (cc < N) {
                    f32x4 d = acc[mf][nf];
                    if (OUT == 3) {
                        if (cc < DI) {
                            float bv = bias[cc];
                            #pragma unroll
                            for (int j = 0; j < 4; ++j) {
                                float v = d[j] + bv;
                                v = (v > 20.f) ? v : log1pf(__expf(v));
                                C[(size_t)(r + j) * ldc + cc] = v;
                            }
                        } else {
                            #pragma unroll
                            for (int j = 0; j < 4; ++j)
                                aux[(size_t)(r + j) * 32 + (cc - DI)] = d[j];
                        }
                    } else {
                        #pragma unroll
                        for (int j = 0; j < 4; ++j) {
                            C[(size_t)(r + j) * ldc + cc] = d[j];
                            if (OUT == 1)
                                Cbf[(size_t)(r + j) * ldc + cc] =
                                    (unsigned short)f2bf(d[j]);
                        }
                    }
                }
            }
        }
    }
}

// ---------------------------------------------------------------------------
// Depthwise causal conv(4) + bias + silu; dual write fp32 + bf16
// ---------------------------------------------------------------------------
__global__ __launch_bounds__(256) void conv_silu_k(
    const float* __restrict__ xz, const float* __restrict__ cw,
    const float* __restrict__ cb, float* __restrict__ xinf,
    unsigned short* __restrict__ xinb)
{
    int i = blockIdx.x * 256 + threadIdx.x;   // over ROWS*DI
    if (i >= ROWS * DI) return;
    int row = i / DI;
    int c = i - row * DI;
    int t = row & (SL - 1);
    int b = row >> 10;
    float acc = cb[c];
    const float* base = xz + (size_t)(b * SL) * (2 * DI) + c;
    #pragma unroll
    for (int k = 0; k < DC; ++k) {
        int tt = t + k - (DC - 1);
        if (tt >= 0) acc += base[(size_t)tt * (2 * DI)] * cw[c * DC + k];
    }
    float v = acc / (1.f + __expf(-acc));
    xinf[i] = v;
    xinb[i] = (unsigned short)f2bf(v);
}

// ---------------------------------------------------------------------------
// Chunked selective scan, 2 kernels. CCH=32 chunks of CLEN=32.
// bc buffer: B = bc[r*bstride + boff + s], C = bc[r*bstride + boff + 16 + s].
// ---------------------------------------------------------------------------
__global__ __launch_bounds__(256) void scan_phase1(
    const float* __restrict__ dt,
    const float* __restrict__ bc, int bstride, int boff,
    const float* __restrict__ xin,
    const float* __restrict__ Alog,
    float* __restrict__ hend,
    float* __restrict__ eprod)
{
    int blk = blockIdx.x;
    int c = blk % CCH;
    int tmp = blk / CCH;
    int dblk = tmp % (DI / 16);
    int b = tmp / (DI / 16);
    int s = threadIdx.x & 15;
    int d = dblk * 16 + (threadIdx.x >> 4);
    float A = -__expf(Alog[d * DS + s]);
    float h = 0.f, P = 1.f;
    const int rowbase = b * SL + c * CLEN;
    #pragma unroll 4
    for (int t = 0; t < CLEN; ++t) {
        int r = rowbase + t;
        float dtv = dt[(size_t)r * DI + d];
        float xv  = xin[(size_t)r * DI + d];
        float Bv  = bc[(size_t)r * bstride + boff + s];
        float e = __expf(dtv * A);
        h = h * e + dtv * xv * Bv;
        P *= e;
    }
    size_t idx = ((size_t)(b * CCH + c) * DI + d) * DS + s;
    hend[idx]  = h;
    eprod[idx] = P;
}

__global__ __launch_bounds__(256) void scan_phase3(
    const float* __restrict__ dt,
    const float* __restrict__ bc, int bstride, int boff,
    const float* __restrict__ xin,
    const float* __restrict__ xz,
    const float* __restrict__ Alog,
    const float* __restrict__ Dp,
    const float* __restrict__ hend,
    const float* __restrict__ eprod,
    unsigned short* __restrict__ ybf)
{
    int blk = blockIdx.x;
    int c = blk % CCH;
    int tmp = blk / CCH;
    int dblk = tmp % (DI / 16);
    int b = tmp / (DI / 16);
    int s = threadIdx.x & 15;
    int d = dblk * 16 + (threadIdx.x >> 4);
    float A = -__expf(Alog[d * DS + s]);
    float Dv = Dp[d];

    float h = 0.f;
    const size_t pbase = ((size_t)b * CCH * DI + d) * DS + s;
    for (int j = 0; j < c; ++j) {
        size_t idx = pbase + (size_t)j * (DI * DS);
        h = h * eprod[idx] + hend[idx];
    }

    const int rowbase = b * SL + c * CLEN;
    #pragma unroll 2
    for (int t = 0; t < CLEN; ++t) {
        int r = rowbase + t;
        float dtv = dt[(size_t)r * DI + d];
        float xv  = xin[(size_t)r * DI + d];
        float Bv  = bc[(size_t)r * bstride + boff + s];
        float Cv  = bc[(size_t)r * bstride + boff + 16 + s];
        float e = __expf(dtv * A);
        h = h * e + dtv * xv * Bv;
        float p = h * Cv;
        p += __shfl_xor(p, 1, 64);
        p += __shfl_xor(p, 2, 64);
        p += __shfl_xor(p, 4, 64);
        p += __shfl_xor(p, 8, 64);
        if (s == 0) {
            float z = xz[(size_t)r * (2 * DI) + DI + d];
            float yv = (p + xv * Dv) * (z / (1.f + __expf(-z)));
            ybf[(size_t)r * DI + d] = (unsigned short)f2bf(yv);
        }
    }
}

// ---------------------------------------------------------------------------
// LayerNorm over rows of 768, bf16 output
// ---------------------------------------------------------------------------
__global__ __launch_bounds__(256) void ln_k(
    const float* __restrict__ x, const float* __restrict__ w,
    const float* __restrict__ b, unsigned short* __restrict__ o)
{
    int row = blockIdx.x;
    int tid = threadIdx.x;
    const float* xr = x + (size_t)row * DM;
    float v0 = xr[tid], v1 = xr[tid + 256], v2 = xr[tid + 512];
    float s = v0 + v1 + v2;
    #pragma unroll
    for (int off = 1; off < 64; off <<= 1) s += __shfl_xor(s, off, 64);
    __shared__ float red[4];
    __shared__ float red2[4];
    int wid = tid >> 6, lane = tid & 63;
    if (lane == 0) red[wid] = s;
    __syncthreads();
    float mu = (red[0] + red[1] + red[2] + red[3]) * (1.f / 768.f);
    float d0 = v0 - mu, d1 = v1 - mu, d2 = v2 - mu;
    float q = d0 * d0 + d1 * d1 + d2 * d2;
    #pragma unroll
    for (int off = 1; off < 64; off <<= 1) q += __shfl_xor(q, off, 64);
    if (lane == 0) red2[wid] = q;
    __syncthreads();
    float var = (red2[0] + red2[1] + red2[2] + red2[3]) * (1.f / 768.f);
    float rs = rsqrtf(var + 1e-5f);
    o[(size_t)row * DM + tid]       = (unsigned short)f2bf(d0 * rs * w[tid]       + b[tid]);
    o[(size_t)row * DM + tid + 256] = (unsigned short)f2bf(d1 * rs * w[tid + 256] + b[tid + 256]);
    o[(size_t)row * DM + tid + 512] = (unsigned short)f2bf(d2 * rs * w[tid + 512] + b[tid + 512]);
}

// ---------------------------------------------------------------------------
extern "C" void kernel_launch(void* const* d_in, const int* in_sizes, int n_in,
                              void* d_out, int out_size, void* d_ws, size_t ws_size,
                              hipStream_t stream) {
    const int*   ids        = (const int*)d_in[0];
    const float* emb        = (const float*)d_in[1];
    const float* in_proj_w  = (const float*)d_in[2];
    const float* conv_w     = (const float*)d_in[3];
    const float* conv_b     = (const float*)d_in[4];
    const float* x_proj_w   = (const float*)d_in[5];
    const float* dt_proj_w  = (const float*)d_in[6];
    const float* dt_proj_b  = (const float*)d_in[7];
    const float* A_log      = (const float*)d_in[8];
    const float* D_param    = (const float*)d_in[9];
    const float* out_proj_w = (const float*)d_in[10];
    const float* norm_w     = (const float*)d_in[11];
    const float* norm_b     = (const float*)d_in[12];
    float* out = (float*)d_out;

    // ---- workspace layout ----
    char* base = (char*)d_ws;
    size_t off = 0;
    auto alloc_f = [&](size_t n) { float* p = (float*)(base + off); off += n * 4; return p; };
    auto alloc_u = [&](size_t n) { unsigned short* p = (unsigned short*)(base + off); off += n * 2; return p; };

    float* x     = alloc_f((size_t)ROWS * DM);
    float* xz    = alloc_f((size_t)ROWS * 2 * DI);
    float* xinf  = alloc_f((size_t)ROWS * DI);
    float* bc    = alloc_f((size_t)ROWS * 32);
    float* dt    = alloc_f((size_t)ROWS * DI);
    float* hend  = alloc_f((size_t)NB * CCH * DI * DS);
    float* eprod = alloc_f((size_t)NB * CCH * DI * DS);
    unsigned short* xbf   = alloc_u((size_t)ROWS * DM);
    unsigned short* ybf   = alloc_u((size_t)ROWS * DI);
    unsigned short* xinb  = alloc_u((size_t)ROWS * DI);
    unsigned short* xlnbf = alloc_u((size_t)ROWS * DM);
    unsigned short* inw_bf = alloc_u((size_t)NLAYER * 2 * DI * DM);
    unsigned short* ow_bf  = alloc_u((size_t)NLAYER * DM * DI);
    unsigned short* wbig  = alloc_u((size_t)NLAYER * NBIG * DI);
    unsigned short* emb_bf = alloc_u((size_t)VOCAB * DM);
    (void)ws_size;

    // ---- weight preconversion (once per call) ----
    {
        int n4a = NLAYER * 2 * DI * DM / 4;
        cvt_bf16_k<<<(n4a + 255) / 256, 256, 0, stream>>>(in_proj_w, inw_bf, n4a);
        int n4b = NLAYER * DM * DI / 4;
        cvt_bf16_k<<<(n4b + 255) / 256, 256, 0, stream>>>(out_proj_w, ow_bf, n4b);
        wc_k<<<dim3(12, 13, NLAYER), 256, 0, stream>>>(dt_proj_w, x_proj_w, wbig);
        int n4e = VOCAB * DM / 4;
        cvt_bf16_k<<<(n4e + 255) / 256, 256, 0, stream>>>(emb, emb_bf, n4e);
    }

    embed_k<<<(ROWS * DM + 255) / 256, 256, 0, stream>>>(ids, emb, xbf);

    const int scan_grid = NB * (DI / 16) * CCH;      // 6144 blocks

    for (int i = 0; i < NLAYER; ++i) {
        const float* cw  = conv_w  + (size_t)i * DI * DC;
        const float* cb  = conv_b  + (size_t)i * DI;
        const float* dtb = dt_proj_b + (size_t)i * DI;
        const float* Al  = A_log   + (size_t)i * DI * DS;
        const float* Dpar= D_param + (size_t)i * DI;

        // in_proj: xz = xbf @ inw^T  (128-tile, GY=16, 24 col tiles)
        const unsigned short* inw = inw_bf + (size_t)i * 2 * DI * DM;
        gemm_bf16<128, true, 0, false><<<24 * 16, 256, 0, stream>>>(
            xbf, DM, inw, DM, xz, nullptr, 2 * DI, 16, 2 * DI, DM, nullptr, nullptr);

        conv_silu_k<<<(ROWS * DI) / 256, 256, 0, stream>>>(xz, cw, cb, xinf, xinb);

        // fused dt + B/C: [dt | bc] = xinb @ wbig[i]^T  (N=1568, K=1536)
        const unsigned short* wb = wbig + (size_t)i * NBIG * DI;
        gemm_bf16<128, true, 3, false><<<13 * 16, 256, 0, stream>>>(
            xinb, DI, wb, DI, dt, nullptr, DI, 16, NBIG, DI, dtb, bc);

        scan_phase1<<<scan_grid, 256, 0, stream>>>(dt, bc, 32, 0, xinf, Al, hend, eprod);
        scan_phase3<<<scan_grid, 256, 0, stream>>>(dt, bc, 32, 0, xinf, xz, Al, Dpar,
                                                   hend, eprod, ybf);

        // out_proj: x(fp32) + xbf(bf16) = ybf @ ow^T  (64-tile, GY=32)
        const unsigned short* ow = ow_bf + (size_t)i * DM * DI;
        gemm_bf16<64, true, 1, false><<<6 * 32, 256, 0, stream>>>(
            ybf, DI, ow, DI, x, xbf, DM, 32, DM, DI, nullptr, nullptr);
    }

    ln_k<<<ROWS, 256, 0, stream>>>(x, norm_w, norm_b, xlnbf);
    // logits: out = xlnbf @ emb^T  (393 col tiles x GY=16; NT transposed epilogue)
    gemm_bf16<128, true, 0, true><<<393 * 16, 256, 0, stream>>>(
        xlnbf, DM, emb_bf, DM, out, nullptr, VOCAB, 16, VOCAB, DM, nullptr, nullptr);
}

// Round 8
// 3407.713 us; speedup vs baseline: 4.9881x; 1.1719x over previous
//
#include <hip/hip_runtime.h>
#include <hip/hip_bf16.h>

#define DI 1536
#define DS 16
#define DC 4
#define DTR 48
#define NB 2
#define SL 1024
#define DM 768
#define NLAYER 12
#define VOCAB 50257
#define ROWS (NB*SL)   // 2048
#define CCH 32         // scan chunks
#define CLEN (SL/CCH)  // 32
#define NBIG (DI+32)   // 1568: fused dt(1536) + B/C(32) outputs

typedef __attribute__((ext_vector_type(8))) short bf16x8;
typedef __attribute__((ext_vector_type(4))) short short4v;
typedef __attribute__((ext_vector_type(4))) float f32x4;

__device__ inline short f2bf(float f) {
    unsigned u = __builtin_bit_cast(unsigned, f);
    unsigned r = (u + 0x7fffu + ((u >> 16) & 1u)) >> 16;
    return (short)r;
}

__device__ __forceinline__ void gl_lds16(const void* g, void* l) {
    __builtin_amdgcn_global_load_lds(
        (const __attribute__((address_space(1))) unsigned int*)g,
        (__attribute__((address_space(3))) unsigned int*)l, 16, 0, 0);
}

// ---------------------------------------------------------------------------
// fp32 -> bf16 elementwise convert (n multiple of 4)
// ---------------------------------------------------------------------------
__global__ __launch_bounds__(256) void cvt_bf16_k(const float* __restrict__ src,
                                                  unsigned short* __restrict__ dst,
                                                  int n4) {
    int i = blockIdx.x * 256 + threadIdx.x;
    if (i >= n4) return;
    float4 v = *reinterpret_cast<const float4*>(src + (size_t)i * 4);
    short4v o;
    o[0] = f2bf(v.x); o[1] = f2bf(v.y); o[2] = f2bf(v.z); o[3] = f2bf(v.w);
    *reinterpret_cast<short4v*>(dst + (size_t)i * 4) = o;
}

// ---------------------------------------------------------------------------
// Wc precompute: wbig[l] rows 0..1535 = dtw @ xpw[:48]  (bf16),
//                rows 1536..1567 = xpw[48:80] (bf16).
// ---------------------------------------------------------------------------
__global__ __launch_bounds__(256) void wc_k(
    const float* __restrict__ dtw_all,   // (NL, DI, DTR)
    const float* __restrict__ xpw_all,   // (NL, 80, DI)
    unsigned short* __restrict__ wbig)   // (NL, NBIG, DI)
{
    int l = blockIdx.z;
    const float* dtw = dtw_all + (size_t)l * DI * DTR;
    const float* xpw = xpw_all + (size_t)l * 80 * DI;
    unsigned short* wb = wbig + (size_t)l * NBIG * DI;
    int tid = threadIdx.x;
    if (blockIdx.y == 12) {
        if (blockIdx.x == 0) {
            for (int idx = tid; idx < 32 * DI; idx += 256) {
                int rr = idx / DI, k = idx - rr * DI;
                wb[(size_t)(DI + rr) * DI + k] =
                    (unsigned short)f2bf(xpw[(size_t)(48 + rr) * DI + k]);
            }
        }
        return;
    }
    __shared__ float sd[128 * 48];
    __shared__ float sx[48 * 128];
    int d0 = blockIdx.y * 128, k0 = blockIdx.x * 128;
    for (int idx = tid; idx < 128 * 48; idx += 256) {
        int r = idx / 48, j = idx - r * 48;
        sd[idx] = dtw[(size_t)(d0 + r) * DTR + j];
    }
    for (int idx = tid; idx < 48 * 128; idx += 256) {
        int j = idx / 128, k = idx - j * 128;
        sx[idx] = xpw[(size_t)j * DI + k0 + k];
    }
    __syncthreads();
    int tx = tid & 15, ty = tid >> 4;
    float acc[8][8] = {};
    for (int j = 0; j < 48; ++j) {
        float a[8], w[8];
        #pragma unroll
        for (int i = 0; i < 8; ++i) a[i] = sd[(ty * 8 + i) * 48 + j];
        #pragma unroll
        for (int i = 0; i < 8; ++i) w[i] = sx[j * 128 + tx * 8 + i];
        #pragma unroll
        for (int i = 0; i < 8; ++i)
            #pragma unroll
            for (int jj = 0; jj < 8; ++jj)
                acc[i][jj] += a[i] * w[jj];
    }
    for (int i = 0; i < 8; ++i)
        for (int jj = 0; jj < 8; ++jj)
            wb[(size_t)(d0 + ty * 8 + i) * DI + k0 + tx * 8 + jj] =
                (unsigned short)f2bf(acc[i][jj]);
}

// ---------------------------------------------------------------------------
// Embedding: xbf[b,s,:] = bf16(emb[ids[b,s]] * sqrt(768))
// ---------------------------------------------------------------------------
__global__ __launch_bounds__(256) void embed_k(const int* __restrict__ ids,
                                               const float* __restrict__ emb,
                                               unsigned short* __restrict__ xbf) {
    int i = blockIdx.x * 256 + threadIdx.x;      // over ROWS*DM
    if (i >= ROWS * DM) return;
    int row = i / DM;
    int c = i - row * DM;
    xbf[i] = (unsigned short)f2bf(emb[(size_t)ids[row] * DM + c] * 27.712812921102035f);
}

// ---------------------------------------------------------------------------
// bf16-MFMA GEMM: C(M,N) = A(M,K)bf16 @ W(N,K)^T, both bf16 in memory.
// MT x 128 tile, BKT = 32 or 64, 4 waves, mfma_f32_16x16x32_bf16.
// global_load_lds staging: linear LDS dest, pre-swizzled global source.
// Swizzle (involution, conflict-free ds_read_b128):
//   BKT=32: chunk ^ ((row>>1)&3);  BKT=64: chunk ^ (row&7).
// OUT: 0 = fp32 store (NT -> LDS-transposed full-line NT epilogue);
//      1 = fp32 + bf16 dual store; 3 = fused dt softplus / BC split.
// ---------------------------------------------------------------------------
template<int MT, int BKT, int OUT, bool NT>
__global__ __launch_bounds__(256) void gemm_bf16(
    const unsigned short* __restrict__ A, int lda,
    const unsigned short* __restrict__ W, int ldw,
    float* __restrict__ C, unsigned short* __restrict__ Cbf, int ldc,
    int GY, int N, int K,
    const float* __restrict__ bias, float* __restrict__ aux)
{
    constexpr int CPR  = BKT / 8;             // 16B chunks per row
    constexpr int ACA  = MT  * BKT / 2048;    // A staging passes
    constexpr int ACW  = 128 * BKT / 2048;    // W staging passes
    constexpr int KSUB = BKT / 32;            // k-subtiles per stage
    constexpr int MFR  = MT / 32;             // M fragments per wave
    constexpr int SMEM_AB = (MT + 128) * BKT * 2;
    constexpr int SMEM_NT = 32 * 132 * 4;
    constexpr int SMEM_SZ = ((OUT == 0 && NT) && SMEM_AB < SMEM_NT) ? SMEM_NT : SMEM_AB;
    __shared__ __align__(16) char smem[SMEM_SZ];
    short* As = (short*)smem;
    short* Ws = (short*)(smem + MT * BKT * 2);

    const int tid  = threadIdx.x;
    const int lane = tid & 63;
    const int wid  = tid >> 6;
    const int wr   = wid >> 1, wc = wid & 1;

    // bijective XCD-chunked swizzle, then col-major decode
    const int nwg = gridDim.x;
    const int q = nwg >> 3, rm = nwg & 7;
    const int xcd = blockIdx.x & 7, bidx = blockIdx.x >> 3;
    const int wg = (xcd < rm ? xcd * (q + 1) : rm * (q + 1) + (xcd - rm) * q) + bidx;
    const int row0 = (wg % GY) * MT;
    const int col0 = (wg / GY) * 128;

    // ---- staging setup (pre-swizzled global sources) ----
    const unsigned short* gA[ACA];
    const unsigned short* gW[ACW];
    #pragma unroll
    for (int i = 0; i < ACA; ++i) {
        int cid = i * 256 + tid;
        int r = cid / CPR, c = cid % CPR;
        int sz = (BKT == 32) ? ((r >> 1) & 3) : (r & 7);
        gA[i] = A + (size_t)(row0 + r) * lda + ((c ^ sz) * 8);
    }
    #pragma unroll
    for (int i = 0; i < ACW; ++i) {
        int cid = i * 256 + tid;
        int r = cid / CPR, c = cid % CPR;
        int sz = (BKT == 32) ? ((r >> 1) & 3) : (r & 7);
        int rg = col0 + r; if (rg > N - 1) rg = N - 1;   // clamp: dup data, store-guarded
        gW[i] = W + (size_t)rg * ldw + ((c ^ sz) * 8);
    }

    const int arow = wr * (MT / 2) + (lane & 15);
    const int brow = wc * 64 + (lane & 15);
    const int szA = (BKT == 32) ? ((arow >> 1) & 3) : (arow & 7);  // row+16 invariant
    const int szB = (BKT == 32) ? ((brow >> 1) & 3) : (brow & 7);
    const int hi = lane >> 4;      // 0..3

    f32x4 acc[MFR][4] = {};

    for (int k0 = 0; k0 < K; k0 += BKT) {
        #pragma unroll
        for (int i = 0; i < ACA; ++i) {
            gl_lds16(gA[i], &As[(size_t)(i * 256 + wid * 64) * 8]);
            gA[i] += BKT;
        }
        #pragma unroll
        for (int i = 0; i < ACW; ++i) {
            gl_lds16(gW[i], &Ws[(size_t)(i * 256 + wid * 64) * 8]);
            gW[i] += BKT;
        }
        __syncthreads();

        #pragma unroll
        for (int ks = 0; ks < KSUB; ++ks) {
            const int kc = hi + 4 * ks;
            bf16x8 a[MFR], b[4];
            #pragma unroll
            for (int mf = 0; mf < MFR; ++mf)
                a[mf] = *reinterpret_cast<const bf16x8*>(
                    &As[(arow + mf * 16) * BKT + ((kc ^ szA) * 8)]);
            #pragma unroll
            for (int nf = 0; nf < 4; ++nf)
                b[nf] = *reinterpret_cast<const bf16x8*>(
                    &Ws[(brow + nf * 16) * BKT + ((kc ^ szB) * 8)]);
            #pragma unroll
            for (int mf = 0; mf < MFR; ++mf)
                #pragma unroll
                for (int nf = 0; nf < 4; ++nf)
                    acc[mf][nf] = __builtin_amdgcn_mfma_f32_16x16x32_bf16(
                        a[mf], b[nf], acc[mf][nf], 0, 0, 0);
        }
        __syncthreads();
    }

    if (OUT == 0 && NT) {
        // LDS-transposed epilogue: full-line NT dword stores.
        float* Cs = (float*)smem;    // [32][132] fp32
        #pragma unroll
        for (int mf = 0; mf < MFR; ++mf) {
            __syncthreads();
            #pragma unroll
            for (int nf = 0; nf < 4; ++nf) {
                #pragma unroll
                for (int j = 0; j < 4; ++j)
                    Cs[(wr * 16 + hi * 4 + j) * 132 + wc * 64 + nf * 16 + (lane & 15)]
                        = acc[mf][nf][j];
            }
            __syncthreads();
            #pragma unroll
            for (int rr = 0; rr < 8; ++rr) {
                int lrow = wid * 8 + rr;      // 0..31
                int grow = row0 + (lrow < 16 ? mf * 16 + lrow
                                             : (MT / 2) + mf * 16 + (lrow - 16));
                #pragma unroll
                for (int hf = 0; hf < 2; ++hf) {
                    int cc = col0 + hf * 64 + lane;
                    if (cc < N)
                        __builtin_nontemporal_store(
                            Cs[lrow * 132 + hf * 64 + lane],
                            &C[(size_t)grow * ldc + cc]);
                }
            }
        }
    } else {
        #pragma unroll
        for (int mf = 0; mf < MFR; ++mf) {
            #pragma unroll
            for (int nf = 0; nf < 4; ++nf) {
                int r  = row0 + wr * (MT / 2) + mf * 16 + hi * 4;
                int cc = col0 + wc * 64 + nf * 16 + (lane & 15);
                if (cc < N) {
                    f32x4 d = acc[mf][nf];
                    if (OUT == 3) {
                        if (cc < DI) {
                            float bv = bias[cc];
                            #pragma unroll
                            for (int j = 0; j < 4; ++j) {
                                float v = d[j] + bv;
                                v = (v > 20.f) ? v : log1pf(__expf(v));
                                C[(size_t)(r + j) * ldc + cc] = v;
                            }
                        } else {
                            #pragma unroll
                            for (int j = 0; j < 4; ++j)
                                aux[(size_t)(r + j) * 32 + (cc - DI)] = d[j];
                        }
                    } else {
                        #pragma unroll
                        for (int j = 0; j < 4; ++j) {
                            C[(size_t)(r + j) * ldc + cc] = d[j];
                            if (OUT == 1)
                                Cbf[(size_t)(r + j) * ldc + cc] =
                                    (unsigned short)f2bf(d[j]);
                        }
                    }
                }
            }
        }
    }
}

// ---------------------------------------------------------------------------
// Depthwise causal conv(4) + bias + silu; dual write fp32 + bf16
// ---------------------------------------------------------------------------
__global__ __launch_bounds__(256) void conv_silu_k(
    const float* __restrict__ xz, const float* __restrict__ cw,
    const float* __restrict__ cb, float* __restrict__ xinf,
    unsigned short* __restrict__ xinb)
{
    int i = blockIdx.x * 256 + threadIdx.x;   // over ROWS*DI
    if (i >= ROWS * DI) return;
    int row = i / DI;
    int c = i - row * DI;
    int t = row & (SL - 1);
    int b = row >> 10;
    float acc = cb[c];
    const float* base = xz + (size_t)(b * SL) * (2 * DI) + c;
    #pragma unroll
    for (int k = 0; k < DC; ++k) {
        int tt = t + k - (DC - 1);
        if (tt >= 0) acc += base[(size_t)tt * (2 * DI)] * cw[c * DC + k];
    }
    float v = acc / (1.f + __expf(-acc));
    xinf[i] = v;
    xinb[i] = (unsigned short)f2bf(v);
}

// ---------------------------------------------------------------------------
// Chunked selective scan, 2 kernels. CCH=32 chunks of CLEN=32.
// bc buffer: B = bc[r*32 + s], C = bc[r*32 + 16 + s].
// ---------------------------------------------------------------------------
__global__ __launch_bounds__(256) void scan_phase1(
    const float* __restrict__ dt,
    const float* __restrict__ bc,
    const float* __restrict__ xin,
    const float* __restrict__ Alog,
    float* __restrict__ hend,
    float* __restrict__ eprod)
{
    int blk = blockIdx.x;
    int c = blk % CCH;
    int tmp = blk / CCH;
    int dblk = tmp % (DI / 16);
    int b = tmp / (DI / 16);
    int s = threadIdx.x & 15;
    int d = dblk * 16 + (threadIdx.x >> 4);
    float A = -__expf(Alog[d * DS + s]);
    float h = 0.f, P = 1.f;
    const int rowbase = b * SL + c * CLEN;
    #pragma unroll 4
    for (int t = 0; t < CLEN; ++t) {
        int r = rowbase + t;
        float dtv = dt[(size_t)r * DI + d];
        float xv  = xin[(size_t)r * DI + d];
        float Bv  = bc[(size_t)r * 32 + s];
        float e = __expf(dtv * A);
        h = h * e + dtv * xv * Bv;
        P *= e;
    }
    size_t idx = ((size_t)(b * CCH + c) * DI + d) * DS + s;
    hend[idx]  = h;
    eprod[idx] = P;
}

__global__ __launch_bounds__(256) void scan_phase3(
    const float* __restrict__ dt,
    const float* __restrict__ bc,
    const float* __restrict__ xin,
    const float* __restrict__ xz,
    const float* __restrict__ Alog,
    const float* __restrict__ Dp,
    const float* __restrict__ hend,
    const float* __restrict__ eprod,
    unsigned short* __restrict__ ybf)
{
    int blk = blockIdx.x;
    int c = blk % CCH;
    int tmp = blk / CCH;
    int dblk = tmp % (DI / 16);
    int b = tmp / (DI / 16);
    int s = threadIdx.x & 15;
    int d = dblk * 16 + (threadIdx.x >> 4);
    float A = -__expf(Alog[d * DS + s]);
    float Dv = Dp[d];

    float h = 0.f;
    const size_t pbase = ((size_t)b * CCH * DI + d) * DS + s;
    for (int j = 0; j < c; ++j) {
        size_t idx = pbase + (size_t)j * (DI * DS);
        h = h * eprod[idx] + hend[idx];
    }

    const int rowbase = b * SL + c * CLEN;
    #pragma unroll 2
    for (int t = 0; t < CLEN; ++t) {
        int r = rowbase + t;
        float dtv = dt[(size_t)r * DI + d];
        float xv  = xin[(size_t)r * DI + d];
        float Bv  = bc[(size_t)r * 32 + s];
        float Cv  = bc[(size_t)r * 32 + 16 + s];
        float e = __expf(dtv * A);
        h = h * e + dtv * xv * Bv;
        float p = h * Cv;
        p += __shfl_xor(p, 1, 64);
        p += __shfl_xor(p, 2, 64);
        p += __shfl_xor(p, 4, 64);
        p += __shfl_xor(p, 8, 64);
        if (s == 0) {
            float z = xz[(size_t)r * (2 * DI) + DI + d];
            float yv = (p + xv * Dv) * (z / (1.f + __expf(-z)));
            ybf[(size_t)r * DI + d] = (unsigned short)f2bf(yv);
        }
    }
}

// ---------------------------------------------------------------------------
// LayerNorm over rows of 768, bf16 output
// ---------------------------------------------------------------------------
__global__ __launch_bounds__(256) void ln_k(
    const float* __restrict__ x, const float* __restrict__ w,
    const float* __restrict__ b, unsigned short* __restrict__ o)
{
    int row = blockIdx.x;
    int tid = threadIdx.x;
    const float* xr = x + (size_t)row * DM;
    float v0 = xr[tid], v1 = xr[tid + 256], v2 = xr[tid + 512];
    float s = v0 + v1 + v2;
    #pragma unroll
    for (int off = 1; off < 64; off <<= 1) s += __shfl_xor(s, off, 64);
    __shared__ float red[4];
    __shared__ float red2[4];
    int wid = tid >> 6, lane = tid & 63;
    if (lane == 0) red[wid] = s;
    __syncthreads();
    float mu = (red[0] + red[1] + red[2] + red[3]) * (1.f / 768.f);
    float d0 = v0 - mu, d1 = v1 - mu, d2 = v2 - mu;
    float q = d0 * d0 + d1 * d1 + d2 * d2;
    #pragma unroll
    for (int off = 1; off < 64; off <<= 1) q += __shfl_xor(q, off, 64);
    if (lane == 0) red2[wid] = q;
    __syncthreads();
    float var = (red2[0] + red2[1] + red2[2] + red2[3]) * (1.f / 768.f);
    float rs = rsqrtf(var + 1e-5f);
    o[(size_t)row * DM + tid]       = (unsigned short)f2bf(d0 * rs * w[tid]       + b[tid]);
    o[(size_t)row * DM + tid + 256] = (unsigned short)f2bf(d1 * rs * w[tid + 256] + b[tid + 256]);
    o[(size_t)row * DM + tid + 512] = (unsigned short)f2bf(d2 * rs * w[tid + 512] + b[tid + 512]);
}

// ---------------------------------------------------------------------------
extern "C" void kernel_launch(void* const* d_in, const int* in_sizes, int n_in,
                              void* d_out, int out_size, void* d_ws, size_t ws_size,
                              hipStream_t stream) {
    const int*   ids        = (const int*)d_in[0];
    const float* emb        = (const float*)d_in[1];
    const float* in_proj_w  = (const float*)d_in[2];
    const float* conv_w     = (const float*)d_in[3];
    const float* conv_b     = (const float*)d_in[4];
    const float* x_proj_w   = (const float*)d_in[5];
    const float* dt_proj_w  = (const float*)d_in[6];
    const float* dt_proj_b  = (const float*)d_in[7];
    const float* A_log      = (const float*)d_in[8];
    const float* D_param    = (const float*)d_in[9];
    const float* out_proj_w = (const float*)d_in[10];
    const float* norm_w     = (const float*)d_in[11];
    const float* norm_b     = (const float*)d_in[12];
    float* out = (float*)d_out;

    // ---- workspace layout ----
    char* base = (char*)d_ws;
    size_t off = 0;
    auto alloc_f = [&](size_t n) { float* p = (float*)(base + off); off += n * 4; return p; };
    auto alloc_u = [&](size_t n) { unsigned short* p = (unsigned short*)(base + off); off += n * 2; return p; };

    float* x     = alloc_f((size_t)ROWS * DM);
    float* xz    = alloc_f((size_t)ROWS * 2 * DI);
    float* xinf  = alloc_f((size_t)ROWS * DI);
    float* bc    = alloc_f((size_t)ROWS * 32);
    float* dt    = alloc_f((size_t)ROWS * DI);
    float* hend  = alloc_f((size_t)NB * CCH * DI * DS);
    float* eprod = alloc_f((size_t)NB * CCH * DI * DS);
    unsigned short* xbf   = alloc_u((size_t)ROWS * DM);
    unsigned short* ybf   = alloc_u((size_t)ROWS * DI);
    unsigned short* xinb  = alloc_u((size_t)ROWS * DI);
    unsigned short* xlnbf = alloc_u((size_t)ROWS * DM);
    unsigned short* inw_bf = alloc_u((size_t)NLAYER * 2 * DI * DM);
    unsigned short* ow_bf  = alloc_u((size_t)NLAYER * DM * DI);
    unsigned short* wbig  = alloc_u((size_t)NLAYER * NBIG * DI);
    unsigned short* emb_bf = alloc_u((size_t)VOCAB * DM);
    (void)ws_size;

    // ---- weight preconversion (once per call) ----
    {
        int n4a = NLAYER * 2 * DI * DM / 4;
        cvt_bf16_k<<<(n4a + 255) / 256, 256, 0, stream>>>(in_proj_w, inw_bf, n4a);
        int n4b = NLAYER * DM * DI / 4;
        cvt_bf16_k<<<(n4b + 255) / 256, 256, 0, stream>>>(out_proj_w, ow_bf, n4b);
        wc_k<<<dim3(12, 13, NLAYER), 256, 0, stream>>>(dt_proj_w, x_proj_w, wbig);
        int n4e = VOCAB * DM / 4;
        cvt_bf16_k<<<(n4e + 255) / 256, 256, 0, stream>>>(emb, emb_bf, n4e);
    }

    embed_k<<<(ROWS * DM + 255) / 256, 256, 0, stream>>>(ids, emb, xbf);

    const int scan_grid = NB * (DI / 16) * CCH;      // 6144 blocks

    for (int i = 0; i < NLAYER; ++i) {
        const float* cw  = conv_w  + (size_t)i * DI * DC;
        const float* cb  = conv_b  + (size_t)i * DI;
        const float* dtb = dt_proj_b + (size_t)i * DI;
        const float* Al  = A_log   + (size_t)i * DI * DS;
        const float* Dpar= D_param + (size_t)i * DI;

        // in_proj: xz = xbf @ inw^T  (64-row tile, GY=32, 24 col tiles = 768 blocks)
        const unsigned short* inw = inw_bf + (size_t)i * 2 * DI * DM;
        gemm_bf16<64, 64, 0, false><<<24 * 32, 256, 0, stream>>>(
            xbf, DM, inw, DM, xz, nullptr, 2 * DI, 32, 2 * DI, DM, nullptr, nullptr);

        conv_silu_k<<<(ROWS * DI) / 256, 256, 0, stream>>>(xz, cw, cb, xinf, xinb);

        // fused dt + B/C: [dt | bc] = xinb @ wbig[i]^T  (N=1568, K=1536, 416 blocks)
        const unsigned short* wb = wbig + (size_t)i * NBIG * DI;
        gemm_bf16<64, 64, 3, false><<<13 * 32, 256, 0, stream>>>(
            xinb, DI, wb, DI, dt, nullptr, DI, 32, NBIG, DI, dtb, bc);

        scan_phase1<<<scan_grid, 256, 0, stream>>>(dt, bc, xinf, Al, hend, eprod);
        scan_phase3<<<scan_grid, 256, 0, stream>>>(dt, bc, xinf, xz, Al, Dpar,
                                                   hend, eprod, ybf);

        // out_proj: x(fp32) + xbf(bf16) = ybf @ ow^T  (64-tile, GY=32)
        const unsigned short* ow = ow_bf + (size_t)i * DM * DI;
        gemm_bf16<64, 64, 1, false><<<6 * 32, 256, 0, stream>>>(
            ybf, DI, ow, DI, x, xbf, DM, 32, DM, DI, nullptr, nullptr);
    }

    ln_k<<<ROWS, 256, 0, stream>>>(x, norm_w, norm_b, xlnbf);
    // logits: out = xlnbf @ emb^T  (BK=32 for occupancy; NT transposed epilogue)
    gemm_bf16<128, 32, 0, true><<<393 * 16, 256, 0, stream>>>(
        xlnbf, DM, emb_bf, DM, out, nullptr, VOCAB, 16, VOCAB, DM, nullptr, nullptr);
}

// Round 9
// 3388.356 us; speedup vs baseline: 5.0166x; 1.0057x over previous
//
#include <hip/hip_runtime.h>
#include <hip/hip_bf16.h>

#define DI 1536
#define DS 16
#define DC 4
#define DTR 48
#define NB 2
#define SL 1024
#define DM 768
#define NLAYER 12
#define VOCAB 50257
#define ROWS (NB*SL)   // 2048
#define CCH 32         // scan chunks
#define CLEN (SL/CCH)  // 32
#define NBIG (DI+32)   // 1568: fused dt(1536) + B/C(32) outputs

typedef __attribute__((ext_vector_type(8))) short bf16x8;
typedef __attribute__((ext_vector_type(4))) short short4v;
typedef __attribute__((ext_vector_type(4))) float f32x4;

__device__ inline short f2bf(float f) {
    unsigned u = __builtin_bit_cast(unsigned, f);
    unsigned r = (u + 0x7fffu + ((u >> 16) & 1u)) >> 16;
    return (short)r;
}

__device__ __forceinline__ void gl_lds16(const void* g, void* l) {
    __builtin_amdgcn_global_load_lds(
        (const __attribute__((address_space(1))) unsigned int*)g,
        (__attribute__((address_space(3))) unsigned int*)l, 16, 0, 0);
}

// ---------------------------------------------------------------------------
// fp32 -> bf16 elementwise convert (n multiple of 4)
// ---------------------------------------------------------------------------
__global__ __launch_bounds__(256) void cvt_bf16_k(const float* __restrict__ src,
                                                  unsigned short* __restrict__ dst,
                                                  int n4) {
    int i = blockIdx.x * 256 + threadIdx.x;
    if (i >= n4) return;
    float4 v = *reinterpret_cast<const float4*>(src + (size_t)i * 4);
    short4v o;
    o[0] = f2bf(v.x); o[1] = f2bf(v.y); o[2] = f2bf(v.z); o[3] = f2bf(v.w);
    *reinterpret_cast<short4v*>(dst + (size_t)i * 4) = o;
}

// ---------------------------------------------------------------------------
// Wc precompute: wbig[l] rows 0..1535 = dtw @ xpw[:48]  (bf16),
//                rows 1536..1567 = xpw[48:80] (bf16).
// ---------------------------------------------------------------------------
__global__ __launch_bounds__(256) void wc_k(
    const float* __restrict__ dtw_all,   // (NL, DI, DTR)
    const float* __restrict__ xpw_all,   // (NL, 80, DI)
    unsigned short* __restrict__ wbig)   // (NL, NBIG, DI)
{
    int l = blockIdx.z;
    const float* dtw = dtw_all + (size_t)l * DI * DTR;
    const float* xpw = xpw_all + (size_t)l * 80 * DI;
    unsigned short* wb = wbig + (size_t)l * NBIG * DI;
    int tid = threadIdx.x;
    if (blockIdx.y == 12) {
        if (blockIdx.x == 0) {
            for (int idx = tid; idx < 32 * DI; idx += 256) {
                int rr = idx / DI, k = idx - rr * DI;
                wb[(size_t)(DI + rr) * DI + k] =
                    (unsigned short)f2bf(xpw[(size_t)(48 + rr) * DI + k]);
            }
        }
        return;
    }
    __shared__ float sd[128 * 48];
    __shared__ float sx[48 * 128];
    int d0 = blockIdx.y * 128, k0 = blockIdx.x * 128;
    for (int idx = tid; idx < 128 * 48; idx += 256) {
        int r = idx / 48, j = idx - r * 48;
        sd[idx] = dtw[(size_t)(d0 + r) * DTR + j];
    }
    for (int idx = tid; idx < 48 * 128; idx += 256) {
        int j = idx / 128, k = idx - j * 128;
        sx[idx] = xpw[(size_t)j * DI + k0 + k];
    }
    __syncthreads();
    int tx = tid & 15, ty = tid >> 4;
    float acc[8][8] = {};
    for (int j = 0; j < 48; ++j) {
        float a[8], w[8];
        #pragma unroll
        for (int i = 0; i < 8; ++i) a[i] = sd[(ty * 8 + i) * 48 + j];
        #pragma unroll
        for (int i = 0; i < 8; ++i) w[i] = sx[j * 128 + tx * 8 + i];
        #pragma unroll
        for (int i = 0; i < 8; ++i)
            #pragma unroll
            for (int jj = 0; jj < 8; ++jj)
                acc[i][jj] += a[i] * w[jj];
    }
    for (int i = 0; i < 8; ++i)
        for (int jj = 0; jj < 8; ++jj)
            wb[(size_t)(d0 + ty * 8 + i) * DI + k0 + tx * 8 + jj] =
                (unsigned short)f2bf(acc[i][jj]);
}

// ---------------------------------------------------------------------------
// Embedding: xbf[b,s,:] = bf16(emb[ids[b,s]] * sqrt(768))
// ---------------------------------------------------------------------------
__global__ __launch_bounds__(256) void embed_k(const int* __restrict__ ids,
                                               const float* __restrict__ emb,
                                               unsigned short* __restrict__ xbf) {
    int i = blockIdx.x * 256 + threadIdx.x;      // over ROWS*DM
    if (i >= ROWS * DM) return;
    int row = i / DM;
    int c = i - row * DM;
    xbf[i] = (unsigned short)f2bf(emb[(size_t)ids[row] * DM + c] * 27.712812921102035f);
}

// ---------------------------------------------------------------------------
// bf16-MFMA GEMM, 2-phase double-buffered (T3 minimal recipe):
//   prologue: STAGE(buf0); barrier
//   loop t:   STAGE(buf^1, t+1) issue; ds_read+MFMA on buf; barrier (drains)
// MT x 128 tile, BKT=32, 4 waves, mfma_f32_16x16x32_bf16.
// global_load_lds staging, linear LDS dest, pre-swizzled source
// (involution chunk ^ ((row>>1)&3), conflict-free ds_read_b128).
// OUT: 0 = fp32 store (NTST -> LDS-transposed full-line NT epilogue);
//      1 = fp32 + bf16 dual store; 3 = fused dt softplus / BC split.
// ---------------------------------------------------------------------------
template<int MT, int OUT, bool NTST>
__global__ __launch_bounds__(256) void gemm_bf16(
    const unsigned short* __restrict__ A, int lda,
    const unsigned short* __restrict__ W, int ldw,
    float* __restrict__ C, unsigned short* __restrict__ Cbf, int ldc,
    int GY, int N, int K,
    const float* __restrict__ bias, float* __restrict__ aux)
{
    constexpr int BKT = 32;
    constexpr int CPR = BKT / 8;              // 4 chunks per row
    constexpr int ACA = MT * CPR / 256;       // A staging issues/thread
    constexpr int ACW = 128 * CPR / 256;      // W staging issues/thread (2)
    constexpr int MFR = MT / 32;              // M fragments per wave
    constexpr int BUFS = (MT + 128) * BKT;    // shorts per buffer
    __shared__ __align__(16) short smem[2 * BUFS];

    const int tid  = threadIdx.x;
    const int lane = tid & 63;
    const int wid  = tid >> 6;
    const int wr   = wid >> 1, wc = wid & 1;

    // bijective XCD-chunked swizzle, then col-major decode
    const int nwg = gridDim.x;
    const int q = nwg >> 3, rm = nwg & 7;
    const int xcd = blockIdx.x & 7, bidx = blockIdx.x >> 3;
    const int wg = (xcd < rm ? xcd * (q + 1) : rm * (q + 1) + (xcd - rm) * q) + bidx;
    const int row0 = (wg % GY) * MT;
    const int col0 = (wg / GY) * 128;

    // ---- staging setup (pre-swizzled global sources) ----
    const unsigned short* gA[ACA];
    const unsigned short* gW[ACW];
    #pragma unroll
    for (int i = 0; i < ACA; ++i) {
        int cid = i * 256 + tid;
        int r = cid / CPR, c = cid % CPR;
        gA[i] = A + (size_t)(row0 + r) * lda + ((c ^ ((r >> 1) & 3)) * 8);
    }
    #pragma unroll
    for (int i = 0; i < ACW; ++i) {
        int cid = i * 256 + tid;
        int r = cid / CPR, c = cid % CPR;
        int rg = col0 + r; if (rg > N - 1) rg = N - 1;   // clamp: dup, store-guarded
        gW[i] = W + (size_t)rg * ldw + ((c ^ ((r >> 1) & 3)) * 8);
    }

    const int arow = wr * (MT / 2) + (lane & 15);
    const int brow = wc * 64 + (lane & 15);
    const int szA = (arow >> 1) & 3;          // row+16 invariant
    const int szB = (brow >> 1) & 3;
    const int hi = lane >> 4;                 // 0..3 (= k-chunk for BKT=32)

    auto STAGE = [&](int buf) {
        short* As = smem + buf * BUFS;
        short* Ws = As + MT * BKT;
        #pragma unroll
        for (int i = 0; i < ACA; ++i) {
            gl_lds16(gA[i], &As[(i * 256 + wid * 64) * 8]);
            gA[i] += BKT;
        }
        #pragma unroll
        for (int i = 0; i < ACW; ++i) {
            gl_lds16(gW[i], &Ws[(i * 256 + wid * 64) * 8]);
            gW[i] += BKT;
        }
    };

    f32x4 acc[MFR][4] = {};

    STAGE(0);
    __syncthreads();

    const int ntiles = K / BKT;
    for (int t = 0; t < ntiles; ++t) {
        const int cur = t & 1;
        if (t + 1 < ntiles) STAGE(cur ^ 1);   // prefetch flies during compute

        const short* As = smem + cur * BUFS;
        const short* Ws = As + MT * BKT;
        bf16x8 a[MFR], b[4];
        #pragma unroll
        for (int mf = 0; mf < MFR; ++mf)
            a[mf] = *reinterpret_cast<const bf16x8*>(
                &As[(arow + mf * 16) * BKT + ((hi ^ szA) * 8)]);
        #pragma unroll
        for (int nf = 0; nf < 4; ++nf)
            b[nf] = *reinterpret_cast<const bf16x8*>(
                &Ws[(brow + nf * 16) * BKT + ((hi ^ szB) * 8)]);
        #pragma unroll
        for (int mf = 0; mf < MFR; ++mf)
            #pragma unroll
            for (int nf = 0; nf < 4; ++nf)
                acc[mf][nf] = __builtin_amdgcn_mfma_f32_16x16x32_bf16(
                    a[mf], b[nf], acc[mf][nf], 0, 0, 0);

        __syncthreads();   // implicit vmcnt(0): prefetch landed; buffers safe
    }

    if (OUT == 0 && NTST) {
        // LDS-transposed epilogue: full-line NT dword stores.
        float* Cs = (float*)smem;    // [32][132] fp32 (16.9KB <= 2*BUFS*2B)
        #pragma unroll
        for (int mf = 0; mf < MFR; ++mf) {
            __syncthreads();
            #pragma unroll
            for (int nf = 0; nf < 4; ++nf) {
                #pragma unroll
                for (int j = 0; j < 4; ++j)
                    Cs[(wr * 16 + hi * 4 + j) * 132 + wc * 64 + nf * 16 + (lane & 15)]
                        = acc[mf][nf][j];
            }
            __syncthreads();
            #pragma unroll
            for (int rr = 0; rr < 8; ++rr) {
                int lrow = wid * 8 + rr;      // 0..31
                int grow = row0 + (lrow < 16 ? mf * 16 + lrow
                                             : (MT / 2) + mf * 16 + (lrow - 16));
                #pragma unroll
                for (int hf = 0; hf < 2; ++hf) {
                    int cc = col0 + hf * 64 + lane;
                    if (cc < N)
                        __builtin_nontemporal_store(
                            Cs[lrow * 132 + hf * 64 + lane],
                            &C[(size_t)grow * ldc + cc]);
                }
            }
        }
    } else {
        #pragma unroll
        for (int mf = 0; mf < MFR; ++mf) {
            #pragma unroll
            for (int nf = 0; nf < 4; ++nf) {
                int r  = row0 + wr * (MT / 2) + mf * 16 + hi * 4;
                int cc = col0 + wc * 64 + nf * 16 + (lane & 15);
                if (cc < N) {
                    f32x4 d = acc[mf][nf];
                    if (OUT == 3) {
                        if (cc < DI) {
                            float bv = bias[cc];
                            #pragma unroll
                            for (int j = 0; j < 4; ++j) {
                                float v = d[j] + bv;
                                v = (v > 20.f) ? v : log1pf(__expf(v));
                                C[(size_t)(r + j) * ldc + cc] = v;
                            }
                        } else {
                            #pragma unroll
                            for (int j = 0; j < 4; ++j)
                                aux[(size_t)(r + j) * 32 + (cc - DI)] = d[j];
                        }
                    } else {
                        #pragma unroll
                        for (int j = 0; j < 4; ++j) {
                            C[(size_t)(r + j) * ldc + cc] = d[j];
                            if (OUT == 1)
                                Cbf[(size_t)(r + j) * ldc + cc] =
                                    (unsigned short)f2bf(d[j]);
                        }
                    }
                }
            }
        }
    }
}

// ---------------------------------------------------------------------------
// Depthwise causal conv(4) + bias + silu; dual write fp32 + bf16
// ---------------------------------------------------------------------------
__global__ __launch_bounds__(256) void conv_silu_k(
    const float* __restrict__ xz, const float* __restrict__ cw,
    const float* __restrict__ cb, float* __restrict__ xinf,
    unsigned short* __restrict__ xinb)
{
    int i = blockIdx.x * 256 + threadIdx.x;   // over ROWS*DI
    if (i >= ROWS * DI) return;
    int row = i / DI;
    int c = i - row * DI;
    int t = row & (SL - 1);
    int b = row >> 10;
    float acc = cb[c];
    const float* base = xz + (size_t)(b * SL) * (2 * DI) + c;
    #pragma unroll
    for (int k = 0; k < DC; ++k) {
        int tt = t + k - (DC - 1);
        if (tt >= 0) acc += base[(size_t)tt * (2 * DI)] * cw[c * DC + k];
    }
    float v = acc / (1.f + __expf(-acc));
    xinf[i] = v;
    xinb[i] = (unsigned short)f2bf(v);
}

// ---------------------------------------------------------------------------
// Chunked selective scan, 2 kernels. CCH=32 chunks of CLEN=32.
// bc buffer: B = bc[r*32 + s], C = bc[r*32 + 16 + s].
// ---------------------------------------------------------------------------
__global__ __launch_bounds__(256) void scan_phase1(
    const float* __restrict__ dt,
    const float* __restrict__ bc,
    const float* __restrict__ xin,
    const float* __restrict__ Alog,
    float* __restrict__ hend,
    float* __restrict__ eprod)
{
    int blk = blockIdx.x;
    int c = blk % CCH;
    int tmp = blk / CCH;
    int dblk = tmp % (DI / 16);
    int b = tmp / (DI / 16);
    int s = threadIdx.x & 15;
    int d = dblk * 16 + (threadIdx.x >> 4);
    float A = -__expf(Alog[d * DS + s]);
    float h = 0.f, P = 1.f;
    const int rowbase = b * SL + c * CLEN;
    #pragma unroll 4
    for (int t = 0; t < CLEN; ++t) {
        int r = rowbase + t;
        float dtv = dt[(size_t)r * DI + d];
        float xv  = xin[(size_t)r * DI + d];
        float Bv  = bc[(size_t)r * 32 + s];
        float e = __expf(dtv * A);
        h = h * e + dtv * xv * Bv;
        P *= e;
    }
    size_t idx = ((size_t)(b * CCH + c) * DI + d) * DS + s;
    hend[idx]  = h;
    eprod[idx] = P;
}

__global__ __launch_bounds__(256) void scan_phase3(
    const float* __restrict__ dt,
    const float* __restrict__ bc,
    const float* __restrict__ xin,
    const float* __restrict__ xz,
    const float* __restrict__ Alog,
    const float* __restrict__ Dp,
    const float* __restrict__ hend,
    const float* __restrict__ eprod,
    unsigned short* __restrict__ ybf)
{
    int blk = blockIdx.x;
    int c = blk % CCH;
    int tmp = blk / CCH;
    int dblk = tmp % (DI / 16);
    int b = tmp / (DI / 16);
    int s = threadIdx.x & 15;
    int d = dblk * 16 + (threadIdx.x >> 4);
    float A = -__expf(Alog[d * DS + s]);
    float Dv = Dp[d];

    float h = 0.f;
    const size_t pbase = ((size_t)b * CCH * DI + d) * DS + s;
    for (int j = 0; j < c; ++j) {
        size_t idx = pbase + (size_t)j * (DI * DS);
        h = h * eprod[idx] + hend[idx];
    }

    const int rowbase = b * SL + c * CLEN;
    #pragma unroll 2
    for (int t = 0; t < CLEN; ++t) {
        int r = rowbase + t;
        float dtv = dt[(size_t)r * DI + d];
        float xv  = xin[(size_t)r * DI + d];
        float Bv  = bc[(size_t)r * 32 + s];
        float Cv  = bc[(size_t)r * 32 + 16 + s];
        float e = __expf(dtv * A);
        h = h * e + dtv * xv * Bv;
        float p = h * Cv;
        p += __shfl_xor(p, 1, 64);
        p += __shfl_xor(p, 2, 64);
        p += __shfl_xor(p, 4, 64);
        p += __shfl_xor(p, 8, 64);
        if (s == 0) {
            float z = xz[(size_t)r * (2 * DI) + DI + d];
            float yv = (p + xv * Dv) * (z / (1.f + __expf(-z)));
            ybf[(size_t)r * DI + d] = (unsigned short)f2bf(yv);
        }
    }
}

// ---------------------------------------------------------------------------
// LayerNorm over rows of 768, bf16 output
// ---------------------------------------------------------------------------
__global__ __launch_bounds__(256) void ln_k(
    const float* __restrict__ x, const float* __restrict__ w,
    const float* __restrict__ b, unsigned short* __restrict__ o)
{
    int row = blockIdx.x;
    int tid = threadIdx.x;
    const float* xr = x + (size_t)row * DM;
    float v0 = xr[tid], v1 = xr[tid + 256], v2 = xr[tid + 512];
    float s = v0 + v1 + v2;
    #pragma unroll
    for (int off = 1; off < 64; off <<= 1) s += __shfl_xor(s, off, 64);
    __shared__ float red[4];
    __shared__ float red2[4];
    int wid = tid >> 6, lane = tid & 63;
    if (lane == 0) red[wid] = s;
    __syncthreads();
    float mu = (red[0] + red[1] + red[2] + red[3]) * (1.f / 768.f);
    float d0 = v0 - mu, d1 = v1 - mu, d2 = v2 - mu;
    float q = d0 * d0 + d1 * d1 + d2 * d2;
    #pragma unroll
    for (int off = 1; off < 64; off <<= 1) q += __shfl_xor(q, off, 64);
    if (lane == 0) red2[wid] = q;
    __syncthreads();
    float var = (red2[0] + red2[1] + red2[2] + red2[3]) * (1.f / 768.f);
    float rs = rsqrtf(var + 1e-5f);
    o[(size_t)row * DM + tid]       = (unsigned short)f2bf(d0 * rs * w[tid]       + b[tid]);
    o[(size_t)row * DM + tid + 256] = (unsigned short)f2bf(d1 * rs * w[tid + 256] + b[tid + 256]);
    o[(size_t)row * DM + tid + 512] = (unsigned short)f2bf(d2 * rs * w[tid + 512] + b[tid + 512]);
}

// ---------------------------------------------------------------------------
extern "C" void kernel_launch(void* const* d_in, const int* in_sizes, int n_in,
                              void* d_out, int out_size, void* d_ws, size_t ws_size,
                              hipStream_t stream) {
    const int*   ids        = (const int*)d_in[0];
    const float* emb        = (const float*)d_in[1];
    const float* in_proj_w  = (const float*)d_in[2];
    const float* conv_w     = (const float*)d_in[3];
    const float* conv_b     = (const float*)d_in[4];
    const float* x_proj_w   = (const float*)d_in[5];
    const float* dt_proj_w  = (const float*)d_in[6];
    const float* dt_proj_b  = (const float*)d_in[7];
    const float* A_log      = (const float*)d_in[8];
    const float* D_param    = (const float*)d_in[9];
    const float* out_proj_w = (const float*)d_in[10];
    const float* norm_w     = (const float*)d_in[11];
    const float* norm_b     = (const float*)d_in[12];
    float* out = (float*)d_out;

    // ---- workspace layout ----
    char* base = (char*)d_ws;
    size_t off = 0;
    auto alloc_f = [&](size_t n) { float* p = (float*)(base + off); off += n * 4; return p; };
    auto alloc_u = [&](size_t n) { unsigned short* p = (unsigned short*)(base + off); off += n * 2; return p; };

    float* x     = alloc_f((size_t)ROWS * DM);
    float* xz    = alloc_f((size_t)ROWS * 2 * DI);
    float* xinf  = alloc_f((size_t)ROWS * DI);
    float* bc    = alloc_f((size_t)ROWS * 32);
    float* dt    = alloc_f((size_t)ROWS * DI);
    float* hend  = alloc_f((size_t)NB * CCH * DI * DS);
    float* eprod = alloc_f((size_t)NB * CCH * DI * DS);
    unsigned short* xbf   = alloc_u((size_t)ROWS * DM);
    unsigned short* ybf   = alloc_u((size_t)ROWS * DI);
    unsigned short* xinb  = alloc_u((size_t)ROWS * DI);
    unsigned short* xlnbf = alloc_u((size_t)ROWS * DM);
    unsigned short* inw_bf = alloc_u((size_t)NLAYER * 2 * DI * DM);
    unsigned short* ow_bf  = alloc_u((size_t)NLAYER * DM * DI);
    unsigned short* wbig  = alloc_u((size_t)NLAYER * NBIG * DI);
    unsigned short* emb_bf = alloc_u((size_t)VOCAB * DM);
    (void)ws_size;

    // ---- weight preconversion (once per call) ----
    {
        int n4a = NLAYER * 2 * DI * DM / 4;
        cvt_bf16_k<<<(n4a + 255) / 256, 256, 0, stream>>>(in_proj_w, inw_bf, n4a);
        int n4b = NLAYER * DM * DI / 4;
        cvt_bf16_k<<<(n4b + 255) / 256, 256, 0, stream>>>(out_proj_w, ow_bf, n4b);
        wc_k<<<dim3(12, 13, NLAYER), 256, 0, stream>>>(dt_proj_w, x_proj_w, wbig);
        int n4e = VOCAB * DM / 4;
        cvt_bf16_k<<<(n4e + 255) / 256, 256, 0, stream>>>(emb, emb_bf, n4e);
    }

    embed_k<<<(ROWS * DM + 255) / 256, 256, 0, stream>>>(ids, emb, xbf);

    const int scan_grid = NB * (DI / 16) * CCH;      // 6144 blocks

    for (int i = 0; i < NLAYER; ++i) {
        const float* cw  = conv_w  + (size_t)i * DI * DC;
        const float* cb  = conv_b  + (size_t)i * DI;
        const float* dtb = dt_proj_b + (size_t)i * DI;
        const float* Al  = A_log   + (size_t)i * DI * DS;
        const float* Dpar= D_param + (size_t)i * DI;

        // in_proj: xz = xbf @ inw^T  (64-row tile, GY=32, 24 col tiles = 768 blocks)
        const unsigned short* inw = inw_bf + (size_t)i * 2 * DI * DM;
        gemm_bf16<64, 0, false><<<24 * 32, 256, 0, stream>>>(
            xbf, DM, inw, DM, xz, nullptr, 2 * DI, 32, 2 * DI, DM, nullptr, nullptr);

        conv_silu_k<<<(ROWS * DI) / 256, 256, 0, stream>>>(xz, cw, cb, xinf, xinb);

        // fused dt + B/C: [dt | bc] = xinb @ wbig[i]^T  (N=1568, K=1536, 416 blocks)
        const unsigned short* wb = wbig + (size_t)i * NBIG * DI;
        gemm_bf16<64, 3, false><<<13 * 32, 256, 0, stream>>>(
            xinb, DI, wb, DI, dt, nullptr, DI, 32, NBIG, DI, dtb, bc);

        scan_phase1<<<scan_grid, 256, 0, stream>>>(dt, bc, xinf, Al, hend, eprod);
        scan_phase3<<<scan_grid, 256, 0, stream>>>(dt, bc, xinf, xz, Al, Dpar,
                                                   hend, eprod, ybf);

        // out_proj: x(fp32) + xbf(bf16) = ybf @ ow^T  (64-tile, GY=32)
        const unsigned short* ow = ow_bf + (size_t)i * DM * DI;
        gemm_bf16<64, 1, false><<<6 * 32, 256, 0, stream>>>(
            ybf, DI, ow, DI, x, xbf, DM, 32, DM, DI, nullptr, nullptr);
    }

    ln_k<<<ROWS, 256, 0, stream>>>(x, norm_w, norm_b, xlnbf);
    // logits: out = xlnbf @ emb^T  (128-tile, dbuf, NT transposed epilogue)
    gemm_bf16<128, 0, true><<<393 * 16, 256, 0, stream>>>(
        xlnbf, DM, emb_bf, DM, out, nullptr, VOCAB, 16, VOCAB, DM, nullptr, nullptr);
}

// Round 10
// 3203.794 us; speedup vs baseline: 5.3056x; 1.0576x over previous
//
#include <hip/hip_runtime.h>
#include <hip/hip_bf16.h>

#define DI 1536
#define DS 16
#define DC 4
#define DTR 48
#define NB 2
#define SL 1024
#define DM 768
#define NLAYER 12
#define VOCAB 50257
#define ROWS (NB*SL)   // 2048
#define CCH 32         // scan chunks
#define CLEN (SL/CCH)  // 32
#define NBIG (DI+32)   // 1568: fused dt(1536) + B/C(32) outputs

typedef __attribute__((ext_vector_type(8))) short bf16x8;
typedef __attribute__((ext_vector_type(4))) short short4v;
typedef __attribute__((ext_vector_type(4))) float f32x4;

__device__ inline short f2bf(float f) {
    unsigned u = __builtin_bit_cast(unsigned, f);
    unsigned r = (u + 0x7fffu + ((u >> 16) & 1u)) >> 16;
    return (short)r;
}
__device__ inline float bf2f(unsigned short u) {
    unsigned x = ((unsigned)u) << 16;
    return __builtin_bit_cast(float, x);
}

__device__ __forceinline__ void gl_lds16(const void* g, void* l) {
    __builtin_amdgcn_global_load_lds(
        (const __attribute__((address_space(1))) unsigned int*)g,
        (__attribute__((address_space(3))) unsigned int*)l, 16, 0, 0);
}

// ---------------------------------------------------------------------------
// fp32 -> bf16 elementwise convert (n multiple of 4)
// ---------------------------------------------------------------------------
__global__ __launch_bounds__(256) void cvt_bf16_k(const float* __restrict__ src,
                                                  unsigned short* __restrict__ dst,
                                                  int n4) {
    int i = blockIdx.x * 256 + threadIdx.x;
    if (i >= n4) return;
    float4 v = *reinterpret_cast<const float4*>(src + (size_t)i * 4);
    short4v o;
    o[0] = f2bf(v.x); o[1] = f2bf(v.y); o[2] = f2bf(v.z); o[3] = f2bf(v.w);
    *reinterpret_cast<short4v*>(dst + (size_t)i * 4) = o;
}

// ---------------------------------------------------------------------------
// Wc precompute: wbig[l] rows 0..1535 = dtw @ xpw[:48]  (bf16),
//                rows 1536..1567 = xpw[48:80] (bf16).
// ---------------------------------------------------------------------------
__global__ __launch_bounds__(256) void wc_k(
    const float* __restrict__ dtw_all,   // (NL, DI, DTR)
    const float* __restrict__ xpw_all,   // (NL, 80, DI)
    unsigned short* __restrict__ wbig)   // (NL, NBIG, DI)
{
    int l = blockIdx.z;
    const float* dtw = dtw_all + (size_t)l * DI * DTR;
    const float* xpw = xpw_all + (size_t)l * 80 * DI;
    unsigned short* wb = wbig + (size_t)l * NBIG * DI;
    int tid = threadIdx.x;
    if (blockIdx.y == 12) {
        if (blockIdx.x == 0) {
            for (int idx = tid; idx < 32 * DI; idx += 256) {
                int rr = idx / DI, k = idx - rr * DI;
                wb[(size_t)(DI + rr) * DI + k] =
                    (unsigned short)f2bf(xpw[(size_t)(48 + rr) * DI + k]);
            }
        }
        return;
    }
    __shared__ float sd[128 * 48];
    __shared__ float sx[48 * 128];
    int d0 = blockIdx.y * 128, k0 = blockIdx.x * 128;
    for (int idx = tid; idx < 128 * 48; idx += 256) {
        int r = idx / 48, j = idx - r * 48;
        sd[idx] = dtw[(size_t)(d0 + r) * DTR + j];
    }
    for (int idx = tid; idx < 48 * 128; idx += 256) {
        int j = idx / 128, k = idx - j * 128;
        sx[idx] = xpw[(size_t)j * DI + k0 + k];
    }
    __syncthreads();
    int tx = tid & 15, ty = tid >> 4;
    float acc[8][8] = {};
    for (int j = 0; j < 48; ++j) {
        float a[8], w[8];
        #pragma unroll
        for (int i = 0; i < 8; ++i) a[i] = sd[(ty * 8 + i) * 48 + j];
        #pragma unroll
        for (int i = 0; i < 8; ++i) w[i] = sx[j * 128 + tx * 8 + i];
        #pragma unroll
        for (int i = 0; i < 8; ++i)
            #pragma unroll
            for (int jj = 0; jj < 8; ++jj)
                acc[i][jj] += a[i] * w[jj];
    }
    for (int i = 0; i < 8; ++i)
        for (int jj = 0; jj < 8; ++jj)
            wb[(size_t)(d0 + ty * 8 + i) * DI + k0 + tx * 8 + jj] =
                (unsigned short)f2bf(acc[i][jj]);
}

// ---------------------------------------------------------------------------
// Embedding: xbf[b,s,:] = bf16(emb[ids[b,s]] * sqrt(768))
// ---------------------------------------------------------------------------
__global__ __launch_bounds__(256) void embed_k(const int* __restrict__ ids,
                                               const float* __restrict__ emb,
                                               unsigned short* __restrict__ xbf) {
    int i = blockIdx.x * 256 + threadIdx.x;      // over ROWS*DM
    if (i >= ROWS * DM) return;
    int row = i / DM;
    int c = i - row * DM;
    xbf[i] = (unsigned short)f2bf(emb[(size_t)ids[row] * DM + c] * 27.712812921102035f);
}

// ---------------------------------------------------------------------------
// bf16-MFMA GEMM, double-buffered with COUNTED vmcnt (T4):
//   loop t: STAGE(next) issue; s_waitcnt vmcnt(ISS) [cur landed, next flies];
//           s_barrier; MFMA on cur; s_barrier [write-after-read guard].
// MT x 128 tile, BKT=32, 4 waves, mfma_f32_16x16x32_bf16.
// global_load_lds staging, linear LDS dest, pre-swizzled source
// (involution chunk ^ ((row>>1)&3), conflict-free ds_read_b128).
// OUT: 0 = fp32 store (NTST -> LDS-transposed full-line NT epilogue);
//      2 = bf16-only store; 3 = fused dt softplus (bf16) / BC (fp32) split.
// ---------------------------------------------------------------------------
template<int MT, int OUT, bool NTST>
__global__ __launch_bounds__(256) void gemm_bf16(
    const unsigned short* __restrict__ A, int lda,
    const unsigned short* __restrict__ W, int ldw,
    float* __restrict__ C, unsigned short* __restrict__ Cbf, int ldc,
    int GY, int N, int K,
    const float* __restrict__ bias, float* __restrict__ aux)
{
    constexpr int BKT = 32;
    constexpr int CPR = BKT / 8;              // 4 chunks per row
    constexpr int ACA = MT * CPR / 256;       // A staging issues/thread
    constexpr int ACW = 128 * CPR / 256;      // W staging issues/thread (2)
    constexpr int ISS = ACA + ACW;            // gl_lds instrs per STAGE
    constexpr int MFR = MT / 32;              // M fragments per wave
    constexpr int BUFS = (MT + 128) * BKT;    // shorts per buffer
    __shared__ __align__(16) short smem[2 * BUFS];

    const int tid  = threadIdx.x;
    const int lane = tid & 63;
    const int wid  = tid >> 6;
    const int wr   = wid >> 1, wc = wid & 1;

    // bijective XCD-chunked swizzle, then col-major decode
    const int nwg = gridDim.x;
    const int q = nwg >> 3, rm = nwg & 7;
    const int xcd = blockIdx.x & 7, bidx = blockIdx.x >> 3;
    const int wg = (xcd < rm ? xcd * (q + 1) : rm * (q + 1) + (xcd - rm) * q) + bidx;
    const int row0 = (wg % GY) * MT;
    const int col0 = (wg / GY) * 128;

    // ---- staging setup (pre-swizzled global sources) ----
    const unsigned short* gA[ACA];
    const unsigned short* gW[ACW];
    #pragma unroll
    for (int i = 0; i < ACA; ++i) {
        int cid = i * 256 + tid;
        int r = cid / CPR, c = cid % CPR;
        gA[i] = A + (size_t)(row0 + r) * lda + ((c ^ ((r >> 1) & 3)) * 8);
    }
    #pragma unroll
    for (int i = 0; i < ACW; ++i) {
        int cid = i * 256 + tid;
        int r = cid / CPR, c = cid % CPR;
        int rg = col0 + r; if (rg > N - 1) rg = N - 1;   // clamp: dup, store-guarded
        gW[i] = W + (size_t)rg * ldw + ((c ^ ((r >> 1) & 3)) * 8);
    }

    const int arow = wr * (MT / 2) + (lane & 15);
    const int brow = wc * 64 + (lane & 15);
    const int szA = (arow >> 1) & 3;          // row+16 invariant
    const int szB = (brow >> 1) & 3;
    const int hi = lane >> 4;                 // 0..3 (= k-chunk for BKT=32)

    auto STAGE = [&](int buf) {
        short* As = smem + buf * BUFS;
        short* Ws = As + MT * BKT;
        #pragma unroll
        for (int i = 0; i < ACA; ++i) {
            gl_lds16(gA[i], &As[(i * 256 + wid * 64) * 8]);
            gA[i] += BKT;
        }
        #pragma unroll
        for (int i = 0; i < ACW; ++i) {
            gl_lds16(gW[i], &Ws[(i * 256 + wid * 64) * 8]);
            gW[i] += BKT;
        }
    };

    f32x4 acc[MFR][4] = {};

    STAGE(0);
    const int ntiles = K / BKT;
    for (int t = 0; t < ntiles; ++t) {
        const int cur = t & 1;
        if (t + 1 < ntiles) {
            STAGE(cur ^ 1);          // next tile's loads stay in flight
            asm volatile("s_waitcnt vmcnt(%0)" :: "n"(ISS) : "memory");
        } else {
            asm volatile("s_waitcnt vmcnt(0)" ::: "memory");
        }
        __builtin_amdgcn_sched_barrier(0);
        __builtin_amdgcn_s_barrier();      // cur buffer visible to all waves

        const short* As = smem + cur * BUFS;
        const short* Ws = As + MT * BKT;
        bf16x8 a[MFR], b[4];
        #pragma unroll
        for (int mf = 0; mf < MFR; ++mf)
            a[mf] = *reinterpret_cast<const bf16x8*>(
                &As[(arow + mf * 16) * BKT + ((hi ^ szA) * 8)]);
        #pragma unroll
        for (int nf = 0; nf < 4; ++nf)
            b[nf] = *reinterpret_cast<const bf16x8*>(
                &Ws[(brow + nf * 16) * BKT + ((hi ^ szB) * 8)]);
        #pragma unroll
        for (int mf = 0; mf < MFR; ++mf)
            #pragma unroll
            for (int nf = 0; nf < 4; ++nf)
                acc[mf][nf] = __builtin_amdgcn_mfma_f32_16x16x32_bf16(
                    a[mf], b[nf], acc[mf][nf], 0, 0, 0);

        __builtin_amdgcn_s_barrier();      // reads retired before overwrite
    }

    if (OUT == 0 && NTST) {
        __syncthreads();
        // LDS-transposed epilogue: full-line NT dword stores.
        float* Cs = (float*)smem;    // [32][132] fp32 (16.9KB <= 2*BUFS*2B)
        #pragma unroll
        for (int mf = 0; mf < MFR; ++mf) {
            __syncthreads();
            #pragma unroll
            for (int nf = 0; nf < 4; ++nf) {
                #pragma unroll
                for (int j = 0; j < 4; ++j)
                    Cs[(wr * 16 + hi * 4 + j) * 132 + wc * 64 + nf * 16 + (lane & 15)]
                        = acc[mf][nf][j];
            }
            __syncthreads();
            #pragma unroll
            for (int rr = 0; rr < 8; ++rr) {
                int lrow = wid * 8 + rr;      // 0..31
                int grow = row0 + (lrow < 16 ? mf * 16 + lrow
                                             : (MT / 2) + mf * 16 + (lrow - 16));
                #pragma unroll
                for (int hf = 0; hf < 2; ++hf) {
                    int cc = col0 + hf * 64 + lane;
                    if (cc < N)
                        __builtin_nontemporal_store(
                            Cs[lrow * 132 + hf * 64 + lane],
                            &C[(size_t)grow * ldc + cc]);
                }
            }
        }
    } else {
        #pragma unroll
        for (int mf = 0; mf < MFR; ++mf) {
            #pragma unroll
            for (int nf = 0; nf < 4; ++nf) {
                int r  = row0 + wr * (MT / 2) + mf * 16 + hi * 4;
                int cc = col0 + wc * 64 + nf * 16 + (lane & 15);
                if (cc < N) {
                    f32x4 d = acc[mf][nf];
                    if (OUT == 3) {
                        if (cc < DI) {
                            float bv = bias[cc];
                            #pragma unroll
                            for (int j = 0; j < 4; ++j) {
                                float v = d[j] + bv;
                                v = (v > 20.f) ? v : log1pf(__expf(v));
                                Cbf[(size_t)(r + j) * ldc + cc] = (unsigned short)f2bf(v);
                            }
                        } else {
                            #pragma unroll
                            for (int j = 0; j < 4; ++j)
                                aux[(size_t)(r + j) * 32 + (cc - DI)] = d[j];
                        }
                    } else if (OUT == 2) {
                        #pragma unroll
                        for (int j = 0; j < 4; ++j)
                            Cbf[(size_t)(r + j) * ldc + cc] = (unsigned short)f2bf(d[j]);
                    } else {
                        #pragma unroll
                        for (int j = 0; j < 4; ++j)
                            C[(size_t)(r + j) * ldc + cc] = d[j];
                    }
                }
            }
        }
    }
}

// ---------------------------------------------------------------------------
// Depthwise causal conv(4) + bias + silu; bf16 in (xz), bf16 out (xinb)
// ---------------------------------------------------------------------------
__global__ __launch_bounds__(256) void conv_silu_k(
    const unsigned short* __restrict__ xz, const float* __restrict__ cw,
    const float* __restrict__ cb, unsigned short* __restrict__ xinb)
{
    int i = blockIdx.x * 256 + threadIdx.x;   // over ROWS*DI
    if (i >= ROWS * DI) return;
    int row = i / DI;
    int c = i - row * DI;
    int t = row & (SL - 1);
    int b = row >> 10;
    float acc = cb[c];
    const unsigned short* base = xz + (size_t)(b * SL) * (2 * DI) + c;
    #pragma unroll
    for (int k = 0; k < DC; ++k) {
        int tt = t + k - (DC - 1);
        if (tt >= 0) acc += bf2f(base[(size_t)tt * (2 * DI)]) * cw[c * DC + k];
    }
    float v = acc / (1.f + __expf(-acc));
    xinb[i] = (unsigned short)f2bf(v);
}

// ---------------------------------------------------------------------------
// Chunked selective scan, 2 kernels. CCH=32 chunks of CLEN=32.
// dt, xin bf16; bc fp32: B = bc[r*32 + s], C = bc[r*32 + 16 + s].
// ---------------------------------------------------------------------------
__global__ __launch_bounds__(256) void scan_phase1(
    const unsigned short* __restrict__ dt,
    const float* __restrict__ bc,
    const unsigned short* __restrict__ xin,
    const float* __restrict__ Alog,
    float* __restrict__ hend,
    float* __restrict__ eprod)
{
    int blk = blockIdx.x;
    int c = blk % CCH;
    int tmp = blk / CCH;
    int dblk = tmp % (DI / 16);
    int b = tmp / (DI / 16);
    int s = threadIdx.x & 15;
    int d = dblk * 16 + (threadIdx.x >> 4);
    float A = -__expf(Alog[d * DS + s]);
    float h = 0.f, P = 1.f;
    const int rowbase = b * SL + c * CLEN;
    #pragma unroll 4
    for (int t = 0; t < CLEN; ++t) {
        int r = rowbase + t;
        float dtv = bf2f(dt[(size_t)r * DI + d]);
        float xv  = bf2f(xin[(size_t)r * DI + d]);
        float Bv  = bc[(size_t)r * 32 + s];
        float e = __expf(dtv * A);
        h = h * e + dtv * xv * Bv;
        P *= e;
    }
    size_t idx = ((size_t)(b * CCH + c) * DI + d) * DS + s;
    hend[idx]  = h;
    eprod[idx] = P;
}

__global__ __launch_bounds__(256) void scan_phase3(
    const unsigned short* __restrict__ dt,
    const float* __restrict__ bc,
    const unsigned short* __restrict__ xin,
    const unsigned short* __restrict__ xz,   // z = cols [DI:2*DI)
    const float* __restrict__ Alog,
    const float* __restrict__ Dp,
    const float* __restrict__ hend,
    const float* __restrict__ eprod,
    unsigned short* __restrict__ ybf)
{
    int blk = blockIdx.x;
    int c = blk % CCH;
    int tmp = blk / CCH;
    int dblk = tmp % (DI / 16);
    int b = tmp / (DI / 16);
    int s = threadIdx.x & 15;
    int d = dblk * 16 + (threadIdx.x >> 4);
    float A = -__expf(Alog[d * DS + s]);
    float Dv = Dp[d];

    float h = 0.f;
    const size_t pbase = ((size_t)b * CCH * DI + d) * DS + s;
    for (int j = 0; j < c; ++j) {
        size_t idx = pbase + (size_t)j * (DI * DS);
        h = h * eprod[idx] + hend[idx];
    }

    const int rowbase = b * SL + c * CLEN;
    #pragma unroll 2
    for (int t = 0; t < CLEN; ++t) {
        int r = rowbase + t;
        float dtv = bf2f(dt[(size_t)r * DI + d]);
        float xv  = bf2f(xin[(size_t)r * DI + d]);
        float Bv  = bc[(size_t)r * 32 + s];
        float Cv  = bc[(size_t)r * 32 + 16 + s];
        float e = __expf(dtv * A);
        h = h * e + dtv * xv * Bv;
        float p = h * Cv;
        p += __shfl_xor(p, 1, 64);
        p += __shfl_xor(p, 2, 64);
        p += __shfl_xor(p, 4, 64);
        p += __shfl_xor(p, 8, 64);
        if (s == 0) {
            float z = bf2f(xz[(size_t)r * (2 * DI) + DI + d]);
            float yv = (p + xv * Dv) * (z / (1.f + __expf(-z)));
            ybf[(size_t)r * DI + d] = (unsigned short)f2bf(yv);
        }
    }
}

// ---------------------------------------------------------------------------
// LayerNorm over rows of 768, bf16 in, bf16 out
// ---------------------------------------------------------------------------
__global__ __launch_bounds__(256) void ln_k(
    const unsigned short* __restrict__ x, const float* __restrict__ w,
    const float* __restrict__ b, unsigned short* __restrict__ o)
{
    int row = blockIdx.x;
    int tid = threadIdx.x;
    const unsigned short* xr = x + (size_t)row * DM;
    float v0 = bf2f(xr[tid]), v1 = bf2f(xr[tid + 256]), v2 = bf2f(xr[tid + 512]);
    float s = v0 + v1 + v2;
    #pragma unroll
    for (int off = 1; off < 64; off <<= 1) s += __shfl_xor(s, off, 64);
    __shared__ float red[4];
    __shared__ float red2[4];
    int wid = tid >> 6, lane = tid & 63;
    if (lane == 0) red[wid] = s;
    __syncthreads();
    float mu = (red[0] + red[1] + red[2] + red[3]) * (1.f / 768.f);
    float d0 = v0 - mu, d1 = v1 - mu, d2 = v2 - mu;
    float q = d0 * d0 + d1 * d1 + d2 * d2;
    #pragma unroll
    for (int off = 1; off < 64; off <<= 1) q += __shfl_xor(q, off, 64);
    if (lane == 0) red2[wid] = q;
    __syncthreads();
    float var = (red2[0] + red2[1] + red2[2] + red2[3]) * (1.f / 768.f);
    float rs = rsqrtf(var + 1e-5f);
    o[(size_t)row * DM + tid]       = (unsigned short)f2bf(d0 * rs * w[tid]       + b[tid]);
    o[(size_t)row * DM + tid + 256] = (unsigned short)f2bf(d1 * rs * w[tid + 256] + b[tid + 256]);
    o[(size_t)row * DM + tid + 512] = (unsigned short)f2bf(d2 * rs * w[tid + 512] + b[tid + 512]);
}

// ---------------------------------------------------------------------------
extern "C" void kernel_launch(void* const* d_in, const int* in_sizes, int n_in,
                              void* d_out, int out_size, void* d_ws, size_t ws_size,
                              hipStream_t stream) {
    const int*   ids        = (const int*)d_in[0];
    const float* emb        = (const float*)d_in[1];
    const float* in_proj_w  = (const float*)d_in[2];
    const float* conv_w     = (const float*)d_in[3];
    const float* conv_b     = (const float*)d_in[4];
    const float* x_proj_w   = (const float*)d_in[5];
    const float* dt_proj_w  = (const float*)d_in[6];
    const float* dt_proj_b  = (const float*)d_in[7];
    const float* A_log      = (const float*)d_in[8];
    const float* D_param    = (const float*)d_in[9];
    const float* out_proj_w = (const float*)d_in[10];
    const float* norm_w     = (const float*)d_in[11];
    const float* norm_b     = (const float*)d_in[12];
    float* out = (float*)d_out;

    // ---- workspace layout ----
    char* base = (char*)d_ws;
    size_t off = 0;
    auto alloc_f = [&](size_t n) { float* p = (float*)(base + off); off += n * 4; return p; };
    auto alloc_u = [&](size_t n) { unsigned short* p = (unsigned short*)(base + off); off += n * 2; return p; };

    float* bc    = alloc_f((size_t)ROWS * 32);
    float* hend  = alloc_f((size_t)NB * CCH * DI * DS);
    float* eprod = alloc_f((size_t)NB * CCH * DI * DS);
    unsigned short* xbf   = alloc_u((size_t)ROWS * DM);
    unsigned short* xzb   = alloc_u((size_t)ROWS * 2 * DI);
    unsigned short* xinb  = alloc_u((size_t)ROWS * DI);
    unsigned short* dtbf  = alloc_u((size_t)ROWS * DI);
    unsigned short* ybf   = alloc_u((size_t)ROWS * DI);
    unsigned short* xlnbf = alloc_u((size_t)ROWS * DM);
    unsigned short* inw_bf = alloc_u((size_t)NLAYER * 2 * DI * DM);
    unsigned short* ow_bf  = alloc_u((size_t)NLAYER * DM * DI);
    unsigned short* wbig  = alloc_u((size_t)NLAYER * NBIG * DI);
    unsigned short* emb_bf = alloc_u((size_t)VOCAB * DM);
    (void)ws_size;

    // ---- weight preconversion (once per call) ----
    {
        int n4a = NLAYER * 2 * DI * DM / 4;
        cvt_bf16_k<<<(n4a + 255) / 256, 256, 0, stream>>>(in_proj_w, inw_bf, n4a);
        int n4b = NLAYER * DM * DI / 4;
        cvt_bf16_k<<<(n4b + 255) / 256, 256, 0, stream>>>(out_proj_w, ow_bf, n4b);
        wc_k<<<dim3(12, 13, NLAYER), 256, 0, stream>>>(dt_proj_w, x_proj_w, wbig);
        int n4e = VOCAB * DM / 4;
        cvt_bf16_k<<<(n4e + 255) / 256, 256, 0, stream>>>(emb, emb_bf, n4e);
    }

    embed_k<<<(ROWS * DM + 255) / 256, 256, 0, stream>>>(ids, emb, xbf);

    const int scan_grid = NB * (DI / 16) * CCH;      // 6144 blocks

    for (int i = 0; i < NLAYER; ++i) {
        const float* cw  = conv_w  + (size_t)i * DI * DC;
        const float* cb  = conv_b  + (size_t)i * DI;
        const float* dtb = dt_proj_b + (size_t)i * DI;
        const float* Al  = A_log   + (size_t)i * DI * DS;
        const float* Dpar= D_param + (size_t)i * DI;

        // in_proj: xzb(bf16) = xbf @ inw^T  (64-row tile, GY=32, 768 blocks)
        const unsigned short* inw = inw_bf + (size_t)i * 2 * DI * DM;
        gemm_bf16<64, 2, false><<<24 * 32, 256, 0, stream>>>(
            xbf, DM, inw, DM, nullptr, xzb, 2 * DI, 32, 2 * DI, DM, nullptr, nullptr);

        conv_silu_k<<<(ROWS * DI) / 256, 256, 0, stream>>>(xzb, cw, cb, xinb);

        // fused dt(bf16,softplus) + B/C(fp32): xinb @ wbig[i]^T  (N=1568)
        const unsigned short* wb = wbig + (size_t)i * NBIG * DI;
        gemm_bf16<64, 3, false><<<13 * 32, 256, 0, stream>>>(
            xinb, DI, wb, DI, nullptr, dtbf, DI, 32, NBIG, DI, dtb, bc);

        scan_phase1<<<scan_grid, 256, 0, stream>>>(dtbf, bc, xinb, Al, hend, eprod);
        scan_phase3<<<scan_grid, 256, 0, stream>>>(dtbf, bc, xinb, xzb, Al, Dpar,
                                                   hend, eprod, ybf);

        // out_proj: xbf(bf16) = ybf @ ow^T  (64-tile, GY=32, 192 blocks)
        const unsigned short* ow = ow_bf + (size_t)i * DM * DI;
        gemm_bf16<64, 2, false><<<6 * 32, 256, 0, stream>>>(
            ybf, DI, ow, DI, nullptr, xbf, DM, 32, DM, DI, nullptr, nullptr);
    }

    ln_k<<<ROWS, 256, 0, stream>>>(xbf, norm_w, norm_b, xlnbf);
    // logits: out = xlnbf @ emb^T  (128-tile, counted-vmcnt dbuf, NT epilogue)
    gemm_bf16<128, 0, true><<<393 * 16, 256, 0, stream>>>(
        xlnbf, DM, emb_bf, DM, out, nullptr, VOCAB, 16, VOCAB, DM, nullptr, nullptr);
}

// Round 11
// 3129.857 us; speedup vs baseline: 5.4310x; 1.0236x over previous
//
#include <hip/hip_runtime.h>
#include <hip/hip_bf16.h>

#define DI 1536
#define DS 16
#define DC 4
#define DTR 48
#define NB 2
#define SL 1024
#define DM 768
#define NLAYER 12
#define VOCAB 50257
#define ROWS (NB*SL)   // 2048
#define CCH 32         // scan chunks
#define CLEN (SL/CCH)  // 32
#define NBIG (DI+32)   // 1568: fused dt(1536) + B/C(32) outputs

typedef __attribute__((ext_vector_type(8))) short bf16x8;
typedef __attribute__((ext_vector_type(4))) short short4v;
typedef __attribute__((ext_vector_type(4))) float f32x4;

__device__ inline short f2bf(float f) {
    unsigned u = __builtin_bit_cast(unsigned, f);
    unsigned r = (u + 0x7fffu + ((u >> 16) & 1u)) >> 16;
    return (short)r;
}
__device__ inline float bf2f(unsigned short u) {
    unsigned x = ((unsigned)u) << 16;
    return __builtin_bit_cast(float, x);
}

__device__ __forceinline__ void gl_lds16(const void* g, void* l) {
    __builtin_amdgcn_global_load_lds(
        (const __attribute__((address_space(1))) unsigned int*)g,
        (__attribute__((address_space(3))) unsigned int*)l, 16, 0, 0);
}

// ---------------------------------------------------------------------------
// fp32 -> bf16 elementwise convert (n multiple of 4)
// ---------------------------------------------------------------------------
__global__ __launch_bounds__(256) void cvt_bf16_k(const float* __restrict__ src,
                                                  unsigned short* __restrict__ dst,
                                                  int n4) {
    int i = blockIdx.x * 256 + threadIdx.x;
    if (i >= n4) return;
    float4 v = *reinterpret_cast<const float4*>(src + (size_t)i * 4);
    short4v o;
    o[0] = f2bf(v.x); o[1] = f2bf(v.y); o[2] = f2bf(v.z); o[3] = f2bf(v.w);
    *reinterpret_cast<short4v*>(dst + (size_t)i * 4) = o;
}

// ---------------------------------------------------------------------------
// Wc precompute: wbig[l] rows 0..1535 = dtw @ xpw[:48]  (bf16),
//                rows 1536..1567 = xpw[48:80] (bf16).
// ---------------------------------------------------------------------------
__global__ __launch_bounds__(256) void wc_k(
    const float* __restrict__ dtw_all,   // (NL, DI, DTR)
    const float* __restrict__ xpw_all,   // (NL, 80, DI)
    unsigned short* __restrict__ wbig)   // (NL, NBIG, DI)
{
    int l = blockIdx.z;
    const float* dtw = dtw_all + (size_t)l * DI * DTR;
    const float* xpw = xpw_all + (size_t)l * 80 * DI;
    unsigned short* wb = wbig + (size_t)l * NBIG * DI;
    int tid = threadIdx.x;
    if (blockIdx.y == 12) {
        if (blockIdx.x == 0) {
            for (int idx = tid; idx < 32 * DI; idx += 256) {
                int rr = idx / DI, k = idx - rr * DI;
                wb[(size_t)(DI + rr) * DI + k] =
                    (unsigned short)f2bf(xpw[(size_t)(48 + rr) * DI + k]);
            }
        }
        return;
    }
    __shared__ float sd[128 * 48];
    __shared__ float sx[48 * 128];
    int d0 = blockIdx.y * 128, k0 = blockIdx.x * 128;
    for (int idx = tid; idx < 128 * 48; idx += 256) {
        int r = idx / 48, j = idx - r * 48;
        sd[idx] = dtw[(size_t)(d0 + r) * DTR + j];
    }
    for (int idx = tid; idx < 48 * 128; idx += 256) {
        int j = idx / 128, k = idx - j * 128;
        sx[idx] = xpw[(size_t)j * DI + k0 + k];
    }
    __syncthreads();
    int tx = tid & 15, ty = tid >> 4;
    float acc[8][8] = {};
    for (int j = 0; j < 48; ++j) {
        float a[8], w[8];
        #pragma unroll
        for (int i = 0; i < 8; ++i) a[i] = sd[(ty * 8 + i) * 48 + j];
        #pragma unroll
        for (int i = 0; i < 8; ++i) w[i] = sx[j * 128 + tx * 8 + i];
        #pragma unroll
        for (int i = 0; i < 8; ++i)
            #pragma unroll
            for (int jj = 0; jj < 8; ++jj)
                acc[i][jj] += a[i] * w[jj];
    }
    for (int i = 0; i < 8; ++i)
        for (int jj = 0; jj < 8; ++jj)
            wb[(size_t)(d0 + ty * 8 + i) * DI + k0 + tx * 8 + jj] =
                (unsigned short)f2bf(acc[i][jj]);
}

// ---------------------------------------------------------------------------
// Embedding (vectorized x4): xbf[row, c4..c4+3] = bf16(emb[ids[row]] * sqrt(768))
// ---------------------------------------------------------------------------
__global__ __launch_bounds__(256) void embed_k(const int* __restrict__ ids,
                                               const float* __restrict__ emb,
                                               unsigned short* __restrict__ xbf) {
    int i = blockIdx.x * 256 + threadIdx.x;      // over ROWS * DM/4
    if (i >= ROWS * (DM / 4)) return;
    int row = i / (DM / 4);
    int c4 = (i - row * (DM / 4)) * 4;
    float4 v = *reinterpret_cast<const float4*>(
        &emb[(size_t)ids[row] * DM + c4]);
    const float s = 27.712812921102035f;
    short4v o;
    o[0] = f2bf(v.x * s); o[1] = f2bf(v.y * s);
    o[2] = f2bf(v.z * s); o[3] = f2bf(v.w * s);
    *reinterpret_cast<short4v*>(&xbf[(size_t)row * DM + c4]) = o;
}

// ---------------------------------------------------------------------------
// bf16-MFMA GEMM, NBUF-deep pipeline with COUNTED vmcnt (T3/T4):
//   prologue: STAGE tiles 0..NBUF-2
//   loop t: STAGE(t+NBUF-1) issue; s_waitcnt vmcnt(ahead*ISS) [tile t landed,
//           newer tiles fly]; s_barrier; MFMA on slot t%NBUF; s_barrier.
// MT x 128 tile (MT = 32/64/128), BKT=32, 4 waves, mfma_f32_16x16x32_bf16.
// global_load_lds staging, linear LDS dest, pre-swizzled source
// (involution chunk ^ ((row>>1)&3), conflict-free ds_read_b128).
// MT==32: waves 2,3 duplicate-issue waves 0,1's A staging (same src+dest;
// benign) so per-wave vmcnt counts stay uniform.
// OUT: 0 = fp32 store (NTST -> LDS-transposed full-line NT epilogue);
//      2 = bf16-only store; 3 = fused dt softplus (bf16) / BC (fp32) split.
// ---------------------------------------------------------------------------
template<int MT, int NBUF, int OUT, bool NTST>
__global__ __launch_bounds__(256) void gemm_bf16(
    const unsigned short* __restrict__ A, int lda,
    const unsigned short* __restrict__ W, int ldw,
    float* __restrict__ C, unsigned short* __restrict__ Cbf, int ldc,
    int GY, int N, int K,
    const float* __restrict__ bias, float* __restrict__ aux)
{
    constexpr int BKT = 32;
    constexpr int CPR = BKT / 8;                  // 4 chunks per row
    constexpr int ACA = (MT * CPR + 255) / 256;   // A staging issues/thread
    constexpr int ACW = 128 * CPR / 256;          // W staging issues/thread (2)
    constexpr int ISS = ACA + ACW;                // gl_lds instrs per STAGE
    constexpr int MFR = MT / 32;                  // M fragments per wave (MT=32 -> 1)
    constexpr int BUFS = (MT + 128) * BKT;        // shorts per buffer
    __shared__ __align__(16) short smem[NBUF * BUFS];

    const int tid  = threadIdx.x;
    const int lane = tid & 63;
    const int wid  = tid >> 6;
    const int wr   = wid >> 1, wc = wid & 1;

    // bijective XCD-chunked swizzle, then col-major decode
    const int nwg = gridDim.x;
    const int q = nwg >> 3, rm = nwg & 7;
    const int xcd = blockIdx.x & 7, bidx = blockIdx.x >> 3;
    const int wg = (xcd < rm ? xcd * (q + 1) : rm * (q + 1) + (xcd - rm) * q) + bidx;
    const int row0 = (wg % GY) * MT;
    const int col0 = (wg / GY) * 128;

    // ---- staging setup (pre-swizzled global sources) ----
    const unsigned short* gA[ACA];
    const unsigned short* gW[ACW];
    #pragma unroll
    for (int i = 0; i < ACA; ++i) {
        int cid = i * 256 + ((MT == 32) ? (tid & 127) : tid);
        int r = cid / CPR, c = cid % CPR;
        gA[i] = A + (size_t)(row0 + r) * lda + ((c ^ ((r >> 1) & 3)) * 8);
    }
    #pragma unroll
    for (int i = 0; i < ACW; ++i) {
        int cid = i * 256 + tid;
        int r = cid / CPR, c = cid % CPR;
        int rg = col0 + r; if (rg > N - 1) rg = N - 1;   // clamp: dup, store-guarded
        gW[i] = W + (size_t)rg * ldw + ((c ^ ((r >> 1) & 3)) * 8);
    }

    const int arow = (MT == 32 ? wr * 16 : wr * (MT / 2)) + (lane & 15);
    const int brow = wc * 64 + (lane & 15);
    const int szA = (arow >> 1) & 3;          // row+16 invariant
    const int szB = (brow >> 1) & 3;
    const int hi = lane >> 4;                 // 0..3 (= k-chunk for BKT=32)

    auto STAGE = [&](int buf) {
        short* As = smem + buf * BUFS;
        short* Ws = As + MT * BKT;
        #pragma unroll
        for (int i = 0; i < ACA; ++i) {
            int cbase = (MT == 32) ? ((wid & 1) * 64) : (i * 256 + wid * 64);
            gl_lds16(gA[i], &As[cbase * 8]);
            gA[i] += BKT;
        }
        #pragma unroll
        for (int i = 0; i < ACW; ++i) {
            gl_lds16(gW[i], &Ws[(i * 256 + wid * 64) * 8]);
            gW[i] += BKT;
        }
    };

    f32x4 acc[MFR][4] = {};

    const int ntiles = K / BKT;               // >= 24 at all call sites
    #pragma unroll
    for (int p = 0; p < NBUF - 1; ++p) STAGE(p);

    for (int t = 0; t < ntiles; ++t) {
        const int next = t + NBUF - 1;
        if (next < ntiles) STAGE(next % NBUF);   // deepest prefetch in flight
        int ahead = ntiles - 1 - t;
        if (ahead > NBUF - 1) ahead = NBUF - 1;
        if (NBUF == 3 && ahead == 2)
            asm volatile("s_waitcnt vmcnt(%0)" :: "n"(2 * ISS) : "memory");
        else if (ahead == 1)
            asm volatile("s_waitcnt vmcnt(%0)" :: "n"(ISS) : "memory");
        else if (ahead == 0)
            asm volatile("s_waitcnt vmcnt(0)" ::: "memory");
        __builtin_amdgcn_sched_barrier(0);
        __builtin_amdgcn_s_barrier();      // tile-t buffer visible to all waves

        const short* As = smem + (t % NBUF) * BUFS;
        const short* Ws = As + MT * BKT;
        bf16x8 a[MFR], b[4];
        #pragma unroll
        for (int mf = 0; mf < MFR; ++mf)
            a[mf] = *reinterpret_cast<const bf16x8*>(
                &As[(arow + mf * 16) * BKT + ((hi ^ szA) * 8)]);
        #pragma unroll
        for (int nf = 0; nf < 4; ++nf)
            b[nf] = *reinterpret_cast<const bf16x8*>(
                &Ws[(brow + nf * 16) * BKT + ((hi ^ szB) * 8)]);
        #pragma unroll
        for (int mf = 0; mf < MFR; ++mf)
            #pragma unroll
            for (int nf = 0; nf < 4; ++nf)
                acc[mf][nf] = __builtin_amdgcn_mfma_f32_16x16x32_bf16(
                    a[mf], b[nf], acc[mf][nf], 0, 0, 0);

        __builtin_amdgcn_s_barrier();      // reads retired before overwrite
    }

    if (OUT == 0 && NTST) {
        __syncthreads();
        // LDS-transposed epilogue: full-line NT dword stores.
        float* Cs = (float*)smem;    // [32][132] fp32 (16.9KB <= NBUF*BUFS*2B)
        #pragma unroll
        for (int mf = 0; mf < MFR; ++mf) {
            __syncthreads();
            #pragma unroll
            for (int nf = 0; nf < 4; ++nf) {
                #pragma unroll
                for (int j = 0; j < 4; ++j)
                    Cs[(wr * 16 + hi * 4 + j) * 132 + wc * 64 + nf * 16 + (lane & 15)]
                        = acc[mf][nf][j];
            }
            __syncthreads();
            #pragma unroll
            for (int rr = 0; rr < 8; ++rr) {
                int lrow = wid * 8 + rr;      // 0..31
                int grow = row0 + (lrow < 16 ? mf * 16 + lrow
                                             : (MT / 2) + mf * 16 + (lrow - 16));
                #pragma unroll
                for (int hf = 0; hf < 2; ++hf) {
                    int cc = col0 + hf * 64 + lane;
                    if (cc < N)
                        __builtin_nontemporal_store(
                            Cs[lrow * 132 + hf * 64 + lane],
                            &C[(size_t)grow * ldc + cc]);
                }
            }
        }
    } else {
        #pragma unroll
        for (int mf = 0; mf < MFR; ++mf) {
            #pragma unroll
            for (int nf = 0; nf < 4; ++nf) {
                int r  = row0 + (MT == 32 ? wr * 16 : wr * (MT / 2)) + mf * 16 + hi * 4;
                int cc = col0 + wc * 64 + nf * 16 + (lane & 15);
                if (cc < N) {
                    f32x4 d = acc[mf][nf];
                    if (OUT == 3) {
                        if (cc < DI) {
                            float bv = bias[cc];
                            #pragma unroll
                            for (int j = 0; j < 4; ++j) {
                                float v = d[j] + bv;
                                v = (v > 20.f) ? v : log1pf(__expf(v));
                                Cbf[(size_t)(r + j) * ldc + cc] = (unsigned short)f2bf(v);
                            }
                        } else {
                            #pragma unroll
                            for (int j = 0; j < 4; ++j)
                                aux[(size_t)(r + j) * 32 + (cc - DI)] = d[j];
                        }
                    } else if (OUT == 2) {
                        #pragma unroll
                        for (int j = 0; j < 4; ++j)
                            Cbf[(size_t)(r + j) * ldc + cc] = (unsigned short)f2bf(d[j]);
                    } else {
                        #pragma unroll
                        for (int j = 0; j < 4; ++j)
                            C[(size_t)(r + j) * ldc + cc] = d[j];
                    }
                }
            }
        }
    }
}

// ---------------------------------------------------------------------------
// Depthwise causal conv(4) + bias + silu, vectorized: 8 channels/thread.
// ---------------------------------------------------------------------------
__global__ __launch_bounds__(256) void conv_silu_k(
    const unsigned short* __restrict__ xz, const float* __restrict__ cw,
    const float* __restrict__ cb, unsigned short* __restrict__ xinb)
{
    int i = blockIdx.x * 256 + threadIdx.x;   // over ROWS * DI/8
    if (i >= ROWS * (DI / 8)) return;
    int row = i / (DI / 8);
    int c = (i - row * (DI / 8)) * 8;
    int t = row & (SL - 1);
    int b = row >> 10;

    float4 wv[8];
    float accv[8];
    #pragma unroll
    for (int j = 0; j < 8; ++j) {
        wv[j] = *reinterpret_cast<const float4*>(&cw[(c + j) * DC]);
        accv[j] = cb[c + j];
    }
    const unsigned short* base = xz + ((size_t)(b * SL)) * (2 * DI) + c;
    #pragma unroll
    for (int k = 0; k < DC; ++k) {
        int tt = t + k - (DC - 1);
        if (tt >= 0) {
            bf16x8 v = *reinterpret_cast<const bf16x8*>(
                &base[(size_t)tt * (2 * DI)]);
            #pragma unroll
            for (int j = 0; j < 8; ++j)
                accv[j] += bf2f((unsigned short)v[j]) *
                           reinterpret_cast<const float*>(&wv[j])[k];
        }
    }
    bf16x8 o;
    #pragma unroll
    for (int j = 0; j < 8; ++j) {
        float v = accv[j] / (1.f + __expf(-accv[j]));
        o[j] = f2bf(v);
    }
    *reinterpret_cast<bf16x8*>(&xinb[(size_t)row * DI + c]) = o;
}

// ---------------------------------------------------------------------------
// Chunked selective scan, 2 kernels. CCH=32 chunks of CLEN=32.
// dt, xin bf16; bc fp32: B = bc[r*32 + s], C = bc[r*32 + 16 + s].
// ---------------------------------------------------------------------------
__global__ __launch_bounds__(256) void scan_phase1(
    const unsigned short* __restrict__ dt,
    const float* __restrict__ bc,
    const unsigned short* __restrict__ xin,
    const float* __restrict__ Alog,
    float* __restrict__ hend,
    float* __restrict__ eprod)
{
    int blk = blockIdx.x;
    int c = blk % CCH;
    int tmp = blk / CCH;
    int dblk = tmp % (DI / 16);
    int b = tmp / (DI / 16);
    int s = threadIdx.x & 15;
    int d = dblk * 16 + (threadIdx.x >> 4);
    float A = -__expf(Alog[d * DS + s]);
    float h = 0.f, P = 1.f;
    const int rowbase = b * SL + c * CLEN;
    #pragma unroll 4
    for (int t = 0; t < CLEN; ++t) {
        int r = rowbase + t;
        float dtv = bf2f(dt[(size_t)r * DI + d]);
        float xv  = bf2f(xin[(size_t)r * DI + d]);
        float Bv  = bc[(size_t)r * 32 + s];
        float e = __expf(dtv * A);
        h = h * e + dtv * xv * Bv;
        P *= e;
    }
    size_t idx = ((size_t)(b * CCH + c) * DI + d) * DS + s;
    hend[idx]  = h;
    eprod[idx] = P;
}

__global__ __launch_bounds__(256) void scan_phase3(
    const unsigned short* __restrict__ dt,
    const float* __restrict__ bc,
    const unsigned short* __restrict__ xin,
    const unsigned short* __restrict__ xz,   // z = cols [DI:2*DI)
    const float* __restrict__ Alog,
    const float* __restrict__ Dp,
    const float* __restrict__ hend,
    const float* __restrict__ eprod,
    unsigned short* __restrict__ ybf)
{
    int blk = blockIdx.x;
    int c = blk % CCH;
    int tmp = blk / CCH;
    int dblk = tmp % (DI / 16);
    int b = tmp / (DI / 16);
    int s = threadIdx.x & 15;
    int d = dblk * 16 + (threadIdx.x >> 4);
    float A = -__expf(Alog[d * DS + s]);
    float Dv = Dp[d];

    float h = 0.f;
    const size_t pbase = ((size_t)b * CCH * DI + d) * DS + s;
    for (int j = 0; j < c; ++j) {
        size_t idx = pbase + (size_t)j * (DI * DS);
        h = h * eprod[idx] + hend[idx];
    }

    const int rowbase = b * SL + c * CLEN;
    #pragma unroll 2
    for (int t = 0; t < CLEN; ++t) {
        int r = rowbase + t;
        float dtv = bf2f(dt[(size_t)r * DI + d]);
        float xv  = bf2f(xin[(size_t)r * DI + d]);
        float Bv  = bc[(size_t)r * 32 + s];
        float Cv  = bc[(size_t)r * 32 + 16 + s];
        float e = __expf(dtv * A);
        h = h * e + dtv * xv * Bv;
        float p = h * Cv;
        p += __shfl_xor(p, 1, 64);
        p += __shfl_xor(p, 2, 64);
        p += __shfl_xor(p, 4, 64);
        p += __shfl_xor(p, 8, 64);
        if (s == 0) {
            float z = bf2f(xz[(size_t)r * (2 * DI) + DI + d]);
            float yv = (p + xv * Dv) * (z / (1.f + __expf(-z)));
            ybf[(size_t)r * DI + d] = (unsigned short)f2bf(yv);
        }
    }
}

// ---------------------------------------------------------------------------
// LayerNorm over rows of 768, bf16 in, bf16 out
// ---------------------------------------------------------------------------
__global__ __launch_bounds__(256) void ln_k(
    const unsigned short* __restrict__ x, const float* __restrict__ w,
    const float* __restrict__ b, unsigned short* __restrict__ o)
{
    int row = blockIdx.x;
    int tid = threadIdx.x;
    const unsigned short* xr = x + (size_t)row * DM;
    float v0 = bf2f(xr[tid]), v1 = bf2f(xr[tid + 256]), v2 = bf2f(xr[tid + 512]);
    float s = v0 + v1 + v2;
    #pragma unroll
    for (int off = 1; off < 64; off <<= 1) s += __shfl_xor(s, off, 64);
    __shared__ float red[4];
    __shared__ float red2[4];
    int wid = tid >> 6, lane = tid & 63;
    if (lane == 0) red[wid] = s;
    __syncthreads();
    float mu = (red[0] + red[1] + red[2] + red[3]) * (1.f / 768.f);
    float d0 = v0 - mu, d1 = v1 - mu, d2 = v2 - mu;
    float q = d0 * d0 + d1 * d1 + d2 * d2;
    #pragma unroll
    for (int off = 1; off < 64; off <<= 1) q += __shfl_xor(q, off, 64);
    if (lane == 0) red2[wid] = q;
    __syncthreads();
    float var = (red2[0] + red2[1] + red2[2] + red2[3]) * (1.f / 768.f);
    float rs = rsqrtf(var + 1e-5f);
    o[(size_t)row * DM + tid]       = (unsigned short)f2bf(d0 * rs * w[tid]       + b[tid]);
    o[(size_t)row * DM + tid + 256] = (unsigned short)f2bf(d1 * rs * w[tid + 256] + b[tid + 256]);
    o[(size_t)row * DM + tid + 512] = (unsigned short)f2bf(d2 * rs * w[tid + 512] + b[tid + 512]);
}

// ---------------------------------------------------------------------------
extern "C" void kernel_launch(void* const* d_in, const int* in_sizes, int n_in,
                              void* d_out, int out_size, void* d_ws, size_t ws_size,
                              hipStream_t stream) {
    const int*   ids        = (const int*)d_in[0];
    const float* emb        = (const float*)d_in[1];
    const float* in_proj_w  = (const float*)d_in[2];
    const float* conv_w     = (const float*)d_in[3];
    const float* conv_b     = (const float*)d_in[4];
    const float* x_proj_w   = (const float*)d_in[5];
    const float* dt_proj_w  = (const float*)d_in[6];
    const float* dt_proj_b  = (const float*)d_in[7];
    const float* A_log      = (const float*)d_in[8];
    const float* D_param    = (const float*)d_in[9];
    const float* out_proj_w = (const float*)d_in[10];
    const float* norm_w     = (const float*)d_in[11];
    const float* norm_b     = (const float*)d_in[12];
    float* out = (float*)d_out;

    // ---- workspace layout ----
    char* base = (char*)d_ws;
    size_t off = 0;
    auto alloc_f = [&](size_t n) { float* p = (float*)(base + off); off += n * 4; return p; };
    auto alloc_u = [&](size_t n) { unsigned short* p = (unsigned short*)(base + off); off += n * 2; return p; };

    float* bc    = alloc_f((size_t)ROWS * 32);
    float* hend  = alloc_f((size_t)NB * CCH * DI * DS);
    float* eprod = alloc_f((size_t)NB * CCH * DI * DS);
    unsigned short* xbf   = alloc_u((size_t)ROWS * DM);
    unsigned short* xzb   = alloc_u((size_t)ROWS * 2 * DI);
    unsigned short* xinb  = alloc_u((size_t)ROWS * DI);
    unsigned short* dtbf  = alloc_u((size_t)ROWS * DI);
    unsigned short* ybf   = alloc_u((size_t)ROWS * DI);
    unsigned short* xlnbf = alloc_u((size_t)ROWS * DM);
    unsigned short* inw_bf = alloc_u((size_t)NLAYER * 2 * DI * DM);
    unsigned short* ow_bf  = alloc_u((size_t)NLAYER * DM * DI);
    unsigned short* wbig  = alloc_u((size_t)NLAYER * NBIG * DI);
    unsigned short* emb_bf = alloc_u((size_t)VOCAB * DM);
    (void)ws_size;

    // ---- weight preconversion (once per call) ----
    {
        int n4a = NLAYER * 2 * DI * DM / 4;
        cvt_bf16_k<<<(n4a + 255) / 256, 256, 0, stream>>>(in_proj_w, inw_bf, n4a);
        int n4b = NLAYER * DM * DI / 4;
        cvt_bf16_k<<<(n4b + 255) / 256, 256, 0, stream>>>(out_proj_w, ow_bf, n4b);
        wc_k<<<dim3(12, 13, NLAYER), 256, 0, stream>>>(dt_proj_w, x_proj_w, wbig);
        int n4e = VOCAB * DM / 4;
        cvt_bf16_k<<<(n4e + 255) / 256, 256, 0, stream>>>(emb, emb_bf, n4e);
    }

    embed_k<<<(ROWS * (DM / 4) + 255) / 256, 256, 0, stream>>>(ids, emb, xbf);

    const int scan_grid = NB * (DI / 16) * CCH;      // 6144 blocks

    for (int i = 0; i < NLAYER; ++i) {
        const float* cw  = conv_w  + (size_t)i * DI * DC;
        const float* cb  = conv_b  + (size_t)i * DI;
        const float* dtb = dt_proj_b + (size_t)i * DI;
        const float* Al  = A_log   + (size_t)i * DI * DS;
        const float* Dpar= D_param + (size_t)i * DI;

        // in_proj: xzb(bf16) = xbf @ inw^T  (64-tile, 3-deep, 768 blocks)
        const unsigned short* inw = inw_bf + (size_t)i * 2 * DI * DM;
        gemm_bf16<64, 3, 2, false><<<24 * 32, 256, 0, stream>>>(
            xbf, DM, inw, DM, nullptr, xzb, 2 * DI, 32, 2 * DI, DM, nullptr, nullptr);

        conv_silu_k<<<(ROWS * (DI / 8)) / 256, 256, 0, stream>>>(xzb, cw, cb, xinb);

        // fused dt(bf16,softplus) + B/C(fp32): xinb @ wbig[i]^T  (N=1568, 3-deep)
        const unsigned short* wb = wbig + (size_t)i * NBIG * DI;
        gemm_bf16<64, 3, 3, false><<<13 * 32, 256, 0, stream>>>(
            xinb, DI, wb, DI, nullptr, dtbf, DI, 32, NBIG, DI, dtb, bc);

        scan_phase1<<<scan_grid, 256, 0, stream>>>(dtbf, bc, xinb, Al, hend, eprod);
        scan_phase3<<<scan_grid, 256, 0, stream>>>(dtbf, bc, xinb, xzb, Al, Dpar,
                                                   hend, eprod, ybf);

        // out_proj: xbf(bf16) = ybf @ ow^T  (32-tile, 3-deep, 384 blocks)
        const unsigned short* ow = ow_bf + (size_t)i * DM * DI;
        gemm_bf16<32, 3, 2, false><<<64 * 6, 256, 0, stream>>>(
            ybf, DI, ow, DI, nullptr, xbf, DM, 64, DM, DI, nullptr, nullptr);
    }

    ln_k<<<ROWS, 256, 0, stream>>>(xbf, norm_w, norm_b, xlnbf);
    // logits: out = xlnbf @ emb^T  (128-tile, 2-deep counted, NT epilogue)
    gemm_bf16<128, 2, 0, true><<<393 * 16, 256, 0, stream>>>(
        xlnbf, DM, emb_bf, DM, out, nullptr, VOCAB, 16, VOCAB, DM, nullptr, nullptr);
}

// Round 12
// 2946.540 us; speedup vs baseline: 5.7688x; 1.0622x over previous
//
#include <hip/hip_runtime.h>
#include <hip/hip_bf16.h>

#define DI 1536
#define DS 16
#define DC 4
#define DTR 48
#define NB 2
#define SL 1024
#define DM 768
#define NLAYER 12
#define VOCAB 50257
#define ROWS (NB*SL)   // 2048
#define CCH 32         // scan chunks
#define CLEN (SL/CCH)  // 32
#define NBIG (DI+32)   // 1568: fused dt(1536) + B/C(32) outputs

typedef __attribute__((ext_vector_type(8))) short bf16x8;
typedef __attribute__((ext_vector_type(4))) short short4v;
typedef __attribute__((ext_vector_type(4))) float f32x4;

__device__ inline short f2bf(float f) {
    unsigned u = __builtin_bit_cast(unsigned, f);
    unsigned r = (u + 0x7fffu + ((u >> 16) & 1u)) >> 16;
    return (short)r;
}
__device__ inline float bf2f(unsigned short u) {
    unsigned x = ((unsigned)u) << 16;
    return __builtin_bit_cast(float, x);
}

__device__ __forceinline__ void gl_lds16(const void* g, void* l) {
    __builtin_amdgcn_global_load_lds(
        (const __attribute__((address_space(1))) unsigned int*)g,
        (__attribute__((address_space(3))) unsigned int*)l, 16, 0, 0);
}

// ---------------------------------------------------------------------------
// fp32 -> bf16 convert for 3 arrays in one dispatch (each n multiple of 4)
// ---------------------------------------------------------------------------
__global__ __launch_bounds__(256) void cvt3_k(
    const float* __restrict__ s0, unsigned short* __restrict__ d0, int n40,
    const float* __restrict__ s1, unsigned short* __restrict__ d1, int n41,
    const float* __restrict__ s2, unsigned short* __restrict__ d2, int n42)
{
    int i = blockIdx.x * 256 + threadIdx.x;
    const float* src; unsigned short* dst;
    if (i < n40) { src = s0; dst = d0; }
    else if (i < n40 + n41) { i -= n40; src = s1; dst = d1; }
    else if (i < n40 + n41 + n42) { i -= n40 + n41; src = s2; dst = d2; }
    else return;
    float4 v = *reinterpret_cast<const float4*>(src + (size_t)i * 4);
    short4v o;
    o[0] = f2bf(v.x); o[1] = f2bf(v.y); o[2] = f2bf(v.z); o[3] = f2bf(v.w);
    *reinterpret_cast<short4v*>(dst + (size_t)i * 4) = o;
}

// ---------------------------------------------------------------------------
// Wc precompute: wbig[l] rows 0..1535 = dtw @ xpw[:48]  (bf16),
//                rows 1536..1567 = xpw[48:80] (bf16).
// ---------------------------------------------------------------------------
__global__ __launch_bounds__(256) void wc_k(
    const float* __restrict__ dtw_all,   // (NL, DI, DTR)
    const float* __restrict__ xpw_all,   // (NL, 80, DI)
    unsigned short* __restrict__ wbig)   // (NL, NBIG, DI)
{
    int l = blockIdx.z;
    const float* dtw = dtw_all + (size_t)l * DI * DTR;
    const float* xpw = xpw_all + (size_t)l * 80 * DI;
    unsigned short* wb = wbig + (size_t)l * NBIG * DI;
    int tid = threadIdx.x;
    if (blockIdx.y == 12) {
        if (blockIdx.x == 0) {
            for (int idx = tid; idx < 32 * DI; idx += 256) {
                int rr = idx / DI, k = idx - rr * DI;
                wb[(size_t)(DI + rr) * DI + k] =
                    (unsigned short)f2bf(xpw[(size_t)(48 + rr) * DI + k]);
            }
        }
        return;
    }
    __shared__ float sd[128 * 48];
    __shared__ float sx[48 * 128];
    int d0 = blockIdx.y * 128, k0 = blockIdx.x * 128;
    for (int idx = tid; idx < 128 * 48; idx += 256) {
        int r = idx / 48, j = idx - r * 48;
        sd[idx] = dtw[(size_t)(d0 + r) * DTR + j];
    }
    for (int idx = tid; idx < 48 * 128; idx += 256) {
        int j = idx / 128, k = idx - j * 128;
        sx[idx] = xpw[(size_t)j * DI + k0 + k];
    }
    __syncthreads();
    int tx = tid & 15, ty = tid >> 4;
    float acc[8][8] = {};
    for (int j = 0; j < 48; ++j) {
        float a[8], w[8];
        #pragma unroll
        for (int i = 0; i < 8; ++i) a[i] = sd[(ty * 8 + i) * 48 + j];
        #pragma unroll
        for (int i = 0; i < 8; ++i) w[i] = sx[j * 128 + tx * 8 + i];
        #pragma unroll
        for (int i = 0; i < 8; ++i)
            #pragma unroll
            for (int jj = 0; jj < 8; ++jj)
                acc[i][jj] += a[i] * w[jj];
    }
    for (int i = 0; i < 8; ++i)
        for (int jj = 0; jj < 8; ++jj)
            wb[(size_t)(d0 + ty * 8 + i) * DI + k0 + tx * 8 + jj] =
                (unsigned short)f2bf(acc[i][jj]);
}

// ---------------------------------------------------------------------------
// Embedding (vectorized x4)
// ---------------------------------------------------------------------------
__global__ __launch_bounds__(256) void embed_k(const int* __restrict__ ids,
                                               const float* __restrict__ emb,
                                               unsigned short* __restrict__ xbf) {
    int i = blockIdx.x * 256 + threadIdx.x;      // over ROWS * DM/4
    if (i >= ROWS * (DM / 4)) return;
    int row = i / (DM / 4);
    int c4 = (i - row * (DM / 4)) * 4;
    float4 v = *reinterpret_cast<const float4*>(
        &emb[(size_t)ids[row] * DM + c4]);
    const float s = 27.712812921102035f;
    short4v o;
    o[0] = f2bf(v.x * s); o[1] = f2bf(v.y * s);
    o[2] = f2bf(v.z * s); o[3] = f2bf(v.w * s);
    *reinterpret_cast<short4v*>(&xbf[(size_t)row * DM + c4]) = o;
}

// ---------------------------------------------------------------------------
// bf16-MFMA GEMM, NBUF-deep pipeline with COUNTED vmcnt (T3/T4).
// MT x NCOL tile (MT = 32/64/128; NCOL = 128/256), BKT=32, 4 waves.
// global_load_lds staging, linear LDS dest, pre-swizzled source
// (involution chunk ^ ((row>>1)&3), conflict-free ds_read_b128).
// OUT: 0 = fp32 store (NTST -> LDS-transposed full-line NT epilogue);
//      2 = bf16-only store; 3 = fused dt softplus (bf16) / BC (fp32) split.
// ---------------------------------------------------------------------------
template<int MT, int NCOL, int NBUF, int OUT, bool NTST>
__global__ __launch_bounds__(256) void gemm_bf16(
    const unsigned short* __restrict__ A, int lda,
    const unsigned short* __restrict__ W, int ldw,
    float* __restrict__ C, unsigned short* __restrict__ Cbf, int ldc,
    int GY, int N, int K,
    const float* __restrict__ bias, float* __restrict__ aux)
{
    constexpr int BKT = 32;
    constexpr int CPR = BKT / 8;                  // 4 chunks per row
    constexpr int ACA = (MT * CPR + 255) / 256;   // A staging issues/thread
    constexpr int ACW = NCOL * CPR / 256;         // W staging issues/thread
    constexpr int ISS = ACA + ACW;                // gl_lds instrs per STAGE
    constexpr int MFR = MT / 32;                  // M fragments per wave
    constexpr int NFR = NCOL / 32;                // N fragments per wave
    constexpr int BUFS = (MT + NCOL) * BKT;       // shorts per buffer
    __shared__ __align__(16) short smem[NBUF * BUFS];

    const int tid  = threadIdx.x;
    const int lane = tid & 63;
    const int wid  = tid >> 6;
    const int wr   = wid >> 1, wc = wid & 1;

    // bijective XCD-chunked swizzle, then col-major decode
    const int nwg = gridDim.x;
    const int q = nwg >> 3, rm = nwg & 7;
    const int xcd = blockIdx.x & 7, bidx = blockIdx.x >> 3;
    const int wg = (xcd < rm ? xcd * (q + 1) : rm * (q + 1) + (xcd - rm) * q) + bidx;
    const int row0 = (wg % GY) * MT;
    const int col0 = (wg / GY) * NCOL;

    // ---- staging setup (pre-swizzled global sources) ----
    const unsigned short* gA[ACA];
    const unsigned short* gW[ACW];
    #pragma unroll
    for (int i = 0; i < ACA; ++i) {
        int cid = i * 256 + ((MT == 32) ? (tid & 127) : tid);
        int r = cid / CPR, c = cid % CPR;
        gA[i] = A + (size_t)(row0 + r) * lda + ((c ^ ((r >> 1) & 3)) * 8);
    }
    #pragma unroll
    for (int i = 0; i < ACW; ++i) {
        int cid = i * 256 + tid;
        int r = cid / CPR, c = cid % CPR;
        int rg = col0 + r; if (rg > N - 1) rg = N - 1;   // clamp: dup, store-guarded
        gW[i] = W + (size_t)rg * ldw + ((c ^ ((r >> 1) & 3)) * 8);
    }

    const int arow = (MT == 32 ? wr * 16 : wr * (MT / 2)) + (lane & 15);
    const int brow = wc * (NCOL / 2) + (lane & 15);
    const int szA = (arow >> 1) & 3;          // row+16 invariant
    const int szB = (brow >> 1) & 3;
    const int hi = lane >> 4;                 // 0..3 (= k-chunk for BKT=32)

    auto STAGE = [&](int buf) {
        short* As = smem + buf * BUFS;
        short* Ws = As + MT * BKT;
        #pragma unroll
        for (int i = 0; i < ACA; ++i) {
            int cbase = (MT == 32) ? ((wid & 1) * 64) : (i * 256 + wid * 64);
            gl_lds16(gA[i], &As[cbase * 8]);
            gA[i] += BKT;
        }
        #pragma unroll
        for (int i = 0; i < ACW; ++i) {
            gl_lds16(gW[i], &Ws[(i * 256 + wid * 64) * 8]);
            gW[i] += BKT;
        }
    };

    f32x4 acc[MFR][NFR] = {};

    const int ntiles = K / BKT;               // >= 24 at all call sites
    #pragma unroll
    for (int p = 0; p < NBUF - 1; ++p) STAGE(p);

    for (int t = 0; t < ntiles; ++t) {
        const int next = t + NBUF - 1;
        if (next < ntiles) STAGE(next % NBUF);   // deepest prefetch in flight
        int ahead = ntiles - 1 - t;
        if (ahead > NBUF - 1) ahead = NBUF - 1;
        if (NBUF == 3 && ahead == 2)
            asm volatile("s_waitcnt vmcnt(%0)" :: "n"(2 * ISS) : "memory");
        else if (ahead == 1)
            asm volatile("s_waitcnt vmcnt(%0)" :: "n"(ISS) : "memory");
        else if (ahead == 0)
            asm volatile("s_waitcnt vmcnt(0)" ::: "memory");
        __builtin_amdgcn_sched_barrier(0);
        __builtin_amdgcn_s_barrier();      // tile-t buffer visible to all waves

        const short* As = smem + (t % NBUF) * BUFS;
        const short* Ws = As + MT * BKT;
        bf16x8 a[MFR], b[NFR];
        #pragma unroll
        for (int mf = 0; mf < MFR; ++mf)
            a[mf] = *reinterpret_cast<const bf16x8*>(
                &As[(arow + mf * 16) * BKT + ((hi ^ szA) * 8)]);
        #pragma unroll
        for (int nf = 0; nf < NFR; ++nf)
            b[nf] = *reinterpret_cast<const bf16x8*>(
                &Ws[(brow + nf * 16) * BKT + ((hi ^ szB) * 8)]);
        #pragma unroll
        for (int mf = 0; mf < MFR; ++mf)
            #pragma unroll
            for (int nf = 0; nf < NFR; ++nf)
                acc[mf][nf] = __builtin_amdgcn_mfma_f32_16x16x32_bf16(
                    a[mf], b[nf], acc[mf][nf], 0, 0, 0);

        __builtin_amdgcn_s_barrier();      // reads retired before overwrite
    }

    if (OUT == 0 && NTST) {
        __syncthreads();
        // LDS-transposed epilogue: full-line NT dword stores.
        constexpr int CSLD = NCOL + 4;
        float* Cs = (float*)smem;    // [32][CSLD] fp32
        #pragma unroll
        for (int mf = 0; mf < MFR; ++mf) {
            __syncthreads();
            #pragma unroll
            for (int nf = 0; nf < NFR; ++nf) {
                #pragma unroll
                for (int j = 0; j < 4; ++j)
                    Cs[(wr * 16 + hi * 4 + j) * CSLD + wc * (NCOL / 2) + nf * 16 + (lane & 15)]
                        = acc[mf][nf][j];
            }
            __syncthreads();
            #pragma unroll
            for (int rr = 0; rr < 8; ++rr) {
                int lrow = wid * 8 + rr;      // 0..31
                int grow = row0 + (lrow < 16 ? mf * 16 + lrow
                                             : (MT / 2) + mf * 16 + (lrow - 16));
                #pragma unroll
                for (int hf = 0; hf < NCOL / 64; ++hf) {
                    int cc = col0 + hf * 64 + lane;
                    if (cc < N)
                        __builtin_nontemporal_store(
                            Cs[lrow * CSLD + hf * 64 + lane],
                            &C[(size_t)grow * ldc + cc]);
                }
            }
        }
    } else {
        #pragma unroll
        for (int mf = 0; mf < MFR; ++mf) {
            #pragma unroll
            for (int nf = 0; nf < NFR; ++nf) {
                int r  = row0 + (MT == 32 ? wr * 16 : wr * (MT / 2)) + mf * 16 + hi * 4;
                int cc = col0 + wc * (NCOL / 2) + nf * 16 + (lane & 15);
                if (cc < N) {
                    f32x4 d = acc[mf][nf];
                    if (OUT == 3) {
                        if (cc < DI) {
                            float bv = bias[cc];
                            #pragma unroll
                            for (int j = 0; j < 4; ++j) {
                                float v = d[j] + bv;
                                v = (v > 20.f) ? v : log1pf(__expf(v));
                                Cbf[(size_t)(r + j) * ldc + cc] = (unsigned short)f2bf(v);
                            }
                        } else {
                            #pragma unroll
                            for (int j = 0; j < 4; ++j)
                                aux[(size_t)(r + j) * 32 + (cc - DI)] = d[j];
                        }
                    } else if (OUT == 2) {
                        #pragma unroll
                        for (int j = 0; j < 4; ++j)
                            Cbf[(size_t)(r + j) * ldc + cc] = (unsigned short)f2bf(d[j]);
                    } else {
                        #pragma unroll
                        for (int j = 0; j < 4; ++j)
                            C[(size_t)(r + j) * ldc + cc] = d[j];
                    }
                }
            }
        }
    }
}

// ---------------------------------------------------------------------------
// Depthwise causal conv(4) + bias + silu, vectorized: 8 channels/thread.
// ---------------------------------------------------------------------------
__global__ __launch_bounds__(256) void conv_silu_k(
    const unsigned short* __restrict__ xz, const float* __restrict__ cw,
    const float* __restrict__ cb, unsigned short* __restrict__ xinb)
{
    int i = blockIdx.x * 256 + threadIdx.x;   // over ROWS * DI/8
    if (i >= ROWS * (DI / 8)) return;
    int row = i / (DI / 8);
    int c = (i - row * (DI / 8)) * 8;
    int t = row & (SL - 1);
    int b = row >> 10;

    float4 wv[8];
    float accv[8];
    #pragma unroll
    for (int j = 0; j < 8; ++j) {
        wv[j] = *reinterpret_cast<const float4*>(&cw[(c + j) * DC]);
        accv[j] = cb[c + j];
    }
    const unsigned short* base = xz + ((size_t)(b * SL)) * (2 * DI) + c;
    #pragma unroll
    for (int k = 0; k < DC; ++k) {
        int tt = t + k - (DC - 1);
        if (tt >= 0) {
            bf16x8 v = *reinterpret_cast<const bf16x8*>(
                &base[(size_t)tt * (2 * DI)]);
            #pragma unroll
            for (int j = 0; j < 8; ++j)
                accv[j] += bf2f((unsigned short)v[j]) *
                           reinterpret_cast<const float*>(&wv[j])[k];
        }
    }
    bf16x8 o;
    #pragma unroll
    for (int j = 0; j < 8; ++j) {
        float v = accv[j] / (1.f + __expf(-accv[j]));
        o[j] = f2bf(v);
    }
    *reinterpret_cast<bf16x8*>(&xinb[(size_t)row * DI + c]) = o;
}

// ---------------------------------------------------------------------------
// Chunked selective scan, 2 kernels. CCH=32 chunks of CLEN=32.
// Batched loads: lane s loads step-s values once per 16-step batch, steps
// consume via __shfl (16x fewer load instructions on dt/xin/z).
// dt, xin bf16; bc fp32: B = bc[r*32 + s], C = bc[r*32 + 16 + s].
// ---------------------------------------------------------------------------
__global__ __launch_bounds__(256) void scan_phase1(
    const unsigned short* __restrict__ dt,
    const float* __restrict__ bc,
    const unsigned short* __restrict__ xin,
    const float* __restrict__ Alog,
    float* __restrict__ hend,
    float* __restrict__ eprod)
{
    int blk = blockIdx.x;
    int c = blk % CCH;
    int tmp = blk / CCH;
    int dblk = tmp % (DI / 16);
    int b = tmp / (DI / 16);
    int lane = threadIdx.x & 63;
    int s = lane & 15;
    int g = lane & 0x30;                 // d-group base within wave
    int d = dblk * 16 + (threadIdx.x >> 4);
    float A = -__expf(Alog[d * DS + s]);
    float h = 0.f, P = 1.f;
    const int rowbase = b * SL + c * CLEN;
    #pragma unroll
    for (int half = 0; half < 2; ++half) {
        int rb = rowbase + half * 16;
        int rl = rb + s;                 // loader row for this lane
        float dtv_b = bf2f(dt[(size_t)rl * DI + d]);
        float xv_b  = bf2f(xin[(size_t)rl * DI + d]);
        #pragma unroll
        for (int t = 0; t < 16; ++t) {
            float dtv = __shfl(dtv_b, g | t, 64);
            float xv  = __shfl(xv_b,  g | t, 64);
            float Bv  = bc[(size_t)(rb + t) * 32 + s];
            float e = __expf(dtv * A);
            h = h * e + dtv * xv * Bv;
            P *= e;
        }
    }
    size_t idx = ((size_t)(b * CCH + c) * DI + d) * DS + s;
    hend[idx]  = h;
    eprod[idx] = P;
}

__global__ __launch_bounds__(256) void scan_phase3(
    const unsigned short* __restrict__ dt,
    const float* __restrict__ bc,
    const unsigned short* __restrict__ xin,
    const unsigned short* __restrict__ xz,   // z = cols [DI:2*DI)
    const float* __restrict__ Alog,
    const float* __restrict__ Dp,
    const float* __restrict__ hend,
    const float* __restrict__ eprod,
    unsigned short* __restrict__ ybf)
{
    int blk = blockIdx.x;
    int c = blk % CCH;
    int tmp = blk / CCH;
    int dblk = tmp % (DI / 16);
    int b = tmp / (DI / 16);
    int lane = threadIdx.x & 63;
    int s = lane & 15;
    int g = lane & 0x30;
    int d = dblk * 16 + (threadIdx.x >> 4);
    float A = -__expf(Alog[d * DS + s]);
    float Dv = Dp[d];

    float h = 0.f;
    const size_t pbase = ((size_t)b * CCH * DI + d) * DS + s;
    for (int j = 0; j < c; ++j) {
        size_t idx = pbase + (size_t)j * (DI * DS);
        h = h * eprod[idx] + hend[idx];
    }

    const int rowbase = b * SL + c * CLEN;
    #pragma unroll
    for (int half = 0; half < 2; ++half) {
        int rb = rowbase + half * 16;
        int rl = rb + s;
        float dtv_b = bf2f(dt[(size_t)rl * DI + d]);
        float xv_b  = bf2f(xin[(size_t)rl * DI + d]);
        float zv_b  = bf2f(xz[(size_t)rl * (2 * DI) + DI + d]);
        #pragma unroll
        for (int t = 0; t < 16; ++t) {
            float dtv = __shfl(dtv_b, g | t, 64);
            float xv  = __shfl(xv_b,  g | t, 64);
            int r = rb + t;
            float Bv  = bc[(size_t)r * 32 + s];
            float Cv  = bc[(size_t)r * 32 + 16 + s];
            float e = __expf(dtv * A);
            h = h * e + dtv * xv * Bv;
            float p = h * Cv;
            p += __shfl_xor(p, 1, 64);
            p += __shfl_xor(p, 2, 64);
            p += __shfl_xor(p, 4, 64);
            p += __shfl_xor(p, 8, 64);
            float z = __shfl(zv_b, g | t, 64);
            if (s == 0) {
                float yv = (p + xv * Dv) * (z / (1.f + __expf(-z)));
                ybf[(size_t)r * DI + d] = (unsigned short)f2bf(yv);
            }
        }
    }
}

// ---------------------------------------------------------------------------
// LayerNorm over rows of 768, bf16 in, bf16 out
// ---------------------------------------------------------------------------
__global__ __launch_bounds__(256) void ln_k(
    const unsigned short* __restrict__ x, const float* __restrict__ w,
    const float* __restrict__ b, unsigned short* __restrict__ o)
{
    int row = blockIdx.x;
    int tid = threadIdx.x;
    const unsigned short* xr = x + (size_t)row * DM;
    float v0 = bf2f(xr[tid]), v1 = bf2f(xr[tid + 256]), v2 = bf2f(xr[tid + 512]);
    float s = v0 + v1 + v2;
    #pragma unroll
    for (int off = 1; off < 64; off <<= 1) s += __shfl_xor(s, off, 64);
    __shared__ float red[4];
    __shared__ float red2[4];
    int wid = tid >> 6, lane = tid & 63;
    if (lane == 0) red[wid] = s;
    __syncthreads();
    float mu = (red[0] + red[1] + red[2] + red[3]) * (1.f / 768.f);
    float d0 = v0 - mu, d1 = v1 - mu, d2 = v2 - mu;
    float q = d0 * d0 + d1 * d1 + d2 * d2;
    #pragma unroll
    for (int off = 1; off < 64; off <<= 1) q += __shfl_xor(q, off, 64);
    if (lane == 0) red2[wid] = q;
    __syncthreads();
    float var = (red2[0] + red2[1] + red2[2] + red2[3]) * (1.f / 768.f);
    float rs = rsqrtf(var + 1e-5f);
    o[(size_t)row * DM + tid]       = (unsigned short)f2bf(d0 * rs * w[tid]       + b[tid]);
    o[(size_t)row * DM + tid + 256] = (unsigned short)f2bf(d1 * rs * w[tid + 256] + b[tid + 256]);
    o[(size_t)row * DM + tid + 512] = (unsigned short)f2bf(d2 * rs * w[tid + 512] + b[tid + 512]);
}

// ---------------------------------------------------------------------------
extern "C" void kernel_launch(void* const* d_in, const int* in_sizes, int n_in,
                              void* d_out, int out_size, void* d_ws, size_t ws_size,
                              hipStream_t stream) {
    const int*   ids        = (const int*)d_in[0];
    const float* emb        = (const float*)d_in[1];
    const float* in_proj_w  = (const float*)d_in[2];
    const float* conv_w     = (const float*)d_in[3];
    const float* conv_b     = (const float*)d_in[4];
    const float* x_proj_w   = (const float*)d_in[5];
    const float* dt_proj_w  = (const float*)d_in[6];
    const float* dt_proj_b  = (const float*)d_in[7];
    const float* A_log      = (const float*)d_in[8];
    const float* D_param    = (const float*)d_in[9];
    const float* out_proj_w = (const float*)d_in[10];
    const float* norm_w     = (const float*)d_in[11];
    const float* norm_b     = (const float*)d_in[12];
    float* out = (float*)d_out;

    // ---- workspace layout ----
    char* base = (char*)d_ws;
    size_t off = 0;
    auto alloc_f = [&](size_t n) { float* p = (float*)(base + off); off += n * 4; return p; };
    auto alloc_u = [&](size_t n) { unsigned short* p = (unsigned short*)(base + off); off += n * 2; return p; };

    float* bc    = alloc_f((size_t)ROWS * 32);
    float* hend  = alloc_f((size_t)NB * CCH * DI * DS);
    float* eprod = alloc_f((size_t)NB * CCH * DI * DS);
    unsigned short* xbf   = alloc_u((size_t)ROWS * DM);
    unsigned short* xzb   = alloc_u((size_t)ROWS * 2 * DI);
    unsigned short* xinb  = alloc_u((size_t)ROWS * DI);
    unsigned short* dtbf  = alloc_u((size_t)ROWS * DI);
    unsigned short* ybf   = alloc_u((size_t)ROWS * DI);
    unsigned short* xlnbf = alloc_u((size_t)ROWS * DM);
    unsigned short* inw_bf = alloc_u((size_t)NLAYER * 2 * DI * DM);
    unsigned short* ow_bf  = alloc_u((size_t)NLAYER * DM * DI);
    unsigned short* wbig  = alloc_u((size_t)NLAYER * NBIG * DI);
    unsigned short* emb_bf = alloc_u((size_t)VOCAB * DM);
    (void)ws_size;

    // ---- weight preconversion (once per call, single cvt dispatch) ----
    {
        int n4a = NLAYER * 2 * DI * DM / 4;
        int n4b = NLAYER * DM * DI / 4;
        int n4e = VOCAB * DM / 4;
        int n4t = n4a + n4b + n4e;
        cvt3_k<<<(n4t + 255) / 256, 256, 0, stream>>>(
            in_proj_w, inw_bf, n4a, out_proj_w, ow_bf, n4b, emb, emb_bf, n4e);
        wc_k<<<dim3(12, 13, NLAYER), 256, 0, stream>>>(dt_proj_w, x_proj_w, wbig);
    }

    embed_k<<<(ROWS * (DM / 4) + 255) / 256, 256, 0, stream>>>(ids, emb, xbf);

    const int scan_grid = NB * (DI / 16) * CCH;      // 6144 blocks

    for (int i = 0; i < NLAYER; ++i) {
        const float* cw  = conv_w  + (size_t)i * DI * DC;
        const float* cb  = conv_b  + (size_t)i * DI;
        const float* dtb = dt_proj_b + (size_t)i * DI;
        const float* Al  = A_log   + (size_t)i * DI * DS;
        const float* Dpar= D_param + (size_t)i * DI;

        // in_proj: xzb(bf16) = xbf @ inw^T  (64-tile, 3-deep, 768 blocks)
        const unsigned short* inw = inw_bf + (size_t)i * 2 * DI * DM;
        gemm_bf16<64, 128, 3, 2, false><<<24 * 32, 256, 0, stream>>>(
            xbf, DM, inw, DM, nullptr, xzb, 2 * DI, 32, 2 * DI, DM, nullptr, nullptr);

        conv_silu_k<<<(ROWS * (DI / 8)) / 256, 256, 0, stream>>>(xzb, cw, cb, xinb);

        // fused dt(bf16,softplus) + B/C(fp32): xinb @ wbig[i]^T  (N=1568, 3-deep)
        const unsigned short* wb = wbig + (size_t)i * NBIG * DI;
        gemm_bf16<64, 128, 3, 3, false><<<13 * 32, 256, 0, stream>>>(
            xinb, DI, wb, DI, nullptr, dtbf, DI, 32, NBIG, DI, dtb, bc);

        scan_phase1<<<scan_grid, 256, 0, stream>>>(dtbf, bc, xinb, Al, hend, eprod);
        scan_phase3<<<scan_grid, 256, 0, stream>>>(dtbf, bc, xinb, xzb, Al, Dpar,
                                                   hend, eprod, ybf);

        // out_proj: xbf(bf16) = ybf @ ow^T  (32-tile, 3-deep, 384 blocks)
        const unsigned short* ow = ow_bf + (size_t)i * DM * DI;
        gemm_bf16<32, 128, 3, 2, false><<<64 * 6, 256, 0, stream>>>(
            ybf, DI, ow, DI, nullptr, xbf, DM, 64, DM, DI, nullptr, nullptr);
    }

    ln_k<<<ROWS, 256, 0, stream>>>(xbf, norm_w, norm_b, xlnbf);
    // logits: out = xlnbf @ emb^T  (128x256 tile, 2-deep counted, NT epilogue)
    gemm_bf16<128, 256, 2, 0, true><<<197 * 16, 256, 0, stream>>>(
        xlnbf, DM, emb_bf, DM, out, nullptr, VOCAB, 16, VOCAB, DM, nullptr, nullptr);
}

// Round 13
// 2889.435 us; speedup vs baseline: 5.8829x; 1.0198x over previous
//
#include <hip/hip_runtime.h>
#include <hip/hip_bf16.h>

#define DI 1536
#define DS 16
#define DC 4
#define DTR 48
#define NB 2
#define SL 1024
#define DM 768
#define NLAYER 12
#define VOCAB 50257
#define ROWS (NB*SL)   // 2048
#define CCH 32         // scan chunks
#define CLEN (SL/CCH)  // 32
#define NBIG (DI+32)   // 1568: fused dt(1536) + B/C(32) outputs

typedef __attribute__((ext_vector_type(8))) short bf16x8;
typedef __attribute__((ext_vector_type(4))) short short4v;
typedef __attribute__((ext_vector_type(4))) float f32x4;

__device__ inline short f2bf(float f) {
    unsigned u = __builtin_bit_cast(unsigned, f);
    unsigned r = (u + 0x7fffu + ((u >> 16) & 1u)) >> 16;
    return (short)r;
}
__device__ inline float bf2f(unsigned short u) {
    unsigned x = ((unsigned)u) << 16;
    return __builtin_bit_cast(float, x);
}

__device__ __forceinline__ void gl_lds16(const void* g, void* l) {
    __builtin_amdgcn_global_load_lds(
        (const __attribute__((address_space(1))) unsigned int*)g,
        (__attribute__((address_space(3))) unsigned int*)l, 16, 0, 0);
}

// ---------------------------------------------------------------------------
// fp32 -> bf16 convert for 3 arrays in one dispatch (each n multiple of 4)
// ---------------------------------------------------------------------------
__global__ __launch_bounds__(256) void cvt3_k(
    const float* __restrict__ s0, unsigned short* __restrict__ d0, int n40,
    const float* __restrict__ s1, unsigned short* __restrict__ d1, int n41,
    const float* __restrict__ s2, unsigned short* __restrict__ d2, int n42)
{
    int i = blockIdx.x * 256 + threadIdx.x;
    const float* src; unsigned short* dst;
    if (i < n40) { src = s0; dst = d0; }
    else if (i < n40 + n41) { i -= n40; src = s1; dst = d1; }
    else if (i < n40 + n41 + n42) { i -= n40 + n41; src = s2; dst = d2; }
    else return;
    float4 v = *reinterpret_cast<const float4*>(src + (size_t)i * 4);
    short4v o;
    o[0] = f2bf(v.x); o[1] = f2bf(v.y); o[2] = f2bf(v.z); o[3] = f2bf(v.w);
    *reinterpret_cast<short4v*>(dst + (size_t)i * 4) = o;
}

// ---------------------------------------------------------------------------
// Wc precompute: wbig[l] rows 0..1535 = dtw @ xpw[:48]  (bf16),
//                rows 1536..1567 = xpw[48:80] (bf16).
// ---------------------------------------------------------------------------
__global__ __launch_bounds__(256) void wc_k(
    const float* __restrict__ dtw_all,   // (NL, DI, DTR)
    const float* __restrict__ xpw_all,   // (NL, 80, DI)
    unsigned short* __restrict__ wbig)   // (NL, NBIG, DI)
{
    int l = blockIdx.z;
    const float* dtw = dtw_all + (size_t)l * DI * DTR;
    const float* xpw = xpw_all + (size_t)l * 80 * DI;
    unsigned short* wb = wbig + (size_t)l * NBIG * DI;
    int tid = threadIdx.x;
    if (blockIdx.y == 12) {
        if (blockIdx.x == 0) {
            for (int idx = tid; idx < 32 * DI; idx += 256) {
                int rr = idx / DI, k = idx - rr * DI;
                wb[(size_t)(DI + rr) * DI + k] =
                    (unsigned short)f2bf(xpw[(size_t)(48 + rr) * DI + k]);
            }
        }
        return;
    }
    __shared__ float sd[128 * 48];
    __shared__ float sx[48 * 128];
    int d0 = blockIdx.y * 128, k0 = blockIdx.x * 128;
    for (int idx = tid; idx < 128 * 48; idx += 256) {
        int r = idx / 48, j = idx - r * 48;
        sd[idx] = dtw[(size_t)(d0 + r) * DTR + j];
    }
    for (int idx = tid; idx < 48 * 128; idx += 256) {
        int j = idx / 128, k = idx - j * 128;
        sx[idx] = xpw[(size_t)j * DI + k0 + k];
    }
    __syncthreads();
    int tx = tid & 15, ty = tid >> 4;
    float acc[8][8] = {};
    for (int j = 0; j < 48; ++j) {
        float a[8], w[8];
        #pragma unroll
        for (int i = 0; i < 8; ++i) a[i] = sd[(ty * 8 + i) * 48 + j];
        #pragma unroll
        for (int i = 0; i < 8; ++i) w[i] = sx[j * 128 + tx * 8 + i];
        #pragma unroll
        for (int i = 0; i < 8; ++i)
            #pragma unroll
            for (int jj = 0; jj < 8; ++jj)
                acc[i][jj] += a[i] * w[jj];
    }
    for (int i = 0; i < 8; ++i)
        for (int jj = 0; jj < 8; ++jj)
            wb[(size_t)(d0 + ty * 8 + i) * DI + k0 + tx * 8 + jj] =
                (unsigned short)f2bf(acc[i][jj]);
}

// ---------------------------------------------------------------------------
// Embedding (vectorized x4)
// ---------------------------------------------------------------------------
__global__ __launch_bounds__(256) void embed_k(const int* __restrict__ ids,
                                               const float* __restrict__ emb,
                                               unsigned short* __restrict__ xbf) {
    int i = blockIdx.x * 256 + threadIdx.x;      // over ROWS * DM/4
    if (i >= ROWS * (DM / 4)) return;
    int row = i / (DM / 4);
    int c4 = (i - row * (DM / 4)) * 4;
    float4 v = *reinterpret_cast<const float4*>(
        &emb[(size_t)ids[row] * DM + c4]);
    const float s = 27.712812921102035f;
    short4v o;
    o[0] = f2bf(v.x * s); o[1] = f2bf(v.y * s);
    o[2] = f2bf(v.z * s); o[3] = f2bf(v.w * s);
    *reinterpret_cast<short4v*>(&xbf[(size_t)row * DM + c4]) = o;
}

// ---------------------------------------------------------------------------
// bf16-MFMA GEMM, NBUF-deep pipeline with COUNTED vmcnt (T3/T4).
// MT x 128 tile (MT = 32/64/128), BKT=32, 4 waves, NBUF = 2..4.
// global_load_lds staging, linear LDS dest, pre-swizzled source
// (involution chunk ^ ((row>>1)&3), conflict-free ds_read_b128).
// OUT: 0 = fp32 store (NTST -> LDS-transposed full-line NT epilogue);
//      2 = bf16-only store; 3 = fused dt softplus (bf16) / BC (fp32) split.
// ---------------------------------------------------------------------------
template<int MT, int NBUF, int OUT, bool NTST>
__global__ __launch_bounds__(256) void gemm_bf16(
    const unsigned short* __restrict__ A, int lda,
    const unsigned short* __restrict__ W, int ldw,
    float* __restrict__ C, unsigned short* __restrict__ Cbf, int ldc,
    int GY, int N, int K,
    const float* __restrict__ bias, float* __restrict__ aux)
{
    constexpr int BKT = 32;
    constexpr int CPR = BKT / 8;                  // 4 chunks per row
    constexpr int ACA = (MT * CPR + 255) / 256;   // A staging issues/thread
    constexpr int ACW = 128 * CPR / 256;          // W staging issues/thread (2)
    constexpr int ISS = ACA + ACW;                // gl_lds instrs per STAGE
    constexpr int MFR = MT / 32;                  // M fragments per wave
    constexpr int BUFS = (MT + 128) * BKT;        // shorts per buffer
    __shared__ __align__(16) short smem[NBUF * BUFS];

    const int tid  = threadIdx.x;
    const int lane = tid & 63;
    const int wid  = tid >> 6;
    const int wr   = wid >> 1, wc = wid & 1;

    // bijective XCD-chunked swizzle, then col-major decode
    const int nwg = gridDim.x;
    const int q = nwg >> 3, rm = nwg & 7;
    const int xcd = blockIdx.x & 7, bidx = blockIdx.x >> 3;
    const int wg = (xcd < rm ? xcd * (q + 1) : rm * (q + 1) + (xcd - rm) * q) + bidx;
    const int row0 = (wg % GY) * MT;
    const int col0 = (wg / GY) * 128;

    // ---- staging setup (pre-swizzled global sources) ----
    const unsigned short* gA[ACA];
    const unsigned short* gW[ACW];
    #pragma unroll
    for (int i = 0; i < ACA; ++i) {
        int cid = i * 256 + ((MT == 32) ? (tid & 127) : tid);
        int r = cid / CPR, c = cid % CPR;
        gA[i] = A + (size_t)(row0 + r) * lda + ((c ^ ((r >> 1) & 3)) * 8);
    }
    #pragma unroll
    for (int i = 0; i < ACW; ++i) {
        int cid = i * 256 + tid;
        int r = cid / CPR, c = cid % CPR;
        int rg = col0 + r; if (rg > N - 1) rg = N - 1;   // clamp: dup, store-guarded
        gW[i] = W + (size_t)rg * ldw + ((c ^ ((r >> 1) & 3)) * 8);
    }

    const int arow = (MT == 32 ? wr * 16 : wr * (MT / 2)) + (lane & 15);
    const int brow = wc * 64 + (lane & 15);
    const int szA = (arow >> 1) & 3;          // row+16 invariant
    const int szB = (brow >> 1) & 3;
    const int hi = lane >> 4;                 // 0..3 (= k-chunk for BKT=32)

    auto STAGE = [&](int buf) {
        short* As = smem + buf * BUFS;
        short* Ws = As + MT * BKT;
        #pragma unroll
        for (int i = 0; i < ACA; ++i) {
            int cbase = (MT == 32) ? ((wid & 1) * 64) : (i * 256 + wid * 64);
            gl_lds16(gA[i], &As[cbase * 8]);
            gA[i] += BKT;
        }
        #pragma unroll
        for (int i = 0; i < ACW; ++i) {
            gl_lds16(gW[i], &Ws[(i * 256 + wid * 64) * 8]);
            gW[i] += BKT;
        }
    };

    f32x4 acc[MFR][4] = {};

    const int ntiles = K / BKT;               // >= 24 at all call sites
    #pragma unroll
    for (int p = 0; p < NBUF - 1; ++p) STAGE(p);

    for (int t = 0; t < ntiles; ++t) {
        const int next = t + NBUF - 1;
        if (next < ntiles) STAGE(next % NBUF);   // deepest prefetch in flight
        int ahead = ntiles - 1 - t;
        if (ahead > NBUF - 1) ahead = NBUF - 1;
        // counted waits: tile t landed, newer tiles stay in flight
        if (NBUF >= 4 && ahead == 3)
            asm volatile("s_waitcnt vmcnt(%0)" :: "n"(3 * ISS) : "memory");
        else if (NBUF >= 3 && ahead == 2)
            asm volatile("s_waitcnt vmcnt(%0)" :: "n"(2 * ISS) : "memory");
        else if (ahead == 1)
            asm volatile("s_waitcnt vmcnt(%0)" :: "n"(ISS) : "memory");
        else if (ahead == 0)
            asm volatile("s_waitcnt vmcnt(0)" ::: "memory");
        __builtin_amdgcn_sched_barrier(0);
        __builtin_amdgcn_s_barrier();      // tile-t buffer visible to all waves

        const short* As = smem + (t % NBUF) * BUFS;
        const short* Ws = As + MT * BKT;
        bf16x8 a[MFR], b[4];
        #pragma unroll
        for (int mf = 0; mf < MFR; ++mf)
            a[mf] = *reinterpret_cast<const bf16x8*>(
                &As[(arow + mf * 16) * BKT + ((hi ^ szA) * 8)]);
        #pragma unroll
        for (int nf = 0; nf < 4; ++nf)
            b[nf] = *reinterpret_cast<const bf16x8*>(
                &Ws[(brow + nf * 16) * BKT + ((hi ^ szB) * 8)]);
        #pragma unroll
        for (int mf = 0; mf < MFR; ++mf)
            #pragma unroll
            for (int nf = 0; nf < 4; ++nf)
                acc[mf][nf] = __builtin_amdgcn_mfma_f32_16x16x32_bf16(
                    a[mf], b[nf], acc[mf][nf], 0, 0, 0);

        __builtin_amdgcn_s_barrier();      // reads retired before overwrite
    }

    if (OUT == 0 && NTST) {
        __syncthreads();
        // LDS-transposed epilogue: full-line NT dword stores.
        float* Cs = (float*)smem;    // [32][132] fp32 (16.9KB <= NBUF*BUFS*2B)
        #pragma unroll
        for (int mf = 0; mf < MFR; ++mf) {
            __syncthreads();
            #pragma unroll
            for (int nf = 0; nf < 4; ++nf) {
                #pragma unroll
                for (int j = 0; j < 4; ++j)
                    Cs[(wr * 16 + hi * 4 + j) * 132 + wc * 64 + nf * 16 + (lane & 15)]
                        = acc[mf][nf][j];
            }
            __syncthreads();
            #pragma unroll
            for (int rr = 0; rr < 8; ++rr) {
                int lrow = wid * 8 + rr;      // 0..31
                int grow = row0 + (lrow < 16 ? mf * 16 + lrow
                                             : (MT / 2) + mf * 16 + (lrow - 16));
                #pragma unroll
                for (int hf = 0; hf < 2; ++hf) {
                    int cc = col0 + hf * 64 + lane;
                    if (cc < N)
                        __builtin_nontemporal_store(
                            Cs[lrow * 132 + hf * 64 + lane],
                            &C[(size_t)grow * ldc + cc]);
                }
            }
        }
    } else {
        #pragma unroll
        for (int mf = 0; mf < MFR; ++mf) {
            #pragma unroll
            for (int nf = 0; nf < 4; ++nf) {
                int r  = row0 + (MT == 32 ? wr * 16 : wr * (MT / 2)) + mf * 16 + hi * 4;
                int cc = col0 + wc * 64 + nf * 16 + (lane & 15);
                if (cc < N) {
                    f32x4 d = acc[mf][nf];
                    if (OUT == 3) {
                        if (cc < DI) {
                            float bv = bias[cc];
                            #pragma unroll
                            for (int j = 0; j < 4; ++j) {
                                float v = d[j] + bv;
                                v = (v > 20.f) ? v : log1pf(__expf(v));
                                Cbf[(size_t)(r + j) * ldc + cc] = (unsigned short)f2bf(v);
                            }
                        } else {
                            #pragma unroll
                            for (int j = 0; j < 4; ++j)
                                aux[(size_t)(r + j) * 32 + (cc - DI)] = d[j];
                        }
                    } else if (OUT == 2) {
                        #pragma unroll
                        for (int j = 0; j < 4; ++j)
                            Cbf[(size_t)(r + j) * ldc + cc] = (unsigned short)f2bf(d[j]);
                    } else {
                        #pragma unroll
                        for (int j = 0; j < 4; ++j)
                            C[(size_t)(r + j) * ldc + cc] = d[j];
                    }
                }
            }
        }
    }
}

// ---------------------------------------------------------------------------
// Depthwise causal conv(4) + bias + silu, vectorized: 8 channels/thread.
// ---------------------------------------------------------------------------
__global__ __launch_bounds__(256) void conv_silu_k(
    const unsigned short* __restrict__ xz, const float* __restrict__ cw,
    const float* __restrict__ cb, unsigned short* __restrict__ xinb)
{
    int i = blockIdx.x * 256 + threadIdx.x;   // over ROWS * DI/8
    if (i >= ROWS * (DI / 8)) return;
    int row = i / (DI / 8);
    int c = (i - row * (DI / 8)) * 8;
    int t = row & (SL - 1);
    int b = row >> 10;

    float4 wv[8];
    float accv[8];
    #pragma unroll
    for (int j = 0; j < 8; ++j) {
        wv[j] = *reinterpret_cast<const float4*>(&cw[(c + j) * DC]);
        accv[j] = cb[c + j];
    }
    const unsigned short* base = xz + ((size_t)(b * SL)) * (2 * DI) + c;
    #pragma unroll
    for (int k = 0; k < DC; ++k) {
        int tt = t + k - (DC - 1);
        if (tt >= 0) {
            bf16x8 v = *reinterpret_cast<const bf16x8*>(
                &base[(size_t)tt * (2 * DI)]);
            #pragma unroll
            for (int j = 0; j < 8; ++j)
                accv[j] += bf2f((unsigned short)v[j]) *
                           reinterpret_cast<const float*>(&wv[j])[k];
        }
    }
    bf16x8 o;
    #pragma unroll
    for (int j = 0; j < 8; ++j) {
        float v = accv[j] / (1.f + __expf(-accv[j]));
        o[j] = f2bf(v);
    }
    *reinterpret_cast<bf16x8*>(&xinb[(size_t)row * DI + c]) = o;
}

// ---------------------------------------------------------------------------
// Chunked selective scan, 2 kernels. CCH=32 chunks of CLEN=32.
// Batched loads: lane s loads step-s values once per 16-step batch, steps
// consume via __shfl (16x fewer load instructions on dt/xin/z).
// dt, xin bf16; bc fp32: B = bc[r*32 + s], C = bc[r*32 + 16 + s].
// ---------------------------------------------------------------------------
__global__ __launch_bounds__(256) void scan_phase1(
    const unsigned short* __restrict__ dt,
    const float* __restrict__ bc,
    const unsigned short* __restrict__ xin,
    const float* __restrict__ Alog,
    float* __restrict__ hend,
    float* __restrict__ eprod)
{
    int blk = blockIdx.x;
    int c = blk % CCH;
    int tmp = blk / CCH;
    int dblk = tmp % (DI / 16);
    int b = tmp / (DI / 16);
    int lane = threadIdx.x & 63;
    int s = lane & 15;
    int g = lane & 0x30;                 // d-group base within wave
    int d = dblk * 16 + (threadIdx.x >> 4);
    float A = -__expf(Alog[d * DS + s]);
    float h = 0.f, P = 1.f;
    const int rowbase = b * SL + c * CLEN;
    #pragma unroll
    for (int half = 0; half < 2; ++half) {
        int rb = rowbase + half * 16;
        int rl = rb + s;                 // loader row for this lane
        float dtv_b = bf2f(dt[(size_t)rl * DI + d]);
        float xv_b  = bf2f(xin[(size_t)rl * DI + d]);
        #pragma unroll
        for (int t = 0; t < 16; ++t) {
            float dtv = __shfl(dtv_b, g | t, 64);
            float xv  = __shfl(xv_b,  g | t, 64);
            float Bv  = bc[(size_t)(rb + t) * 32 + s];
            float e = __expf(dtv * A);
            h = h * e + dtv * xv * Bv;
            P *= e;
        }
    }
    size_t idx = ((size_t)(b * CCH + c) * DI + d) * DS + s;
    hend[idx]  = h;
    eprod[idx] = P;
}

__global__ __launch_bounds__(256) void scan_phase3(
    const unsigned short* __restrict__ dt,
    const float* __restrict__ bc,
    const unsigned short* __restrict__ xin,
    const unsigned short* __restrict__ xz,   // z = cols [DI:2*DI)
    const float* __restrict__ Alog,
    const float* __restrict__ Dp,
    const float* __restrict__ hend,
    const float* __restrict__ eprod,
    unsigned short* __restrict__ ybf)
{
    int blk = blockIdx.x;
    int c = blk % CCH;
    int tmp = blk / CCH;
    int dblk = tmp % (DI / 16);
    int b = tmp / (DI / 16);
    int lane = threadIdx.x & 63;
    int s = lane & 15;
    int g = lane & 0x30;
    int d = dblk * 16 + (threadIdx.x >> 4);
    float A = -__expf(Alog[d * DS + s]);
    float Dv = Dp[d];

    float h = 0.f;
    const size_t pbase = ((size_t)b * CCH * DI + d) * DS + s;
    for (int j = 0; j < c; ++j) {
        size_t idx = pbase + (size_t)j * (DI * DS);
        h = h * eprod[idx] + hend[idx];
    }

    const int rowbase = b * SL + c * CLEN;
    #pragma unroll
    for (int half = 0; half < 2; ++half) {
        int rb = rowbase + half * 16;
        int rl = rb + s;
        float dtv_b = bf2f(dt[(size_t)rl * DI + d]);
        float xv_b  = bf2f(xin[(size_t)rl * DI + d]);
        float zv_b  = bf2f(xz[(size_t)rl * (2 * DI) + DI + d]);
        #pragma unroll
        for (int t = 0; t < 16; ++t) {
            float dtv = __shfl(dtv_b, g | t, 64);
            float xv  = __shfl(xv_b,  g | t, 64);
            int r = rb + t;
            float Bv  = bc[(size_t)r * 32 + s];
            float Cv  = bc[(size_t)r * 32 + 16 + s];
            float e = __expf(dtv * A);
            h = h * e + dtv * xv * Bv;
            float p = h * Cv;
            p += __shfl_xor(p, 1, 64);
            p += __shfl_xor(p, 2, 64);
            p += __shfl_xor(p, 4, 64);
            p += __shfl_xor(p, 8, 64);
            float z = __shfl(zv_b, g | t, 64);
            if (s == 0) {
                float yv = (p + xv * Dv) * (z / (1.f + __expf(-z)));
                ybf[(size_t)r * DI + d] = (unsigned short)f2bf(yv);
            }
        }
    }
}

// ---------------------------------------------------------------------------
// LayerNorm over rows of 768, bf16 in, bf16 out
// ---------------------------------------------------------------------------
__global__ __launch_bounds__(256) void ln_k(
    const unsigned short* __restrict__ x, const float* __restrict__ w,
    const float* __restrict__ b, unsigned short* __restrict__ o)
{
    int row = blockIdx.x;
    int tid = threadIdx.x;
    const unsigned short* xr = x + (size_t)row * DM;
    float v0 = bf2f(xr[tid]), v1 = bf2f(xr[tid + 256]), v2 = bf2f(xr[tid + 512]);
    float s = v0 + v1 + v2;
    #pragma unroll
    for (int off = 1; off < 64; off <<= 1) s += __shfl_xor(s, off, 64);
    __shared__ float red[4];
    __shared__ float red2[4];
    int wid = tid >> 6, lane = tid & 63;
    if (lane == 0) red[wid] = s;
    __syncthreads();
    float mu = (red[0] + red[1] + red[2] + red[3]) * (1.f / 768.f);
    float d0 = v0 - mu, d1 = v1 - mu, d2 = v2 - mu;
    float q = d0 * d0 + d1 * d1 + d2 * d2;
    #pragma unroll
    for (int off = 1; off < 64; off <<= 1) q += __shfl_xor(q, off, 64);
    if (lane == 0) red2[wid] = q;
    __syncthreads();
    float var = (red2[0] + red2[1] + red2[2] + red2[3]) * (1.f / 768.f);
    float rs = rsqrtf(var + 1e-5f);
    o[(size_t)row * DM + tid]       = (unsigned short)f2bf(d0 * rs * w[tid]       + b[tid]);
    o[(size_t)row * DM + tid + 256] = (unsigned short)f2bf(d1 * rs * w[tid + 256] + b[tid + 256]);
    o[(size_t)row * DM + tid + 512] = (unsigned short)f2bf(d2 * rs * w[tid + 512] + b[tid + 512]);
}

// ---------------------------------------------------------------------------
extern "C" void kernel_launch(void* const* d_in, const int* in_sizes, int n_in,
                              void* d_out, int out_size, void* d_ws, size_t ws_size,
                              hipStream_t stream) {
    const int*   ids        = (const int*)d_in[0];
    const float* emb        = (const float*)d_in[1];
    const float* in_proj_w  = (const float*)d_in[2];
    const float* conv_w     = (const float*)d_in[3];
    const float* conv_b     = (const float*)d_in[4];
    const float* x_proj_w   = (const float*)d_in[5];
    const float* dt_proj_w  = (const float*)d_in[6];
    const float* dt_proj_b  = (const float*)d_in[7];
    const float* A_log      = (const float*)d_in[8];
    const float* D_param    = (const float*)d_in[9];
    const float* out_proj_w = (const float*)d_in[10];
    const float* norm_w     = (const float*)d_in[11];
    const float* norm_b     = (const float*)d_in[12];
    float* out = (float*)d_out;

    // ---- workspace layout ----
    char* base = (char*)d_ws;
    size_t off = 0;
    auto alloc_f = [&](size_t n) { float* p = (float*)(base + off); off += n * 4; return p; };
    auto alloc_u = [&](size_t n) { unsigned short* p = (unsigned short*)(base + off); off += n * 2; return p; };

    float* bc    = alloc_f((size_t)ROWS * 32);
    float* hend  = alloc_f((size_t)NB * CCH * DI * DS);
    float* eprod = alloc_f((size_t)NB * CCH * DI * DS);
    unsigned short* xbf   = alloc_u((size_t)ROWS * DM);
    unsigned short* xzb   = alloc_u((size_t)ROWS * 2 * DI);
    unsigned short* xinb  = alloc_u((size_t)ROWS * DI);
    unsigned short* dtbf  = alloc_u((size_t)ROWS * DI);
    unsigned short* ybf   = alloc_u((size_t)ROWS * DI);
    unsigned short* xlnbf = alloc_u((size_t)ROWS * DM);
    unsigned short* inw_bf = alloc_u((size_t)NLAYER * 2 * DI * DM);
    unsigned short* ow_bf  = alloc_u((size_t)NLAYER * DM * DI);
    unsigned short* wbig  = alloc_u((size_t)NLAYER * NBIG * DI);
    unsigned short* emb_bf = alloc_u((size_t)VOCAB * DM);
    (void)ws_size;

    // ---- weight preconversion (once per call, single cvt dispatch) ----
    {
        int n4a = NLAYER * 2 * DI * DM / 4;
        int n4b = NLAYER * DM * DI / 4;
        int n4e = VOCAB * DM / 4;
        int n4t = n4a + n4b + n4e;
        cvt3_k<<<(n4t + 255) / 256, 256, 0, stream>>>(
            in_proj_w, inw_bf, n4a, out_proj_w, ow_bf, n4b, emb, emb_bf, n4e);
        wc_k<<<dim3(12, 13, NLAYER), 256, 0, stream>>>(dt_proj_w, x_proj_w, wbig);
    }

    embed_k<<<(ROWS * (DM / 4) + 255) / 256, 256, 0, stream>>>(ids, emb, xbf);

    const int scan_grid = NB * (DI / 16) * CCH;      // 6144 blocks

    for (int i = 0; i < NLAYER; ++i) {
        const float* cw  = conv_w  + (size_t)i * DI * DC;
        const float* cb  = conv_b  + (size_t)i * DI;
        const float* dtb = dt_proj_b + (size_t)i * DI;
        const float* Al  = A_log   + (size_t)i * DI * DS;
        const float* Dpar= D_param + (size_t)i * DI;

        // in_proj: xzb(bf16) = xbf @ inw^T  (64-tile, 4-deep, 768 blocks = 3/CU)
        const unsigned short* inw = inw_bf + (size_t)i * 2 * DI * DM;
        gemm_bf16<64, 4, 2, false><<<24 * 32, 256, 0, stream>>>(
            xbf, DM, inw, DM, nullptr, xzb, 2 * DI, 32, 2 * DI, DM, nullptr, nullptr);

        conv_silu_k<<<(ROWS * (DI / 8)) / 256, 256, 0, stream>>>(xzb, cw, cb, xinb);

        // fused dt(bf16,softplus) + B/C(fp32): xinb @ wbig[i]^T  (N=1568, 4-deep)
        const unsigned short* wb = wbig + (size_t)i * NBIG * DI;
        gemm_bf16<64, 4, 3, false><<<13 * 32, 256, 0, stream>>>(
            xinb, DI, wb, DI, nullptr, dtbf, DI, 32, NBIG, DI, dtb, bc);

        scan_phase1<<<scan_grid, 256, 0, stream>>>(dtbf, bc, xinb, Al, hend, eprod);
        scan_phase3<<<scan_grid, 256, 0, stream>>>(dtbf, bc, xinb, xzb, Al, Dpar,
                                                   hend, eprod, ybf);

        // out_proj: xbf(bf16) = ybf @ ow^T  (32-tile, 4-deep, 384 blocks)
        const unsigned short* ow = ow_bf + (size_t)i * DM * DI;
        gemm_bf16<32, 4, 2, false><<<64 * 6, 256, 0, stream>>>(
            ybf, DI, ow, DI, nullptr, xbf, DM, 64, DM, DI, nullptr, nullptr);
    }

    ln_k<<<ROWS, 256, 0, stream>>>(xbf, norm_w, norm_b, xlnbf);
    // logits: out = xlnbf @ emb^T  (128x128 tile, 2-deep counted, NT epilogue)
    gemm_bf16<128, 2, 0, true><<<393 * 16, 256, 0, stream>>>(
        xlnbf, DM, emb_bf, DM, out, nullptr, VOCAB, 16, VOCAB, DM, nullptr, nullptr);
}

// Round 14
// 2771.634 us; speedup vs baseline: 6.1329x; 1.0425x over previous
//
#include <hip/hip_runtime.h>
#include <hip/hip_bf16.h>

#define DI 1536
#define DS 16
#define DC 4
#define DTR 48
#define NB 2
#define SL 1024
#define DM 768
#define NLAYER 12
#define VOCAB 50257
#define ROWS (NB*SL)   // 2048
#define CCH 32         // scan chunks
#define CLEN (SL/CCH)  // 32
#define NBIG (DI+32)   // 1568: fused dt(1536) + B/C(32) outputs

typedef __attribute__((ext_vector_type(8))) short bf16x8;
typedef __attribute__((ext_vector_type(4))) short short4v;
typedef __attribute__((ext_vector_type(4))) float f32x4;

__device__ inline short f2bf(float f) {
    unsigned u = __builtin_bit_cast(unsigned, f);
    unsigned r = (u + 0x7fffu + ((u >> 16) & 1u)) >> 16;
    return (short)r;
}
__device__ inline float bf2f(unsigned short u) {
    unsigned x = ((unsigned)u) << 16;
    return __builtin_bit_cast(float, x);
}

__device__ __forceinline__ void gl_lds16(const void* g, void* l) {
    __builtin_amdgcn_global_load_lds(
        (const __attribute__((address_space(1))) unsigned int*)g,
        (__attribute__((address_space(3))) unsigned int*)l, 16, 0, 0);
}

// ---------------------------------------------------------------------------
// fp32 -> bf16 convert for 3 arrays in one dispatch (each n multiple of 4)
// ---------------------------------------------------------------------------
__global__ __launch_bounds__(256) void cvt3_k(
    const float* __restrict__ s0, unsigned short* __restrict__ d0, int n40,
    const float* __restrict__ s1, unsigned short* __restrict__ d1, int n41,
    const float* __restrict__ s2, unsigned short* __restrict__ d2, int n42)
{
    int i = blockIdx.x * 256 + threadIdx.x;
    const float* src; unsigned short* dst;
    if (i < n40) { src = s0; dst = d0; }
    else if (i < n40 + n41) { i -= n40; src = s1; dst = d1; }
    else if (i < n40 + n41 + n42) { i -= n40 + n41; src = s2; dst = d2; }
    else return;
    float4 v = *reinterpret_cast<const float4*>(src + (size_t)i * 4);
    short4v o;
    o[0] = f2bf(v.x); o[1] = f2bf(v.y); o[2] = f2bf(v.z); o[3] = f2bf(v.w);
    *reinterpret_cast<short4v*>(dst + (size_t)i * 4) = o;
}

// ---------------------------------------------------------------------------
// Wc precompute: wbig[l] rows 0..1535 = dtw @ xpw[:48]  (bf16),
//                rows 1536..1567 = xpw[48:80] (bf16).
// ---------------------------------------------------------------------------
__global__ __launch_bounds__(256) void wc_k(
    const float* __restrict__ dtw_all,   // (NL, DI, DTR)
    const float* __restrict__ xpw_all,   // (NL, 80, DI)
    unsigned short* __restrict__ wbig)   // (NL, NBIG, DI)
{
    int l = blockIdx.z;
    const float* dtw = dtw_all + (size_t)l * DI * DTR;
    const float* xpw = xpw_all + (size_t)l * 80 * DI;
    unsigned short* wb = wbig + (size_t)l * NBIG * DI;
    int tid = threadIdx.x;
    if (blockIdx.y == 12) {
        if (blockIdx.x == 0) {
            for (int idx = tid; idx < 32 * DI; idx += 256) {
                int rr = idx / DI, k = idx - rr * DI;
                wb[(size_t)(DI + rr) * DI + k] =
                    (unsigned short)f2bf(xpw[(size_t)(48 + rr) * DI + k]);
            }
        }
        return;
    }
    __shared__ float sd[128 * 48];
    __shared__ float sx[48 * 128];
    int d0 = blockIdx.y * 128, k0 = blockIdx.x * 128;
    for (int idx = tid; idx < 128 * 48; idx += 256) {
        int r = idx / 48, j = idx - r * 48;
        sd[idx] = dtw[(size_t)(d0 + r) * DTR + j];
    }
    for (int idx = tid; idx < 48 * 128; idx += 256) {
        int j = idx / 128, k = idx - j * 128;
        sx[idx] = xpw[(size_t)j * DI + k0 + k];
    }
    __syncthreads();
    int tx = tid & 15, ty = tid >> 4;
    float acc[8][8] = {};
    for (int j = 0; j < 48; ++j) {
        float a[8], w[8];
        #pragma unroll
        for (int i = 0; i < 8; ++i) a[i] = sd[(ty * 8 + i) * 48 + j];
        #pragma unroll
        for (int i = 0; i < 8; ++i) w[i] = sx[j * 128 + tx * 8 + i];
        #pragma unroll
        for (int i = 0; i < 8; ++i)
            #pragma unroll
            for (int jj = 0; jj < 8; ++jj)
                acc[i][jj] += a[i] * w[jj];
    }
    for (int i = 0; i < 8; ++i)
        for (int jj = 0; jj < 8; ++jj)
            wb[(size_t)(d0 + ty * 8 + i) * DI + k0 + tx * 8 + jj] =
                (unsigned short)f2bf(acc[i][jj]);
}

// ---------------------------------------------------------------------------
// Embedding (vectorized x4)
// ---------------------------------------------------------------------------
__global__ __launch_bounds__(256) void embed_k(const int* __restrict__ ids,
                                               const float* __restrict__ emb,
                                               unsigned short* __restrict__ xbf) {
    int i = blockIdx.x * 256 + threadIdx.x;      // over ROWS * DM/4
    if (i >= ROWS * (DM / 4)) return;
    int row = i / (DM / 4);
    int c4 = (i - row * (DM / 4)) * 4;
    float4 v = *reinterpret_cast<const float4*>(
        &emb[(size_t)ids[row] * DM + c4]);
    const float s = 27.712812921102035f;
    short4v o;
    o[0] = f2bf(v.x * s); o[1] = f2bf(v.y * s);
    o[2] = f2bf(v.z * s); o[3] = f2bf(v.w * s);
    *reinterpret_cast<short4v*>(&xbf[(size_t)row * DM + c4]) = o;
}

// ---------------------------------------------------------------------------
// bf16-MFMA GEMM, NBUF-deep pipeline with COUNTED vmcnt (T3/T4).
// BS threads (256: 4 waves 2x2; 512: 8 waves 4x2), MT x 128 tile, BKT=32.
// global_load_lds staging, linear LDS dest, pre-swizzled source
// (involution chunk ^ ((row>>1)&3), conflict-free ds_read_b128).
// OUT: 0 = fp32 store (NTST -> LDS-transposed full-line NT epilogue);
//      2 = bf16-only store; 3 = fused dt softplus (bf16) / BC (fp32) split.
// ---------------------------------------------------------------------------
template<int BS, int MT, int NBUF, int OUT, bool NTST>
__global__ __launch_bounds__(BS) void gemm_bf16(
    const unsigned short* __restrict__ A, int lda,
    const unsigned short* __restrict__ W, int ldw,
    float* __restrict__ C, unsigned short* __restrict__ Cbf, int ldc,
    int GY, int N, int K,
    const float* __restrict__ bias, float* __restrict__ aux)
{
    constexpr int BKT = 32;
    constexpr int CPR = BKT / 8;                  // 4 chunks per row
    constexpr int WRG = (BS / 64) / 2;            // wr groups (2 or 4)
    constexpr int ACH = MT * CPR;                 // A chunks per tile
    constexpr int ACA = (ACH >= BS) ? ACH / BS : 1;
    constexpr int ACW = (128 * CPR) / BS;         // W staging issues/thread
    constexpr int ISS = ACA + ACW;                // gl_lds instrs per STAGE
    constexpr int MFR = MT / (16 * WRG);          // M fragments per wave
    constexpr int BUFS = (MT + 128) * BKT;        // shorts per buffer
    __shared__ __align__(16) short smem[NBUF * BUFS];

    const int tid  = threadIdx.x;
    const int lane = tid & 63;
    const int wid  = tid >> 6;
    const int wr   = wid >> 1, wc = wid & 1;

    // bijective XCD-chunked swizzle, then col-major decode
    const int nwg = gridDim.x;
    const int q = nwg >> 3, rm = nwg & 7;
    const int xcd = blockIdx.x & 7, bidx = blockIdx.x >> 3;
    const int wg = (xcd < rm ? xcd * (q + 1) : rm * (q + 1) + (xcd - rm) * q) + bidx;
    const int row0 = (wg % GY) * MT;
    const int col0 = (wg / GY) * 128;

    // ---- staging setup (pre-swizzled global sources) ----
    const unsigned short* gA[ACA];
    const unsigned short* gW[ACW];
    #pragma unroll
    for (int i = 0; i < ACA; ++i) {
        int cid = (ACH >= BS) ? (i * BS + tid) : (tid & (ACH - 1));
        int r = cid >> 2, c = cid & 3;
        gA[i] = A + (size_t)(row0 + r) * lda + ((c ^ ((r >> 1) & 3)) * 8);
    }
    #pragma unroll
    for (int i = 0; i < ACW; ++i) {
        int cid = i * BS + tid;
        int r = cid >> 2, c = cid & 3;
        int rg = col0 + r; if (rg > N - 1) rg = N - 1;   // clamp: dup, store-guarded
        gW[i] = W + (size_t)rg * ldw + ((c ^ ((r >> 1) & 3)) * 8);
    }

    const int arow = wr * (MT / WRG) + (lane & 15);
    const int brow = wc * 64 + (lane & 15);
    const int szA = (arow >> 1) & 3;          // row+16 invariant
    const int szB = (brow >> 1) & 3;
    const int hi = lane >> 4;                 // 0..3 (= k-chunk for BKT=32)

    auto STAGE = [&](int buf) {
        short* As = smem + buf * BUFS;
        short* Ws = As + MT * BKT;
        #pragma unroll
        for (int i = 0; i < ACA; ++i) {
            int cbase = (ACH >= BS) ? (i * BS + wid * 64)
                                    : ((wid % (ACH / 64)) * 64);
            gl_lds16(gA[i], &As[cbase * 8]);
            gA[i] += BKT;
        }
        #pragma unroll
        for (int i = 0; i < ACW; ++i) {
            gl_lds16(gW[i], &Ws[(i * BS + wid * 64) * 8]);
            gW[i] += BKT;
        }
    };

    f32x4 acc[MFR][4] = {};

    const int ntiles = K / BKT;               // >= 24 at all call sites
    #pragma unroll
    for (int p = 0; p < NBUF - 1; ++p) STAGE(p);

    for (int t = 0; t < ntiles; ++t) {
        const int next = t + NBUF - 1;
        if (next < ntiles) STAGE(next % NBUF);   // deepest prefetch in flight
        int ahead = ntiles - 1 - t;
        if (ahead > NBUF - 1) ahead = NBUF - 1;
        // counted waits: tile t landed, newer tiles stay in flight
        if (NBUF >= 4 && ahead == 3)
            asm volatile("s_waitcnt vmcnt(%0)" :: "n"(3 * ISS) : "memory");
        else if (NBUF >= 3 && ahead == 2)
            asm volatile("s_waitcnt vmcnt(%0)" :: "n"(2 * ISS) : "memory");
        else if (ahead == 1)
            asm volatile("s_waitcnt vmcnt(%0)" :: "n"(ISS) : "memory");
        else if (ahead == 0)
            asm volatile("s_waitcnt vmcnt(0)" ::: "memory");
        __builtin_amdgcn_sched_barrier(0);
        __builtin_amdgcn_s_barrier();      // tile-t buffer visible to all waves

        const short* As = smem + (t % NBUF) * BUFS;
        const short* Ws = As + MT * BKT;
        bf16x8 a[MFR], b[4];
        #pragma unroll
        for (int mf = 0; mf < MFR; ++mf)
            a[mf] = *reinterpret_cast<const bf16x8*>(
                &As[(arow + mf * 16) * BKT + ((hi ^ szA) * 8)]);
        #pragma unroll
        for (int nf = 0; nf < 4; ++nf)
            b[nf] = *reinterpret_cast<const bf16x8*>(
                &Ws[(brow + nf * 16) * BKT + ((hi ^ szB) * 8)]);
        #pragma unroll
        for (int mf = 0; mf < MFR; ++mf)
            #pragma unroll
            for (int nf = 0; nf < 4; ++nf)
                acc[mf][nf] = __builtin_amdgcn_mfma_f32_16x16x32_bf16(
                    a[mf], b[nf], acc[mf][nf], 0, 0, 0);

        __builtin_amdgcn_s_barrier();      // reads retired before overwrite
    }

    if (OUT == 0 && NTST) {
        __syncthreads();
        // LDS-transposed epilogue: full-line NT dword stores.
        // Cs is [WRG*16][132] fp32; fits in NBUF*BUFS*2 bytes.
        float* Cs = (float*)smem;
        #pragma unroll
        for (int mf = 0; mf < MFR; ++mf) {
            __syncthreads();
            #pragma unroll
            for (int nf = 0; nf < 4; ++nf) {
                #pragma unroll
                for (int j = 0; j < 4; ++j)
                    Cs[(wr * 16 + hi * 4 + j) * 132 + wc * 64 + nf * 16 + (lane & 15)]
                        = acc[mf][nf][j];
            }
            __syncthreads();
            #pragma unroll
            for (int rr = 0; rr < 8; ++rr) {
                int lrow = wid * 8 + rr;          // 0..WRG*16-1
                int qq = lrow >> 4, rmr = lrow & 15;
                int grow = row0 + qq * (MT / WRG) + mf * 16 + rmr;
                #pragma unroll
                for (int hf = 0; hf < 2; ++hf) {
                    int cc = col0 + hf * 64 + lane;
                    if (cc < N)
                        __builtin_nontemporal_store(
                            Cs[lrow * 132 + hf * 64 + lane],
                            &C[(size_t)grow * ldc + cc]);
                }
            }
        }
    } else {
        #pragma unroll
        for (int mf = 0; mf < MFR; ++mf) {
            #pragma unroll
            for (int nf = 0; nf < 4; ++nf) {
                int r  = row0 + wr * (MT / WRG) + mf * 16 + hi * 4;
                int cc = col0 + wc * 64 + nf * 16 + (lane & 15);
                if (cc < N) {
                    f32x4 d = acc[mf][nf];
                    if (OUT == 3) {
                        if (cc < DI) {
                            float bv = bias[cc];
                            #pragma unroll
                            for (int j = 0; j < 4; ++j) {
                                float v = d[j] + bv;
                                v = (v > 20.f) ? v : log1pf(__expf(v));
                                Cbf[(size_t)(r + j) * ldc + cc] = (unsigned short)f2bf(v);
                            }
                        } else {
                            #pragma unroll
                            for (int j = 0; j < 4; ++j)
                                aux[(size_t)(r + j) * 32 + (cc - DI)] = d[j];
                        }
                    } else if (OUT == 2) {
                        #pragma unroll
                        for (int j = 0; j < 4; ++j)
                            Cbf[(size_t)(r + j) * ldc + cc] = (unsigned short)f2bf(d[j]);
                    } else {
                        #pragma unroll
                        for (int j = 0; j < 4; ++j)
                            C[(size_t)(r + j) * ldc + cc] = d[j];
                    }
                }
            }
        }
    }
}

// ---------------------------------------------------------------------------
// Depthwise causal conv(4) + bias + silu, vectorized: 8 channels/thread.
// ---------------------------------------------------------------------------
__global__ __launch_bounds__(256) void conv_silu_k(
    const unsigned short* __restrict__ xz, const float* __restrict__ cw,
    const float* __restrict__ cb, unsigned short* __restrict__ xinb)
{
    int i = blockIdx.x * 256 + threadIdx.x;   // over ROWS * DI/8
    if (i >= ROWS * (DI / 8)) return;
    int row = i / (DI / 8);
    int c = (i - row * (DI / 8)) * 8;
    int t = row & (SL - 1);
    int b = row >> 10;

    float4 wv[8];
    float accv[8];
    #pragma unroll
    for (int j = 0; j < 8; ++j) {
        wv[j] = *reinterpret_cast<const float4*>(&cw[(c + j) * DC]);
        accv[j] = cb[c + j];
    }
    const unsigned short* base = xz + ((size_t)(b * SL)) * (2 * DI) + c;
    #pragma unroll
    for (int k = 0; k < DC; ++k) {
        int tt = t + k - (DC - 1);
        if (tt >= 0) {
            bf16x8 v = *reinterpret_cast<const bf16x8*>(
                &base[(size_t)tt * (2 * DI)]);
            #pragma unroll
            for (int j = 0; j < 8; ++j)
                accv[j] += bf2f((unsigned short)v[j]) *
                           reinterpret_cast<const float*>(&wv[j])[k];
        }
    }
    bf16x8 o;
    #pragma unroll
    for (int j = 0; j < 8; ++j) {
        float v = accv[j] / (1.f + __expf(-accv[j]));
        o[j] = f2bf(v);
    }
    *reinterpret_cast<bf16x8*>(&xinb[(size_t)row * DI + c]) = o;
}

// ---------------------------------------------------------------------------
// Chunked selective scan, 2 kernels. CCH=32 chunks of CLEN=32.
// Batched loads: lane s loads step-s dt/xin/z once per 16-step batch (shfl
// broadcast); bc chunk staged in LDS (one float4 per thread, broadcast reads).
// dt, xin bf16; bc fp32: B = sbc[t*32 + s], C = sbc[t*32 + 16 + s].
// ---------------------------------------------------------------------------
__global__ __launch_bounds__(256) void scan_phase1(
    const unsigned short* __restrict__ dt,
    const float* __restrict__ bc,
    const unsigned short* __restrict__ xin,
    const float* __restrict__ Alog,
    float* __restrict__ hend,
    float* __restrict__ eprod)
{
    int blk = blockIdx.x;
    int c = blk % CCH;
    int tmp = blk / CCH;
    int dblk = tmp % (DI / 16);
    int b = tmp / (DI / 16);
    int lane = threadIdx.x & 63;
    int s = lane & 15;
    int g = lane & 0x30;                 // d-group base within wave
    int d = dblk * 16 + (threadIdx.x >> 4);
    const int rowbase = b * SL + c * CLEN;

    __shared__ float sbc[CLEN * 32];     // 4 KB: B/C for the whole chunk
    *reinterpret_cast<float4*>(&sbc[threadIdx.x * 4]) =
        *reinterpret_cast<const float4*>(&bc[(size_t)rowbase * 32 + threadIdx.x * 4]);
    float A = -__expf(Alog[d * DS + s]);
    __syncthreads();

    float h = 0.f, P = 1.f;
    #pragma unroll
    for (int half = 0; half < 2; ++half) {
        int rb = rowbase + half * 16;
        int rl = rb + s;                 // loader row for this lane
        float dtv_b = bf2f(dt[(size_t)rl * DI + d]);
        float xv_b  = bf2f(xin[(size_t)rl * DI + d]);
        #pragma unroll
        for (int t = 0; t < 16; ++t) {
            float dtv = __shfl(dtv_b, g | t, 64);
            float xv  = __shfl(xv_b,  g | t, 64);
            float Bv  = sbc[(half * 16 + t) * 32 + s];
            float e = __expf(dtv * A);
            h = h * e + dtv * xv * Bv;
            P *= e;
        }
    }
    size_t idx = ((size_t)(b * CCH + c) * DI + d) * DS + s;
    hend[idx]  = h;
    eprod[idx] = P;
}

__global__ __launch_bounds__(256) void scan_phase3(
    const unsigned short* __restrict__ dt,
    const float* __restrict__ bc,
    const unsigned short* __restrict__ xin,
    const unsigned short* __restrict__ xz,   // z = cols [DI:2*DI)
    const float* __restrict__ Alog,
    const float* __restrict__ Dp,
    const float* __restrict__ hend,
    const float* __restrict__ eprod,
    unsigned short* __restrict__ ybf)
{
    int blk = blockIdx.x;
    int c = blk % CCH;
    int tmp = blk / CCH;
    int dblk = tmp % (DI / 16);
    int b = tmp / (DI / 16);
    int lane = threadIdx.x & 63;
    int s = lane & 15;
    int g = lane & 0x30;
    int d = dblk * 16 + (threadIdx.x >> 4);
    const int rowbase = b * SL + c * CLEN;

    __shared__ float sbc[CLEN * 32];
    *reinterpret_cast<float4*>(&sbc[threadIdx.x * 4]) =
        *reinterpret_cast<const float4*>(&bc[(size_t)rowbase * 32 + threadIdx.x * 4]);
    float A = -__expf(Alog[d * DS + s]);
    float Dv = Dp[d];

    float h = 0.f;
    const size_t pbase = ((size_t)b * CCH * DI + d) * DS + s;
    for (int j = 0; j < c; ++j) {
        size_t idx = pbase + (size_t)j * (DI * DS);
        h = h * eprod[idx] + hend[idx];
    }
    __syncthreads();

    #pragma unroll
    for (int half = 0; half < 2; ++half) {
        int rb = rowbase + half * 16;
        int rl = rb + s;
        float dtv_b = bf2f(dt[(size_t)rl * DI + d]);
        float xv_b  = bf2f(xin[(size_t)rl * DI + d]);
        float zv_b  = bf2f(xz[(size_t)rl * (2 * DI) + DI + d]);
        #pragma unroll
        for (int t = 0; t < 16; ++t) {
            float dtv = __shfl(dtv_b, g | t, 64);
            float xv  = __shfl(xv_b,  g | t, 64);
            int r = rb + t;
            float Bv  = sbc[(half * 16 + t) * 32 + s];
            float Cv  = sbc[(half * 16 + t) * 32 + 16 + s];
            float e = __expf(dtv * A);
            h = h * e + dtv * xv * Bv;
            float p = h * Cv;
            p += __shfl_xor(p, 1, 64);
            p += __shfl_xor(p, 2, 64);
            p += __shfl_xor(p, 4, 64);
            p += __shfl_xor(p, 8, 64);
            float z = __shfl(zv_b, g | t, 64);
            if (s == 0) {
                float yv = (p + xv * Dv) * (z / (1.f + __expf(-z)));
                ybf[(size_t)r * DI + d] = (unsigned short)f2bf(yv);
            }
        }
    }
}

// ---------------------------------------------------------------------------
// LayerNorm over rows of 768, bf16 in, bf16 out
// ---------------------------------------------------------------------------
__global__ __launch_bounds__(256) void ln_k(
    const unsigned short* __restrict__ x, const float* __restrict__ w,
    const float* __restrict__ b, unsigned short* __restrict__ o)
{
    int row = blockIdx.x;
    int tid = threadIdx.x;
    const unsigned short* xr = x + (size_t)row * DM;
    float v0 = bf2f(xr[tid]), v1 = bf2f(xr[tid + 256]), v2 = bf2f(xr[tid + 512]);
    float s = v0 + v1 + v2;
    #pragma unroll
    for (int off = 1; off < 64; off <<= 1) s += __shfl_xor(s, off, 64);
    __shared__ float red[4];
    __shared__ float red2[4];
    int wid = tid >> 6, lane = tid & 63;
    if (lane == 0) red[wid] = s;
    __syncthreads();
    float mu = (red[0] + red[1] + red[2] + red[3]) * (1.f / 768.f);
    float d0 = v0 - mu, d1 = v1 - mu, d2 = v2 - mu;
    float q = d0 * d0 + d1 * d1 + d2 * d2;
    #pragma unroll
    for (int off = 1; off < 64; off <<= 1) q += __shfl_xor(q, off, 64);
    if (lane == 0) red2[wid] = q;
    __syncthreads();
    float var = (red2[0] + red2[1] + red2[2] + red2[3]) * (1.f / 768.f);
    float rs = rsqrtf(var + 1e-5f);
    o[(size_t)row * DM + tid]       = (unsigned short)f2bf(d0 * rs * w[tid]       + b[tid]);
    o[(size_t)row * DM + tid + 256] = (unsigned short)f2bf(d1 * rs * w[tid + 256] + b[tid + 256]);
    o[(size_t)row * DM + tid + 512] = (unsigned short)f2bf(d2 * rs * w[tid + 512] + b[tid + 512]);
}

// ---------------------------------------------------------------------------
extern "C" void kernel_launch(void* const* d_in, const int* in_sizes, int n_in,
                              void* d_out, int out_size, void* d_ws, size_t ws_size,
                              hipStream_t stream) {
    const int*   ids        = (const int*)d_in[0];
    const float* emb        = (const float*)d_in[1];
    const float* in_proj_w  = (const float*)d_in[2];
    const float* conv_w     = (const float*)d_in[3];
    const float* conv_b     = (const float*)d_in[4];
    const float* x_proj_w   = (const float*)d_in[5];
    const float* dt_proj_w  = (const float*)d_in[6];
    const float* dt_proj_b  = (const float*)d_in[7];
    const float* A_log      = (const float*)d_in[8];
    const float* D_param    = (const float*)d_in[9];
    const float* out_proj_w = (const float*)d_in[10];
    const float* norm_w     = (const float*)d_in[11];
    const float* norm_b     = (const float*)d_in[12];
    float* out = (float*)d_out;

    // ---- workspace layout ----
    char* base = (char*)d_ws;
    size_t off = 0;
    auto alloc_f = [&](size_t n) { float* p = (float*)(base + off); off += n * 4; return p; };
    auto alloc_u = [&](size_t n) { unsigned short* p = (unsigned short*)(base + off); off += n * 2; return p; };

    float* bc    = alloc_f((size_t)ROWS * 32);
    float* hend  = alloc_f((size_t)NB * CCH * DI * DS);
    float* eprod = alloc_f((size_t)NB * CCH * DI * DS);
    unsigned short* xbf   = alloc_u((size_t)ROWS * DM);
    unsigned short* xzb   = alloc_u((size_t)ROWS * 2 * DI);
    unsigned short* xinb  = alloc_u((size_t)ROWS * DI);
    unsigned short* dtbf  = alloc_u((size_t)ROWS * DI);
    unsigned short* ybf   = alloc_u((size_t)ROWS * DI);
    unsigned short* xlnbf = alloc_u((size_t)ROWS * DM);
    unsigned short* inw_bf = alloc_u((size_t)NLAYER * 2 * DI * DM);
    unsigned short* ow_bf  = alloc_u((size_t)NLAYER * DM * DI);
    unsigned short* wbig  = alloc_u((size_t)NLAYER * NBIG * DI);
    unsigned short* emb_bf = alloc_u((size_t)VOCAB * DM);
    (void)ws_size;

    // ---- weight preconversion (once per call, single cvt dispatch) ----
    {
        int n4a = NLAYER * 2 * DI * DM / 4;
        int n4b = NLAYER * DM * DI / 4;
        int n4e = VOCAB * DM / 4;
        int n4t = n4a + n4b + n4e;
        cvt3_k<<<(n4t + 255) / 256, 256, 0, stream>>>(
            in_proj_w, inw_bf, n4a, out_proj_w, ow_bf, n4b, emb, emb_bf, n4e);
        wc_k<<<dim3(12, 13, NLAYER), 256, 0, stream>>>(dt_proj_w, x_proj_w, wbig);
    }

    embed_k<<<(ROWS * (DM / 4) + 255) / 256, 256, 0, stream>>>(ids, emb, xbf);

    const int scan_grid = NB * (DI / 16) * CCH;      // 6144 blocks

    for (int i = 0; i < NLAYER; ++i) {
        const float* cw  = conv_w  + (size_t)i * DI * DC;
        const float* cb  = conv_b  + (size_t)i * DI;
        const float* dtb = dt_proj_b + (size_t)i * DI;
        const float* Al  = A_log   + (size_t)i * DI * DS;
        const float* Dpar= D_param + (size_t)i * DI;

        // in_proj: xzb(bf16) = xbf @ inw^T  (64-tile, 4-deep, 768 blocks)
        const unsigned short* inw = inw_bf + (size_t)i * 2 * DI * DM;
        gemm_bf16<256, 64, 4, 2, false><<<24 * 32, 256, 0, stream>>>(
            xbf, DM, inw, DM, nullptr, xzb, 2 * DI, 32, 2 * DI, DM, nullptr, nullptr);

        conv_silu_k<<<(ROWS * (DI / 8)) / 256, 256, 0, stream>>>(xzb, cw, cb, xinb);

        // fused dt(bf16,softplus) + B/C(fp32): xinb @ wbig[i]^T  (N=1568, 4-deep)
        const unsigned short* wb = wbig + (size_t)i * NBIG * DI;
        gemm_bf16<256, 64, 4, 3, false><<<13 * 32, 256, 0, stream>>>(
            xinb, DI, wb, DI, nullptr, dtbf, DI, 32, NBIG, DI, dtb, bc);

        scan_phase1<<<scan_grid, 256, 0, stream>>>(dtbf, bc, xinb, Al, hend, eprod);
        scan_phase3<<<scan_grid, 256, 0, stream>>>(dtbf, bc, xinb, xzb, Al, Dpar,
                                                   hend, eprod, ybf);

        // out_proj: xbf(bf16) = ybf @ ow^T  (32-tile, 4-deep, 384 blocks)
        const unsigned short* ow = ow_bf + (size_t)i * DM * DI;
        gemm_bf16<256, 32, 4, 2, false><<<64 * 6, 256, 0, stream>>>(
            ybf, DI, ow, DI, nullptr, xbf, DM, 64, DM, DI, nullptr, nullptr);
    }

    ln_k<<<ROWS, 256, 0, stream>>>(xbf, norm_w, norm_b, xlnbf);
    // logits: out = xlnbf @ emb^T  (512 threads, 256x128 tile, 2-deep, NT epi)
    gemm_bf16<512, 256, 2, 0, true><<<393 * 8, 512, 0, stream>>>(
        xlnbf, DM, emb_bf, DM, out, nullptr, VOCAB, 8, VOCAB, DM, nullptr, nullptr);
}

// Round 15
// 2769.518 us; speedup vs baseline: 6.1376x; 1.0008x over previous
//
#include <hip/hip_runtime.h>
#include <hip/hip_bf16.h>

#define DI 1536
#define DS 16
#define DC 4
#define DTR 48
#define NB 2
#define SL 1024
#define DM 768
#define NLAYER 12
#define VOCAB 50257
#define ROWS (NB*SL)   // 2048
#define CCH 32         // scan chunks
#define CLEN (SL/CCH)  // 32
#define NBIG (DI+32)   // 1568: fused dt(1536) + B/C(32) outputs

typedef __attribute__((ext_vector_type(8))) short bf16x8;
typedef __attribute__((ext_vector_type(4))) short short4v;
typedef __attribute__((ext_vector_type(4))) float f32x4;

__device__ inline short f2bf(float f) {
    unsigned u = __builtin_bit_cast(unsigned, f);
    unsigned r = (u + 0x7fffu + ((u >> 16) & 1u)) >> 16;
    return (short)r;
}
__device__ inline float bf2f(unsigned short u) {
    unsigned x = ((unsigned)u) << 16;
    return __builtin_bit_cast(float, x);
}

__device__ __forceinline__ void gl_lds16(const void* g, void* l) {
    __builtin_amdgcn_global_load_lds(
        (const __attribute__((address_space(1))) unsigned int*)g,
        (__attribute__((address_space(3))) unsigned int*)l, 16, 0, 0);
}

// ---------------------------------------------------------------------------
// fp32 -> bf16 convert for 3 arrays in one dispatch (each n multiple of 4)
// ---------------------------------------------------------------------------
__global__ __launch_bounds__(256) void cvt3_k(
    const float* __restrict__ s0, unsigned short* __restrict__ d0, int n40,
    const float* __restrict__ s1, unsigned short* __restrict__ d1, int n41,
    const float* __restrict__ s2, unsigned short* __restrict__ d2, int n42)
{
    int i = blockIdx.x * 256 + threadIdx.x;
    const float* src; unsigned short* dst;
    if (i < n40) { src = s0; dst = d0; }
    else if (i < n40 + n41) { i -= n40; src = s1; dst = d1; }
    else if (i < n40 + n41 + n42) { i -= n40 + n41; src = s2; dst = d2; }
    else return;
    float4 v = *reinterpret_cast<const float4*>(src + (size_t)i * 4);
    short4v o;
    o[0] = f2bf(v.x); o[1] = f2bf(v.y); o[2] = f2bf(v.z); o[3] = f2bf(v.w);
    *reinterpret_cast<short4v*>(dst + (size_t)i * 4) = o;
}

// ---------------------------------------------------------------------------
// Wc precompute: wbig[l] rows 0..1535 = dtw @ xpw[:48]  (bf16),
//                rows 1536..1567 = xpw[48:80] (bf16).
// ---------------------------------------------------------------------------
__global__ __launch_bounds__(256) void wc_k(
    const float* __restrict__ dtw_all,   // (NL, DI, DTR)
    const float* __restrict__ xpw_all,   // (NL, 80, DI)
    unsigned short* __restrict__ wbig)   // (NL, NBIG, DI)
{
    int l = blockIdx.z;
    const float* dtw = dtw_all + (size_t)l * DI * DTR;
    const float* xpw = xpw_all + (size_t)l * 80 * DI;
    unsigned short* wb = wbig + (size_t)l * NBIG * DI;
    int tid = threadIdx.x;
    if (blockIdx.y == 12) {
        if (blockIdx.x == 0) {
            for (int idx = tid; idx < 32 * DI; idx += 256) {
                int rr = idx / DI, k = idx - rr * DI;
                wb[(size_t)(DI + rr) * DI + k] =
                    (unsigned short)f2bf(xpw[(size_t)(48 + rr) * DI + k]);
            }
        }
        return;
    }
    __shared__ float sd[128 * 48];
    __shared__ float sx[48 * 128];
    int d0 = blockIdx.y * 128, k0 = blockIdx.x * 128;
    for (int idx = tid; idx < 128 * 48; idx += 256) {
        int r = idx / 48, j = idx - r * 48;
        sd[idx] = dtw[(size_t)(d0 + r) * DTR + j];
    }
    for (int idx = tid; idx < 48 * 128; idx += 256) {
        int j = idx / 128, k = idx - j * 128;
        sx[idx] = xpw[(size_t)j * DI + k0 + k];
    }
    __syncthreads();
    int tx = tid & 15, ty = tid >> 4;
    float acc[8][8] = {};
    for (int j = 0; j < 48; ++j) {
        float a[8], w[8];
        #pragma unroll
        for (int i = 0; i < 8; ++i) a[i] = sd[(ty * 8 + i) * 48 + j];
        #pragma unroll
        for (int i = 0; i < 8; ++i) w[i] = sx[j * 128 + tx * 8 + i];
        #pragma unroll
        for (int i = 0; i < 8; ++i)
            #pragma unroll
            for (int jj = 0; jj < 8; ++jj)
                acc[i][jj] += a[i] * w[jj];
    }
    for (int i = 0; i < 8; ++i)
        for (int jj = 0; jj < 8; ++jj)
            wb[(size_t)(d0 + ty * 8 + i) * DI + k0 + tx * 8 + jj] =
                (unsigned short)f2bf(acc[i][jj]);
}

// ---------------------------------------------------------------------------
// Embedding (vectorized x4)
// ---------------------------------------------------------------------------
__global__ __launch_bounds__(256) void embed_k(const int* __restrict__ ids,
                                               const float* __restrict__ emb,
                                               unsigned short* __restrict__ xbf) {
    int i = blockIdx.x * 256 + threadIdx.x;      // over ROWS * DM/4
    if (i >= ROWS * (DM / 4)) return;
    int row = i / (DM / 4);
    int c4 = (i - row * (DM / 4)) * 4;
    float4 v = *reinterpret_cast<const float4*>(
        &emb[(size_t)ids[row] * DM + c4]);
    const float s = 27.712812921102035f;
    short4v o;
    o[0] = f2bf(v.x * s); o[1] = f2bf(v.y * s);
    o[2] = f2bf(v.z * s); o[3] = f2bf(v.w * s);
    *reinterpret_cast<short4v*>(&xbf[(size_t)row * DM + c4]) = o;
}

// ---------------------------------------------------------------------------
// bf16-MFMA GEMM, single-barrier pipeline with COUNTED vmcnt (T3/T4).
// PF = prefetch distance (tiles ahead); REQUIRES NBUF >= PF+2 so the slot
// being staged (tile t+PF -> slot (t+PF)%NBUF) was last read at iter t-2,
// whose ds_reads are ordered before this staging by the barrier at iter t-1.
// -> only ONE s_barrier per k-tile (after the counted vmcnt).
// BS=256 threads (4 waves 2x2), MT x 128 tile, BKT=32.
// global_load_lds staging, linear LDS dest, pre-swizzled source
// (involution chunk ^ ((row>>1)&3), conflict-free ds_read_b128).
// OUT: 0 = fp32 store (NTST -> LDS-transposed full-line NT epilogue);
//      2 = bf16-only store; 3 = fused dt softplus (bf16) / BC (fp32) split.
// ---------------------------------------------------------------------------
template<int BS, int MT, int NBUF, int PF, int OUT, bool NTST>
__global__ __launch_bounds__(BS) void gemm_bf16(
    const unsigned short* __restrict__ A, int lda,
    const unsigned short* __restrict__ W, int ldw,
    float* __restrict__ C, unsigned short* __restrict__ Cbf, int ldc,
    int GY, int N, int K,
    const float* __restrict__ bias, float* __restrict__ aux)
{
    static_assert(NBUF >= PF + 2, "WAR safety needs NBUF >= PF+2");
    constexpr int BKT = 32;
    constexpr int CPR = BKT / 8;                  // 4 chunks per row
    constexpr int WRG = (BS / 64) / 2;            // wr groups (2)
    constexpr int ACH = MT * CPR;                 // A chunks per tile
    constexpr int ACA = (ACH >= BS) ? ACH / BS : 1;
    constexpr int ACW = (128 * CPR) / BS;         // W staging issues/thread
    constexpr int ISS = ACA + ACW;                // gl_lds instrs per STAGE
    constexpr int MFR = MT / (16 * WRG);          // M fragments per wave
    constexpr int BUFS = (MT + 128) * BKT;        // shorts per buffer
    __shared__ __align__(16) short smem[NBUF * BUFS];

    const int tid  = threadIdx.x;
    const int lane = tid & 63;
    const int wid  = tid >> 6;
    const int wr   = wid >> 1, wc = wid & 1;

    // bijective XCD-chunked swizzle, then col-major decode
    const int nwg = gridDim.x;
    const int q = nwg >> 3, rm = nwg & 7;
    const int xcd = blockIdx.x & 7, bidx = blockIdx.x >> 3;
    const int wg = (xcd < rm ? xcd * (q + 1) : rm * (q + 1) + (xcd - rm) * q) + bidx;
    const int row0 = (wg % GY) * MT;
    const int col0 = (wg / GY) * 128;

    // ---- staging setup (pre-swizzled global sources) ----
    const unsigned short* gA[ACA];
    const unsigned short* gW[ACW];
    #pragma unroll
    for (int i = 0; i < ACA; ++i) {
        int cid = (ACH >= BS) ? (i * BS + tid) : (tid & (ACH - 1));
        int r = cid >> 2, c = cid & 3;
        gA[i] = A + (size_t)(row0 + r) * lda + ((c ^ ((r >> 1) & 3)) * 8);
    }
    #pragma unroll
    for (int i = 0; i < ACW; ++i) {
        int cid = i * BS + tid;
        int r = cid >> 2, c = cid & 3;
        int rg = col0 + r; if (rg > N - 1) rg = N - 1;   // clamp: dup, store-guarded
        gW[i] = W + (size_t)rg * ldw + ((c ^ ((r >> 1) & 3)) * 8);
    }

    const int arow = wr * (MT / WRG) + (lane & 15);
    const int brow = wc * 64 + (lane & 15);
    const int szA = (arow >> 1) & 3;          // row+16 invariant
    const int szB = (brow >> 1) & 3;
    const int hi = lane >> 4;                 // 0..3 (= k-chunk for BKT=32)

    auto STAGE = [&](int buf) {
        short* As = smem + buf * BUFS;
        short* Ws = As + MT * BKT;
        #pragma unroll
        for (int i = 0; i < ACA; ++i) {
            int cbase = (ACH >= BS) ? (i * BS + wid * 64)
                                    : ((wid % (ACH / 64)) * 64);
            gl_lds16(gA[i], &As[cbase * 8]);
            gA[i] += BKT;
        }
        #pragma unroll
        for (int i = 0; i < ACW; ++i) {
            gl_lds16(gW[i], &Ws[(i * BS + wid * 64) * 8]);
            gW[i] += BKT;
        }
    };

    f32x4 acc[MFR][4] = {};

    const int ntiles = K / BKT;               // >= 24 at all call sites
    #pragma unroll
    for (int p = 0; p < PF; ++p) STAGE(p);

    for (int t = 0; t < ntiles; ++t) {
        if (t + PF < ntiles) STAGE((t + PF) % NBUF);   // deepest prefetch
        int ahead = ntiles - 1 - t;
        if (ahead > PF) ahead = PF;
        // counted waits: tile t landed, newer tiles stay in flight
        if (PF >= 2 && ahead == 2)
            asm volatile("s_waitcnt vmcnt(%0)" :: "n"(2 * ISS) : "memory");
        else if (ahead == 1)
            asm volatile("s_waitcnt vmcnt(%0)" :: "n"(ISS) : "memory");
        else if (ahead == 0)
            asm volatile("s_waitcnt vmcnt(0)" ::: "memory");
        __builtin_amdgcn_sched_barrier(0);
        __builtin_amdgcn_s_barrier();      // tile-t visible; also orders the
                                           // (t-2)-slot reads before staging

        const short* As = smem + (t % NBUF) * BUFS;
        const short* Ws = As + MT * BKT;
        bf16x8 a[MFR], b[4];
        #pragma unroll
        for (int mf = 0; mf < MFR; ++mf)
            a[mf] = *reinterpret_cast<const bf16x8*>(
                &As[(arow + mf * 16) * BKT + ((hi ^ szA) * 8)]);
        #pragma unroll
        for (int nf = 0; nf < 4; ++nf)
            b[nf] = *reinterpret_cast<const bf16x8*>(
                &Ws[(brow + nf * 16) * BKT + ((hi ^ szB) * 8)]);
        #pragma unroll
        for (int mf = 0; mf < MFR; ++mf)
            #pragma unroll
            for (int nf = 0; nf < 4; ++nf)
                acc[mf][nf] = __builtin_amdgcn_mfma_f32_16x16x32_bf16(
                    a[mf], b[nf], acc[mf][nf], 0, 0, 0);
        // no trailing barrier: WAR protected by NBUF >= PF+2 (see header)
    }

    if (OUT == 0 && NTST) {
        __syncthreads();
        // LDS-transposed epilogue: full-line NT dword stores.
        float* Cs = (float*)smem;    // [WRG*16][132] fp32
        #pragma unroll
        for (int mf = 0; mf < MFR; ++mf) {
            __syncthreads();
            #pragma unroll
            for (int nf = 0; nf < 4; ++nf) {
                #pragma unroll
                for (int j = 0; j < 4; ++j)
                    Cs[(wr * 16 + hi * 4 + j) * 132 + wc * 64 + nf * 16 + (lane & 15)]
                        = acc[mf][nf][j];
            }
            __syncthreads();
            #pragma unroll
            for (int rr = 0; rr < 32 / (BS / 64); ++rr) {
                int lrow = wid * (32 / (BS / 64)) + rr;   // 0..31
                int qq = lrow >> 4, rmr = lrow & 15;
                int grow = row0 + qq * (MT / WRG) + mf * 16 + rmr;
                #pragma unroll
                for (int hf = 0; hf < 2; ++hf) {
                    int cc = col0 + hf * 64 + lane;
                    if (cc < N)
                        __builtin_nontemporal_store(
                            Cs[lrow * 132 + hf * 64 + lane],
                            &C[(size_t)grow * ldc + cc]);
                }
            }
        }
    } else {
        #pragma unroll
        for (int mf = 0; mf < MFR; ++mf) {
            #pragma unroll
            for (int nf = 0; nf < 4; ++nf) {
                int r  = row0 + wr * (MT / WRG) + mf * 16 + hi * 4;
                int cc = col0 + wc * 64 + nf * 16 + (lane & 15);
                if (cc < N) {
                    f32x4 d = acc[mf][nf];
                    if (OUT == 3) {
                        if (cc < DI) {
                            float bv = bias[cc];
                            #pragma unroll
                            for (int j = 0; j < 4; ++j) {
                                float v = d[j] + bv;
                                v = (v > 20.f) ? v : log1pf(__expf(v));
                                Cbf[(size_t)(r + j) * ldc + cc] = (unsigned short)f2bf(v);
                            }
                        } else {
                            #pragma unroll
                            for (int j = 0; j < 4; ++j)
                                aux[(size_t)(r + j) * 32 + (cc - DI)] = d[j];
                        }
                    } else if (OUT == 2) {
                        #pragma unroll
                        for (int j = 0; j < 4; ++j)
                            Cbf[(size_t)(r + j) * ldc + cc] = (unsigned short)f2bf(d[j]);
                    } else {
                        #pragma unroll
                        for (int j = 0; j < 4; ++j)
                            C[(size_t)(r + j) * ldc + cc] = d[j];
                    }
                }
            }
        }
    }
}

// ---------------------------------------------------------------------------
// Depthwise causal conv(4) + bias + silu, vectorized: 8 channels/thread.
// ---------------------------------------------------------------------------
__global__ __launch_bounds__(256) void conv_silu_k(
    const unsigned short* __restrict__ xz, const float* __restrict__ cw,
    const float* __restrict__ cb, unsigned short* __restrict__ xinb)
{
    int i = blockIdx.x * 256 + threadIdx.x;   // over ROWS * DI/8
    if (i >= ROWS * (DI / 8)) return;
    int row = i / (DI / 8);
    int c = (i - row * (DI / 8)) * 8;
    int t = row & (SL - 1);
    int b = row >> 10;

    float4 wv[8];
    float accv[8];
    #pragma unroll
    for (int j = 0; j < 8; ++j) {
        wv[j] = *reinterpret_cast<const float4*>(&cw[(c + j) * DC]);
        accv[j] = cb[c + j];
    }
    const unsigned short* base = xz + ((size_t)(b * SL)) * (2 * DI) + c;
    #pragma unroll
    for (int k = 0; k < DC; ++k) {
        int tt = t + k - (DC - 1);
        if (tt >= 0) {
            bf16x8 v = *reinterpret_cast<const bf16x8*>(
                &base[(size_t)tt * (2 * DI)]);
            #pragma unroll
            for (int j = 0; j < 8; ++j)
                accv[j] += bf2f((unsigned short)v[j]) *
                           reinterpret_cast<const float*>(&wv[j])[k];
        }
    }
    bf16x8 o;
    #pragma unroll
    for (int j = 0; j < 8; ++j) {
        float v = accv[j] / (1.f + __expf(-accv[j]));
        o[j] = f2bf(v);
    }
    *reinterpret_cast<bf16x8*>(&xinb[(size_t)row * DI + c]) = o;
}

// ---------------------------------------------------------------------------
// Chunked selective scan, 2 kernels. CCH=32 chunks of CLEN=32.
// Batched loads: lane s loads step-s dt/xin/z once per 16-step batch (shfl
// broadcast); bc chunk staged in LDS (one float4 per thread, broadcast reads).
// ---------------------------------------------------------------------------
__global__ __launch_bounds__(256) void scan_phase1(
    const unsigned short* __restrict__ dt,
    const float* __restrict__ bc,
    const unsigned short* __restrict__ xin,
    const float* __restrict__ Alog,
    float* __restrict__ hend,
    float* __restrict__ eprod)
{
    int blk = blockIdx.x;
    int c = blk % CCH;
    int tmp = blk / CCH;
    int dblk = tmp % (DI / 16);
    int b = tmp / (DI / 16);
    int lane = threadIdx.x & 63;
    int s = lane & 15;
    int g = lane & 0x30;                 // d-group base within wave
    int d = dblk * 16 + (threadIdx.x >> 4);
    const int rowbase = b * SL + c * CLEN;

    __shared__ float sbc[CLEN * 32];     // 4 KB: B/C for the whole chunk
    *reinterpret_cast<float4*>(&sbc[threadIdx.x * 4]) =
        *reinterpret_cast<const float4*>(&bc[(size_t)rowbase * 32 + threadIdx.x * 4]);
    float A = -__expf(Alog[d * DS + s]);
    __syncthreads();

    float h = 0.f, P = 1.f;
    #pragma unroll
    for (int half = 0; half < 2; ++half) {
        int rb = rowbase + half * 16;
        int rl = rb + s;                 // loader row for this lane
        float dtv_b = bf2f(dt[(size_t)rl * DI + d]);
        float xv_b  = bf2f(xin[(size_t)rl * DI + d]);
        #pragma unroll
        for (int t = 0; t < 16; ++t) {
            float dtv = __shfl(dtv_b, g | t, 64);
            float xv  = __shfl(xv_b,  g | t, 64);
            float Bv  = sbc[(half * 16 + t) * 32 + s];
            float e = __expf(dtv * A);
            h = h * e + dtv * xv * Bv;
            P *= e;
        }
    }
    size_t idx = ((size_t)(b * CCH + c) * DI + d) * DS + s;
    hend[idx]  = h;
    eprod[idx] = P;
}

__global__ __launch_bounds__(256) void scan_phase3(
    const unsigned short* __restrict__ dt,
    const float* __restrict__ bc,
    const unsigned short* __restrict__ xin,
    const unsigned short* __restrict__ xz,   // z = cols [DI:2*DI)
    const float* __restrict__ Alog,
    const float* __restrict__ Dp,
    const float* __restrict__ hend,
    const float* __restrict__ eprod,
    unsigned short* __restrict__ ybf)
{
    int blk = blockIdx.x;
    int c = blk % CCH;
    int tmp = blk / CCH;
    int dblk = tmp % (DI / 16);
    int b = tmp / (DI / 16);
    int lane = threadIdx.x & 63;
    int s = lane & 15;
    int g = lane & 0x30;
    int d = dblk * 16 + (threadIdx.x >> 4);
    const int rowbase = b * SL + c * CLEN;

    __shared__ float sbc[CLEN * 32];
    *reinterpret_cast<float4*>(&sbc[threadIdx.x * 4]) =
        *reinterpret_cast<const float4*>(&bc[(size_t)rowbase * 32 + threadIdx.x * 4]);
    float A = -__expf(Alog[d * DS + s]);
    float Dv = Dp[d];

    float h = 0.f;
    const size_t pbase = ((size_t)b * CCH * DI + d) * DS + s;
    for (int j = 0; j < c; ++j) {
        size_t idx = pbase + (size_t)j * (DI * DS);
        h = h * eprod[idx] + hend[idx];
    }
    __syncthreads();

    #pragma unroll
    for (int half = 0; half < 2; ++half) {
        int rb = rowbase + half * 16;
        int rl = rb + s;
        float dtv_b = bf2f(dt[(size_t)rl * DI + d]);
        float xv_b  = bf2f(xin[(size_t)rl * DI + d]);
        float zv_b  = bf2f(xz[(size_t)rl * (2 * DI) + DI + d]);
        #pragma unroll
        for (int t = 0; t < 16; ++t) {
            float dtv = __shfl(dtv_b, g | t, 64);
            float xv  = __shfl(xv_b,  g | t, 64);
            int r = rb + t;
            float Bv  = sbc[(half * 16 + t) * 32 + s];
            float Cv  = sbc[(half * 16 + t) * 32 + 16 + s];
            float e = __expf(dtv * A);
            h = h * e + dtv * xv * Bv;
            float p = h * Cv;
            p += __shfl_xor(p, 1, 64);
            p += __shfl_xor(p, 2, 64);
            p += __shfl_xor(p, 4, 64);
            p += __shfl_xor(p, 8, 64);
            float z = __shfl(zv_b, g | t, 64);
            if (s == 0) {
                float yv = (p + xv * Dv) * (z / (1.f + __expf(-z)));
                ybf[(size_t)r * DI + d] = (unsigned short)f2bf(yv);
            }
        }
    }
}

// ---------------------------------------------------------------------------
// LayerNorm over rows of 768, bf16 in, bf16 out
// ---------------------------------------------------------------------------
__global__ __launch_bounds__(256) void ln_k(
    const unsigned short* __restrict__ x, const float* __restrict__ w,
    const float* __restrict__ b, unsigned short* __restrict__ o)
{
    int row = blockIdx.x;
    int tid = threadIdx.x;
    const unsigned short* xr = x + (size_t)row * DM;
    float v0 = bf2f(xr[tid]), v1 = bf2f(xr[tid + 256]), v2 = bf2f(xr[tid + 512]);
    float s = v0 + v1 + v2;
    #pragma unroll
    for (int off = 1; off < 64; off <<= 1) s += __shfl_xor(s, off, 64);
    __shared__ float red[4];
    __shared__ float red2[4];
    int wid = tid >> 6, lane = tid & 63;
    if (lane == 0) red[wid] = s;
    __syncthreads();
    float mu = (red[0] + red[1] + red[2] + red[3]) * (1.f / 768.f);
    float d0 = v0 - mu, d1 = v1 - mu, d2 = v2 - mu;
    float q = d0 * d0 + d1 * d1 + d2 * d2;
    #pragma unroll
    for (int off = 1; off < 64; off <<= 1) q += __shfl_xor(q, off, 64);
    if (lane == 0) red2[wid] = q;
    __syncthreads();
    float var = (red2[0] + red2[1] + red2[2] + red2[3]) * (1.f / 768.f);
    float rs = rsqrtf(var + 1e-5f);
    o[(size_t)row * DM + tid]       = (unsigned short)f2bf(d0 * rs * w[tid]       + b[tid]);
    o[(size_t)row * DM + tid + 256] = (unsigned short)f2bf(d1 * rs * w[tid + 256] + b[tid + 256]);
    o[(size_t)row * DM + tid + 512] = (unsigned short)f2bf(d2 * rs * w[tid + 512] + b[tid + 512]);
}

// ---------------------------------------------------------------------------
extern "C" void kernel_launch(void* const* d_in, const int* in_sizes, int n_in,
                              void* d_out, int out_size, void* d_ws, size_t ws_size,
                              hipStream_t stream) {
    const int*   ids        = (const int*)d_in[0];
    const float* emb        = (const float*)d_in[1];
    const float* in_proj_w  = (const float*)d_in[2];
    const float* conv_w     = (const float*)d_in[3];
    const float* conv_b     = (const float*)d_in[4];
    const float* x_proj_w   = (const float*)d_in[5];
    const float* dt_proj_w  = (const float*)d_in[6];
    const float* dt_proj_b  = (const float*)d_in[7];
    const float* A_log      = (const float*)d_in[8];
    const float* D_param    = (const float*)d_in[9];
    const float* out_proj_w = (const float*)d_in[10];
    const float* norm_w     = (const float*)d_in[11];
    const float* norm_b     = (const float*)d_in[12];
    float* out = (float*)d_out;

    // ---- workspace layout ----
    char* base = (char*)d_ws;
    size_t off = 0;
    auto alloc_f = [&](size_t n) { float* p = (float*)(base + off); off += n * 4; return p; };
    auto alloc_u = [&](size_t n) { unsigned short* p = (unsigned short*)(base + off); off += n * 2; return p; };

    float* bc    = alloc_f((size_t)ROWS * 32);
    float* hend  = alloc_f((size_t)NB * CCH * DI * DS);
    float* eprod = alloc_f((size_t)NB * CCH * DI * DS);
    unsigned short* xbf   = alloc_u((size_t)ROWS * DM);
    unsigned short* xzb   = alloc_u((size_t)ROWS * 2 * DI);
    unsigned short* xinb  = alloc_u((size_t)ROWS * DI);
    unsigned short* dtbf  = alloc_u((size_t)ROWS * DI);
    unsigned short* ybf   = alloc_u((size_t)ROWS * DI);
    unsigned short* xlnbf = alloc_u((size_t)ROWS * DM);
    unsigned short* inw_bf = alloc_u((size_t)NLAYER * 2 * DI * DM);
    unsigned short* ow_bf  = alloc_u((size_t)NLAYER * DM * DI);
    unsigned short* wbig  = alloc_u((size_t)NLAYER * NBIG * DI);
    unsigned short* emb_bf = alloc_u((size_t)VOCAB * DM);
    (void)ws_size;

    // ---- weight preconversion (once per call, single cvt dispatch) ----
    {
        int n4a = NLAYER * 2 * DI * DM / 4;
        int n4b = NLAYER * DM * DI / 4;
        int n4e = VOCAB * DM / 4;
        int n4t = n4a + n4b + n4e;
        cvt3_k<<<(n4t + 255) / 256, 256, 0, stream>>>(
            in_proj_w, inw_bf, n4a, out_proj_w, ow_bf, n4b, emb, emb_bf, n4e);
        wc_k<<<dim3(12, 13, NLAYER), 256, 0, stream>>>(dt_proj_w, x_proj_w, wbig);
    }

    embed_k<<<(ROWS * (DM / 4) + 255) / 256, 256, 0, stream>>>(ids, emb, xbf);

    const int scan_grid = NB * (DI / 16) * CCH;      // 6144 blocks

    for (int i = 0; i < NLAYER; ++i) {
        const float* cw  = conv_w  + (size_t)i * DI * DC;
        const float* cb  = conv_b  + (size_t)i * DI;
        const float* dtb = dt_proj_b + (size_t)i * DI;
        const float* Al  = A_log   + (size_t)i * DI * DS;
        const float* Dpar= D_param + (size_t)i * DI;

        // in_proj: xzb(bf16) = xbf @ inw^T  (64-tile, NBUF4/PF2, 768 blocks)
        const unsigned short* inw = inw_bf + (size_t)i * 2 * DI * DM;
        gemm_bf16<256, 64, 4, 2, 2, false><<<24 * 32, 256, 0, stream>>>(
            xbf, DM, inw, DM, nullptr, xzb, 2 * DI, 32, 2 * DI, DM, nullptr, nullptr);

        conv_silu_k<<<(ROWS * (DI / 8)) / 256, 256, 0, stream>>>(xzb, cw, cb, xinb);

        // fused dt(bf16,softplus) + B/C(fp32): xinb @ wbig[i]^T  (N=1568)
        const unsigned short* wb = wbig + (size_t)i * NBIG * DI;
        gemm_bf16<256, 64, 4, 2, 3, false><<<13 * 32, 256, 0, stream>>>(
            xinb, DI, wb, DI, nullptr, dtbf, DI, 32, NBIG, DI, dtb, bc);

        scan_phase1<<<scan_grid, 256, 0, stream>>>(dtbf, bc, xinb, Al, hend, eprod);
        scan_phase3<<<scan_grid, 256, 0, stream>>>(dtbf, bc, xinb, xzb, Al, Dpar,
                                                   hend, eprod, ybf);

        // out_proj: xbf(bf16) = ybf @ ow^T  (32-tile, NBUF4/PF2, 384 blocks)
        const unsigned short* ow = ow_bf + (size_t)i * DM * DI;
        gemm_bf16<256, 32, 4, 2, 2, false><<<64 * 6, 256, 0, stream>>>(
            ybf, DI, ow, DI, nullptr, xbf, DM, 64, DM, DI, nullptr, nullptr);
    }

    ln_k<<<ROWS, 256, 0, stream>>>(xbf, norm_w, norm_b, xlnbf);
    // logits: out = xlnbf @ emb^T  (128-tile, NBUF3/PF1 single-barrier, NT epi)
    gemm_bf16<256, 128, 3, 1, 0, true><<<393 * 16, 256, 0, stream>>>(
        xlnbf, DM, emb_bf, DM, out, nullptr, VOCAB, 16, VOCAB, DM, nullptr, nullptr);
}

// Round 16
// 2754.162 us; speedup vs baseline: 6.1718x; 1.0056x over previous
//
#include <hip/hip_runtime.h>
#include <hip/hip_bf16.h>

#define DI 1536
#define DS 16
#define DC 4
#define DTR 48
#define NB 2
#define SL 1024
#define DM 768
#define NLAYER 12
#define VOCAB 50257
#define ROWS (NB*SL)   // 2048
#define CCH 32         // scan chunks
#define CLEN (SL/CCH)  // 32
#define NBIG (DI+32)   // 1568: fused dt(1536) + B/C(32) outputs

typedef __attribute__((ext_vector_type(8))) short bf16x8;
typedef __attribute__((ext_vector_type(4))) short short4v;
typedef __attribute__((ext_vector_type(4))) float f32x4;

__device__ inline short f2bf(float f) {
    unsigned u = __builtin_bit_cast(unsigned, f);
    unsigned r = (u + 0x7fffu + ((u >> 16) & 1u)) >> 16;
    return (short)r;
}
__device__ inline float bf2f(unsigned short u) {
    unsigned x = ((unsigned)u) << 16;
    return __builtin_bit_cast(float, x);
}

__device__ __forceinline__ void gl_lds16(const void* g, void* l) {
    __builtin_amdgcn_global_load_lds(
        (const __attribute__((address_space(1))) unsigned int*)g,
        (__attribute__((address_space(3))) unsigned int*)l, 16, 0, 0);
}

// ---------------------------------------------------------------------------
// fp32 -> bf16 convert for 3 arrays in one dispatch (each n multiple of 4)
// ---------------------------------------------------------------------------
__global__ __launch_bounds__(256) void cvt3_k(
    const float* __restrict__ s0, unsigned short* __restrict__ d0, int n40,
    const float* __restrict__ s1, unsigned short* __restrict__ d1, int n41,
    const float* __restrict__ s2, unsigned short* __restrict__ d2, int n42)
{
    int i = blockIdx.x * 256 + threadIdx.x;
    const float* src; unsigned short* dst;
    if (i < n40) { src = s0; dst = d0; }
    else if (i < n40 + n41) { i -= n40; src = s1; dst = d1; }
    else if (i < n40 + n41 + n42) { i -= n40 + n41; src = s2; dst = d2; }
    else return;
    float4 v = *reinterpret_cast<const float4*>(src + (size_t)i * 4);
    short4v o;
    o[0] = f2bf(v.x); o[1] = f2bf(v.y); o[2] = f2bf(v.z); o[3] = f2bf(v.w);
    *reinterpret_cast<short4v*>(dst + (size_t)i * 4) = o;
}

// ---------------------------------------------------------------------------
// Wc precompute: wbig[l] rows 0..1535 = dtw @ xpw[:48]  (bf16),
//                rows 1536..1567 = xpw[48:80] (bf16).
// ---------------------------------------------------------------------------
__global__ __launch_bounds__(256) void wc_k(
    const float* __restrict__ dtw_all,   // (NL, DI, DTR)
    const float* __restrict__ xpw_all,   // (NL, 80, DI)
    unsigned short* __restrict__ wbig)   // (NL, NBIG, DI)
{
    int l = blockIdx.z;
    const float* dtw = dtw_all + (size_t)l * DI * DTR;
    const float* xpw = xpw_all + (size_t)l * 80 * DI;
    unsigned short* wb = wbig + (size_t)l * NBIG * DI;
    int tid = threadIdx.x;
    if (blockIdx.y == 12) {
        if (blockIdx.x == 0) {
            for (int idx = tid; idx < 32 * DI; idx += 256) {
                int rr = idx / DI, k = idx - rr * DI;
                wb[(size_t)(DI + rr) * DI + k] =
                    (unsigned short)f2bf(xpw[(size_t)(48 + rr) * DI + k]);
            }
        }
        return;
    }
    __shared__ float sd[128 * 48];
    __shared__ float sx[48 * 128];
    int d0 = blockIdx.y * 128, k0 = blockIdx.x * 128;
    for (int idx = tid; idx < 128 * 48; idx += 256) {
        int r = idx / 48, j = idx - r * 48;
        sd[idx] = dtw[(size_t)(d0 + r) * DTR + j];
    }
    for (int idx = tid; idx < 48 * 128; idx += 256) {
        int j = idx / 128, k = idx - j * 128;
        sx[idx] = xpw[(size_t)j * DI + k0 + k];
    }
    __syncthreads();
    int tx = tid & 15, ty = tid >> 4;
    float acc[8][8] = {};
    for (int j = 0; j < 48; ++j) {
        float a[8], w[8];
        #pragma unroll
        for (int i = 0; i < 8; ++i) a[i] = sd[(ty * 8 + i) * 48 + j];
        #pragma unroll
        for (int i = 0; i < 8; ++i) w[i] = sx[j * 128 + tx * 8 + i];
        #pragma unroll
        for (int i = 0; i < 8; ++i)
            #pragma unroll
            for (int jj = 0; jj < 8; ++jj)
                acc[i][jj] += a[i] * w[jj];
    }
    for (int i = 0; i < 8; ++i)
        for (int jj = 0; jj < 8; ++jj)
            wb[(size_t)(d0 + ty * 8 + i) * DI + k0 + tx * 8 + jj] =
                (unsigned short)f2bf(acc[i][jj]);
}

// ---------------------------------------------------------------------------
// Embedding (vectorized x4)
// ---------------------------------------------------------------------------
__global__ __launch_bounds__(256) void embed_k(const int* __restrict__ ids,
                                               const float* __restrict__ emb,
                                               unsigned short* __restrict__ xbf) {
    int i = blockIdx.x * 256 + threadIdx.x;      // over ROWS * DM/4
    if (i >= ROWS * (DM / 4)) return;
    int row = i / (DM / 4);
    int c4 = (i - row * (DM / 4)) * 4;
    float4 v = *reinterpret_cast<const float4*>(
        &emb[(size_t)ids[row] * DM + c4]);
    const float s = 27.712812921102035f;
    short4v o;
    o[0] = f2bf(v.x * s); o[1] = f2bf(v.y * s);
    o[2] = f2bf(v.z * s); o[3] = f2bf(v.w * s);
    *reinterpret_cast<short4v*>(&xbf[(size_t)row * DM + c4]) = o;
}

// ---------------------------------------------------------------------------
// bf16-MFMA GEMM with COUNTED vmcnt (T3/T4). Two schedule variants:
//   SB=false (dual-barrier): NBUF >= PF+1. Trailing s_barrier WAR-guards the
//            slot re-staged next iter. (Best measured for logits: NBUF2/PF1.)
//   SB=true  (single-barrier): NBUF >= PF+2 so the slot staged at iter t was
//            last read at iter t-2; the iter t-1 top barrier orders it.
//            (Best measured for small layer GEMMs: NBUF4/PF2.)
// BS=256 threads (4 waves 2x2), MT x 128 tile, BKT=32.
// global_load_lds staging, linear LDS dest, pre-swizzled source
// (involution chunk ^ ((row>>1)&3), conflict-free ds_read_b128).
// OUT: 0 = fp32 store (NTST -> LDS-transposed full-line NT epilogue);
//      2 = bf16-only store; 3 = fused dt softplus (bf16) / BC (fp32) split.
// ---------------------------------------------------------------------------
template<int BS, int MT, int NBUF, int PF, bool SB, int OUT, bool NTST>
__global__ __launch_bounds__(BS) void gemm_bf16(
    const unsigned short* __restrict__ A, int lda,
    const unsigned short* __restrict__ W, int ldw,
    float* __restrict__ C, unsigned short* __restrict__ Cbf, int ldc,
    int GY, int N, int K,
    const float* __restrict__ bias, float* __restrict__ aux)
{
    static_assert(SB ? (NBUF >= PF + 2) : (NBUF >= PF + 1),
                  "WAR safety: SB needs NBUF>=PF+2, dual-barrier NBUF>=PF+1");
    constexpr int BKT = 32;
    constexpr int WRG = (BS / 64) / 2;            // wr groups (2)
    constexpr int ACH = MT * (BKT / 8);           // A chunks per tile
    constexpr int ACA = (ACH >= BS) ? ACH / BS : 1;
    constexpr int ACW = (128 * (BKT / 8)) / BS;   // W staging issues/thread
    constexpr int ISS = ACA + ACW;                // gl_lds instrs per STAGE
    constexpr int MFR = MT / (16 * WRG);          // M fragments per wave
    constexpr int BUFS = (MT + 128) * BKT;        // shorts per buffer
    __shared__ __align__(16) short smem[NBUF * BUFS];

    const int tid  = threadIdx.x;
    const int lane = tid & 63;
    const int wid  = tid >> 6;
    const int wr   = wid >> 1, wc = wid & 1;

    // bijective XCD-chunked swizzle, then col-major decode
    const int nwg = gridDim.x;
    const int q = nwg >> 3, rm = nwg & 7;
    const int xcd = blockIdx.x & 7, bidx = blockIdx.x >> 3;
    const int wg = (xcd < rm ? xcd * (q + 1) : rm * (q + 1) + (xcd - rm) * q) + bidx;
    const int row0 = (wg % GY) * MT;
    const int col0 = (wg / GY) * 128;

    // ---- staging setup (pre-swizzled global sources) ----
    const unsigned short* gA[ACA];
    const unsigned short* gW[ACW];
    #pragma unroll
    for (int i = 0; i < ACA; ++i) {
        int cid = (ACH >= BS) ? (i * BS + tid) : (tid & (ACH - 1));
        int r = cid >> 2, c = cid & 3;
        gA[i] = A + (size_t)(row0 + r) * lda + ((c ^ ((r >> 1) & 3)) * 8);
    }
    #pragma unroll
    for (int i = 0; i < ACW; ++i) {
        int cid = i * BS + tid;
        int r = cid >> 2, c = cid & 3;
        int rg = col0 + r; if (rg > N - 1) rg = N - 1;   // clamp: dup, store-guarded
        gW[i] = W + (size_t)rg * ldw + ((c ^ ((r >> 1) & 3)) * 8);
    }

    const int arow = wr * (MT / WRG) + (lane & 15);
    const int brow = wc * 64 + (lane & 15);
    const int szA = (arow >> 1) & 3;          // row+16 invariant
    const int szB = (brow >> 1) & 3;
    const int hi = lane >> 4;                 // 0..3 (= k-chunk for BKT=32)

    auto STAGE = [&](int buf) {
        short* As = smem + buf * BUFS;
        short* Ws = As + MT * BKT;
        #pragma unroll
        for (int i = 0; i < ACA; ++i) {
            int cbase = (ACH >= BS) ? (i * BS + wid * 64)
                                    : ((wid % (ACH / 64)) * 64);
            gl_lds16(gA[i], &As[cbase * 8]);
            gA[i] += BKT;
        }
        #pragma unroll
        for (int i = 0; i < ACW; ++i) {
            gl_lds16(gW[i], &Ws[(i * BS + wid * 64) * 8]);
            gW[i] += BKT;
        }
    };

    f32x4 acc[MFR][4] = {};

    const int ntiles = K / BKT;               // >= 24 at all call sites
    #pragma unroll
    for (int p = 0; p < PF; ++p) STAGE(p);

    for (int t = 0; t < ntiles; ++t) {
        if (t + PF < ntiles) STAGE((t + PF) % NBUF);   // deepest prefetch
        int ahead = ntiles - 1 - t;
        if (ahead > PF) ahead = PF;
        // counted waits: tile t landed, newer tiles stay in flight
        if (PF >= 2 && ahead == 2)
            asm volatile("s_waitcnt vmcnt(%0)" :: "n"(2 * ISS) : "memory");
        else if (ahead == 1)
            asm volatile("s_waitcnt vmcnt(%0)" :: "n"(ISS) : "memory");
        else if (ahead == 0)
            asm volatile("s_waitcnt vmcnt(0)" ::: "memory");
        __builtin_amdgcn_sched_barrier(0);
        __builtin_amdgcn_s_barrier();      // tile-t buffer visible to all waves

        const short* As = smem + (t % NBUF) * BUFS;
        const short* Ws = As + MT * BKT;
        bf16x8 a[MFR], b[4];
        #pragma unroll
        for (int mf = 0; mf < MFR; ++mf)
            a[mf] = *reinterpret_cast<const bf16x8*>(
                &As[(arow + mf * 16) * BKT + ((hi ^ szA) * 8)]);
        #pragma unroll
        for (int nf = 0; nf < 4; ++nf)
            b[nf] = *reinterpret_cast<const bf16x8*>(
                &Ws[(brow + nf * 16) * BKT + ((hi ^ szB) * 8)]);
        #pragma unroll
        for (int mf = 0; mf < MFR; ++mf)
            #pragma unroll
            for (int nf = 0; nf < 4; ++nf)
                acc[mf][nf] = __builtin_amdgcn_mfma_f32_16x16x32_bf16(
                    a[mf], b[nf], acc[mf][nf], 0, 0, 0);

        if (!SB) __builtin_amdgcn_s_barrier();   // WAR guard (dual-barrier)
        // SB=true: WAR protected by NBUF >= PF+2 + next iter's top barrier
    }

    if (OUT == 0 && NTST) {
        __syncthreads();
        // LDS-transposed epilogue: full-line NT dword stores.
        float* Cs = (float*)smem;    // [WRG*16][132] fp32
        #pragma unroll
        for (int mf = 0; mf < MFR; ++mf) {
            __syncthreads();
            #pragma unroll
            for (int nf = 0; nf < 4; ++nf) {
                #pragma unroll
                for (int j = 0; j < 4; ++j)
                    Cs[(wr * 16 + hi * 4 + j) * 132 + wc * 64 + nf * 16 + (lane & 15)]
                        = acc[mf][nf][j];
            }
            __syncthreads();
            #pragma unroll
            for (int rr = 0; rr < 32 / (BS / 64); ++rr) {
                int lrow = wid * (32 / (BS / 64)) + rr;   // 0..31
                int qq = lrow >> 4, rmr = lrow & 15;
                int grow = row0 + qq * (MT / WRG) + mf * 16 + rmr;
                #pragma unroll
                for (int hf = 0; hf < 2; ++hf) {
                    int cc = col0 + hf * 64 + lane;
                    if (cc < N)
                        __builtin_nontemporal_store(
                            Cs[lrow * 132 + hf * 64 + lane],
                            &C[(size_t)grow * ldc + cc]);
                }
            }
        }
    } else {
        #pragma unroll
        for (int mf = 0; mf < MFR; ++mf) {
            #pragma unroll
            for (int nf = 0; nf < 4; ++nf) {
                int r  = row0 + wr * (MT / WRG) + mf * 16 + hi * 4;
                int cc = col0 + wc * 64 + nf * 16 + (lane & 15);
                if (cc < N) {
                    f32x4 d = acc[mf][nf];
                    if (OUT == 3) {
                        if (cc < DI) {
                            float bv = bias[cc];
                            #pragma unroll
                            for (int j = 0; j < 4; ++j) {
                                float v = d[j] + bv;
                                v = (v > 20.f) ? v : log1pf(__expf(v));
                                Cbf[(size_t)(r + j) * ldc + cc] = (unsigned short)f2bf(v);
                            }
                        } else {
                            #pragma unroll
                            for (int j = 0; j < 4; ++j)
                                aux[(size_t)(r + j) * 32 + (cc - DI)] = d[j];
                        }
                    } else if (OUT == 2) {
                        #pragma unroll
                        for (int j = 0; j < 4; ++j)
                            Cbf[(size_t)(r + j) * ldc + cc] = (unsigned short)f2bf(d[j]);
                    } else {
                        #pragma unroll
                        for (int j = 0; j < 4; ++j)
                            C[(size_t)(r + j) * ldc + cc] = d[j];
                    }
                }
            }
        }
    }
}

// ---------------------------------------------------------------------------
// Depthwise causal conv(4) + bias + silu, vectorized: 8 channels/thread.
// ---------------------------------------------------------------------------
__global__ __launch_bounds__(256) void conv_silu_k(
    const unsigned short* __restrict__ xz, const float* __restrict__ cw,
    const float* __restrict__ cb, unsigned short* __restrict__ xinb)
{
    int i = blockIdx.x * 256 + threadIdx.x;   // over ROWS * DI/8
    if (i >= ROWS * (DI / 8)) return;
    int row = i / (DI / 8);
    int c = (i - row * (DI / 8)) * 8;
    int t = row & (SL - 1);
    int b = row >> 10;

    float4 wv[8];
    float accv[8];
    #pragma unroll
    for (int j = 0; j < 8; ++j) {
        wv[j] = *reinterpret_cast<const float4*>(&cw[(c + j) * DC]);
        accv[j] = cb[c + j];
    }
    const unsigned short* base = xz + ((size_t)(b * SL)) * (2 * DI) + c;
    #pragma unroll
    for (int k = 0; k < DC; ++k) {
        int tt = t + k - (DC - 1);
        if (tt >= 0) {
            bf16x8 v = *reinterpret_cast<const bf16x8*>(
                &base[(size_t)tt * (2 * DI)]);
            #pragma unroll
            for (int j = 0; j < 8; ++j)
                accv[j] += bf2f((unsigned short)v[j]) *
                           reinterpret_cast<const float*>(&wv[j])[k];
        }
    }
    bf16x8 o;
    #pragma unroll
    for (int j = 0; j < 8; ++j) {
        float v = accv[j] / (1.f + __expf(-accv[j]));
        o[j] = f2bf(v);
    }
    *reinterpret_cast<bf16x8*>(&xinb[(size_t)row * DI + c]) = o;
}

// ---------------------------------------------------------------------------
// Chunked selective scan, 2 kernels. CCH=32 chunks of CLEN=32.
// Batched loads: lane s loads step-s dt/xin/z once per 16-step batch (shfl
// broadcast); bc chunk staged in LDS (one float4 per thread, broadcast reads).
// ---------------------------------------------------------------------------
__global__ __launch_bounds__(256) void scan_phase1(
    const unsigned short* __restrict__ dt,
    const float* __restrict__ bc,
    const unsigned short* __restrict__ xin,
    const float* __restrict__ Alog,
    float* __restrict__ hend,
    float* __restrict__ eprod)
{
    int blk = blockIdx.x;
    int c = blk % CCH;
    int tmp = blk / CCH;
    int dblk = tmp % (DI / 16);
    int b = tmp / (DI / 16);
    int lane = threadIdx.x & 63;
    int s = lane & 15;
    int g = lane & 0x30;                 // d-group base within wave
    int d = dblk * 16 + (threadIdx.x >> 4);
    const int rowbase = b * SL + c * CLEN;

    __shared__ float sbc[CLEN * 32];     // 4 KB: B/C for the whole chunk
    *reinterpret_cast<float4*>(&sbc[threadIdx.x * 4]) =
        *reinterpret_cast<const float4*>(&bc[(size_t)rowbase * 32 + threadIdx.x * 4]);
    float A = -__expf(Alog[d * DS + s]);
    __syncthreads();

    float h = 0.f, P = 1.f;
    #pragma unroll
    for (int half = 0; half < 2; ++half) {
        int rb = rowbase + half * 16;
        int rl = rb + s;                 // loader row for this lane
        float dtv_b = bf2f(dt[(size_t)rl * DI + d]);
        float xv_b  = bf2f(xin[(size_t)rl * DI + d]);
        #pragma unroll
        for (int t = 0; t < 16; ++t) {
            float dtv = __shfl(dtv_b, g | t, 64);
            float xv  = __shfl(xv_b,  g | t, 64);
            float Bv  = sbc[(half * 16 + t) * 32 + s];
            float e = __expf(dtv * A);
            h = h * e + dtv * xv * Bv;
            P *= e;
        }
    }
    size_t idx = ((size_t)(b * CCH + c) * DI + d) * DS + s;
    hend[idx]  = h;
    eprod[idx] = P;
}

__global__ __launch_bounds__(256) void scan_phase3(
    const unsigned short* __restrict__ dt,
    const float* __restrict__ bc,
    const unsigned short* __restrict__ xin,
    const unsigned short* __restrict__ xz,   // z = cols [DI:2*DI)
    const float* __restrict__ Alog,
    const float* __restrict__ Dp,
    const float* __restrict__ hend,
    const float* __restrict__ eprod,
    unsigned short* __restrict__ ybf)
{
    int blk = blockIdx.x;
    int c = blk % CCH;
    int tmp = blk / CCH;
    int dblk = tmp % (DI / 16);
    int b = tmp / (DI / 16);
    int lane = threadIdx.x & 63;
    int s = lane & 15;
    int g = lane & 0x30;
    int d = dblk * 16 + (threadIdx.x >> 4);
    const int rowbase = b * SL + c * CLEN;

    __shared__ float sbc[CLEN * 32];
    *reinterpret_cast<float4*>(&sbc[threadIdx.x * 4]) =
        *reinterpret_cast<const float4*>(&bc[(size_t)rowbase * 32 + threadIdx.x * 4]);
    float A = -__expf(Alog[d * DS + s]);
    float Dv = Dp[d];

    float h = 0.f;
    const size_t pbase = ((size_t)b * CCH * DI + d) * DS + s;
    for (int j = 0; j < c; ++j) {
        size_t idx = pbase + (size_t)j * (DI * DS);
        h = h * eprod[idx] + hend[idx];
    }
    __syncthreads();

    #pragma unroll
    for (int half = 0; half < 2; ++half) {
        int rb = rowbase + half * 16;
        int rl = rb + s;
        float dtv_b = bf2f(dt[(size_t)rl * DI + d]);
        float xv_b  = bf2f(xin[(size_t)rl * DI + d]);
        float zv_b  = bf2f(xz[(size_t)rl * (2 * DI) + DI + d]);
        #pragma unroll
        for (int t = 0; t < 16; ++t) {
            float dtv = __shfl(dtv_b, g | t, 64);
            float xv  = __shfl(xv_b,  g | t, 64);
            int r = rb + t;
            float Bv  = sbc[(half * 16 + t) * 32 + s];
            float Cv  = sbc[(half * 16 + t) * 32 + 16 + s];
            float e = __expf(dtv * A);
            h = h * e + dtv * xv * Bv;
            float p = h * Cv;
            p += __shfl_xor(p, 1, 64);
            p += __shfl_xor(p, 2, 64);
            p += __shfl_xor(p, 4, 64);
            p += __shfl_xor(p, 8, 64);
            float z = __shfl(zv_b, g | t, 64);
            if (s == 0) {
                float yv = (p + xv * Dv) * (z / (1.f + __expf(-z)));
                ybf[(size_t)r * DI + d] = (unsigned short)f2bf(yv);
            }
        }
    }
}

// ---------------------------------------------------------------------------
// LayerNorm over rows of 768, bf16 in, bf16 out
// ---------------------------------------------------------------------------
__global__ __launch_bounds__(256) void ln_k(
    const unsigned short* __restrict__ x, const float* __restrict__ w,
    const float* __restrict__ b, unsigned short* __restrict__ o)
{
    int row = blockIdx.x;
    int tid = threadIdx.x;
    const unsigned short* xr = x + (size_t)row * DM;
    float v0 = bf2f(xr[tid]), v1 = bf2f(xr[tid + 256]), v2 = bf2f(xr[tid + 512]);
    float s = v0 + v1 + v2;
    #pragma unroll
    for (int off = 1; off < 64; off <<= 1) s += __shfl_xor(s, off, 64);
    __shared__ float red[4];
    __shared__ float red2[4];
    int wid = tid >> 6, lane = tid & 63;
    if (lane == 0) red[wid] = s;
    __syncthreads();
    float mu = (red[0] + red[1] + red[2] + red[3]) * (1.f / 768.f);
    float d0 = v0 - mu, d1 = v1 - mu, d2 = v2 - mu;
    float q = d0 * d0 + d1 * d1 + d2 * d2;
    #pragma unroll
    for (int off = 1; off < 64; off <<= 1) q += __shfl_xor(q, off, 64);
    if (lane == 0) red2[wid] = q;
    __syncthreads();
    float var = (red2[0] + red2[1] + red2[2] + red2[3]) * (1.f / 768.f);
    float rs = rsqrtf(var + 1e-5f);
    o[(size_t)row * DM + tid]       = (unsigned short)f2bf(d0 * rs * w[tid]       + b[tid]);
    o[(size_t)row * DM + tid + 256] = (unsigned short)f2bf(d1 * rs * w[tid + 256] + b[tid + 256]);
    o[(size_t)row * DM + tid + 512] = (unsigned short)f2bf(d2 * rs * w[tid + 512] + b[tid + 512]);
}

// ---------------------------------------------------------------------------
extern "C" void kernel_launch(void* const* d_in, const int* in_sizes, int n_in,
                              void* d_out, int out_size, void* d_ws, size_t ws_size,
                              hipStream_t stream) {
    const int*   ids        = (const int*)d_in[0];
    const float* emb        = (const float*)d_in[1];
    const float* in_proj_w  = (const float*)d_in[2];
    const float* conv_w     = (const float*)d_in[3];
    const float* conv_b     = (const float*)d_in[4];
    const float* x_proj_w   = (const float*)d_in[5];
    const float* dt_proj_w  = (const float*)d_in[6];
    const float* dt_proj_b  = (const float*)d_in[7];
    const float* A_log      = (const float*)d_in[8];
    const float* D_param    = (const float*)d_in[9];
    const float* out_proj_w = (const float*)d_in[10];
    const float* norm_w     = (const float*)d_in[11];
    const float* norm_b     = (const float*)d_in[12];
    float* out = (float*)d_out;

    // ---- workspace layout ----
    char* base = (char*)d_ws;
    size_t off = 0;
    auto alloc_f = [&](size_t n) { float* p = (float*)(base + off); off += n * 4; return p; };
    auto alloc_u = [&](size_t n) { unsigned short* p = (unsigned short*)(base + off); off += n * 2; return p; };

    float* bc    = alloc_f((size_t)ROWS * 32);
    float* hend  = alloc_f((size_t)NB * CCH * DI * DS);
    float* eprod = alloc_f((size_t)NB * CCH * DI * DS);
    unsigned short* xbf   = alloc_u((size_t)ROWS * DM);
    unsigned short* xzb   = alloc_u((size_t)ROWS * 2 * DI);
    unsigned short* xinb  = alloc_u((size_t)ROWS * DI);
    unsigned short* dtbf  = alloc_u((size_t)ROWS * DI);
    unsigned short* ybf   = alloc_u((size_t)ROWS * DI);
    unsigned short* xlnbf = alloc_u((size_t)ROWS * DM);
    unsigned short* inw_bf = alloc_u((size_t)NLAYER * 2 * DI * DM);
    unsigned short* ow_bf  = alloc_u((size_t)NLAYER * DM * DI);
    unsigned short* wbig  = alloc_u((size_t)NLAYER * NBIG * DI);
    unsigned short* emb_bf = alloc_u((size_t)VOCAB * DM);
    (void)ws_size;

    // ---- weight preconversion (once per call, single cvt dispatch) ----
    {
        int n4a = NLAYER * 2 * DI * DM / 4;
        int n4b = NLAYER * DM * DI / 4;
        int n4e = VOCAB * DM / 4;
        int n4t = n4a + n4b + n4e;
        cvt3_k<<<(n4t + 255) / 256, 256, 0, stream>>>(
            in_proj_w, inw_bf, n4a, out_proj_w, ow_bf, n4b, emb, emb_bf, n4e);
        wc_k<<<dim3(12, 13, NLAYER), 256, 0, stream>>>(dt_proj_w, x_proj_w, wbig);
    }

    embed_k<<<(ROWS * (DM / 4) + 255) / 256, 256, 0, stream>>>(ids, emb, xbf);

    const int scan_grid = NB * (DI / 16) * CCH;      // 6144 blocks

    for (int i = 0; i < NLAYER; ++i) {
        const float* cw  = conv_w  + (size_t)i * DI * DC;
        const float* cb  = conv_b  + (size_t)i * DI;
        const float* dtb = dt_proj_b + (size_t)i * DI;
        const float* Al  = A_log   + (size_t)i * DI * DS;
        const float* Dpar= D_param + (size_t)i * DI;

        // in_proj: xzb(bf16) = xbf @ inw^T  (64-tile, single-barrier NBUF4/PF2)
        const unsigned short* inw = inw_bf + (size_t)i * 2 * DI * DM;
        gemm_bf16<256, 64, 4, 2, true, 2, false><<<24 * 32, 256, 0, stream>>>(
            xbf, DM, inw, DM, nullptr, xzb, 2 * DI, 32, 2 * DI, DM, nullptr, nullptr);

        conv_silu_k<<<(ROWS * (DI / 8)) / 256, 256, 0, stream>>>(xzb, cw, cb, xinb);

        // fused dt(bf16,softplus) + B/C(fp32): xinb @ wbig[i]^T  (N=1568)
        const unsigned short* wb = wbig + (size_t)i * NBIG * DI;
        gemm_bf16<256, 64, 4, 2, true, 3, false><<<13 * 32, 256, 0, stream>>>(
            xinb, DI, wb, DI, nullptr, dtbf, DI, 32, NBIG, DI, dtb, bc);

        scan_phase1<<<scan_grid, 256, 0, stream>>>(dtbf, bc, xinb, Al, hend, eprod);
        scan_phase3<<<scan_grid, 256, 0, stream>>>(dtbf, bc, xinb, xzb, Al, Dpar,
                                                   hend, eprod, ybf);

        // out_proj: xbf(bf16) = ybf @ ow^T  (32-tile, single-barrier NBUF4/PF2)
        const unsigned short* ow = ow_bf + (size_t)i * DM * DI;
        gemm_bf16<256, 32, 4, 2, true, 2, false><<<64 * 6, 256, 0, stream>>>(
            ybf, DI, ow, DI, nullptr, xbf, DM, 64, DM, DI, nullptr, nullptr);
    }

    ln_k<<<ROWS, 256, 0, stream>>>(xbf, norm_w, norm_b, xlnbf);
    // logits: out = xlnbf @ emb^T  (r12 config: 128-tile, dual-barrier NBUF2/PF1)
    gemm_bf16<256, 128, 2, 1, false, 0, true><<<393 * 16, 256, 0, stream>>>(
        xlnbf, DM, emb_bf, DM, out, nullptr, VOCAB, 16, VOCAB, DM, nullptr, nullptr);
}